// Round 1
// baseline (2332.224 us; speedup 1.0000x reference)
//
#include <hip/hip_runtime.h>

#define EPSV 1e-5f
#define Bn 8
#define Cn 64
#define Hn 128
#define Wn 128
#define Pn (Hn*Wn)          // 16384
#define NPIX (Bn*Pn)        // 131072
#define NELEM (Bn*Cn*Pn)    // 8388608

// ---------------- prep: weight transposes + BN folds ----------------
__global__ __launch_bounds__(256) void k_prep(
    const float* __restrict__ w1, const float* __restrict__ w5,
    const float* __restrict__ w7, const float* __restrict__ w9,
    const float* __restrict__ w11, const float* __restrict__ pww,
    const float* __restrict__ frw, const float* __restrict__ cw,
    const float* __restrict__ gwb, const float* __restrict__ gbg,
    const float* __restrict__ gbb, const float* __restrict__ gbm,
    const float* __restrict__ gbv, const float* __restrict__ ensw,
    const float* __restrict__ ensb, const float* __restrict__ bng,
    const float* __restrict__ bnb, const float* __restrict__ bnm,
    const float* __restrict__ bnv,
    float* __restrict__ wT, float* __restrict__ wt1, float* __restrict__ wt4,
    float* __restrict__ wt6, float* __restrict__ cwT, float* __restrict__ Agw,
    float* __restrict__ Bgw, float* __restrict__ wmT, float* __restrict__ esc,
    float* __restrict__ ebi)
{
  int id = blockIdx.x * 256 + threadIdx.x;
  if (id < 147456) {               // wT[i][d][k][o] = W_d[o][i][k]
    int o = id & 63; int r = id >> 6; int k = r % 9; r /= 9;
    int d = r & 3; int i = r >> 2;
    const float* src = (d == 0) ? w5 : (d == 1) ? w7 : (d == 2) ? w9 : w11;
    wT[id] = src[(o * 64 + i) * 9 + k];
    return;
  }
  id -= 147456;
  if (id < 4096) { wt1[id] = w1[(id & 63) * 64 + (id >> 6)]; return; }  // [i][o]
  id -= 4096;
  if (id < 4096) { wt4[id] = pww[(id & 63) * 64 + (id >> 6)]; return; }
  id -= 4096;
  if (id < 4096) { wt6[id] = frw[(id & 63) * 64 + (id >> 6)]; return; }
  id -= 4096;
  if (id < 36864) {                // cwT[c][k][o] = conv_w[o][c][k]
    int o = id & 63; int r = id >> 6; int k = r % 9; int c = r / 9;
    cwT[id] = cw[(o * 64 + c) * 9 + k];
    return;
  }
  id -= 36864;
  if (id < 576) {                  // gw BN fold, per (c*9+j)
    float s = gbg[id] / sqrtf(gbv[id] + EPSV);
    Agw[id] = s;
    Bgw[id] = (gwb[id] - gbm[id]) * s + gbb[id];
    return;
  }
  id -= 576;
  if (id < 36864) {                // wmT[i][k][o] = mean_e ens_w[e][o][i][k]
    int o = id & 63; int r = id >> 6; int k = r % 9; int i = r / 9;
    float v = (ensw[((0 * 64 + o) * 64 + i) * 9 + k] +
               ensw[((64 + o) * 64 + i) * 9 + k] +
               ensw[((128 + o) * 64 + i) * 9 + k]) * (1.f / 3.f);
    wmT[id] = v;
    return;
  }
  id -= 36864;
  if (id < 64) {                   // final BN fold (+ mean ensemble bias)
    float s = bng[id] / sqrtf(bnv[id] + EPSV);
    esc[id] = s;
    float bm = (ensb[id] + ensb[64 + id] + ensb[128 + id]) * (1.f / 3.f);
    ebi[id] = (bm - bnm[id]) * s + bnb[id];
  }
}

// ---------------- pointwise (1x1) conv; optional input-relu / residual ------
// Safe for in-place use (no __restrict__; all reads precede all writes
// within the owning thread).
template<bool RELU_IN, bool RESID>
__global__ __launch_bounds__(256) void k_pw(const float* in, const float* wt,
                                            const float* bias, float bscale,
                                            float* out)
{
  int p = blockIdx.x * 256 + threadIdx.x;
  int b = p >> 14, pp = p & (Pn - 1);
  const float* ib = in + ((size_t)b * Cn) * Pn + pp;
  float acc[Cn];
  #pragma unroll
  for (int o = 0; o < Cn; o++) acc[o] = bias[o] * bscale;
  for (int i = 0; i < Cn; i++) {
    float xi = ib[i * Pn];
    if (RELU_IN) xi = fmaxf(xi, 0.f);
    const float* wp = wt + i * Cn;
    #pragma unroll
    for (int o = 0; o < Cn; o++) acc[o] += wp[o] * xi;
  }
  if (RESID) {
    #pragma unroll
    for (int o = 0; o < Cn; o++) acc[o] += ib[o * Pn];
  }
  float* ob = out + ((size_t)b * Cn) * Pn + pp;
  #pragma unroll
  for (int o = 0; o < Cn; o++) ob[o * Pn] = acc[o];
}

// ---------------- fused 4-dilation 3x3 conv (sum over d=5,7,9,11) ----------
__global__ __launch_bounds__(256) void k_cdcm4(const float* __restrict__ y,
                                               const float* __restrict__ wT,
                                               float* __restrict__ S)
{
  __shared__ float tile[38 * 38];
  int tx = threadIdx.x & 15, ty = threadIdx.x >> 4;
  int w0 = blockIdx.x * 16, h0 = blockIdx.y * 16, b = blockIdx.z;
  float acc[Cn];
  #pragma unroll
  for (int o = 0; o < Cn; o++) acc[o] = 0.f;
  for (int i = 0; i < Cn; i++) {
    const float* yc = y + ((size_t)b * Cn + i) * Pn;
    __syncthreads();
    for (int t = threadIdx.x; t < 38 * 38; t += 256) {
      int r = t / 38, c2 = t - r * 38;
      int hh = h0 + r - 11, ww = w0 + c2 - 11;
      tile[t] = ((unsigned)hh < Hn && (unsigned)ww < Wn) ? yc[hh * Wn + ww] : 0.f;
    }
    __syncthreads();
    const float* wi = wT + i * 2304;
    #pragma unroll
    for (int d = 0; d < 4; d++) {
      const int dil = 5 + 2 * d;
      #pragma unroll
      for (int k = 0; k < 9; k++) {
        const int ky = k / 3, kx = k % 3;
        float v = tile[(ty + 11 + (ky - 1) * dil) * 38 + tx + 11 + (kx - 1) * dil];
        const float* wp = wi + (d * 9 + k) * 64;
        #pragma unroll
        for (int o = 0; o < Cn; o++) acc[o] += wp[o] * v;
      }
    }
  }
  int pp = (h0 + ty) * Wn + (w0 + tx);
  float* ob = S + ((size_t)b * Cn) * Pn + pp;
  #pragma unroll
  for (int o = 0; o < Cn; o++) ob[o * Pn] = acc[o];
}

// ---------------- depthwise 3x3 (pad 1), bias*4 -----------------------------
__global__ __launch_bounds__(256) void k_dw(const float* __restrict__ in,
                                            const float* __restrict__ wdw,
                                            const float* __restrict__ bias,
                                            float* __restrict__ out)
{
  int idx = blockIdx.x * 256 + threadIdx.x;
  int pp = idx & (Pn - 1);
  int bc = idx >> 14;
  int c = bc & (Cn - 1);
  int h = pp >> 7, w = pp & (Wn - 1);
  const float* ib = in + (size_t)bc * Pn;
  const float* wc = wdw + c * 9;
  float a = 4.f * bias[c];
  #pragma unroll
  for (int ky = 0; ky < 3; ky++) {
    int hh = h + ky - 1;
    if ((unsigned)hh >= Hn) continue;
    #pragma unroll
    for (int kx = 0; kx < 3; kx++) {
      int ww = w + kx - 1;
      if ((unsigned)ww >= Wn) continue;
      a += wc[ky * 3 + kx] * ib[hh * Wn + ww];
    }
  }
  out[idx] = a;
}

// ---------------- fused involution: gw matmul + BN + softmax + contraction --
__global__ __launch_bounds__(256) void k_invol(const float* __restrict__ y2,
                                               const float* __restrict__ gww,
                                               const float* __restrict__ Agw,
                                               const float* __restrict__ Bgw,
                                               const float* __restrict__ cwT,
                                               const float* __restrict__ cb,
                                               float* __restrict__ out)
{
  __shared__ float tile[18 * 18];
  int tx = threadIdx.x & 15, ty = threadIdx.x >> 4;
  int w0 = blockIdx.x * 16, h0 = blockIdx.y * 16, b = blockIdx.z;
  float acc[Cn];
  #pragma unroll
  for (int o = 0; o < Cn; o++) acc[o] = cb[o];
  for (int c = 0; c < Cn; c++) {
    const float* yc = y2 + ((size_t)b * Cn + c) * Pn;
    __syncthreads();
    for (int t = threadIdx.x; t < 324; t += 256) {
      int r = t / 18, c2 = t - r * 18;
      int hh = h0 + r - 1, ww = w0 + c2 - 1;
      tile[t] = ((unsigned)hh < Hn && (unsigned)ww < Wn) ? yc[hh * Wn + ww] : 0.f;
    }
    __syncthreads();
    float p[9];
    #pragma unroll
    for (int k = 0; k < 9; k++)
      p[k] = tile[(ty + k / 3) * 18 + (tx + k % 3)];
    const float* gc = gww + c * 81;
    const float* Ac = Agw + c * 9;
    const float* Bc = Bgw + c * 9;
    float e[9]; float mx = -1e30f;
    #pragma unroll
    for (int o = 0; o < 9; o++) {
      float s = 0.f;
      #pragma unroll
      for (int i2 = 0; i2 < 9; i2++) s += gc[o * 9 + i2] * p[i2];
      s = s * Ac[o] + Bc[o];
      e[o] = s;
      mx = fmaxf(mx, s);
    }
    float sum = 0.f;
    #pragma unroll
    for (int o = 0; o < 9; o++) { float t2 = __expf(e[o] - mx); e[o] = t2; sum += t2; }
    float inv = 1.f / sum;
    #pragma unroll
    for (int k = 0; k < 9; k++) p[k] *= e[k] * inv;
    const float* cwc = cwT + c * 576;
    #pragma unroll
    for (int k = 0; k < 9; k++) {
      float v = p[k];
      const float* wp = cwc + k * 64;
      #pragma unroll
      for (int o = 0; o < Cn; o++) acc[o] += wp[o] * v;
    }
  }
  int pp = (h0 + ty) * Wn + (w0 + tx);
  float* ob = out + ((size_t)b * Cn) * Pn + pp;
  #pragma unroll
  for (int o = 0; o < Cn; o++) ob[o * Pn] = acc[o];
}

// ---------------- ensemble conv3x3 (averaged weights) + BN + ReLU -----------
__global__ __launch_bounds__(256) void k_ens(const float* __restrict__ in,
                                             const float* __restrict__ wmT,
                                             const float* __restrict__ esc,
                                             const float* __restrict__ ebi,
                                             float* __restrict__ out)
{
  __shared__ float tile[18 * 18];
  int tx = threadIdx.x & 15, ty = threadIdx.x >> 4;
  int w0 = blockIdx.x * 16, h0 = blockIdx.y * 16, b = blockIdx.z;
  float acc[Cn];
  #pragma unroll
  for (int o = 0; o < Cn; o++) acc[o] = 0.f;
  for (int i = 0; i < Cn; i++) {
    const float* yc = in + ((size_t)b * Cn + i) * Pn;
    __syncthreads();
    for (int t = threadIdx.x; t < 324; t += 256) {
      int r = t / 18, c2 = t - r * 18;
      int hh = h0 + r - 1, ww = w0 + c2 - 1;
      tile[t] = ((unsigned)hh < Hn && (unsigned)ww < Wn) ? yc[hh * Wn + ww] : 0.f;
    }
    __syncthreads();
    const float* wi = wmT + i * 576;
    #pragma unroll
    for (int k = 0; k < 9; k++) {
      float v = tile[(ty + k / 3) * 18 + (tx + k % 3)];
      const float* wp = wi + k * 64;
      #pragma unroll
      for (int o = 0; o < Cn; o++) acc[o] += wp[o] * v;
    }
  }
  int pp = (h0 + ty) * Wn + (w0 + tx);
  float* ob = out + ((size_t)b * Cn) * Pn + pp;
  #pragma unroll
  for (int o = 0; o < Cn; o++) {
    float r = acc[o] * esc[o] + ebi[o];
    ob[o * Pn] = r > 0.f ? r : 0.f;
  }
}

extern "C" void kernel_launch(void* const* d_in, const int* in_sizes, int n_in,
                              void* d_out, int out_size, void* d_ws, size_t ws_size,
                              hipStream_t stream)
{
  const float* x    = (const float*)d_in[0];
  const float* w1   = (const float*)d_in[1];
  const float* b1   = (const float*)d_in[2];
  const float* w5   = (const float*)d_in[3];
  const float* w7   = (const float*)d_in[4];
  const float* w9   = (const float*)d_in[5];
  const float* w11  = (const float*)d_in[6];
  const float* dww  = (const float*)d_in[7];
  const float* dwb  = (const float*)d_in[8];
  const float* pww  = (const float*)d_in[9];
  const float* pwb  = (const float*)d_in[10];
  const float* gww  = (const float*)d_in[11];
  const float* gwb  = (const float*)d_in[12];
  const float* gbg  = (const float*)d_in[13];
  const float* gbb  = (const float*)d_in[14];
  const float* gbm  = (const float*)d_in[15];
  const float* gbv  = (const float*)d_in[16];
  const float* cw   = (const float*)d_in[17];
  const float* cb   = (const float*)d_in[18];
  const float* frw  = (const float*)d_in[19];
  const float* frb  = (const float*)d_in[20];
  const float* ensw = (const float*)d_in[21];
  const float* ensb = (const float*)d_in[22];
  const float* bng  = (const float*)d_in[23];
  const float* bnb  = (const float*)d_in[24];
  const float* bnm  = (const float*)d_in[25];
  const float* bnv  = (const float*)d_in[26];

  float* ws0 = (float*)d_ws;          // one big scratch tensor (NELEM floats)
  float* wT  = ws0 + NELEM;           // 147456
  float* wt1 = wT  + 147456;          // 4096
  float* wt4 = wt1 + 4096;            // 4096
  float* wt6 = wt4 + 4096;            // 4096
  float* cwT = wt6 + 4096;            // 36864
  float* Agw = cwT + 36864;           // 576
  float* Bgw = Agw + 576;             // 576
  float* wmT = Bgw + 576;             // 36864
  float* esc = wmT + 36864;           // 64
  float* ebi = esc + 64;              // 64

  float* dout = (float*)d_out;        // also used as alternating scratch

  k_prep<<<915, 256, 0, stream>>>(w1, w5, w7, w9, w11, pww, frw, cw,
                                  gwb, gbg, gbb, gbm, gbv, ensw, ensb,
                                  bng, bnb, bnm, bnv,
                                  wT, wt1, wt4, wt6, cwT, Agw, Bgw, wmT, esc, ebi);

  dim3 g3(Wn / 16, Hn / 16, Bn);

  // 1) y = conv1x1(relu(x))                       -> d_out
  k_pw<true, false><<<NPIX / 256, 256, 0, stream>>>(x, wt1, b1, 1.f, dout);
  // 2) S = sum_d dilated_conv3x3_d(y)             -> ws0
  k_cdcm4<<<g3, 256, 0, stream>>>(dout, wT, ws0);
  // 3) dw = depthwise3x3(S) + 4*dw_b              -> d_out
  k_dw<<<NELEM / 256, 256, 0, stream>>>(ws0, dww, dwb, dout);
  // 4) y2 = pointwise(dw) + 4*pw_b                (in-place on d_out)
  k_pw<false, false><<<NPIX / 256, 256, 0, stream>>>(dout, wt4, pwb, 4.f, dout);
  // 5) inv = involution(y2)                       -> ws0
  k_invol<<<g3, 256, 0, stream>>>(dout, gww, Agw, Bgw, cwT, cb, ws0);
  // 6) out2 = fr(inv) + inv                       (in-place on ws0)
  k_pw<false, true><<<NPIX / 256, 256, 0, stream>>>(ws0, wt6, frb, 1.f, ws0);
  // 7) final = relu(BN(ens_conv3x3(out2)))        -> d_out
  k_ens<<<g3, 256, 0, stream>>>(ws0, wmT, esc, ebi, dout);
}

// Round 2
// 1219.283 us; speedup vs baseline: 1.9128x; 1.9128x over previous
//
#include <hip/hip_runtime.h>

#define EPSV 1e-5f
#define Bn 8
#define Cn 64
#define Hn 128
#define Wn 128
#define Pn (Hn*Wn)          // 16384
#define NPIX (Bn*Pn)        // 131072
#define NELEM (Bn*Cn*Pn)    // 8388608

// ---------------- prep: weight transposes + BN folds ----------------
__global__ __launch_bounds__(256) void k_prep(
    const float* __restrict__ w1, const float* __restrict__ w5,
    const float* __restrict__ w7, const float* __restrict__ w9,
    const float* __restrict__ w11, const float* __restrict__ pww,
    const float* __restrict__ frw, const float* __restrict__ cw,
    const float* __restrict__ gwb, const float* __restrict__ gbg,
    const float* __restrict__ gbb, const float* __restrict__ gbm,
    const float* __restrict__ gbv, const float* __restrict__ ensw,
    const float* __restrict__ ensb, const float* __restrict__ bng,
    const float* __restrict__ bnb, const float* __restrict__ bnm,
    const float* __restrict__ bnv,
    float* __restrict__ wT, float* __restrict__ wt1, float* __restrict__ wt4,
    float* __restrict__ wt6, float* __restrict__ cwT, float* __restrict__ Agw,
    float* __restrict__ Bgw, float* __restrict__ wmT, float* __restrict__ esc,
    float* __restrict__ ebi)
{
  int id = blockIdx.x * 256 + threadIdx.x;
  if (id < 147456) {               // wT[i][d][k][o] = W_d[o][i][k]
    int o = id & 63; int r = id >> 6; int k = r % 9; r /= 9;
    int d = r & 3; int i = r >> 2;
    const float* src = (d == 0) ? w5 : (d == 1) ? w7 : (d == 2) ? w9 : w11;
    wT[id] = src[(o * 64 + i) * 9 + k];
    return;
  }
  id -= 147456;
  if (id < 4096) { wt1[id] = w1[(id & 63) * 64 + (id >> 6)]; return; }  // [i][o]
  id -= 4096;
  if (id < 4096) { wt4[id] = pww[(id & 63) * 64 + (id >> 6)]; return; }
  id -= 4096;
  if (id < 4096) { wt6[id] = frw[(id & 63) * 64 + (id >> 6)]; return; }
  id -= 4096;
  if (id < 36864) {                // cwT[c][k][o] = conv_w[o][c][k]
    int o = id & 63; int r = id >> 6; int k = r % 9; int c = r / 9;
    cwT[id] = cw[(o * 64 + c) * 9 + k];
    return;
  }
  id -= 36864;
  if (id < 576) {                  // gw BN fold, per (c*9+j)
    float s = gbg[id] / sqrtf(gbv[id] + EPSV);
    Agw[id] = s;
    Bgw[id] = (gwb[id] - gbm[id]) * s + gbb[id];
    return;
  }
  id -= 576;
  if (id < 36864) {                // wmT[i][k][o] = mean_e ens_w[e][o][i][k]
    int o = id & 63; int r = id >> 6; int k = r % 9; int i = r / 9;
    float v = (ensw[((0 * 64 + o) * 64 + i) * 9 + k] +
               ensw[((64 + o) * 64 + i) * 9 + k] +
               ensw[((128 + o) * 64 + i) * 9 + k]) * (1.f / 3.f);
    wmT[id] = v;
    return;
  }
  id -= 36864;
  if (id < 64) {                   // final BN fold (+ mean ensemble bias)
    float s = bng[id] / sqrtf(bnv[id] + EPSV);
    esc[id] = s;
    float bm = (ensb[id] + ensb[64 + id] + ensb[128 + id]) * (1.f / 3.f);
    ebi[id] = (bm - bnm[id]) * s + bnb[id];
  }
}

// ---------------- pointwise (1x1) conv, out-group tiled ---------------------
// grid (NPIX/256, 4). Thread: 1 pixel x 16 out channels. NOT in-place safe.
template<bool RELU_IN, bool RESID>
__global__ __launch_bounds__(256) void k_pw(const float* __restrict__ in,
                                            const float* __restrict__ wt,
                                            const float* __restrict__ bias,
                                            float bscale,
                                            float* __restrict__ out)
{
  __shared__ float ws[1024];       // ws[i*16+j] = wt[i][og*16+j]
  int og = blockIdx.y;
  for (int t = threadIdx.x; t < 1024; t += 256)
    ws[t] = wt[(t >> 4) * 64 + og * 16 + (t & 15)];
  __syncthreads();
  int p = blockIdx.x * 256 + threadIdx.x;
  int b = p >> 14, pp = p & (Pn - 1);
  const float* ib = in + ((size_t)b * Cn) * Pn + pp;
  float acc[16];
  #pragma unroll
  for (int j = 0; j < 16; j++) acc[j] = bias[og * 16 + j] * bscale;
  #pragma unroll 4
  for (int i = 0; i < 64; i++) {
    float xi = ib[i * Pn];
    if (RELU_IN) xi = fmaxf(xi, 0.f);
    float wv[16];
    *(float4*)&wv[0]  = *(const float4*)&ws[i * 16];
    *(float4*)&wv[4]  = *(const float4*)&ws[i * 16 + 4];
    *(float4*)&wv[8]  = *(const float4*)&ws[i * 16 + 8];
    *(float4*)&wv[12] = *(const float4*)&ws[i * 16 + 12];
    #pragma unroll
    for (int j = 0; j < 16; j++) acc[j] += wv[j] * xi;
  }
  if (RESID) {
    #pragma unroll
    for (int j = 0; j < 16; j++) acc[j] += ib[(og * 16 + j) * Pn];
  }
  float* ob = out + ((size_t)b * Cn + og * 16) * Pn + pp;
  #pragma unroll
  for (int j = 0; j < 16; j++) ob[j * Pn] = acc[j];
}

// ---------------- fused 4-dilation 3x3 conv (sum over d=5,7,9,11) ----------
// grid (8,8,8). 16x16 px tile. Thread: (og=tid>>6) x (4 px quad) x 16 outs.
__global__ __launch_bounds__(256) void k_cdcm4(const float* __restrict__ y,
                                               const float* __restrict__ wT,
                                               float* __restrict__ S)
{
  __shared__ float tile[38 * 39];  // odd stride 39: bank spread
  __shared__ float wbuf[2304];     // per-channel weights [d*9+k][64]
  const int tid = threadIdx.x;
  const int og = tid >> 6;
  const int q = tid & 63;
  const int r = q >> 2, cq = q & 3;      // px row 0..15, col quad 0..3
  const int w0 = blockIdx.x * 16, h0 = blockIdx.y * 16, b = blockIdx.z;

  float acc[4][16];
  #pragma unroll
  for (int p = 0; p < 4; p++)
    #pragma unroll
    for (int j = 0; j < 16; j++) acc[p][j] = 0.f;

  for (int i = 0; i < Cn; i++) {
    const float* yc = y + ((size_t)b * Cn + i) * Pn;
    __syncthreads();
    for (int t = tid; t < 1444; t += 256) {
      int r2 = t / 38, c2 = t - r2 * 38;
      int hh = h0 + r2 - 11, ww = w0 + c2 - 11;
      tile[r2 * 39 + c2] =
          ((unsigned)hh < Hn && (unsigned)ww < Wn) ? yc[hh * Wn + ww] : 0.f;
    }
    const float* wsrc = wT + i * 2304;
    for (int t = tid; t < 2304; t += 256) wbuf[t] = wsrc[t];
    __syncthreads();

    for (int d = 0; d < 4; d++) {
      const int dil = 5 + 2 * d;
      #pragma unroll
      for (int ky = 0; ky < 3; ky++) {
        const int rowoff = (r + 11 + (ky - 1) * dil) * 39 + 4 * cq + 11;
        #pragma unroll
        for (int kx = 0; kx < 3; kx++) {
          const int base = rowoff + (kx - 1) * dil;
          float v0 = tile[base + 0];
          float v1 = tile[base + 1];
          float v2 = tile[base + 2];
          float v3 = tile[base + 3];
          const float* wp = &wbuf[(d * 9 + ky * 3 + kx) * 64 + og * 16];
          float wv[16];
          *(float4*)&wv[0]  = *(const float4*)&wp[0];
          *(float4*)&wv[4]  = *(const float4*)&wp[4];
          *(float4*)&wv[8]  = *(const float4*)&wp[8];
          *(float4*)&wv[12] = *(const float4*)&wp[12];
          #pragma unroll
          for (int j = 0; j < 16; j++) {
            acc[0][j] += wv[j] * v0;
            acc[1][j] += wv[j] * v1;
            acc[2][j] += wv[j] * v2;
            acc[3][j] += wv[j] * v3;
          }
        }
      }
    }
  }
  float* ob = S + ((size_t)b * Cn + og * 16) * Pn + (h0 + r) * Wn + w0 + 4 * cq;
  #pragma unroll
  for (int j = 0; j < 16; j++) {
    float4 st = make_float4(acc[0][j], acc[1][j], acc[2][j], acc[3][j]);
    *(float4*)&ob[j * Pn] = st;
  }
}

// ---------------- depthwise 3x3 (pad 1), bias*4 -----------------------------
__global__ __launch_bounds__(256) void k_dw(const float* __restrict__ in,
                                            const float* __restrict__ wdw,
                                            const float* __restrict__ bias,
                                            float* __restrict__ out)
{
  int idx = blockIdx.x * 256 + threadIdx.x;
  int pp = idx & (Pn - 1);
  int bc = idx >> 14;
  int c = bc & (Cn - 1);
  int h = pp >> 7, w = pp & (Wn - 1);
  const float* ib = in + (size_t)bc * Pn;
  const float* wc = wdw + c * 9;
  float a = 4.f * bias[c];
  #pragma unroll
  for (int ky = 0; ky < 3; ky++) {
    int hh = h + ky - 1;
    if ((unsigned)hh >= Hn) continue;
    #pragma unroll
    for (int kx = 0; kx < 3; kx++) {
      int ww = w + kx - 1;
      if ((unsigned)ww >= Wn) continue;
      a += wc[ky * 3 + kx] * ib[hh * Wn + ww];
    }
  }
  out[idx] = a;
}

// ---------------- fused involution ------------------------------------------
// grid (8,16,8): 16w x 8h px tile. Thread: og x (2 px pair) x 16 outs.
__global__ __launch_bounds__(256) void k_invol(const float* __restrict__ y2,
                                               const float* __restrict__ gww,
                                               const float* __restrict__ Agw,
                                               const float* __restrict__ Bgw,
                                               const float* __restrict__ cwT,
                                               const float* __restrict__ cb,
                                               float* __restrict__ out)
{
  __shared__ float tile[10 * 19];  // 10 rows x 18 cols halo, stride 19
  __shared__ float cwb[576];       // conv weights [k][64] for channel c
  __shared__ float gwb_s[81];      // gw weights [o][i] for channel c
  __shared__ float AB[18];         // Agw[9], Bgw[9] for channel c
  const int tid = threadIdx.x;
  const int og = tid >> 6;
  const int q = tid & 63;
  const int r = q >> 3, cp = q & 7;      // px row 0..7, col pair 0..7
  const int w0 = blockIdx.x * 16, h0 = blockIdx.y * 8, b = blockIdx.z;

  float acc[2][16];
  #pragma unroll
  for (int j = 0; j < 16; j++) {
    float cv = cb[og * 16 + j];
    acc[0][j] = cv; acc[1][j] = cv;
  }

  for (int c = 0; c < Cn; c++) {
    const float* yc = y2 + ((size_t)b * Cn + c) * Pn;
    __syncthreads();
    for (int t = tid; t < 180; t += 256) {
      int r2 = t / 18, c2 = t - r2 * 18;
      int hh = h0 + r2 - 1, ww = w0 + c2 - 1;
      tile[r2 * 19 + c2] =
          ((unsigned)hh < Hn && (unsigned)ww < Wn) ? yc[hh * Wn + ww] : 0.f;
    }
    for (int t = tid; t < 576; t += 256) cwb[t] = cwT[c * 576 + t];
    if (tid < 81) gwb_s[tid] = gww[c * 81 + tid];
    else if (tid < 90) AB[tid - 81] = Agw[c * 9 + tid - 81];
    else if (tid < 99) AB[tid - 81] = Bgw[c * 9 + tid - 90];
    __syncthreads();

    // patch values: rows r..r+2, cols 2cp..2cp+3
    float tv[3][4];
    #pragma unroll
    for (int rr = 0; rr < 3; rr++)
      #pragma unroll
      for (int cc = 0; cc < 4; cc++)
        tv[rr][cc] = tile[(r + rr) * 19 + 2 * cp + cc];

    // gw matmul for both pixels
    float s0[9], s1[9];
    #pragma unroll
    for (int o = 0; o < 9; o++) { s0[o] = 0.f; s1[o] = 0.f; }
    #pragma unroll
    for (int o = 0; o < 9; o++)
      #pragma unroll
      for (int i2 = 0; i2 < 9; i2++) {
        float g = gwb_s[o * 9 + i2];
        s0[o] += g * tv[i2 / 3][i2 % 3];
        s1[o] += g * tv[i2 / 3][1 + i2 % 3];
      }
    // BN + softmax, then fold into patch product
    float pr0[9], pr1[9];
    {
      float mx0 = -1e30f, mx1 = -1e30f;
      #pragma unroll
      for (int o = 0; o < 9; o++) {
        s0[o] = s0[o] * AB[o] + AB[9 + o];
        s1[o] = s1[o] * AB[o] + AB[9 + o];
        mx0 = fmaxf(mx0, s0[o]); mx1 = fmaxf(mx1, s1[o]);
      }
      float sm0 = 0.f, sm1 = 0.f;
      #pragma unroll
      for (int o = 0; o < 9; o++) {
        s0[o] = __expf(s0[o] - mx0); sm0 += s0[o];
        s1[o] = __expf(s1[o] - mx1); sm1 += s1[o];
      }
      float iv0 = 1.f / sm0, iv1 = 1.f / sm1;
      #pragma unroll
      for (int k = 0; k < 9; k++) {
        pr0[k] = tv[k / 3][k % 3] * s0[k] * iv0;
        pr1[k] = tv[k / 3][1 + k % 3] * s1[k] * iv1;
      }
    }
    // contraction over 9 kernel positions
    #pragma unroll
    for (int k = 0; k < 9; k++) {
      const float* wp = &cwb[k * 64 + og * 16];
      float wv[16];
      *(float4*)&wv[0]  = *(const float4*)&wp[0];
      *(float4*)&wv[4]  = *(const float4*)&wp[4];
      *(float4*)&wv[8]  = *(const float4*)&wp[8];
      *(float4*)&wv[12] = *(const float4*)&wp[12];
      #pragma unroll
      for (int j = 0; j < 16; j++) {
        acc[0][j] += wv[j] * pr0[k];
        acc[1][j] += wv[j] * pr1[k];
      }
    }
  }
  float* ob = out + ((size_t)b * Cn + og * 16) * Pn + (h0 + r) * Wn + w0 + 2 * cp;
  #pragma unroll
  for (int j = 0; j < 16; j++) {
    float2 st = make_float2(acc[0][j], acc[1][j]);
    *(float2*)&ob[j * Pn] = st;
  }
}

// ---------------- ensemble conv3x3 (averaged weights) + BN + ReLU -----------
// grid (8,8,8). 16x16 tile. Thread: og x (4 px quad) x 16 outs.
__global__ __launch_bounds__(256) void k_ens(const float* __restrict__ in,
                                             const float* __restrict__ wmT,
                                             const float* __restrict__ esc,
                                             const float* __restrict__ ebi,
                                             float* __restrict__ out)
{
  __shared__ float tile[18 * 19];
  __shared__ float wbuf[576];
  const int tid = threadIdx.x;
  const int og = tid >> 6;
  const int q = tid & 63;
  const int r = q >> 2, cq = q & 3;
  const int w0 = blockIdx.x * 16, h0 = blockIdx.y * 16, b = blockIdx.z;

  float acc[4][16];
  #pragma unroll
  for (int p = 0; p < 4; p++)
    #pragma unroll
    for (int j = 0; j < 16; j++) acc[p][j] = 0.f;

  for (int i = 0; i < Cn; i++) {
    const float* yc = in + ((size_t)b * Cn + i) * Pn;
    __syncthreads();
    for (int t = tid; t < 324; t += 256) {
      int r2 = t / 18, c2 = t - r2 * 18;
      int hh = h0 + r2 - 1, ww = w0 + c2 - 1;
      tile[r2 * 19 + c2] =
          ((unsigned)hh < Hn && (unsigned)ww < Wn) ? yc[hh * Wn + ww] : 0.f;
    }
    for (int t = tid; t < 576; t += 256) wbuf[t] = wmT[i * 576 + t];
    __syncthreads();

    // input values rows r..r+2, cols 4cq..4cq+5
    float tv[3][6];
    #pragma unroll
    for (int rr = 0; rr < 3; rr++)
      #pragma unroll
      for (int cc = 0; cc < 6; cc++)
        tv[rr][cc] = tile[(r + rr) * 19 + 4 * cq + cc];

    #pragma unroll
    for (int ky = 0; ky < 3; ky++)
      #pragma unroll
      for (int kx = 0; kx < 3; kx++) {
        const float* wp = &wbuf[(ky * 3 + kx) * 64 + og * 16];
        float wv[16];
        *(float4*)&wv[0]  = *(const float4*)&wp[0];
        *(float4*)&wv[4]  = *(const float4*)&wp[4];
        *(float4*)&wv[8]  = *(const float4*)&wp[8];
        *(float4*)&wv[12] = *(const float4*)&wp[12];
        #pragma unroll
        for (int j = 0; j < 16; j++) {
          acc[0][j] += wv[j] * tv[ky][kx + 0];
          acc[1][j] += wv[j] * tv[ky][kx + 1];
          acc[2][j] += wv[j] * tv[ky][kx + 2];
          acc[3][j] += wv[j] * tv[ky][kx + 3];
        }
      }
  }
  float* ob = out + ((size_t)b * Cn + og * 16) * Pn + (h0 + r) * Wn + w0 + 4 * cq;
  #pragma unroll
  for (int j = 0; j < 16; j++) {
    float sc = esc[og * 16 + j], bi = ebi[og * 16 + j];
    float4 st = make_float4(fmaxf(acc[0][j] * sc + bi, 0.f),
                            fmaxf(acc[1][j] * sc + bi, 0.f),
                            fmaxf(acc[2][j] * sc + bi, 0.f),
                            fmaxf(acc[3][j] * sc + bi, 0.f));
    *(float4*)&ob[j * Pn] = st;
  }
}

extern "C" void kernel_launch(void* const* d_in, const int* in_sizes, int n_in,
                              void* d_out, int out_size, void* d_ws, size_t ws_size,
                              hipStream_t stream)
{
  const float* x    = (const float*)d_in[0];
  const float* w1   = (const float*)d_in[1];
  const float* b1   = (const float*)d_in[2];
  const float* w5   = (const float*)d_in[3];
  const float* w7   = (const float*)d_in[4];
  const float* w9   = (const float*)d_in[5];
  const float* w11  = (const float*)d_in[6];
  const float* dww  = (const float*)d_in[7];
  const float* dwb  = (const float*)d_in[8];
  const float* pww  = (const float*)d_in[9];
  const float* pwb  = (const float*)d_in[10];
  const float* gww  = (const float*)d_in[11];
  const float* gwb  = (const float*)d_in[12];
  const float* gbg  = (const float*)d_in[13];
  const float* gbb  = (const float*)d_in[14];
  const float* gbm  = (const float*)d_in[15];
  const float* gbv  = (const float*)d_in[16];
  const float* cw   = (const float*)d_in[17];
  const float* cb   = (const float*)d_in[18];
  const float* frw  = (const float*)d_in[19];
  const float* frb  = (const float*)d_in[20];
  const float* ensw = (const float*)d_in[21];
  const float* ensb = (const float*)d_in[22];
  const float* bng  = (const float*)d_in[23];
  const float* bnb  = (const float*)d_in[24];
  const float* bnm  = (const float*)d_in[25];
  const float* bnv  = (const float*)d_in[26];

  float* ws0 = (float*)d_ws;          // big scratch tensor (NELEM floats)
  float* wT  = ws0 + NELEM;           // 147456
  float* wt1 = wT  + 147456;          // 4096
  float* wt4 = wt1 + 4096;            // 4096
  float* wt6 = wt4 + 4096;            // 4096
  float* cwT = wt6 + 4096;            // 36864
  float* Agw = cwT + 36864;           // 576
  float* Bgw = Agw + 576;             // 576
  float* wmT = Bgw + 576;             // 36864
  float* esc = wmT + 36864;           // 64
  float* ebi = esc + 64;              // 64

  float* dout = (float*)d_out;        // ping-pong partner of ws0

  k_prep<<<915, 256, 0, stream>>>(w1, w5, w7, w9, w11, pww, frw, cw,
                                  gwb, gbg, gbb, gbm, gbv, ensw, ensb,
                                  bng, bnb, bnm, bnv,
                                  wT, wt1, wt4, wt6, cwT, Agw, Bgw, wmT, esc, ebi);

  dim3 gpw(NPIX / 256, 4);
  dim3 g3(Wn / 16, Hn / 16, Bn);
  dim3 gi(Wn / 16, Hn / 8, Bn);

  // strict ping-pong: dout -> ws0 -> dout -> ... -> final lands in dout
  // 1) y = conv1x1(relu(x))                       x    -> dout
  k_pw<true, false><<<gpw, 256, 0, stream>>>(x, wt1, b1, 1.f, dout);
  // 2) S = sum_d dilated_conv3x3_d(y)             dout -> ws0
  k_cdcm4<<<g3, 256, 0, stream>>>(dout, wT, ws0);
  // 3) dw = depthwise3x3(S) + 4*dw_b              ws0  -> dout
  k_dw<<<NELEM / 256, 256, 0, stream>>>(ws0, dww, dwb, dout);
  // 4) y2 = pointwise(dw) + 4*pw_b                dout -> ws0
  k_pw<false, false><<<gpw, 256, 0, stream>>>(dout, wt4, pwb, 4.f, ws0);
  // 5) inv = involution(y2)                       ws0  -> dout
  k_invol<<<gi, 256, 0, stream>>>(ws0, gww, Agw, Bgw, cwT, cb, dout);
  // 6) out2 = fr(inv) + inv                       dout -> ws0
  k_pw<false, true><<<gpw, 256, 0, stream>>>(dout, wt6, frb, 1.f, ws0);
  // 7) final = relu(BN(ens_conv3x3(out2)))        ws0  -> dout
  k_ens<<<g3, 256, 0, stream>>>(ws0, wmT, esc, ebi, dout);
}

// Round 3
// 811.197 us; speedup vs baseline: 2.8750x; 1.5031x over previous
//
#include <hip/hip_runtime.h>
#include <hip/hip_bf16.h>

#define EPSV 1e-5f
#define Bn 8
#define Cn 64
#define Hn 128
#define Wn 128
#define Pn (Hn*Wn)          // 16384
#define NPIX (Bn*Pn)        // 131072
#define NELEM (Bn*Cn*Pn)    // 8388608
#define PR 150              // padded row length (11 + 128 + 11)
#define YPAD_ELEMS (Bn*PR*PR*Cn)   // 11,520,000 bf16 elems

typedef __bf16 v8bf __attribute__((ext_vector_type(8)));
typedef float v16f __attribute__((ext_vector_type(16)));
typedef unsigned short ushort8v __attribute__((ext_vector_type(8)));

// ---------------- prep: weight packs + BN folds ----------------
__global__ __launch_bounds__(256) void k_prep(
    const float* __restrict__ w1, const float* __restrict__ w5,
    const float* __restrict__ w7, const float* __restrict__ w9,
    const float* __restrict__ w11, const float* __restrict__ pww,
    const float* __restrict__ frw, const float* __restrict__ cw,
    const float* __restrict__ gwb, const float* __restrict__ gbg,
    const float* __restrict__ gbb, const float* __restrict__ gbm,
    const float* __restrict__ gbv, const float* __restrict__ ensw,
    const float* __restrict__ ensb, const float* __restrict__ bng,
    const float* __restrict__ bnb, const float* __restrict__ bnm,
    const float* __restrict__ bnv,
    unsigned short* __restrict__ apack,
    float* __restrict__ wt1, float* __restrict__ wt4,
    float* __restrict__ wt6, float* __restrict__ cwT, float* __restrict__ Agw,
    float* __restrict__ Bgw, float* __restrict__ wmT, float* __restrict__ esc,
    float* __restrict__ ebi)
{
  int id = blockIdx.x * 256 + threadIdx.x;
  if (id < 147456) {
    // apack[tap][kb][mh][lane*8+e] = bf16( W_d[m][ch][k9] )
    // lane l: m = mh*32 + (l&31), ch = kb*16 + (l>>5)*8 + e
    int e = id & 7, l = (id >> 3) & 63, mh = (id >> 9) & 1,
        kb = (id >> 10) & 3, tap = id >> 12;
    int d = tap / 9, k9 = tap - 9 * d;
    int m = mh * 32 + (l & 31);
    int ch = kb * 16 + (l >> 5) * 8 + e;
    const float* src = (d == 0) ? w5 : (d == 1) ? w7 : (d == 2) ? w9 : w11;
    float v = src[(m * 64 + ch) * 9 + k9];
    __hip_bfloat16 hb = __float2bfloat16(v);
    apack[id] = *reinterpret_cast<const unsigned short*>(&hb);
    return;
  }
  id -= 147456;
  if (id < 4096) { wt1[id] = w1[(id & 63) * 64 + (id >> 6)]; return; }  // [i][o]
  id -= 4096;
  if (id < 4096) { wt4[id] = pww[(id & 63) * 64 + (id >> 6)]; return; }
  id -= 4096;
  if (id < 4096) { wt6[id] = frw[(id & 63) * 64 + (id >> 6)]; return; }
  id -= 4096;
  if (id < 36864) {                // cwT[c][k][o] = conv_w[o][c][k]
    int o = id & 63; int r = id >> 6; int k = r % 9; int c = r / 9;
    cwT[id] = cw[(o * 64 + c) * 9 + k];
    return;
  }
  id -= 36864;
  if (id < 576) {                  // gw BN fold, per (c*9+j)
    float s = gbg[id] / sqrtf(gbv[id] + EPSV);
    Agw[id] = s;
    Bgw[id] = (gwb[id] - gbm[id]) * s + gbb[id];
    return;
  }
  id -= 576;
  if (id < 36864) {                // wmT[i][k][o] = mean_e ens_w[e][o][i][k]
    int o = id & 63; int r = id >> 6; int k = r % 9; int i = r / 9;
    float v = (ensw[((0 * 64 + o) * 64 + i) * 9 + k] +
               ensw[((64 + o) * 64 + i) * 9 + k] +
               ensw[((128 + o) * 64 + i) * 9 + k]) * (1.f / 3.f);
    wmT[id] = v;
    return;
  }
  id -= 36864;
  if (id < 64) {                   // final BN fold (+ mean ensemble bias)
    float s = bng[id] / sqrtf(bnv[id] + EPSV);
    esc[id] = s;
    float bm = (ensb[id] + ensb[64 + id] + ensb[128 + id]) * (1.f / 3.f);
    ebi[id] = (bm - bnm[id]) * s + bnb[id];
  }
}

// ---------------- zero-fill ypad ----------------
__global__ __launch_bounds__(256) void k_zfill(ushort8v* __restrict__ p, int n8)
{
  ushort8v z = {0, 0, 0, 0, 0, 0, 0, 0};
  for (int i = blockIdx.x * 256 + threadIdx.x; i < n8; i += gridDim.x * 256)
    p[i] = z;
}

// ---------------- stage 1: y = conv1x1(relu(x)) -> padded channel-last bf16 -
__global__ __launch_bounds__(256) void k_pw_pad(const float* __restrict__ in,
                                               const float* __restrict__ wt,
                                               const float* __restrict__ bias,
                                               unsigned short* __restrict__ ypad)
{
  __shared__ float ws[1024];
  int og = blockIdx.y;
  for (int t = threadIdx.x; t < 1024; t += 256)
    ws[t] = wt[(t >> 4) * 64 + og * 16 + (t & 15)];
  __syncthreads();
  int p = blockIdx.x * 256 + threadIdx.x;
  int b = p >> 14, pp = p & (Pn - 1);
  int h = pp >> 7, w = pp & (Wn - 1);
  const float* ib = in + ((size_t)b * Cn) * Pn + pp;
  float acc[16];
  #pragma unroll
  for (int j = 0; j < 16; j++) acc[j] = bias[og * 16 + j];
  #pragma unroll 4
  for (int i = 0; i < 64; i++) {
    float xi = fmaxf(ib[i * Pn], 0.f);
    float wv[16];
    *(float4*)&wv[0]  = *(const float4*)&ws[i * 16];
    *(float4*)&wv[4]  = *(const float4*)&ws[i * 16 + 4];
    *(float4*)&wv[8]  = *(const float4*)&ws[i * 16 + 8];
    *(float4*)&wv[12] = *(const float4*)&ws[i * 16 + 12];
    #pragma unroll
    for (int j = 0; j < 16; j++) acc[j] += wv[j] * xi;
  }
  unsigned short tmp[16];
  #pragma unroll
  for (int j = 0; j < 16; j++) {
    __hip_bfloat16 hb = __float2bfloat16(acc[j]);
    tmp[j] = *reinterpret_cast<const unsigned short*>(&hb);
  }
  unsigned short* dst =
      ypad + (((size_t)b * PR + h + 11) * PR + w + 11) * 64 + og * 16;
  *(ushort8v*)dst = *(const ushort8v*)&tmp[0];
  *(ushort8v*)(dst + 8) = *(const ushort8v*)&tmp[8];
}

// ---------------- stage 2: cdcm via bf16 MFMA implicit GEMM -----------------
// grid (128, 8) = (h, b). Block: 4 waves; wave wv owns px cols wv*32..+31,
// all 64 out channels (acc0: outs 0-31, acc1: outs 32-63).
__global__ __launch_bounds__(256, 4) void k_cdcm_mfma(
    const unsigned short* __restrict__ ypad,
    const unsigned short* __restrict__ apack,
    float* __restrict__ S)
{
  const int tid = threadIdx.x;
  const int wv = tid >> 6;
  const int l = tid & 63;
  const int ln31 = l & 31, g = l >> 5;
  const int h = blockIdx.x, b = blockIdx.y;

  v16f acc0, acc1;
  #pragma unroll
  for (int r = 0; r < 16; r++) { acc0[r] = 0.f; acc1[r] = 0.f; }

  const int voffB = ln31 * 64 + g * 8;   // per-lane B offset (elems)
  const unsigned short* yrow =
      ypad + (((size_t)b * PR) + h + 11) * PR * 64;  // row h, col_p 0
  const unsigned short* apl = apack + l * 8;

  #pragma unroll
  for (int d = 0; d < 4; d++) {
    const int dil = 5 + 2 * d;
    #pragma unroll
    for (int ky = 0; ky < 3; ky++) {
      const int dh = (ky - 1) * dil;
      #pragma unroll
      for (int kx = 0; kx < 3; kx++) {
        const int dw = (kx - 1) * dil;
        const int tap = d * 9 + ky * 3 + kx;
        const unsigned short* bp =
            yrow + (dh * PR + wv * 32 + dw + 11) * 64 + voffB;
        const unsigned short* ap = apl + tap * 4096;
        #pragma unroll
        for (int kb = 0; kb < 4; kb++) {
          v8bf Bf = *(const v8bf*)(bp + kb * 16);
          v8bf A0 = *(const v8bf*)(ap + kb * 1024);
          v8bf A1 = *(const v8bf*)(ap + kb * 1024 + 512);
          acc0 = __builtin_amdgcn_mfma_f32_32x32x16_bf16(A0, Bf, acc0, 0, 0, 0);
          acc1 = __builtin_amdgcn_mfma_f32_32x32x16_bf16(A1, Bf, acc1, 0, 0, 0);
        }
      }
    }
  }
  // D layout: col = lane&31 (px), row = (r&3) + 8*(r>>2) + 4*g (out ch)
  float* sp = S + ((size_t)b * Cn) * Pn + h * Wn + wv * 32 + ln31;
  #pragma unroll
  for (int r = 0; r < 16; r++) {
    int o0 = (r & 3) + 8 * (r >> 2) + 4 * g;
    sp[(size_t)o0 * Pn] = acc0[r];
    sp[(size_t)(o0 + 32) * Pn] = acc1[r];
  }
}

// ---------------- stage 3: fused depthwise3x3 + pointwise -------------------
// grid (8,8,8). 16x16 tile. Thread: og x (4 px quad) x 16 outs.
__global__ __launch_bounds__(256) void k_dwpw(const float* __restrict__ in,
                                              const float* __restrict__ dww,
                                              const float* __restrict__ dwb,
                                              const float* __restrict__ wt4,
                                              const float* __restrict__ pwb,
                                              float* __restrict__ out)
{
  __shared__ float tile[18 * 19];
  __shared__ float wpw[4096];
  __shared__ float wdw[576];
  __shared__ float bdw[64];
  const int tid = threadIdx.x;
  const int og = tid >> 6;
  const int q = tid & 63;
  const int r = q >> 2, cq = q & 3;
  const int w0 = blockIdx.x * 16, h0 = blockIdx.y * 16, b = blockIdx.z;

  for (int t = tid; t < 4096; t += 256) wpw[t] = wt4[t];
  for (int t = tid; t < 576; t += 256) wdw[t] = dww[t];
  if (tid < 64) bdw[tid] = dwb[tid];

  float acc[4][16];
  #pragma unroll
  for (int j = 0; j < 16; j++) {
    float bv = 4.f * pwb[og * 16 + j];
    acc[0][j] = bv; acc[1][j] = bv; acc[2][j] = bv; acc[3][j] = bv;
  }

  for (int i = 0; i < Cn; i++) {
    const float* yc = in + ((size_t)b * Cn + i) * Pn;
    __syncthreads();
    for (int t = tid; t < 324; t += 256) {
      int r2 = t / 18, c2 = t - r2 * 18;
      int hh = h0 + r2 - 1, ww = w0 + c2 - 1;
      tile[r2 * 19 + c2] =
          ((unsigned)hh < Hn && (unsigned)ww < Wn) ? yc[hh * Wn + ww] : 0.f;
    }
    __syncthreads();
    float tv[3][6];
    #pragma unroll
    for (int rr = 0; rr < 3; rr++)
      #pragma unroll
      for (int cc = 0; cc < 6; cc++)
        tv[rr][cc] = tile[(r + rr) * 19 + 4 * cq + cc];
    // depthwise for the 4 pixels
    float dv[4];
    float bi = 4.f * bdw[i];
    #pragma unroll
    for (int p = 0; p < 4; p++) dv[p] = bi;
    #pragma unroll
    for (int ky = 0; ky < 3; ky++)
      #pragma unroll
      for (int kx = 0; kx < 3; kx++) {
        float wk = wdw[i * 9 + ky * 3 + kx];
        #pragma unroll
        for (int p = 0; p < 4; p++) dv[p] += wk * tv[ky][kx + p];
      }
    // pointwise accumulate
    const float* wp = &wpw[i * 64 + og * 16];
    float wv[16];
    *(float4*)&wv[0]  = *(const float4*)&wp[0];
    *(float4*)&wv[4]  = *(const float4*)&wp[4];
    *(float4*)&wv[8]  = *(const float4*)&wp[8];
    *(float4*)&wv[12] = *(const float4*)&wp[12];
    #pragma unroll
    for (int j = 0; j < 16; j++) {
      acc[0][j] += wv[j] * dv[0];
      acc[1][j] += wv[j] * dv[1];
      acc[2][j] += wv[j] * dv[2];
      acc[3][j] += wv[j] * dv[3];
    }
  }
  float* ob = out + ((size_t)b * Cn + og * 16) * Pn + (h0 + r) * Wn + w0 + 4 * cq;
  #pragma unroll
  for (int j = 0; j < 16; j++) {
    float4 st = make_float4(acc[0][j], acc[1][j], acc[2][j], acc[3][j]);
    *(float4*)&ob[j * Pn] = st;
  }
}

// ---------------- pointwise (1x1) conv, out-group tiled ---------------------
template<bool RELU_IN, bool RESID>
__global__ __launch_bounds__(256) void k_pw(const float* __restrict__ in,
                                            const float* __restrict__ wt,
                                            const float* __restrict__ bias,
                                            float bscale,
                                            float* __restrict__ out)
{
  __shared__ float ws[1024];
  int og = blockIdx.y;
  for (int t = threadIdx.x; t < 1024; t += 256)
    ws[t] = wt[(t >> 4) * 64 + og * 16 + (t & 15)];
  __syncthreads();
  int p = blockIdx.x * 256 + threadIdx.x;
  int b = p >> 14, pp = p & (Pn - 1);
  const float* ib = in + ((size_t)b * Cn) * Pn + pp;
  float acc[16];
  #pragma unroll
  for (int j = 0; j < 16; j++) acc[j] = bias[og * 16 + j] * bscale;
  #pragma unroll 4
  for (int i = 0; i < 64; i++) {
    float xi = ib[i * Pn];
    if (RELU_IN) xi = fmaxf(xi, 0.f);
    float wv[16];
    *(float4*)&wv[0]  = *(const float4*)&ws[i * 16];
    *(float4*)&wv[4]  = *(const float4*)&ws[i * 16 + 4];
    *(float4*)&wv[8]  = *(const float4*)&ws[i * 16 + 8];
    *(float4*)&wv[12] = *(const float4*)&ws[i * 16 + 12];
    #pragma unroll
    for (int j = 0; j < 16; j++) acc[j] += wv[j] * xi;
  }
  if (RESID) {
    #pragma unroll
    for (int j = 0; j < 16; j++) acc[j] += ib[(og * 16 + j) * Pn];
  }
  float* ob = out + ((size_t)b * Cn + og * 16) * Pn + pp;
  #pragma unroll
  for (int j = 0; j < 16; j++) ob[j * Pn] = acc[j];
}

// ---------------- fused involution ------------------------------------------
__global__ __launch_bounds__(256) void k_invol(const float* __restrict__ y2,
                                               const float* __restrict__ gww,
                                               const float* __restrict__ Agw,
                                               const float* __restrict__ Bgw,
                                               const float* __restrict__ cwT,
                                               const float* __restrict__ cb,
                                               float* __restrict__ out)
{
  __shared__ float tile[10 * 19];
  __shared__ float cwb[576];
  __shared__ float gwb_s[81];
  __shared__ float AB[18];
  const int tid = threadIdx.x;
  const int og = tid >> 6;
  const int q = tid & 63;
  const int r = q >> 3, cp = q & 7;
  const int w0 = blockIdx.x * 16, h0 = blockIdx.y * 8, b = blockIdx.z;

  float acc[2][16];
  #pragma unroll
  for (int j = 0; j < 16; j++) {
    float cv = cb[og * 16 + j];
    acc[0][j] = cv; acc[1][j] = cv;
  }

  for (int c = 0; c < Cn; c++) {
    const float* yc = y2 + ((size_t)b * Cn + c) * Pn;
    __syncthreads();
    for (int t = tid; t < 180; t += 256) {
      int r2 = t / 18, c2 = t - r2 * 18;
      int hh = h0 + r2 - 1, ww = w0 + c2 - 1;
      tile[r2 * 19 + c2] =
          ((unsigned)hh < Hn && (unsigned)ww < Wn) ? yc[hh * Wn + ww] : 0.f;
    }
    for (int t = tid; t < 576; t += 256) cwb[t] = cwT[c * 576 + t];
    if (tid < 81) gwb_s[tid] = gww[c * 81 + tid];
    else if (tid < 90) AB[tid - 81] = Agw[c * 9 + tid - 81];
    else if (tid < 99) AB[tid - 81] = Bgw[c * 9 + tid - 90];
    __syncthreads();

    float tv[3][4];
    #pragma unroll
    for (int rr = 0; rr < 3; rr++)
      #pragma unroll
      for (int cc = 0; cc < 4; cc++)
        tv[rr][cc] = tile[(r + rr) * 19 + 2 * cp + cc];

    float s0[9], s1[9];
    #pragma unroll
    for (int o = 0; o < 9; o++) { s0[o] = 0.f; s1[o] = 0.f; }
    #pragma unroll
    for (int o = 0; o < 9; o++)
      #pragma unroll
      for (int i2 = 0; i2 < 9; i2++) {
        float gv = gwb_s[o * 9 + i2];
        s0[o] += gv * tv[i2 / 3][i2 % 3];
        s1[o] += gv * tv[i2 / 3][1 + i2 % 3];
      }
    float pr0[9], pr1[9];
    {
      float mx0 = -1e30f, mx1 = -1e30f;
      #pragma unroll
      for (int o = 0; o < 9; o++) {
        s0[o] = s0[o] * AB[o] + AB[9 + o];
        s1[o] = s1[o] * AB[o] + AB[9 + o];
        mx0 = fmaxf(mx0, s0[o]); mx1 = fmaxf(mx1, s1[o]);
      }
      float sm0 = 0.f, sm1 = 0.f;
      #pragma unroll
      for (int o = 0; o < 9; o++) {
        s0[o] = __expf(s0[o] - mx0); sm0 += s0[o];
        s1[o] = __expf(s1[o] - mx1); sm1 += s1[o];
      }
      float iv0 = 1.f / sm0, iv1 = 1.f / sm1;
      #pragma unroll
      for (int k = 0; k < 9; k++) {
        pr0[k] = tv[k / 3][k % 3] * s0[k] * iv0;
        pr1[k] = tv[k / 3][1 + k % 3] * s1[k] * iv1;
      }
    }
    #pragma unroll
    for (int k = 0; k < 9; k++) {
      const float* wp = &cwb[k * 64 + og * 16];
      float wv[16];
      *(float4*)&wv[0]  = *(const float4*)&wp[0];
      *(float4*)&wv[4]  = *(const float4*)&wp[4];
      *(float4*)&wv[8]  = *(const float4*)&wp[8];
      *(float4*)&wv[12] = *(const float4*)&wp[12];
      #pragma unroll
      for (int j = 0; j < 16; j++) {
        acc[0][j] += wv[j] * pr0[k];
        acc[1][j] += wv[j] * pr1[k];
      }
    }
  }
  float* ob = out + ((size_t)b * Cn + og * 16) * Pn + (h0 + r) * Wn + w0 + 2 * cp;
  #pragma unroll
  for (int j = 0; j < 16; j++) {
    float2 st = make_float2(acc[0][j], acc[1][j]);
    *(float2*)&ob[j * Pn] = st;
  }
}

// ---------------- ensemble conv3x3 (averaged weights) + BN + ReLU -----------
__global__ __launch_bounds__(256) void k_ens(const float* __restrict__ in,
                                             const float* __restrict__ wmT,
                                             const float* __restrict__ esc,
                                             const float* __restrict__ ebi,
                                             float* __restrict__ out)
{
  __shared__ float tile[18 * 19];
  __shared__ float wbuf[576];
  const int tid = threadIdx.x;
  const int og = tid >> 6;
  const int q = tid & 63;
  const int r = q >> 2, cq = q & 3;
  const int w0 = blockIdx.x * 16, h0 = blockIdx.y * 16, b = blockIdx.z;

  float acc[4][16];
  #pragma unroll
  for (int p = 0; p < 4; p++)
    #pragma unroll
    for (int j = 0; j < 16; j++) acc[p][j] = 0.f;

  for (int i = 0; i < Cn; i++) {
    const float* yc = in + ((size_t)b * Cn + i) * Pn;
    __syncthreads();
    for (int t = tid; t < 324; t += 256) {
      int r2 = t / 18, c2 = t - r2 * 18;
      int hh = h0 + r2 - 1, ww = w0 + c2 - 1;
      tile[r2 * 19 + c2] =
          ((unsigned)hh < Hn && (unsigned)ww < Wn) ? yc[hh * Wn + ww] : 0.f;
    }
    for (int t = tid; t < 576; t += 256) wbuf[t] = wmT[i * 576 + t];
    __syncthreads();

    float tv[3][6];
    #pragma unroll
    for (int rr = 0; rr < 3; rr++)
      #pragma unroll
      for (int cc = 0; cc < 6; cc++)
        tv[rr][cc] = tile[(r + rr) * 19 + 4 * cq + cc];

    #pragma unroll
    for (int ky = 0; ky < 3; ky++)
      #pragma unroll
      for (int kx = 0; kx < 3; kx++) {
        const float* wp = &wbuf[(ky * 3 + kx) * 64 + og * 16];
        float wv[16];
        *(float4*)&wv[0]  = *(const float4*)&wp[0];
        *(float4*)&wv[4]  = *(const float4*)&wp[4];
        *(float4*)&wv[8]  = *(const float4*)&wp[8];
        *(float4*)&wv[12] = *(const float4*)&wp[12];
        #pragma unroll
        for (int j = 0; j < 16; j++) {
          acc[0][j] += wv[j] * tv[ky][kx + 0];
          acc[1][j] += wv[j] * tv[ky][kx + 1];
          acc[2][j] += wv[j] * tv[ky][kx + 2];
          acc[3][j] += wv[j] * tv[ky][kx + 3];
        }
      }
  }
  float* ob = out + ((size_t)b * Cn + og * 16) * Pn + (h0 + r) * Wn + w0 + 4 * cq;
  #pragma unroll
  for (int j = 0; j < 16; j++) {
    float sc = esc[og * 16 + j], bi = ebi[og * 16 + j];
    float4 st = make_float4(fmaxf(acc[0][j] * sc + bi, 0.f),
                            fmaxf(acc[1][j] * sc + bi, 0.f),
                            fmaxf(acc[2][j] * sc + bi, 0.f),
                            fmaxf(acc[3][j] * sc + bi, 0.f));
    *(float4*)&ob[j * Pn] = st;
  }
}

extern "C" void kernel_launch(void* const* d_in, const int* in_sizes, int n_in,
                              void* d_out, int out_size, void* d_ws, size_t ws_size,
                              hipStream_t stream)
{
  const float* x    = (const float*)d_in[0];
  const float* w1   = (const float*)d_in[1];
  const float* b1   = (const float*)d_in[2];
  const float* w5   = (const float*)d_in[3];
  const float* w7   = (const float*)d_in[4];
  const float* w9   = (const float*)d_in[5];
  const float* w11  = (const float*)d_in[6];
  const float* dww  = (const float*)d_in[7];
  const float* dwb  = (const float*)d_in[8];
  const float* pww  = (const float*)d_in[9];
  const float* pwb  = (const float*)d_in[10];
  const float* gww  = (const float*)d_in[11];
  const float* gwb  = (const float*)d_in[12];
  const float* gbg  = (const float*)d_in[13];
  const float* gbb  = (const float*)d_in[14];
  const float* gbm  = (const float*)d_in[15];
  const float* gbv  = (const float*)d_in[16];
  const float* cw   = (const float*)d_in[17];
  const float* cb   = (const float*)d_in[18];
  const float* frw  = (const float*)d_in[19];
  const float* frb  = (const float*)d_in[20];
  const float* ensw = (const float*)d_in[21];
  const float* ensb = (const float*)d_in[22];
  const float* bng  = (const float*)d_in[23];
  const float* bnb  = (const float*)d_in[24];
  const float* bnm  = (const float*)d_in[25];
  const float* bnv  = (const float*)d_in[26];

  float* W1 = (float*)d_ws;                 // big slot: ypad (bf16) then fp32
  unsigned short* ypad = (unsigned short*)d_ws;
  unsigned short* apack = (unsigned short*)(W1 + NELEM);  // 147456 bf16
  float* wt1 = W1 + NELEM + 73728;          // 4096
  float* wt4 = wt1 + 4096;
  float* wt6 = wt4 + 4096;
  float* cwT = wt6 + 4096;                  // 36864
  float* Agw = cwT + 36864;                 // 576
  float* Bgw = Agw + 576;                   // 576
  float* wmT = Bgw + 576;                   // 36864
  float* esc = wmT + 36864;                 // 64
  float* ebi = esc + 64;                    // 64

  float* D = (float*)d_out;

  k_prep<<<915, 256, 0, stream>>>(w1, w5, w7, w9, w11, pww, frw, cw,
                                  gwb, gbg, gbb, gbm, gbv, ensw, ensb,
                                  bng, bnb, bnm, bnv,
                                  apack, wt1, wt4, wt6, cwT, Agw, Bgw, wmT,
                                  esc, ebi);
  k_zfill<<<2048, 256, 0, stream>>>((ushort8v*)ypad, YPAD_ELEMS / 8);

  dim3 gpw(NPIX / 256, 4);
  dim3 g3(Wn / 16, Hn / 16, Bn);
  dim3 gi(Wn / 16, Hn / 8, Bn);
  dim3 gc(Hn, Bn);

  // 1) ypad = conv1x1(relu(x))  (bf16, padded, channel-last)   x -> W1(ypad)
  k_pw_pad<<<gpw, 256, 0, stream>>>(x, wt1, b1, ypad);
  // 2) S = sum_d dilated_conv3x3_d(y)  via MFMA                ypad -> D
  k_cdcm_mfma<<<gc, 256, 0, stream>>>(ypad, apack, D);
  // 3) y2 = PW(DW(S)) fused                                    D -> W1
  k_dwpw<<<g3, 256, 0, stream>>>(D, dww, dwb, wt4, pwb, W1);
  // 4) inv = involution(y2)                                    W1 -> D
  k_invol<<<gi, 256, 0, stream>>>(W1, gww, Agw, Bgw, cwT, cb, D);
  // 5) out2 = fr(inv) + inv                                    D -> W1
  k_pw<false, true><<<gpw, 256, 0, stream>>>(D, wt6, frb, 1.f, W1);
  // 6) final = relu(BN(ens_conv3x3(out2)))                     W1 -> D
  k_ens<<<g3, 256, 0, stream>>>(W1, wmT, esc, ebi, D);
}

// Round 4
// 407.264 us; speedup vs baseline: 5.7266x; 1.9918x over previous
//
#include <hip/hip_runtime.h>
#include <hip/hip_bf16.h>

#define EPSV 1e-5f
#define Bn 8
#define Cn 64
#define Hn 128
#define Wn 128
#define Pn (Hn*Wn)          // 16384
#define NPIX (Bn*Pn)        // 131072
#define NELEM (Bn*Cn*Pn)    // 8388608
#define PR 150              // cdcm pad: 11 + 128 + 11
#define PE 130              // 1-pad: 1 + 128 + 1
#define YPAD_ELEMS (Bn*PR*PR*Cn)   // 11,520,000 fp16
#define Y2_ELEMS   (Bn*PE*PE*Cn)   // 8,652,800 fp16

typedef _Float16 v8h __attribute__((ext_vector_type(8)));
typedef float v16f __attribute__((ext_vector_type(16)));
typedef unsigned short ushort8v __attribute__((ext_vector_type(8)));

__device__ __forceinline__ unsigned short f2h(float v) {
  _Float16 h = (_Float16)v;
  return *reinterpret_cast<const unsigned short*>(&h);
}

// ---------------- prep: weight packs + BN folds ----------------
__global__ __launch_bounds__(256) void k_prep(
    const float* __restrict__ w1, const float* __restrict__ w5,
    const float* __restrict__ w7, const float* __restrict__ w9,
    const float* __restrict__ w11, const float* __restrict__ pww,
    const float* __restrict__ frw, const float* __restrict__ cw,
    const float* __restrict__ gwb, const float* __restrict__ gbg,
    const float* __restrict__ gbb, const float* __restrict__ gbm,
    const float* __restrict__ gbv, const float* __restrict__ ensw,
    const float* __restrict__ ensb, const float* __restrict__ bng,
    const float* __restrict__ bnb, const float* __restrict__ bnm,
    const float* __restrict__ bnv,
    unsigned short* __restrict__ apack,   // [36 taps][4 kb][2 mh][512]
    unsigned short* __restrict__ apinv,   // [9 taps][4 kb][2 mh][512]
    unsigned short* __restrict__ apens,   // [9 taps][4 kb][2 mh][512]
    float* __restrict__ wt1, float* __restrict__ wt4,
    float* __restrict__ wt6, float* __restrict__ Agw,
    float* __restrict__ Bgw, float* __restrict__ esc,
    float* __restrict__ ebi)
{
  int id = blockIdx.x * 256 + threadIdx.x;
  if (id < 147456) {
    // apack: lane l, elem e: m = mh*32+(l&31), ch = kb*16+(l>>5)*8+e
    int e = id & 7, l = (id >> 3) & 63, mh = (id >> 9) & 1,
        kb = (id >> 10) & 3, tap = id >> 12;
    int d = tap / 9, k9 = tap - 9 * d;
    int m = mh * 32 + (l & 31);
    int ch = kb * 16 + (l >> 5) * 8 + e;
    const float* src = (d == 0) ? w5 : (d == 1) ? w7 : (d == 2) ? w9 : w11;
    apack[id] = f2h(src[(m * 64 + ch) * 9 + k9]);
    return;
  }
  id -= 147456;
  if (id < 36864) {                // apinv from conv_w [O][C][9]
    int e = id & 7, l = (id >> 3) & 63, mh = (id >> 9) & 1,
        kb = (id >> 10) & 3, tap = id >> 12;   // tap 0..8
    int m = mh * 32 + (l & 31);
    int c = kb * 16 + (l >> 5) * 8 + e;
    apinv[id] = f2h(cw[(m * 64 + c) * 9 + tap]);
    return;
  }
  id -= 36864;
  if (id < 36864) {                // apens = mean_e ens_w
    int e = id & 7, l = (id >> 3) & 63, mh = (id >> 9) & 1,
        kb = (id >> 10) & 3, tap = id >> 12;
    int m = mh * 32 + (l & 31);
    int c = kb * 16 + (l >> 5) * 8 + e;
    float v = (ensw[((0 * 64 + m) * 64 + c) * 9 + tap] +
               ensw[((64 + m) * 64 + c) * 9 + tap] +
               ensw[((128 + m) * 64 + c) * 9 + tap]) * (1.f / 3.f);
    apens[id] = f2h(v);
    return;
  }
  id -= 36864;
  if (id < 4096) { wt1[id] = w1[(id & 63) * 64 + (id >> 6)]; return; }  // [i][o]
  id -= 4096;
  if (id < 4096) { wt4[id] = pww[(id & 63) * 64 + (id >> 6)]; return; }
  id -= 4096;
  if (id < 4096) { wt6[id] = frw[(id & 63) * 64 + (id >> 6)]; return; }
  id -= 4096;
  if (id < 576) {                  // gw BN fold, per (c*9+j)
    float s = gbg[id] / sqrtf(gbv[id] + EPSV);
    Agw[id] = s;
    Bgw[id] = (gwb[id] - gbm[id]) * s + gbb[id];
    return;
  }
  id -= 576;
  if (id < 64) {                   // final BN fold (+ mean ensemble bias)
    float s = bng[id] / sqrtf(bnv[id] + EPSV);
    esc[id] = s;
    float bm = (ensb[id] + ensb[64 + id] + ensb[128 + id]) * (1.f / 3.f);
    ebi[id] = (bm - bnm[id]) * s + bnb[id];
  }
}

// ---------------- zero-fill ----------------
__global__ __launch_bounds__(256) void k_zfill(ushort8v* __restrict__ p, int n8)
{
  ushort8v z = {0, 0, 0, 0, 0, 0, 0, 0};
  for (int i = blockIdx.x * 256 + threadIdx.x; i < n8; i += gridDim.x * 256)
    p[i] = z;
}

// ---------------- stage 1: y = conv1x1(relu(x)) -> padded channel-last fp16 -
__global__ __launch_bounds__(256) void k_pw_pad(const float* __restrict__ in,
                                               const float* __restrict__ wt,
                                               const float* __restrict__ bias,
                                               unsigned short* __restrict__ ypad)
{
  __shared__ float ws[1024];
  int og = blockIdx.y;
  for (int t = threadIdx.x; t < 1024; t += 256)
    ws[t] = wt[(t >> 4) * 64 + og * 16 + (t & 15)];
  __syncthreads();
  int p = blockIdx.x * 256 + threadIdx.x;
  int b = p >> 14, pp = p & (Pn - 1);
  int h = pp >> 7, w = pp & (Wn - 1);
  const float* ib = in + ((size_t)b * Cn) * Pn + pp;
  float acc[16];
  #pragma unroll
  for (int j = 0; j < 16; j++) acc[j] = bias[og * 16 + j];
  #pragma unroll 4
  for (int i = 0; i < 64; i++) {
    float xi = fmaxf(ib[i * Pn], 0.f);
    float wv[16];
    *(float4*)&wv[0]  = *(const float4*)&ws[i * 16];
    *(float4*)&wv[4]  = *(const float4*)&ws[i * 16 + 4];
    *(float4*)&wv[8]  = *(const float4*)&ws[i * 16 + 8];
    *(float4*)&wv[12] = *(const float4*)&ws[i * 16 + 12];
    #pragma unroll
    for (int j = 0; j < 16; j++) acc[j] += wv[j] * xi;
  }
  unsigned short tmp[16];
  #pragma unroll
  for (int j = 0; j < 16; j++) tmp[j] = f2h(acc[j]);
  unsigned short* dst =
      ypad + (((size_t)b * PR + h + 11) * PR + w + 11) * 64 + og * 16;
  *(ushort8v*)dst = *(const ushort8v*)&tmp[0];
  *(ushort8v*)(dst + 8) = *(const ushort8v*)&tmp[8];
}

// ---------------- stage 2: cdcm via fp16 MFMA implicit GEMM -----------------
__global__ __launch_bounds__(256, 4) void k_cdcm_mfma(
    const unsigned short* __restrict__ ypad,
    const unsigned short* __restrict__ apack,
    float* __restrict__ S)
{
  const int tid = threadIdx.x;
  const int wv = tid >> 6;
  const int l = tid & 63;
  const int ln31 = l & 31, g = l >> 5;
  const int h = blockIdx.x, b = blockIdx.y;

  v16f acc0, acc1;
  #pragma unroll
  for (int r = 0; r < 16; r++) { acc0[r] = 0.f; acc1[r] = 0.f; }

  const int voffB = ln31 * 64 + g * 8;
  const unsigned short* yrow =
      ypad + (((size_t)b * PR) + h + 11) * PR * 64;
  const unsigned short* apl = apack + l * 8;

  #pragma unroll
  for (int d = 0; d < 4; d++) {
    const int dil = 5 + 2 * d;
    #pragma unroll
    for (int ky = 0; ky < 3; ky++) {
      const int dh = (ky - 1) * dil;
      #pragma unroll
      for (int kx = 0; kx < 3; kx++) {
        const int dw = (kx - 1) * dil;
        const int tap = d * 9 + ky * 3 + kx;
        const unsigned short* bp =
            yrow + (dh * PR + wv * 32 + dw + 11) * 64 + voffB;
        const unsigned short* ap = apl + tap * 4096;
        #pragma unroll
        for (int kb = 0; kb < 4; kb++) {
          v8h Bf = *(const v8h*)(bp + kb * 16);
          v8h A0 = *(const v8h*)(ap + kb * 1024);
          v8h A1 = *(const v8h*)(ap + kb * 1024 + 512);
          acc0 = __builtin_amdgcn_mfma_f32_32x32x16_f16(A0, Bf, acc0, 0, 0, 0);
          acc1 = __builtin_amdgcn_mfma_f32_32x32x16_f16(A1, Bf, acc1, 0, 0, 0);
        }
      }
    }
  }
  float* sp = S + ((size_t)b * Cn) * Pn + h * Wn + wv * 32 + ln31;
  #pragma unroll
  for (int r = 0; r < 16; r++) {
    int o0 = (r & 3) + 8 * (r >> 2) + 4 * g;
    sp[(size_t)o0 * Pn] = acc0[r];
    sp[(size_t)(o0 + 32) * Pn] = acc1[r];
  }
}

// ---------------- stage 3: fused depthwise3x3 + pointwise -------------------
// out: y2 as padded channel-last fp16 [b][130][130][64]
__global__ __launch_bounds__(256) void k_dwpw(const float* __restrict__ in,
                                              const float* __restrict__ dww,
                                              const float* __restrict__ dwb,
                                              const float* __restrict__ wt4,
                                              const float* __restrict__ pwb,
                                              unsigned short* __restrict__ y2pad)
{
  __shared__ float tile[18 * 19];
  __shared__ float wpw[4096];
  __shared__ float wdw[576];
  __shared__ float bdw[64];
  const int tid = threadIdx.x;
  const int og = tid >> 6;
  const int q = tid & 63;
  const int r = q >> 2, cq = q & 3;
  const int w0 = blockIdx.x * 16, h0 = blockIdx.y * 16, b = blockIdx.z;

  for (int t = tid; t < 4096; t += 256) wpw[t] = wt4[t];
  for (int t = tid; t < 576; t += 256) wdw[t] = dww[t];
  if (tid < 64) bdw[tid] = dwb[tid];

  float acc[4][16];
  #pragma unroll
  for (int j = 0; j < 16; j++) {
    float bv = 4.f * pwb[og * 16 + j];
    acc[0][j] = bv; acc[1][j] = bv; acc[2][j] = bv; acc[3][j] = bv;
  }

  for (int i = 0; i < Cn; i++) {
    const float* yc = in + ((size_t)b * Cn + i) * Pn;
    __syncthreads();
    for (int t = tid; t < 324; t += 256) {
      int r2 = t / 18, c2 = t - r2 * 18;
      int hh = h0 + r2 - 1, ww = w0 + c2 - 1;
      tile[r2 * 19 + c2] =
          ((unsigned)hh < Hn && (unsigned)ww < Wn) ? yc[hh * Wn + ww] : 0.f;
    }
    __syncthreads();
    float tv[3][6];
    #pragma unroll
    for (int rr = 0; rr < 3; rr++)
      #pragma unroll
      for (int cc = 0; cc < 6; cc++)
        tv[rr][cc] = tile[(r + rr) * 19 + 4 * cq + cc];
    float dv[4];
    float bi = 4.f * bdw[i];
    #pragma unroll
    for (int p = 0; p < 4; p++) dv[p] = bi;
    #pragma unroll
    for (int ky = 0; ky < 3; ky++)
      #pragma unroll
      for (int kx = 0; kx < 3; kx++) {
        float wk = wdw[i * 9 + ky * 3 + kx];
        #pragma unroll
        for (int p = 0; p < 4; p++) dv[p] += wk * tv[ky][kx + p];
      }
    const float* wp = &wpw[i * 64 + og * 16];
    float wv[16];
    *(float4*)&wv[0]  = *(const float4*)&wp[0];
    *(float4*)&wv[4]  = *(const float4*)&wp[4];
    *(float4*)&wv[8]  = *(const float4*)&wp[8];
    *(float4*)&wv[12] = *(const float4*)&wp[12];
    #pragma unroll
    for (int j = 0; j < 16; j++) {
      acc[0][j] += wv[j] * dv[0];
      acc[1][j] += wv[j] * dv[1];
      acc[2][j] += wv[j] * dv[2];
      acc[3][j] += wv[j] * dv[3];
    }
  }
  unsigned short* ob =
      y2pad + (((size_t)b * PE + h0 + r + 1) * PE + (w0 + 4 * cq + 1)) * 64 +
      og * 16;
  #pragma unroll
  for (int p = 0; p < 4; p++) {
    unsigned short tmp[16];
    #pragma unroll
    for (int j = 0; j < 16; j++) tmp[j] = f2h(acc[p][j]);
    *(ushort8v*)(ob + p * 64) = *(const ushort8v*)&tmp[0];
    *(ushort8v*)(ob + p * 64 + 8) = *(const ushort8v*)&tmp[8];
  }
}

// ---------------- stage 4: involution via fp16 MFMA -------------------------
// grid (128, 8). 4 waves; wave: 32 px x all 64 outs. Lane: 1 px, 8-ch groups.
__global__ __launch_bounds__(256) void k_invol_mfma(
    const unsigned short* __restrict__ y2pad,
    const float* __restrict__ gww,
    const float* __restrict__ Agw, const float* __restrict__ Bgw,
    const unsigned short* __restrict__ apinv,
    const float* __restrict__ cbias,
    float* __restrict__ out)
{
  __shared__ float gws[5184];
  __shared__ float As[576];
  __shared__ float Bs[576];
  const int tid = threadIdx.x;
  for (int t = tid; t < 5184; t += 256) gws[t] = gww[t];
  for (int t = tid; t < 576; t += 256) { As[t] = Agw[t]; Bs[t] = Bgw[t]; }
  __syncthreads();

  const int wv = tid >> 6, l = tid & 63;
  const int p32 = l & 31, g = l >> 5;
  const int h = blockIdx.x, b = blockIdx.y;
  const int w = wv * 32 + p32;
  const unsigned short* ybase =
      y2pad + (((size_t)b * PE + h + 1) * PE + (w + 1)) * 64;

  v16f acc0, acc1;
  #pragma unroll
  for (int r = 0; r < 16; r++) { acc0[r] = 0.f; acc1[r] = 0.f; }

  for (int cb4 = 0; cb4 < 4; cb4++) {
    const int c0 = cb4 * 16 + g * 8;
    v8h pt[9];
    #pragma unroll
    for (int k = 0; k < 9; k++) {
      const int dy = k / 3 - 1, dx = k % 3 - 1;
      pt[k] = *(const v8h*)(ybase + (dy * PE + dx) * 64 + c0);
    }
    #pragma unroll
    for (int e = 0; e < 8; e++) {
      const int c = c0 + e;
      float pf[9];
      #pragma unroll
      for (int k = 0; k < 9; k++) pf[k] = (float)pt[k][e];
      const float* gc = &gws[c * 81];
      const float* Ac = &As[c * 9];
      const float* Bc = &Bs[c * 9];
      float s[9]; float mx = -1e30f;
      #pragma unroll
      for (int o = 0; o < 9; o++) {
        float t = 0.f;
        #pragma unroll
        for (int i = 0; i < 9; i++) t += gc[o * 9 + i] * pf[i];
        t = t * Ac[o] + Bc[o];
        s[o] = t;
        mx = fmaxf(mx, t);
      }
      float sum = 0.f;
      #pragma unroll
      for (int o = 0; o < 9; o++) { s[o] = __expf(s[o] - mx); sum += s[o]; }
      float inv = 1.f / sum;
      #pragma unroll
      for (int k = 0; k < 9; k++) pt[k][e] = (_Float16)(pf[k] * s[k] * inv);
    }
    const unsigned short* ap = apinv + l * 8;
    #pragma unroll
    for (int k = 0; k < 9; k++) {
      const unsigned short* a2 = ap + ((k * 4 + cb4) * 2) * 512;
      v8h A0 = *(const v8h*)(a2);
      v8h A1 = *(const v8h*)(a2 + 512);
      acc0 = __builtin_amdgcn_mfma_f32_32x32x16_f16(A0, pt[k], acc0, 0, 0, 0);
      acc1 = __builtin_amdgcn_mfma_f32_32x32x16_f16(A1, pt[k], acc1, 0, 0, 0);
    }
  }
  float* sp = out + ((size_t)b * Cn) * Pn + h * Wn + w;
  #pragma unroll
  for (int r = 0; r < 16; r++) {
    const int o0 = (r & 3) + 8 * (r >> 2) + 4 * g;
    sp[(size_t)o0 * Pn] = acc0[r] + cbias[o0];
    sp[(size_t)(o0 + 32) * Pn] = acc1[r] + cbias[o0 + 32];
  }
}

// ---------------- stage 5: fr 1x1 + residual -> padded channel-last fp16 ----
__global__ __launch_bounds__(256) void k_pw_frpad(const float* __restrict__ in,
                                                 const float* __restrict__ wt,
                                                 const float* __restrict__ bias,
                                                 unsigned short* __restrict__ opad)
{
  __shared__ float ws[1024];
  int og = blockIdx.y;
  for (int t = threadIdx.x; t < 1024; t += 256)
    ws[t] = wt[(t >> 4) * 64 + og * 16 + (t & 15)];
  __syncthreads();
  int p = blockIdx.x * 256 + threadIdx.x;
  int b = p >> 14, pp = p & (Pn - 1);
  int h = pp >> 7, w = pp & (Wn - 1);
  const float* ib = in + ((size_t)b * Cn) * Pn + pp;
  float acc[16];
  #pragma unroll
  for (int j = 0; j < 16; j++) acc[j] = bias[og * 16 + j];
  #pragma unroll 4
  for (int i = 0; i < 64; i++) {
    float xi = ib[i * Pn];
    float wv[16];
    *(float4*)&wv[0]  = *(const float4*)&ws[i * 16];
    *(float4*)&wv[4]  = *(const float4*)&ws[i * 16 + 4];
    *(float4*)&wv[8]  = *(const float4*)&ws[i * 16 + 8];
    *(float4*)&wv[12] = *(const float4*)&ws[i * 16 + 12];
    #pragma unroll
    for (int j = 0; j < 16; j++) acc[j] += wv[j] * xi;
  }
  #pragma unroll
  for (int j = 0; j < 16; j++) acc[j] += ib[(og * 16 + j) * Pn];
  unsigned short tmp[16];
  #pragma unroll
  for (int j = 0; j < 16; j++) tmp[j] = f2h(acc[j]);
  unsigned short* dst =
      opad + (((size_t)b * PE + h + 1) * PE + (w + 1)) * 64 + og * 16;
  *(ushort8v*)dst = *(const ushort8v*)&tmp[0];
  *(ushort8v*)(dst + 8) = *(const ushort8v*)&tmp[8];
}

// ---------------- stage 6: ensemble conv3x3 via MFMA + BN + ReLU ------------
__global__ __launch_bounds__(256, 4) void k_ens_mfma(
    const unsigned short* __restrict__ opad,
    const unsigned short* __restrict__ apens,
    const float* __restrict__ esc, const float* __restrict__ ebi,
    float* __restrict__ out)
{
  const int tid = threadIdx.x;
  const int wv = tid >> 6;
  const int l = tid & 63;
  const int ln31 = l & 31, g = l >> 5;
  const int h = blockIdx.x, b = blockIdx.y;

  v16f acc0, acc1;
  #pragma unroll
  for (int r = 0; r < 16; r++) { acc0[r] = 0.f; acc1[r] = 0.f; }

  const int voffB = ln31 * 64 + g * 8;
  const unsigned short* yrow = opad + ((size_t)b * PE + h + 1) * PE * 64;
  const unsigned short* apl = apens + l * 8;

  #pragma unroll
  for (int ky = 0; ky < 3; ky++) {
    #pragma unroll
    for (int kx = 0; kx < 3; kx++) {
      const int tap = ky * 3 + kx;
      const unsigned short* bp =
          yrow + ((ky - 1) * PE + wv * 32 + kx) * 64 + voffB;
      const unsigned short* ap = apl + tap * 4096;
      #pragma unroll
      for (int kb = 0; kb < 4; kb++) {
        v8h Bf = *(const v8h*)(bp + kb * 16);
        v8h A0 = *(const v8h*)(ap + kb * 1024);
        v8h A1 = *(const v8h*)(ap + kb * 1024 + 512);
        acc0 = __builtin_amdgcn_mfma_f32_32x32x16_f16(A0, Bf, acc0, 0, 0, 0);
        acc1 = __builtin_amdgcn_mfma_f32_32x32x16_f16(A1, Bf, acc1, 0, 0, 0);
      }
    }
  }
  float* sp = out + ((size_t)b * Cn) * Pn + h * Wn + wv * 32 + ln31;
  #pragma unroll
  for (int r = 0; r < 16; r++) {
    int o0 = (r & 3) + 8 * (r >> 2) + 4 * g;
    float v0 = acc0[r] * esc[o0] + ebi[o0];
    float v1 = acc1[r] * esc[o0 + 32] + ebi[o0 + 32];
    sp[(size_t)o0 * Pn] = fmaxf(v0, 0.f);
    sp[(size_t)(o0 + 32) * Pn] = fmaxf(v1, 0.f);
  }
}

extern "C" void kernel_launch(void* const* d_in, const int* in_sizes, int n_in,
                              void* d_out, int out_size, void* d_ws, size_t ws_size,
                              hipStream_t stream)
{
  const float* x    = (const float*)d_in[0];
  const float* w1   = (const float*)d_in[1];
  const float* b1   = (const float*)d_in[2];
  const float* w5   = (const float*)d_in[3];
  const float* w7   = (const float*)d_in[4];
  const float* w9   = (const float*)d_in[5];
  const float* w11  = (const float*)d_in[6];
  const float* dww  = (const float*)d_in[7];
  const float* dwb  = (const float*)d_in[8];
  const float* pww  = (const float*)d_in[9];
  const float* pwb  = (const float*)d_in[10];
  const float* gww  = (const float*)d_in[11];
  const float* gwb  = (const float*)d_in[12];
  const float* gbg  = (const float*)d_in[13];
  const float* gbb  = (const float*)d_in[14];
  const float* gbm  = (const float*)d_in[15];
  const float* gbv  = (const float*)d_in[16];
  const float* cw   = (const float*)d_in[17];
  const float* cb   = (const float*)d_in[18];
  const float* frw  = (const float*)d_in[19];
  const float* frb  = (const float*)d_in[20];
  const float* ensw = (const float*)d_in[21];
  const float* ensb = (const float*)d_in[22];
  const float* bng  = (const float*)d_in[23];
  const float* bnb  = (const float*)d_in[24];
  const float* bnm  = (const float*)d_in[25];
  const float* bnv  = (const float*)d_in[26];

  // ws layout (fp16 units first)
  unsigned short* wsu   = (unsigned short*)d_ws;
  unsigned short* ypad  = wsu;                      // region A: 11,520,000
  unsigned short* y2pad = wsu;                      // reused (130^2 geometry)
  unsigned short* opad  = wsu;                      // reused again
  unsigned short* apack = wsu + YPAD_ELEMS;         // 147,456
  unsigned short* apinv = apack + 147456;           // 36,864
  unsigned short* apens = apinv + 36864;            // 36,864
  float* wf  = (float*)(apens + 36864);
  float* wt1 = wf;                                  // 4096
  float* wt4 = wt1 + 4096;
  float* wt6 = wt4 + 4096;
  float* Agw = wt6 + 4096;                          // 576
  float* Bgw = Agw + 576;                           // 576
  float* esc = Bgw + 576;                           // 64
  float* ebi = esc + 64;                            // 64

  float* D = (float*)d_out;

  k_prep<<<915, 256, 0, stream>>>(w1, w5, w7, w9, w11, pww, frw, cw,
                                  gwb, gbg, gbb, gbm, gbv, ensw, ensb,
                                  bng, bnb, bnm, bnv,
                                  apack, apinv, apens, wt1, wt4, wt6,
                                  Agw, Bgw, esc, ebi);
  k_zfill<<<2048, 256, 0, stream>>>((ushort8v*)ypad, YPAD_ELEMS / 8);

  dim3 gpw(NPIX / 256, 4);
  dim3 g3(Wn / 16, Hn / 16, Bn);
  dim3 gc(Hn, Bn);

  // 1) ypad = conv1x1(relu(x))  (fp16, pad 11, channel-last)
  k_pw_pad<<<gpw, 256, 0, stream>>>(x, wt1, b1, ypad);
  // 2) S = sum_d dilated_conv3x3_d(y)  via MFMA      ypad -> D (fp32 planar)
  k_cdcm_mfma<<<gc, 256, 0, stream>>>(ypad, apack, D);
  // re-zero region A for the 130x130 geometry (borders for y2pad/opad)
  k_zfill<<<2048, 256, 0, stream>>>((ushort8v*)y2pad, Y2_ELEMS / 8);
  // 3) y2 = PW(DW(S))                               D -> y2pad (fp16 pad 1)
  k_dwpw<<<g3, 256, 0, stream>>>(D, dww, dwb, wt4, pwb, y2pad);
  // 4) inv = involution(y2) via MFMA                y2pad -> D (fp32 planar)
  k_invol_mfma<<<gc, 256, 0, stream>>>(y2pad, gww, Agw, Bgw, apinv, cb, D);
  // 5) out2 = fr(inv) + inv                         D -> opad (fp16 pad 1)
  k_pw_frpad<<<gpw, 256, 0, stream>>>(D, wt6, frb, opad);
  // 6) final = relu(BN(ens_conv3x3(out2))) via MFMA opad -> D
  k_ens_mfma<<<gc, 256, 0, stream>>>(opad, apens, esc, ebi, D);
}

// Round 6
// 295.131 us; speedup vs baseline: 7.9023x; 1.3799x over previous
//
#include <hip/hip_runtime.h>
#include <hip/hip_bf16.h>

#define EPSV 1e-5f
#define Bn 8
#define Cn 64
#define Hn 128
#define Wn 128
#define Pn (Hn*Wn)          // 16384
#define PR 150              // cdcm pad: 11 + 128 + 11
#define PE 130              // 1-pad: 1 + 128 + 1
#define YPAD_ELEMS (Bn*PR*PR*Cn)   // 11,520,000 fp16

typedef _Float16 v8h __attribute__((ext_vector_type(8)));
typedef float v16f __attribute__((ext_vector_type(16)));
typedef unsigned short ushort8v __attribute__((ext_vector_type(8)));
typedef unsigned short ushort4v __attribute__((ext_vector_type(4)));

__device__ __forceinline__ unsigned short f2h(float v) {
  _Float16 h = (_Float16)v;
  return *reinterpret_cast<const unsigned short*>(&h);
}

// batch-major XCD swizzle: 1024 blocks, XCD r gets batch r's rows in order
__device__ __forceinline__ void swz_bh(int& b, int& h) {
  int bid = blockIdx.x;
  int w = (bid & 7) * 128 + (bid >> 3);
  b = w >> 7; h = w & 127;
}

// ---------------- prep: weight packs + BN folds ----------------
// A-pack layout: [tap][kb][mh][lane*8+e], m=mh*32+(l&31), c=kb*16+(l>>5)*8+e
__global__ __launch_bounds__(256) void k_prep(
    const float* __restrict__ w1, const float* __restrict__ w5,
    const float* __restrict__ w7, const float* __restrict__ w9,
    const float* __restrict__ w11, const float* __restrict__ pww,
    const float* __restrict__ frw, const float* __restrict__ cw,
    const float* __restrict__ gwb, const float* __restrict__ gbg,
    const float* __restrict__ gbb, const float* __restrict__ gbm,
    const float* __restrict__ gbv, const float* __restrict__ ensw,
    const float* __restrict__ ensb, const float* __restrict__ bng,
    const float* __restrict__ bnb, const float* __restrict__ bnm,
    const float* __restrict__ bnv,
    unsigned short* __restrict__ apack, unsigned short* __restrict__ apinv,
    unsigned short* __restrict__ apens, unsigned short* __restrict__ appw1,
    unsigned short* __restrict__ appw, unsigned short* __restrict__ apfr,
    unsigned short* __restrict__ apid,
    float* __restrict__ Agw, float* __restrict__ Bgw,
    float* __restrict__ esc, float* __restrict__ ebi)
{
  int id = blockIdx.x * 256 + threadIdx.x;
  if (id < 147456) {               // cdcm: 36 taps
    int e = id & 7, l = (id >> 3) & 63, mh = (id >> 9) & 1,
        kb = (id >> 10) & 3, tap = id >> 12;
    int d = tap / 9, k9 = tap - 9 * d;
    int m = mh * 32 + (l & 31);
    int c = kb * 16 + (l >> 5) * 8 + e;
    const float* src = (d == 0) ? w5 : (d == 1) ? w7 : (d == 2) ? w9 : w11;
    apack[id] = f2h(src[(m * 64 + c) * 9 + k9]);
    return;
  }
  id -= 147456;
  if (id < 36864) {                // involution conv_w: 9 taps
    int e = id & 7, l = (id >> 3) & 63, mh = (id >> 9) & 1,
        kb = (id >> 10) & 3, tap = id >> 12;
    int m = mh * 32 + (l & 31);
    int c = kb * 16 + (l >> 5) * 8 + e;
    apinv[id] = f2h(cw[(m * 64 + c) * 9 + tap]);
    return;
  }
  id -= 36864;
  if (id < 36864) {                // ensemble mean weights: 9 taps
    int e = id & 7, l = (id >> 3) & 63, mh = (id >> 9) & 1,
        kb = (id >> 10) & 3, tap = id >> 12;
    int m = mh * 32 + (l & 31);
    int c = kb * 16 + (l >> 5) * 8 + e;
    float v = (ensw[((0 * 64 + m) * 64 + c) * 9 + tap] +
               ensw[((64 + m) * 64 + c) * 9 + tap] +
               ensw[((128 + m) * 64 + c) * 9 + tap]) * (1.f / 3.f);
    apens[id] = f2h(v);
    return;
  }
  id -= 36864;
  if (id < 4096) {                 // conv1 1x1
    int e = id & 7, l = (id >> 3) & 63, mh = (id >> 9) & 1, kb = (id >> 10) & 3;
    int m = mh * 32 + (l & 31);
    int c = kb * 16 + (l >> 5) * 8 + e;
    appw1[id] = f2h(w1[m * 64 + c]);
    return;
  }
  id -= 4096;
  if (id < 4096) {                 // dsc pointwise 1x1
    int e = id & 7, l = (id >> 3) & 63, mh = (id >> 9) & 1, kb = (id >> 10) & 3;
    int m = mh * 32 + (l & 31);
    int c = kb * 16 + (l >> 5) * 8 + e;
    appw[id] = f2h(pww[m * 64 + c]);
    return;
  }
  id -= 4096;
  if (id < 4096) {                 // fr 1x1
    int e = id & 7, l = (id >> 3) & 63, mh = (id >> 9) & 1, kb = (id >> 10) & 3;
    int m = mh * 32 + (l & 31);
    int c = kb * 16 + (l >> 5) * 8 + e;
    apfr[id] = f2h(frw[m * 64 + c]);
    return;
  }
  id -= 4096;
  if (id < 4096) {                 // identity (residual via MFMA)
    int e = id & 7, l = (id >> 3) & 63, mh = (id >> 9) & 1, kb = (id >> 10) & 3;
    int m = mh * 32 + (l & 31);
    int c = kb * 16 + (l >> 5) * 8 + e;
    apid[id] = f2h((m == c) ? 1.f : 0.f);
    return;
  }
  id -= 4096;
  if (id < 576) {                  // gw BN fold
    float s = gbg[id] / sqrtf(gbv[id] + EPSV);
    Agw[id] = s;
    Bgw[id] = (gwb[id] - gbm[id]) * s + gbb[id];
    return;
  }
  id -= 576;
  if (id < 64) {                   // final BN fold (+ mean ensemble bias)
    float s = bng[id] / sqrtf(bnv[id] + EPSV);
    esc[id] = s;
    float bm = (ensb[id] + ensb[64 + id] + ensb[128 + id]) * (1.f / 3.f);
    ebi[id] = (bm - bnm[id]) * s + bnb[id];
  }
}

// ---------------- zero only the border pixels of a padded CL buffer ---------
__global__ __launch_bounds__(256) void k_zb(unsigned short* __restrict__ buf,
                                            int PD, int pad)
{
  int per_b = 2 * pad * PD + 128 * 2 * pad;
  int id = blockIdx.x * 256 + threadIdx.x;
  int b = id / per_b;
  if (b >= Bn) return;
  int r = id - b * per_b;
  int tb = 2 * pad * PD;
  int row, col;
  if (r < tb) {
    int rr = r / PD; col = r - rr * PD;
    row = (rr < pad) ? rr : (rr + 128);
  } else {
    int r2 = r - tb;
    row = pad + r2 / (2 * pad);
    int cc = r2 - (r2 / (2 * pad)) * (2 * pad);
    col = (cc < pad) ? cc : (cc + 128);
  }
  unsigned short* p = buf + (((size_t)b * PD + row) * PD + col) * 64;
  ushort8v z = {0, 0, 0, 0, 0, 0, 0, 0};
  #pragma unroll
  for (int k = 0; k < 8; k++) *(ushort8v*)(p + k * 8) = z;
}

// ---------------- stage 1: conv1x1(relu(x)) via MFMA, planar fp32 in --------
__global__ __launch_bounds__(256, 4) void k_pw1x(const float* __restrict__ x,
    const unsigned short* __restrict__ apw, const float* __restrict__ bias,
    unsigned short* __restrict__ ypad)
{
  int b, h; swz_bh(b, h);
  const int tid = threadIdx.x, wv = tid >> 6, l = tid & 63;
  const int ln31 = l & 31, g = l >> 5;
  const int px = wv * 32 + ln31;
  const float* xb = x + ((size_t)b * Cn) * Pn + h * Wn + px;
  v16f acc0, acc1;
  #pragma unroll
  for (int r = 0; r < 16; r++) { acc0[r] = 0.f; acc1[r] = 0.f; }
  const unsigned short* apl = apw + l * 8;
  #pragma unroll
  for (int kb = 0; kb < 4; kb++) {
    int c0 = kb * 16 + g * 8;
    v8h Bf;
    #pragma unroll
    for (int e = 0; e < 8; e++)
      Bf[e] = (_Float16)fmaxf(xb[(size_t)(c0 + e) * Pn], 0.f);
    v8h A0 = *(const v8h*)(apl + (kb * 2) * 512);
    v8h A1 = *(const v8h*)(apl + (kb * 2 + 1) * 512);
    acc0 = __builtin_amdgcn_mfma_f32_32x32x16_f16(A0, Bf, acc0, 0, 0, 0);
    acc1 = __builtin_amdgcn_mfma_f32_32x32x16_f16(A1, Bf, acc1, 0, 0, 0);
  }
  unsigned short* dst =
      ypad + (((size_t)b * PR + h + 11) * PR + px + 11) * 64;
  #pragma unroll
  for (int t = 0; t < 4; t++) {
    int c0 = 8 * t + 4 * g;
    ushort4v s0, s1;
    #pragma unroll
    for (int u = 0; u < 4; u++) {
      s0[u] = f2h(acc0[4 * t + u] + bias[c0 + u]);
      s1[u] = f2h(acc1[4 * t + u] + bias[c0 + u + 32]);
    }
    *(ushort4v*)(dst + c0) = s0;
    *(ushort4v*)(dst + c0 + 32) = s1;
  }
}

// ---------------- stage 2: cdcm via fp16 MFMA, out fp16 CL pad-1 ------------
__global__ __launch_bounds__(256, 4) void k_cdcm_mfma(
    const unsigned short* __restrict__ ypad,
    const unsigned short* __restrict__ apack,
    unsigned short* __restrict__ spad)
{
  int b, h; swz_bh(b, h);
  const int tid = threadIdx.x, wv = tid >> 6, l = tid & 63;
  const int ln31 = l & 31, g = l >> 5;

  v16f acc0, acc1;
  #pragma unroll
  for (int r = 0; r < 16; r++) { acc0[r] = 0.f; acc1[r] = 0.f; }

  const int voffB = ln31 * 64 + g * 8;
  const unsigned short* yrow = ypad + (((size_t)b * PR) + h + 11) * PR * 64;
  const unsigned short* apl = apack + l * 8;

  #pragma unroll
  for (int d = 0; d < 4; d++) {
    const int dil = 5 + 2 * d;
    #pragma unroll
    for (int ky = 0; ky < 3; ky++) {
      const int dh = (ky - 1) * dil;
      #pragma unroll
      for (int kx = 0; kx < 3; kx++) {
        const int dw = (kx - 1) * dil;
        const int tap = d * 9 + ky * 3 + kx;
        const unsigned short* bp =
            yrow + (dh * PR + wv * 32 + dw + 11) * 64 + voffB;
        const unsigned short* ap = apl + tap * 4096;
        #pragma unroll
        for (int kb = 0; kb < 4; kb++) {
          v8h Bf = *(const v8h*)(bp + kb * 16);
          v8h A0 = *(const v8h*)(ap + kb * 1024);
          v8h A1 = *(const v8h*)(ap + kb * 1024 + 512);
          acc0 = __builtin_amdgcn_mfma_f32_32x32x16_f16(A0, Bf, acc0, 0, 0, 0);
          acc1 = __builtin_amdgcn_mfma_f32_32x32x16_f16(A1, Bf, acc1, 0, 0, 0);
        }
      }
    }
  }
  unsigned short* dst =
      spad + (((size_t)b * PE + h + 1) * PE + wv * 32 + ln31 + 1) * 64;
  #pragma unroll
  for (int t = 0; t < 4; t++) {
    int c0 = 8 * t + 4 * g;
    ushort4v s0, s1;
    #pragma unroll
    for (int u = 0; u < 4; u++) {
      s0[u] = f2h(acc0[4 * t + u]);
      s1[u] = f2h(acc1[4 * t + u]);
    }
    *(ushort4v*)(dst + c0) = s0;
    *(ushort4v*)(dst + c0 + 32) = s1;
  }
}

// ---------------- stage 3: depthwise (VALU) + pointwise (MFMA) --------------
__global__ __launch_bounds__(256, 4) void k_dwpw_mfma(
    const unsigned short* __restrict__ spad,
    const float* __restrict__ dww, const float* __restrict__ dwb,
    const unsigned short* __restrict__ appw, const float* __restrict__ pwb,
    unsigned short* __restrict__ y2pad)
{
  __shared__ float wdw[576];
  __shared__ float bdw[64];
  const int tid = threadIdx.x;
  for (int t = tid; t < 576; t += 256) wdw[t] = dww[t];
  if (tid < 64) bdw[tid] = dwb[tid];
  __syncthreads();

  int b, h; swz_bh(b, h);
  const int wv = tid >> 6, l = tid & 63;
  const int ln31 = l & 31, g = l >> 5;
  const int w = wv * 32 + ln31;
  const unsigned short* ybase =
      spad + (((size_t)b * PE + h + 1) * PE + w + 1) * 64;

  v16f acc0, acc1;
  #pragma unroll
  for (int r = 0; r < 16; r++) { acc0[r] = 0.f; acc1[r] = 0.f; }
  const unsigned short* apl = appw + l * 8;

  #pragma unroll
  for (int kb = 0; kb < 4; kb++) {
    const int c0 = kb * 16 + g * 8;
    v8h t[9];
    #pragma unroll
    for (int k = 0; k < 9; k++) {
      const int dy = k / 3 - 1, dx = k % 3 - 1;
      t[k] = *(const v8h*)(ybase + (dy * PE + dx) * 64 + c0);
    }
    v8h dvh;
    #pragma unroll
    for (int e = 0; e < 8; e++) {
      const int c = c0 + e;
      float a = 4.f * bdw[c];
      #pragma unroll
      for (int k = 0; k < 9; k++) a += wdw[c * 9 + k] * (float)t[k][e];
      dvh[e] = (_Float16)a;
    }
    v8h A0 = *(const v8h*)(apl + (kb * 2) * 512);
    v8h A1 = *(const v8h*)(apl + (kb * 2 + 1) * 512);
    acc0 = __builtin_amdgcn_mfma_f32_32x32x16_f16(A0, dvh, acc0, 0, 0, 0);
    acc1 = __builtin_amdgcn_mfma_f32_32x32x16_f16(A1, dvh, acc1, 0, 0, 0);
  }
  unsigned short* dst =
      y2pad + (((size_t)b * PE + h + 1) * PE + w + 1) * 64;
  #pragma unroll
  for (int t = 0; t < 4; t++) {
    int c0 = 8 * t + 4 * g;
    ushort4v s0, s1;
    #pragma unroll
    for (int u = 0; u < 4; u++) {
      s0[u] = f2h(acc0[4 * t + u] + 4.f * pwb[c0 + u]);
      s1[u] = f2h(acc1[4 * t + u] + 4.f * pwb[c0 + u + 32]);
    }
    *(ushort4v*)(dst + c0) = s0;
    *(ushort4v*)(dst + c0 + 32) = s1;
  }
}

// ---------------- stage 4: involution via fp16 MFMA, out fp16 CL ------------
__global__ __launch_bounds__(256) void k_invol_mfma(
    const unsigned short* __restrict__ y2pad,
    const float* __restrict__ gww,
    const float* __restrict__ Agw, const float* __restrict__ Bgw,
    const unsigned short* __restrict__ apinv,
    const float* __restrict__ cbias,
    unsigned short* __restrict__ ipad)
{
  __shared__ float gws[5184];
  __shared__ float As[576];
  __shared__ float Bs[576];
  const int tid = threadIdx.x;
  for (int t = tid; t < 5184; t += 256) gws[t] = gww[t];
  for (int t = tid; t < 576; t += 256) { As[t] = Agw[t]; Bs[t] = Bgw[t]; }
  __syncthreads();

  int b, h; swz_bh(b, h);
  const int wv = tid >> 6, l = tid & 63;
  const int p32 = l & 31, g = l >> 5;
  const int w = wv * 32 + p32;
  const unsigned short* ybase =
      y2pad + (((size_t)b * PE + h + 1) * PE + (w + 1)) * 64;

  v16f acc0, acc1;
  #pragma unroll
  for (int r = 0; r < 16; r++) { acc0[r] = 0.f; acc1[r] = 0.f; }

  for (int cb4 = 0; cb4 < 4; cb4++) {
    const int c0 = cb4 * 16 + g * 8;
    v8h pt[9];
    #pragma unroll
    for (int k = 0; k < 9; k++) {
      const int dy = k / 3 - 1, dx = k % 3 - 1;
      pt[k] = *(const v8h*)(ybase + (dy * PE + dx) * 64 + c0);
    }
    #pragma unroll
    for (int e = 0; e < 8; e++) {
      const int c = c0 + e;
      float pf[9];
      #pragma unroll
      for (int k = 0; k < 9; k++) pf[k] = (float)pt[k][e];
      const float* gc = &gws[c * 81];
      const float* Ac = &As[c * 9];
      const float* Bc = &Bs[c * 9];
      float s[9]; float mx = -1e30f;
      #pragma unroll
      for (int o = 0; o < 9; o++) {
        float t = 0.f;
        #pragma unroll
        for (int i = 0; i < 9; i++) t += gc[o * 9 + i] * pf[i];
        t = t * Ac[o] + Bc[o];
        s[o] = t;
        mx = fmaxf(mx, t);
      }
      float sum = 0.f;
      #pragma unroll
      for (int o = 0; o < 9; o++) { s[o] = __expf(s[o] - mx); sum += s[o]; }
      float inv = 1.f / sum;
      #pragma unroll
      for (int k = 0; k < 9; k++) pt[k][e] = (_Float16)(pf[k] * s[k] * inv);
    }
    const unsigned short* ap = apinv + l * 8;
    #pragma unroll
    for (int k = 0; k < 9; k++) {
      const unsigned short* a2 = ap + ((k * 4 + cb4) * 2) * 512;
      v8h A0 = *(const v8h*)(a2);
      v8h A1 = *(const v8h*)(a2 + 512);
      acc0 = __builtin_amdgcn_mfma_f32_32x32x16_f16(A0, pt[k], acc0, 0, 0, 0);
      acc1 = __builtin_amdgcn_mfma_f32_32x32x16_f16(A1, pt[k], acc1, 0, 0, 0);
    }
  }
  unsigned short* dst = ipad + ((size_t)b * Pn + h * Wn + w) * 64;
  #pragma unroll
  for (int t = 0; t < 4; t++) {
    int c0 = 8 * t + 4 * g;
    ushort4v s0, s1;
    #pragma unroll
    for (int u = 0; u < 4; u++) {
      s0[u] = f2h(acc0[4 * t + u] + cbias[c0 + u]);
      s1[u] = f2h(acc1[4 * t + u] + cbias[c0 + u + 32]);
    }
    *(ushort4v*)(dst + c0) = s0;
    *(ushort4v*)(dst + c0 + 32) = s1;
  }
}

// ---------------- stage 5: fr 1x1 + residual (identity MFMA) ----------------
__global__ __launch_bounds__(256, 4) void k_fr_mfma(
    const unsigned short* __restrict__ ipad,
    const unsigned short* __restrict__ apfr,
    const unsigned short* __restrict__ apid,
    const float* __restrict__ bias,
    unsigned short* __restrict__ opad)
{
  int b, h; swz_bh(b, h);
  const int tid = threadIdx.x, wv = tid >> 6, l = tid & 63;
  const int ln31 = l & 31, g = l >> 5;
  const int px = wv * 32 + ln31;
  const unsigned short* bp0 = ipad + ((size_t)b * Pn + h * Wn + px) * 64;
  v16f acc0, acc1;
  #pragma unroll
  for (int r = 0; r < 16; r++) { acc0[r] = 0.f; acc1[r] = 0.f; }
  const unsigned short* apl = apfr + l * 8;
  const unsigned short* idl = apid + l * 8;
  #pragma unroll
  for (int kb = 0; kb < 4; kb++) {
    v8h Bf = *(const v8h*)(bp0 + kb * 16 + g * 8);
    v8h A0 = *(const v8h*)(apl + (kb * 2) * 512);
    v8h A1 = *(const v8h*)(apl + (kb * 2 + 1) * 512);
    v8h I0 = *(const v8h*)(idl + (kb * 2) * 512);
    v8h I1 = *(const v8h*)(idl + (kb * 2 + 1) * 512);
    acc0 = __builtin_amdgcn_mfma_f32_32x32x16_f16(A0, Bf, acc0, 0, 0, 0);
    acc1 = __builtin_amdgcn_mfma_f32_32x32x16_f16(A1, Bf, acc1, 0, 0, 0);
    acc0 = __builtin_amdgcn_mfma_f32_32x32x16_f16(I0, Bf, acc0, 0, 0, 0);
    acc1 = __builtin_amdgcn_mfma_f32_32x32x16_f16(I1, Bf, acc1, 0, 0, 0);
  }
  unsigned short* dst =
      opad + (((size_t)b * PE + h + 1) * PE + px + 1) * 64;
  #pragma unroll
  for (int t = 0; t < 4; t++) {
    int c0 = 8 * t + 4 * g;
    ushort4v s0, s1;
    #pragma unroll
    for (int u = 0; u < 4; u++) {
      s0[u] = f2h(acc0[4 * t + u] + bias[c0 + u]);
      s1[u] = f2h(acc1[4 * t + u] + bias[c0 + u + 32]);
    }
    *(ushort4v*)(dst + c0) = s0;
    *(ushort4v*)(dst + c0 + 32) = s1;
  }
}

// ---------------- stage 6: ensemble conv3x3 via MFMA + BN + ReLU ------------
__global__ __launch_bounds__(256, 4) void k_ens_mfma(
    const unsigned short* __restrict__ opad,
    const unsigned short* __restrict__ apens,
    const float* __restrict__ esc, const float* __restrict__ ebi,
    float* __restrict__ out)
{
  int b, h; swz_bh(b, h);
  const int tid = threadIdx.x, wv = tid >> 6, l = tid & 63;
  const int ln31 = l & 31, g = l >> 5;

  v16f acc0, acc1;
  #pragma unroll
  for (int r = 0; r < 16; r++) { acc0[r] = 0.f; acc1[r] = 0.f; }

  const int voffB = ln31 * 64 + g * 8;
  const unsigned short* yrow = opad + ((size_t)b * PE + h + 1) * PE * 64;
  const unsigned short* apl = apens + l * 8;

  #pragma unroll
  for (int ky = 0; ky < 3; ky++) {
    #pragma unroll
    for (int kx = 0; kx < 3; kx++) {
      const int tap = ky * 3 + kx;
      const unsigned short* bp =
          yrow + ((ky - 1) * PE + wv * 32 + kx) * 64 + voffB;
      const unsigned short* ap = apl + tap * 4096;
      #pragma unroll
      for (int kb = 0; kb < 4; kb++) {
        v8h Bf = *(const v8h*)(bp + kb * 16);
        v8h A0 = *(const v8h*)(ap + kb * 1024);
        v8h A1 = *(const v8h*)(ap + kb * 1024 + 512);
        acc0 = __builtin_amdgcn_mfma_f32_32x32x16_f16(A0, Bf, acc0, 0, 0, 0);
        acc1 = __builtin_amdgcn_mfma_f32_32x32x16_f16(A1, Bf, acc1, 0, 0, 0);
      }
    }
  }
  float* sp = out + ((size_t)b * Cn) * Pn + h * Wn + wv * 32 + ln31;
  #pragma unroll
  for (int r = 0; r < 16; r++) {
    int o0 = (r & 3) + 8 * (r >> 2) + 4 * g;
    float v0 = acc0[r] * esc[o0] + ebi[o0];
    float v1 = acc1[r] * esc[o0 + 32] + ebi[o0 + 32];
    sp[(size_t)o0 * Pn] = fmaxf(v0, 0.f);
    sp[(size_t)(o0 + 32) * Pn] = fmaxf(v1, 0.f);
  }
}

extern "C" void kernel_launch(void* const* d_in, const int* in_sizes, int n_in,
                              void* d_out, int out_size, void* d_ws, size_t ws_size,
                              hipStream_t stream)
{
  const float* x    = (const float*)d_in[0];
  const float* w1   = (const float*)d_in[1];
  const float* b1   = (const float*)d_in[2];
  const float* w5   = (const float*)d_in[3];
  const float* w7   = (const float*)d_in[4];
  const float* w9   = (const float*)d_in[5];
  const float* w11  = (const float*)d_in[6];
  const float* dww  = (const float*)d_in[7];
  const float* dwb  = (const float*)d_in[8];
  const float* pww  = (const float*)d_in[9];
  const float* pwb  = (const float*)d_in[10];
  const float* gww  = (const float*)d_in[11];
  const float* gwb  = (const float*)d_in[12];
  const float* gbg  = (const float*)d_in[13];
  const float* gbb  = (const float*)d_in[14];
  const float* gbm  = (const float*)d_in[15];
  const float* gbv  = (const float*)d_in[16];
  const float* cw   = (const float*)d_in[17];
  const float* cb   = (const float*)d_in[18];
  const float* frw  = (const float*)d_in[19];
  const float* frb  = (const float*)d_in[20];
  const float* ensw = (const float*)d_in[21];
  const float* ensb = (const float*)d_in[22];
  const float* bng  = (const float*)d_in[23];
  const float* bnb  = (const float*)d_in[24];
  const float* bnm  = (const float*)d_in[25];
  const float* bnv  = (const float*)d_in[26];

  // ws: ypad (pad-11) region, overlaid later by y2pad then opad (pad-1)
  unsigned short* wsu   = (unsigned short*)d_ws;
  unsigned short* ypad  = wsu;
  unsigned short* y2pad = wsu;
  unsigned short* opad  = wsu;
  unsigned short* apack = wsu + YPAD_ELEMS;         // 147456
  unsigned short* apinv = apack + 147456;           // 36864
  unsigned short* apens = apinv + 36864;            // 36864
  unsigned short* appw1 = apens + 36864;            // 4096
  unsigned short* appw  = appw1 + 4096;             // 4096
  unsigned short* apfr  = appw + 4096;              // 4096
  unsigned short* apid  = apfr + 4096;              // 4096
  float* Agw = (float*)(apid + 4096);               // 576
  float* Bgw = Agw + 576;                           // 576
  float* esc = Bgw + 576;                           // 64
  float* ebi = esc + 64;                            // 64

  // d_out: spad (fp16 CL pad-1) -> ipad (fp16 CL) -> final planar fp32
  unsigned short* spad = (unsigned short*)d_out;
  unsigned short* ipad = (unsigned short*)d_out;
  float* D = (float*)d_out;

  k_prep<<<931, 256, 0, stream>>>(w1, w5, w7, w9, w11, pww, frw, cw,
                                  gwb, gbg, gbb, gbm, gbv, ensw, ensb,
                                  bng, bnb, bnm, bnv,
                                  apack, apinv, apens, appw1, appw, apfr, apid,
                                  Agw, Bgw, esc, ebi);
  // border zeros that are safe now: ypad (ws, pad 11), spad (d_out, pad 1)
  k_zb<<<192, 256, 0, stream>>>(ypad, PR, 11);
  k_zb<<<17, 256, 0, stream>>>(spad, PE, 1);

  // 1) ypad = conv1x1(relu(x))           x (planar f32) -> ypad (fp16 CL)
  k_pw1x<<<1024, 256, 0, stream>>>(x, appw1, b1, ypad);
  // 2) spad = sum_d dilconv_d(y)         ypad -> spad (d_out, fp16 CL pad-1)
  k_cdcm_mfma<<<1024, 256, 0, stream>>>(ypad, apack, spad);
  // ws region now dead (ypad fully consumed): zero pad-1 borders for
  // y2pad/opad. These borders survive stages 3-5 (interior-only writes).
  k_zb<<<17, 256, 0, stream>>>(y2pad, PE, 1);
  // 3) y2pad = PW(DW(spad))              spad -> y2pad (ws, fp16 CL pad-1)
  k_dwpw_mfma<<<1024, 256, 0, stream>>>(spad, dww, dwb, appw, pwb, y2pad);
  // 4) ipad = involution(y2pad)          y2pad -> ipad (d_out, fp16 CL)
  k_invol_mfma<<<1024, 256, 0, stream>>>(y2pad, gww, Agw, Bgw, apinv, cb, ipad);
  // 5) opad = fr(ipad) + ipad            ipad -> opad (ws, fp16 CL pad-1)
  k_fr_mfma<<<1024, 256, 0, stream>>>(ipad, apfr, apid, frb, opad);
  // 6) out = relu(BN(ens3x3(opad)))      opad -> D (planar fp32)
  k_ens_mfma<<<1024, 256, 0, stream>>>(opad, apens, esc, ebi, D);
}

// Round 7
// 226.414 us; speedup vs baseline: 10.3007x; 1.3035x over previous
//
#include <hip/hip_runtime.h>
#include <hip/hip_bf16.h>

#define EPSV 1e-5f
#define Bn 8
#define Cn 64
#define Hn 128
#define Wn 128
#define Pn (Hn*Wn)          // 16384
#define PR 150              // cdcm pad: 11 + 128 + 11
#define PE 130              // 1-pad: 1 + 128 + 1
#define YPAD_ELEMS (Bn*PR*PR*Cn)   // 11,520,000 fp16

typedef _Float16 v8h __attribute__((ext_vector_type(8)));
typedef float v16f __attribute__((ext_vector_type(16)));
typedef unsigned short ushort8v __attribute__((ext_vector_type(8)));
typedef unsigned short ushort4v __attribute__((ext_vector_type(4)));

__device__ __forceinline__ unsigned short f2h(float v) {
  _Float16 h = (_Float16)v;
  return *reinterpret_cast<const unsigned short*>(&h);
}

// channel-blocked CL addressing: [b][row][kb(4)][col][16], elems
__device__ __forceinline__ size_t clb(int b, int row, int kb, int col, int PD) {
  return ((((size_t)b * PD + row) * 4 + kb) * PD + col) * 16;
}

// batch-major XCD swizzle: 1024 blocks, XCD r gets batch r's rows in order
__device__ __forceinline__ void swz_bh(int& b, int& h) {
  int bid = blockIdx.x;
  int w = (bid & 7) * 128 + (bid >> 3);
  b = w >> 7; h = w & 127;
}

// ---------------- prep: weight packs + BN folds ----------------
// A-pack layout: [tap][kb][mh][lane*8+e], m=mh*32+(l&31), c=kb*16+(l>>5)*8+e
__global__ __launch_bounds__(256) void k_prep(
    const float* __restrict__ w1, const float* __restrict__ w5,
    const float* __restrict__ w7, const float* __restrict__ w9,
    const float* __restrict__ w11, const float* __restrict__ pww,
    const float* __restrict__ frw, const float* __restrict__ cw,
    const float* __restrict__ gwb, const float* __restrict__ gbg,
    const float* __restrict__ gbb, const float* __restrict__ gbm,
    const float* __restrict__ gbv, const float* __restrict__ ensw,
    const float* __restrict__ ensb, const float* __restrict__ bng,
    const float* __restrict__ bnb, const float* __restrict__ bnm,
    const float* __restrict__ bnv,
    unsigned short* __restrict__ apack, unsigned short* __restrict__ apinv,
    unsigned short* __restrict__ apens, unsigned short* __restrict__ appw1,
    unsigned short* __restrict__ appw, unsigned short* __restrict__ apfr,
    unsigned short* __restrict__ apid,
    float* __restrict__ Agw, float* __restrict__ Bgw,
    float* __restrict__ esc, float* __restrict__ ebi)
{
  int id = blockIdx.x * 256 + threadIdx.x;
  if (id < 147456) {               // cdcm: 36 taps
    int e = id & 7, l = (id >> 3) & 63, mh = (id >> 9) & 1,
        kb = (id >> 10) & 3, tap = id >> 12;
    int d = tap / 9, k9 = tap - 9 * d;
    int m = mh * 32 + (l & 31);
    int c = kb * 16 + (l >> 5) * 8 + e;
    const float* src = (d == 0) ? w5 : (d == 1) ? w7 : (d == 2) ? w9 : w11;
    apack[id] = f2h(src[(m * 64 + c) * 9 + k9]);
    return;
  }
  id -= 147456;
  if (id < 36864) {                // involution conv_w: 9 taps
    int e = id & 7, l = (id >> 3) & 63, mh = (id >> 9) & 1,
        kb = (id >> 10) & 3, tap = id >> 12;
    int m = mh * 32 + (l & 31);
    int c = kb * 16 + (l >> 5) * 8 + e;
    apinv[id] = f2h(cw[(m * 64 + c) * 9 + tap]);
    return;
  }
  id -= 36864;
  if (id < 36864) {                // ensemble mean weights: 9 taps
    int e = id & 7, l = (id >> 3) & 63, mh = (id >> 9) & 1,
        kb = (id >> 10) & 3, tap = id >> 12;
    int m = mh * 32 + (l & 31);
    int c = kb * 16 + (l >> 5) * 8 + e;
    float v = (ensw[((0 * 64 + m) * 64 + c) * 9 + tap] +
               ensw[((64 + m) * 64 + c) * 9 + tap] +
               ensw[((128 + m) * 64 + c) * 9 + tap]) * (1.f / 3.f);
    apens[id] = f2h(v);
    return;
  }
  id -= 36864;
  if (id < 4096) {                 // conv1 1x1
    int e = id & 7, l = (id >> 3) & 63, mh = (id >> 9) & 1, kb = (id >> 10) & 3;
    int m = mh * 32 + (l & 31);
    int c = kb * 16 + (l >> 5) * 8 + e;
    appw1[id] = f2h(w1[m * 64 + c]);
    return;
  }
  id -= 4096;
  if (id < 4096) {                 // dsc pointwise 1x1
    int e = id & 7, l = (id >> 3) & 63, mh = (id >> 9) & 1, kb = (id >> 10) & 3;
    int m = mh * 32 + (l & 31);
    int c = kb * 16 + (l >> 5) * 8 + e;
    appw[id] = f2h(pww[m * 64 + c]);
    return;
  }
  id -= 4096;
  if (id < 4096) {                 // fr 1x1
    int e = id & 7, l = (id >> 3) & 63, mh = (id >> 9) & 1, kb = (id >> 10) & 3;
    int m = mh * 32 + (l & 31);
    int c = kb * 16 + (l >> 5) * 8 + e;
    apfr[id] = f2h(frw[m * 64 + c]);
    return;
  }
  id -= 4096;
  if (id < 4096) {                 // identity (residual via MFMA)
    int e = id & 7, l = (id >> 3) & 63, mh = (id >> 9) & 1, kb = (id >> 10) & 3;
    int m = mh * 32 + (l & 31);
    int c = kb * 16 + (l >> 5) * 8 + e;
    apid[id] = f2h((m == c) ? 1.f : 0.f);
    return;
  }
  id -= 4096;
  if (id < 576) {                  // gw BN fold
    float s = gbg[id] / sqrtf(gbv[id] + EPSV);
    Agw[id] = s;
    Bgw[id] = (gwb[id] - gbm[id]) * s + gbb[id];
    return;
  }
  id -= 576;
  if (id < 64) {                   // final BN fold (+ mean ensemble bias)
    float s = bng[id] / sqrtf(bnv[id] + EPSV);
    esc[id] = s;
    float bm = (ensb[id] + ensb[64 + id] + ensb[128 + id]) * (1.f / 3.f);
    ebi[id] = (bm - bnm[id]) * s + bnb[id];
  }
}

// ---------------- zero border pixels of a blocked-CL padded buffer ----------
__global__ __launch_bounds__(256) void k_zb(unsigned short* __restrict__ buf,
                                            int PD, int pad)
{
  int per_b = 2 * pad * PD + 128 * 2 * pad;
  int id = blockIdx.x * 256 + threadIdx.x;
  int b = id / per_b;
  if (b >= Bn) return;
  int r = id - b * per_b;
  int tb = 2 * pad * PD;
  int row, col;
  if (r < tb) {
    int rr = r / PD; col = r - rr * PD;
    row = (rr < pad) ? rr : (rr + 128);
  } else {
    int r2 = r - tb;
    row = pad + r2 / (2 * pad);
    int cc = r2 - (r2 / (2 * pad)) * (2 * pad);
    col = (cc < pad) ? cc : (cc + 128);
  }
  ushort8v z = {0, 0, 0, 0, 0, 0, 0, 0};
  #pragma unroll
  for (int kb = 0; kb < 4; kb++) {
    unsigned short* p = buf + clb(b, row, kb, col, PD);
    *(ushort8v*)p = z;
    *(ushort8v*)(p + 8) = z;
  }
}

// ---------------- stage 1: conv1x1(relu(x)) via MFMA, planar fp32 in --------
__global__ __launch_bounds__(256, 4) void k_pw1x(const float* __restrict__ x,
    const unsigned short* __restrict__ apw, const float* __restrict__ bias,
    unsigned short* __restrict__ ypad)
{
  int b, h; swz_bh(b, h);
  const int tid = threadIdx.x, wv = tid >> 6, l = tid & 63;
  const int ln31 = l & 31, g = l >> 5;
  const int px = wv * 32 + ln31;
  const float* xb = x + ((size_t)b * Cn) * Pn + h * Wn + px;
  v16f acc0, acc1;
  #pragma unroll
  for (int r = 0; r < 16; r++) { acc0[r] = 0.f; acc1[r] = 0.f; }
  const unsigned short* apl = apw + l * 8;
  #pragma unroll
  for (int kb = 0; kb < 4; kb++) {
    int c0 = kb * 16 + g * 8;
    v8h Bf;
    #pragma unroll
    for (int e = 0; e < 8; e++)
      Bf[e] = (_Float16)fmaxf(xb[(size_t)(c0 + e) * Pn], 0.f);
    v8h A0 = *(const v8h*)(apl + (kb * 2) * 512);
    v8h A1 = *(const v8h*)(apl + (kb * 2 + 1) * 512);
    acc0 = __builtin_amdgcn_mfma_f32_32x32x16_f16(A0, Bf, acc0, 0, 0, 0);
    acc1 = __builtin_amdgcn_mfma_f32_32x32x16_f16(A1, Bf, acc1, 0, 0, 0);
  }
  #pragma unroll
  for (int t = 0; t < 4; t++) {
    int c0 = 8 * t + 4 * g;
    int kb = c0 >> 4, sub = c0 & 15;
    ushort4v s0, s1;
    #pragma unroll
    for (int u = 0; u < 4; u++) {
      s0[u] = f2h(acc0[4 * t + u] + bias[c0 + u]);
      s1[u] = f2h(acc1[4 * t + u] + bias[c0 + u + 32]);
    }
    *(ushort4v*)(ypad + clb(b, h + 11, kb, px + 11, PR) + sub) = s0;
    *(ushort4v*)(ypad + clb(b, h + 11, kb + 2, px + 11, PR) + sub) = s1;
  }
}

// ---------------- stage 2: cdcm via fp16 MFMA, out fp16 blocked-CL pad-1 ----
__global__ __launch_bounds__(256, 4) void k_cdcm_mfma(
    const unsigned short* __restrict__ ypad,
    const unsigned short* __restrict__ apack,
    unsigned short* __restrict__ spad)
{
  int b, h; swz_bh(b, h);
  const int tid = threadIdx.x, wv = tid >> 6, l = tid & 63;
  const int ln31 = l & 31, g = l >> 5;

  v16f acc0, acc1;
  #pragma unroll
  for (int r = 0; r < 16; r++) { acc0[r] = 0.f; acc1[r] = 0.f; }

  const unsigned short* apl = apack + l * 8;

  #pragma unroll
  for (int d = 0; d < 4; d++) {
    const int dil = 5 + 2 * d;
    #pragma unroll
    for (int ky = 0; ky < 3; ky++) {
      const int row = h + 11 + (ky - 1) * dil;
      #pragma unroll
      for (int kx = 0; kx < 3; kx++) {
        const int col = wv * 32 + ln31 + (kx - 1) * dil + 11;
        const int tap = d * 9 + ky * 3 + kx;
        const unsigned short* ap = apl + tap * 4096;
        #pragma unroll
        for (int kb = 0; kb < 4; kb++) {
          v8h Bf = *(const v8h*)(ypad + clb(b, row, kb, col, PR) + g * 8);
          v8h A0 = *(const v8h*)(ap + kb * 1024);
          v8h A1 = *(const v8h*)(ap + kb * 1024 + 512);
          acc0 = __builtin_amdgcn_mfma_f32_32x32x16_f16(A0, Bf, acc0, 0, 0, 0);
          acc1 = __builtin_amdgcn_mfma_f32_32x32x16_f16(A1, Bf, acc1, 0, 0, 0);
        }
      }
    }
  }
  const int px = wv * 32 + ln31;
  #pragma unroll
  for (int t = 0; t < 4; t++) {
    int c0 = 8 * t + 4 * g;
    int kb = c0 >> 4, sub = c0 & 15;
    ushort4v s0, s1;
    #pragma unroll
    for (int u = 0; u < 4; u++) {
      s0[u] = f2h(acc0[4 * t + u]);
      s1[u] = f2h(acc1[4 * t + u]);
    }
    *(ushort4v*)(spad + clb(b, h + 1, kb, px + 1, PE) + sub) = s0;
    *(ushort4v*)(spad + clb(b, h + 1, kb + 2, px + 1, PE) + sub) = s1;
  }
}

// ---------------- stage 3: depthwise (VALU) + pointwise (MFMA) --------------
__global__ __launch_bounds__(256, 4) void k_dwpw_mfma(
    const unsigned short* __restrict__ spad,
    const float* __restrict__ dww, const float* __restrict__ dwb,
    const unsigned short* __restrict__ appw, const float* __restrict__ pwb,
    unsigned short* __restrict__ y2pad)
{
  __shared__ float wdw[576];
  __shared__ float bdw[64];
  const int tid = threadIdx.x;
  for (int t = tid; t < 576; t += 256) wdw[t] = dww[t];
  if (tid < 64) bdw[tid] = dwb[tid];
  __syncthreads();

  int b, h; swz_bh(b, h);
  const int wv = tid >> 6, l = tid & 63;
  const int ln31 = l & 31, g = l >> 5;
  const int w = wv * 32 + ln31;

  v16f acc0, acc1;
  #pragma unroll
  for (int r = 0; r < 16; r++) { acc0[r] = 0.f; acc1[r] = 0.f; }
  const unsigned short* apl = appw + l * 8;

  #pragma unroll
  for (int kb = 0; kb < 4; kb++) {
    const int c0 = kb * 16 + g * 8;
    v8h t[9];
    #pragma unroll
    for (int k = 0; k < 9; k++) {
      const int dy = k / 3 - 1, dx = k % 3 - 1;
      t[k] = *(const v8h*)(spad + clb(b, h + 1 + dy, kb, w + 1 + dx, PE) + g * 8);
    }
    v8h dvh;
    #pragma unroll
    for (int e = 0; e < 8; e++) {
      const int c = c0 + e;
      float a = 4.f * bdw[c];
      #pragma unroll
      for (int k = 0; k < 9; k++) a += wdw[c * 9 + k] * (float)t[k][e];
      dvh[e] = (_Float16)a;
    }
    v8h A0 = *(const v8h*)(apl + (kb * 2) * 512);
    v8h A1 = *(const v8h*)(apl + (kb * 2 + 1) * 512);
    acc0 = __builtin_amdgcn_mfma_f32_32x32x16_f16(A0, dvh, acc0, 0, 0, 0);
    acc1 = __builtin_amdgcn_mfma_f32_32x32x16_f16(A1, dvh, acc1, 0, 0, 0);
  }
  #pragma unroll
  for (int t = 0; t < 4; t++) {
    int c0 = 8 * t + 4 * g;
    int kb = c0 >> 4, sub = c0 & 15;
    ushort4v s0, s1;
    #pragma unroll
    for (int u = 0; u < 4; u++) {
      s0[u] = f2h(acc0[4 * t + u] + 4.f * pwb[c0 + u]);
      s1[u] = f2h(acc1[4 * t + u] + 4.f * pwb[c0 + u + 32]);
    }
    *(ushort4v*)(y2pad + clb(b, h + 1, kb, w + 1, PE) + sub) = s0;
    *(ushort4v*)(y2pad + clb(b, h + 1, kb + 2, w + 1, PE) + sub) = s1;
  }
}

// ---------------- stage 4: involution via fp16 MFMA, out fp16 blocked-CL ----
__global__ __launch_bounds__(256) void k_invol_mfma(
    const unsigned short* __restrict__ y2pad,
    const float* __restrict__ gww,
    const float* __restrict__ Agw, const float* __restrict__ Bgw,
    const unsigned short* __restrict__ apinv,
    const float* __restrict__ cbias,
    unsigned short* __restrict__ ipad)
{
  __shared__ float gws[5184];
  __shared__ float As[576];
  __shared__ float Bs[576];
  const int tid = threadIdx.x;
  for (int t = tid; t < 5184; t += 256) gws[t] = gww[t];
  for (int t = tid; t < 576; t += 256) { As[t] = Agw[t]; Bs[t] = Bgw[t]; }
  __syncthreads();

  int b, h; swz_bh(b, h);
  const int wv = tid >> 6, l = tid & 63;
  const int p32 = l & 31, g = l >> 5;
  const int w = wv * 32 + p32;

  v16f acc0, acc1;
  #pragma unroll
  for (int r = 0; r < 16; r++) { acc0[r] = 0.f; acc1[r] = 0.f; }

  for (int cb4 = 0; cb4 < 4; cb4++) {
    const int c0 = cb4 * 16 + g * 8;
    v8h pt[9];
    #pragma unroll
    for (int k = 0; k < 9; k++) {
      const int dy = k / 3 - 1, dx = k % 3 - 1;
      pt[k] = *(const v8h*)(y2pad + clb(b, h + 1 + dy, cb4, w + 1 + dx, PE) + g * 8);
    }
    #pragma unroll
    for (int e = 0; e < 8; e++) {
      const int c = c0 + e;
      float pf[9];
      #pragma unroll
      for (int k = 0; k < 9; k++) pf[k] = (float)pt[k][e];
      const float* gc = &gws[c * 81];
      const float* Ac = &As[c * 9];
      const float* Bc = &Bs[c * 9];
      float s[9]; float mx = -1e30f;
      #pragma unroll
      for (int o = 0; o < 9; o++) {
        float t = 0.f;
        #pragma unroll
        for (int i = 0; i < 9; i++) t += gc[o * 9 + i] * pf[i];
        t = t * Ac[o] + Bc[o];
        s[o] = t;
        mx = fmaxf(mx, t);
      }
      float sum = 0.f;
      #pragma unroll
      for (int o = 0; o < 9; o++) { s[o] = __expf(s[o] - mx); sum += s[o]; }
      float inv = 1.f / sum;
      #pragma unroll
      for (int k = 0; k < 9; k++) pt[k][e] = (_Float16)(pf[k] * s[k] * inv);
    }
    const unsigned short* ap = apinv + l * 8;
    #pragma unroll
    for (int k = 0; k < 9; k++) {
      const unsigned short* a2 = ap + ((k * 4 + cb4) * 2) * 512;
      v8h A0 = *(const v8h*)(a2);
      v8h A1 = *(const v8h*)(a2 + 512);
      acc0 = __builtin_amdgcn_mfma_f32_32x32x16_f16(A0, pt[k], acc0, 0, 0, 0);
      acc1 = __builtin_amdgcn_mfma_f32_32x32x16_f16(A1, pt[k], acc1, 0, 0, 0);
    }
  }
  #pragma unroll
  for (int t = 0; t < 4; t++) {
    int c0 = 8 * t + 4 * g;
    int kb = c0 >> 4, sub = c0 & 15;
    ushort4v s0, s1;
    #pragma unroll
    for (int u = 0; u < 4; u++) {
      s0[u] = f2h(acc0[4 * t + u] + cbias[c0 + u]);
      s1[u] = f2h(acc1[4 * t + u] + cbias[c0 + u + 32]);
    }
    *(ushort4v*)(ipad + clb(b, h, kb, w, 128) + sub) = s0;
    *(ushort4v*)(ipad + clb(b, h, kb + 2, w, 128) + sub) = s1;
  }
}

// ---------------- stage 5: fr 1x1 + residual (identity MFMA) ----------------
__global__ __launch_bounds__(256, 4) void k_fr_mfma(
    const unsigned short* __restrict__ ipad,
    const unsigned short* __restrict__ apfr,
    const unsigned short* __restrict__ apid,
    const float* __restrict__ bias,
    unsigned short* __restrict__ opad)
{
  int b, h; swz_bh(b, h);
  const int tid = threadIdx.x, wv = tid >> 6, l = tid & 63;
  const int ln31 = l & 31, g = l >> 5;
  const int px = wv * 32 + ln31;
  v16f acc0, acc1;
  #pragma unroll
  for (int r = 0; r < 16; r++) { acc0[r] = 0.f; acc1[r] = 0.f; }
  const unsigned short* apl = apfr + l * 8;
  const unsigned short* idl = apid + l * 8;
  #pragma unroll
  for (int kb = 0; kb < 4; kb++) {
    v8h Bf = *(const v8h*)(ipad + clb(b, h, kb, px, 128) + g * 8);
    v8h A0 = *(const v8h*)(apl + (kb * 2) * 512);
    v8h A1 = *(const v8h*)(apl + (kb * 2 + 1) * 512);
    v8h I0 = *(const v8h*)(idl + (kb * 2) * 512);
    v8h I1 = *(const v8h*)(idl + (kb * 2 + 1) * 512);
    acc0 = __builtin_amdgcn_mfma_f32_32x32x16_f16(A0, Bf, acc0, 0, 0, 0);
    acc1 = __builtin_amdgcn_mfma_f32_32x32x16_f16(A1, Bf, acc1, 0, 0, 0);
    acc0 = __builtin_amdgcn_mfma_f32_32x32x16_f16(I0, Bf, acc0, 0, 0, 0);
    acc1 = __builtin_amdgcn_mfma_f32_32x32x16_f16(I1, Bf, acc1, 0, 0, 0);
  }
  #pragma unroll
  for (int t = 0; t < 4; t++) {
    int c0 = 8 * t + 4 * g;
    int kb = c0 >> 4, sub = c0 & 15;
    ushort4v s0, s1;
    #pragma unroll
    for (int u = 0; u < 4; u++) {
      s0[u] = f2h(acc0[4 * t + u] + bias[c0 + u]);
      s1[u] = f2h(acc1[4 * t + u] + bias[c0 + u + 32]);
    }
    *(ushort4v*)(opad + clb(b, h + 1, kb, px + 1, PE) + sub) = s0;
    *(ushort4v*)(opad + clb(b, h + 1, kb + 2, px + 1, PE) + sub) = s1;
  }
}

// ---------------- stage 6: ensemble conv3x3 via MFMA + BN + ReLU ------------
__global__ __launch_bounds__(256, 4) void k_ens_mfma(
    const unsigned short* __restrict__ opad,
    const unsigned short* __restrict__ apens,
    const float* __restrict__ esc, const float* __restrict__ ebi,
    float* __restrict__ out)
{
  int b, h; swz_bh(b, h);
  const int tid = threadIdx.x, wv = tid >> 6, l = tid & 63;
  const int ln31 = l & 31, g = l >> 5;

  v16f acc0, acc1;
  #pragma unroll
  for (int r = 0; r < 16; r++) { acc0[r] = 0.f; acc1[r] = 0.f; }

  const unsigned short* apl = apens + l * 8;

  #pragma unroll
  for (int ky = 0; ky < 3; ky++) {
    #pragma unroll
    for (int kx = 0; kx < 3; kx++) {
      const int tap = ky * 3 + kx;
      const int row = h + ky;              // (h+1) + (ky-1)
      const int col = wv * 32 + ln31 + kx; // (+1) + (kx-1)
      const unsigned short* ap = apl + tap * 4096;
      #pragma unroll
      for (int kb = 0; kb < 4; kb++) {
        v8h Bf = *(const v8h*)(opad + clb(b, row, kb, col, PE) + g * 8);
        v8h A0 = *(const v8h*)(ap + kb * 1024);
        v8h A1 = *(const v8h*)(ap + kb * 1024 + 512);
        acc0 = __builtin_amdgcn_mfma_f32_32x32x16_f16(A0, Bf, acc0, 0, 0, 0);
        acc1 = __builtin_amdgcn_mfma_f32_32x32x16_f16(A1, Bf, acc1, 0, 0, 0);
      }
    }
  }
  float* sp = out + ((size_t)b * Cn) * Pn + h * Wn + wv * 32 + ln31;
  #pragma unroll
  for (int r = 0; r < 16; r++) {
    int o0 = (r & 3) + 8 * (r >> 2) + 4 * g;
    float v0 = acc0[r] * esc[o0] + ebi[o0];
    float v1 = acc1[r] * esc[o0 + 32] + ebi[o0 + 32];
    sp[(size_t)o0 * Pn] = fmaxf(v0, 0.f);
    sp[(size_t)(o0 + 32) * Pn] = fmaxf(v1, 0.f);
  }
}

extern "C" void kernel_launch(void* const* d_in, const int* in_sizes, int n_in,
                              void* d_out, int out_size, void* d_ws, size_t ws_size,
                              hipStream_t stream)
{
  const float* x    = (const float*)d_in[0];
  const float* w1   = (const float*)d_in[1];
  const float* b1   = (const float*)d_in[2];
  const float* w5   = (const float*)d_in[3];
  const float* w7   = (const float*)d_in[4];
  const float* w9   = (const float*)d_in[5];
  const float* w11  = (const float*)d_in[6];
  const float* dww  = (const float*)d_in[7];
  const float* dwb  = (const float*)d_in[8];
  const float* pww  = (const float*)d_in[9];
  const float* pwb  = (const float*)d_in[10];
  const float* gww  = (const float*)d_in[11];
  const float* gwb  = (const float*)d_in[12];
  const float* gbg  = (const float*)d_in[13];
  const float* gbb  = (const float*)d_in[14];
  const float* gbm  = (const float*)d_in[15];
  const float* gbv  = (const float*)d_in[16];
  const float* cw   = (const float*)d_in[17];
  const float* cb   = (const float*)d_in[18];
  const float* frw  = (const float*)d_in[19];
  const float* frb  = (const float*)d_in[20];
  const float* ensw = (const float*)d_in[21];
  const float* ensb = (const float*)d_in[22];
  const float* bng  = (const float*)d_in[23];
  const float* bnb  = (const float*)d_in[24];
  const float* bnm  = (const float*)d_in[25];
  const float* bnv  = (const float*)d_in[26];

  // ws: ypad (pad-11) region, overlaid later by y2pad then opad (pad-1)
  unsigned short* wsu   = (unsigned short*)d_ws;
  unsigned short* ypad  = wsu;
  unsigned short* y2pad = wsu;
  unsigned short* opad  = wsu;
  unsigned short* apack = wsu + YPAD_ELEMS;         // 147456
  unsigned short* apinv = apack + 147456;           // 36864
  unsigned short* apens = apinv + 36864;            // 36864
  unsigned short* appw1 = apens + 36864;            // 4096
  unsigned short* appw  = appw1 + 4096;             // 4096
  unsigned short* apfr  = appw + 4096;              // 4096
  unsigned short* apid  = apfr + 4096;              // 4096
  float* Agw = (float*)(apid + 4096);               // 576
  float* Bgw = Agw + 576;                           // 576
  float* esc = Bgw + 576;                           // 64
  float* ebi = esc + 64;                            // 64

  // d_out: spad (fp16 blocked-CL pad-1) -> ipad (blocked-CL) -> planar fp32
  unsigned short* spad = (unsigned short*)d_out;
  unsigned short* ipad = (unsigned short*)d_out;
  float* D = (float*)d_out;

  k_prep<<<931, 256, 0, stream>>>(w1, w5, w7, w9, w11, pww, frw, cw,
                                  gwb, gbg, gbb, gbm, gbv, ensw, ensb,
                                  bng, bnb, bnm, bnv,
                                  apack, apinv, apens, appw1, appw, apfr, apid,
                                  Agw, Bgw, esc, ebi);
  // border zeros that are safe now: ypad (ws, pad 11), spad (d_out, pad 1)
  k_zb<<<192, 256, 0, stream>>>(ypad, PR, 11);
  k_zb<<<17, 256, 0, stream>>>(spad, PE, 1);

  // 1) ypad = conv1x1(relu(x))           x (planar f32) -> ypad (blocked CL)
  k_pw1x<<<1024, 256, 0, stream>>>(x, appw1, b1, ypad);
  // 2) spad = sum_d dilconv_d(y)         ypad -> spad (d_out, pad-1)
  k_cdcm_mfma<<<1024, 256, 0, stream>>>(ypad, apack, spad);
  // ws region now dead (ypad fully consumed): zero pad-1 borders for
  // y2pad/opad. These borders survive stages 3-5 (interior-only writes).
  k_zb<<<17, 256, 0, stream>>>(y2pad, PE, 1);
  // 3) y2pad = PW(DW(spad))              spad -> y2pad (ws, pad-1)
  k_dwpw_mfma<<<1024, 256, 0, stream>>>(spad, dww, dwb, appw, pwb, y2pad);
  // 4) ipad = involution(y2pad)          y2pad -> ipad (d_out)
  k_invol_mfma<<<1024, 256, 0, stream>>>(y2pad, gww, Agw, Bgw, apinv, cb, ipad);
  // 5) opad = fr(ipad) + ipad            ipad -> opad (ws, pad-1)
  k_fr_mfma<<<1024, 256, 0, stream>>>(ipad, apfr, apid, frb, opad);
  // 6) out = relu(BN(ens3x3(opad)))      opad -> D (planar fp32)
  k_ens_mfma<<<1024, 256, 0, stream>>>(opad, apens, esc, ebi, D);
}

// Round 8
// 185.811 us; speedup vs baseline: 12.5516x; 1.2185x over previous
//
#include <hip/hip_runtime.h>
#include <hip/hip_bf16.h>
#include <hip/hip_fp16.h>

#define EPSV 1e-5f
#define Bn 8
#define Cn 64
#define Hn 128
#define Wn 128
#define Pn (Hn*Wn)          // 16384
#define PR 150              // cdcm pad: 11 + 128 + 11
#define PE 130              // 1-pad: 1 + 128 + 1
#define YPAD_ELEMS (Bn*PR*PR*Cn)   // 11,520,000 fp16

typedef _Float16 v8h __attribute__((ext_vector_type(8)));
typedef float v16f __attribute__((ext_vector_type(16)));
typedef unsigned short ushort8v __attribute__((ext_vector_type(8)));
typedef unsigned short ushort4v __attribute__((ext_vector_type(4)));

__device__ __forceinline__ unsigned short f2h(float v) {
  _Float16 h = (_Float16)v;
  return *reinterpret_cast<const unsigned short*>(&h);
}

__device__ __forceinline__ v8h exp8h(v8h x) {
  union { v8h v; __half2 h[4]; } u; u.v = x;
  #pragma unroll
  for (int i = 0; i < 4; i++) u.h[i] = h2exp(u.h[i]);
  return u.v;
}
__device__ __forceinline__ v8h rcp8h(v8h x) {
  union { v8h v; __half2 h[4]; } u; u.v = x;
  #pragma unroll
  for (int i = 0; i < 4; i++) u.h[i] = h2rcp(u.h[i]);
  return u.v;
}

// channel-blocked CL addressing: [b][row][kb(4)][col][16], elems
__device__ __forceinline__ size_t clb(int b, int row, int kb, int col, int PD) {
  return ((((size_t)b * PD + row) * 4 + kb) * PD + col) * 16;
}

// batch-major XCD swizzle: 1024 blocks, XCD r gets batch r's rows in order
__device__ __forceinline__ void swz_bh(int& b, int& h) {
  int bid = blockIdx.x;
  int w = (bid & 7) * 128 + (bid >> 3);
  b = w >> 7; h = w & 127;
}

// ---------------- prep: weight packs + BN folds ----------------
// A-pack layout: [tap][kb][mh][lane*8+e], m=mh*32+(l&31), c=kb*16+(l>>5)*8+e
__global__ __launch_bounds__(256) void k_prep(
    const float* __restrict__ w1, const float* __restrict__ w5,
    const float* __restrict__ w7, const float* __restrict__ w9,
    const float* __restrict__ w11, const float* __restrict__ pww,
    const float* __restrict__ frw, const float* __restrict__ cw,
    const float* __restrict__ gww, const float* __restrict__ gwb,
    const float* __restrict__ gbg, const float* __restrict__ gbb,
    const float* __restrict__ gbm, const float* __restrict__ gbv,
    const float* __restrict__ ensw, const float* __restrict__ ensb,
    const float* __restrict__ bng, const float* __restrict__ bnb,
    const float* __restrict__ bnm, const float* __restrict__ bnv,
    unsigned short* __restrict__ apack, unsigned short* __restrict__ apinv,
    unsigned short* __restrict__ apens, unsigned short* __restrict__ appw1,
    unsigned short* __restrict__ appw, unsigned short* __restrict__ apfr,
    unsigned short* __restrict__ apid, unsigned short* __restrict__ gwpk,
    unsigned short* __restrict__ apk, unsigned short* __restrict__ bpk,
    float* __restrict__ esc, float* __restrict__ ebi)
{
  int id = blockIdx.x * 256 + threadIdx.x;
  if (id < 147456) {               // cdcm: 36 taps
    int e = id & 7, l = (id >> 3) & 63, mh = (id >> 9) & 1,
        kb = (id >> 10) & 3, tap = id >> 12;
    int d = tap / 9, k9 = tap - 9 * d;
    int m = mh * 32 + (l & 31);
    int c = kb * 16 + (l >> 5) * 8 + e;
    const float* src = (d == 0) ? w5 : (d == 1) ? w7 : (d == 2) ? w9 : w11;
    apack[id] = f2h(src[(m * 64 + c) * 9 + k9]);
    return;
  }
  id -= 147456;
  if (id < 36864) {                // involution conv_w: 9 taps
    int e = id & 7, l = (id >> 3) & 63, mh = (id >> 9) & 1,
        kb = (id >> 10) & 3, tap = id >> 12;
    int m = mh * 32 + (l & 31);
    int c = kb * 16 + (l >> 5) * 8 + e;
    apinv[id] = f2h(cw[(m * 64 + c) * 9 + tap]);
    return;
  }
  id -= 36864;
  if (id < 36864) {                // ensemble mean weights: 9 taps
    int e = id & 7, l = (id >> 3) & 63, mh = (id >> 9) & 1,
        kb = (id >> 10) & 3, tap = id >> 12;
    int m = mh * 32 + (l & 31);
    int c = kb * 16 + (l >> 5) * 8 + e;
    float v = (ensw[((0 * 64 + m) * 64 + c) * 9 + tap] +
               ensw[((64 + m) * 64 + c) * 9 + tap] +
               ensw[((128 + m) * 64 + c) * 9 + tap]) * (1.f / 3.f);
    apens[id] = f2h(v);
    return;
  }
  id -= 36864;
  if (id < 4096) {                 // conv1 1x1
    int e = id & 7, l = (id >> 3) & 63, mh = (id >> 9) & 1, kb = (id >> 10) & 3;
    int m = mh * 32 + (l & 31);
    int c = kb * 16 + (l >> 5) * 8 + e;
    appw1[id] = f2h(w1[m * 64 + c]);
    return;
  }
  id -= 4096;
  if (id < 4096) {                 // dsc pointwise 1x1
    int e = id & 7, l = (id >> 3) & 63, mh = (id >> 9) & 1, kb = (id >> 10) & 3;
    int m = mh * 32 + (l & 31);
    int c = kb * 16 + (l >> 5) * 8 + e;
    appw[id] = f2h(pww[m * 64 + c]);
    return;
  }
  id -= 4096;
  if (id < 4096) {                 // fr 1x1
    int e = id & 7, l = (id >> 3) & 63, mh = (id >> 9) & 1, kb = (id >> 10) & 3;
    int m = mh * 32 + (l & 31);
    int c = kb * 16 + (l >> 5) * 8 + e;
    apfr[id] = f2h(frw[m * 64 + c]);
    return;
  }
  id -= 4096;
  if (id < 4096) {                 // identity (residual via MFMA)
    int e = id & 7, l = (id >> 3) & 63, mh = (id >> 9) & 1, kb = (id >> 10) & 3;
    int m = mh * 32 + (l & 31);
    int c = kb * 16 + (l >> 5) * 8 + e;
    apid[id] = f2h((m == c) ? 1.f : 0.f);
    return;
  }
  id -= 4096;
  if (id < 5184) {                 // packed gw weights [cblk8][tap81][ch8]
    int cblk = id / 648, r = id - cblk * 648;
    int tap = r >> 3, ch = r & 7;
    int c = cblk * 8 + ch;
    gwpk[id] = f2h(gww[c * 81 + tap]);
    return;
  }
  id -= 5184;
  if (id < 576) {                  // packed BN scale [cblk8][o9][ch8]
    int cblk = id / 72, r = id - cblk * 72;
    int o = r >> 3, ch = r & 7;
    int c = cblk * 8 + ch;
    float A = gbg[c * 9 + o] / sqrtf(gbv[c * 9 + o] + EPSV);
    apk[id] = f2h(A);
    return;
  }
  id -= 576;
  if (id < 576) {                  // packed BN shift
    int cblk = id / 72, r = id - cblk * 72;
    int o = r >> 3, ch = r & 7;
    int c = cblk * 8 + ch;
    float A = gbg[c * 9 + o] / sqrtf(gbv[c * 9 + o] + EPSV);
    float B = (gwb[c * 9 + o] - gbm[c * 9 + o]) * A + gbb[c * 9 + o];
    bpk[id] = f2h(B);
    return;
  }
  id -= 576;
  if (id < 64) {                   // final BN fold (+ mean ensemble bias)
    float s = bng[id] / sqrtf(bnv[id] + EPSV);
    esc[id] = s;
    float bm = (ensb[id] + ensb[64 + id] + ensb[128 + id]) * (1.f / 3.f);
    ebi[id] = (bm - bnm[id]) * s + bnb[id];
  }
}

// ---------------- zero border pixels of a blocked-CL padded buffer ----------
__global__ __launch_bounds__(256) void k_zb(unsigned short* __restrict__ buf,
                                            int PD, int pad)
{
  int per_b = 2 * pad * PD + 128 * 2 * pad;
  int id = blockIdx.x * 256 + threadIdx.x;
  int b = id / per_b;
  if (b >= Bn) return;
  int r = id - b * per_b;
  int tb = 2 * pad * PD;
  int row, col;
  if (r < tb) {
    int rr = r / PD; col = r - rr * PD;
    row = (rr < pad) ? rr : (rr + 128);
  } else {
    int r2 = r - tb;
    row = pad + r2 / (2 * pad);
    int cc = r2 - (r2 / (2 * pad)) * (2 * pad);
    col = (cc < pad) ? cc : (cc + 128);
  }
  ushort8v z = {0, 0, 0, 0, 0, 0, 0, 0};
  #pragma unroll
  for (int kb = 0; kb < 4; kb++) {
    unsigned short* p = buf + clb(b, row, kb, col, PD);
    *(ushort8v*)p = z;
    *(ushort8v*)(p + 8) = z;
  }
}

// ---------------- stage 1: conv1x1(relu(x)) via MFMA, planar fp32 in --------
__global__ __launch_bounds__(256, 4) void k_pw1x(const float* __restrict__ x,
    const unsigned short* __restrict__ apw, const float* __restrict__ bias,
    unsigned short* __restrict__ ypad)
{
  int b, h; swz_bh(b, h);
  const int tid = threadIdx.x, wv = tid >> 6, l = tid & 63;
  const int ln31 = l & 31, g = l >> 5;
  const int px = wv * 32 + ln31;
  const float* xb = x + ((size_t)b * Cn) * Pn + h * Wn + px;
  v16f acc0, acc1;
  #pragma unroll
  for (int r = 0; r < 16; r++) { acc0[r] = 0.f; acc1[r] = 0.f; }
  const unsigned short* apl = apw + l * 8;
  #pragma unroll
  for (int kb = 0; kb < 4; kb++) {
    int c0 = kb * 16 + g * 8;
    v8h Bf;
    #pragma unroll
    for (int e = 0; e < 8; e++)
      Bf[e] = (_Float16)fmaxf(xb[(size_t)(c0 + e) * Pn], 0.f);
    v8h A0 = *(const v8h*)(apl + (kb * 2) * 512);
    v8h A1 = *(const v8h*)(apl + (kb * 2 + 1) * 512);
    acc0 = __builtin_amdgcn_mfma_f32_32x32x16_f16(A0, Bf, acc0, 0, 0, 0);
    acc1 = __builtin_amdgcn_mfma_f32_32x32x16_f16(A1, Bf, acc1, 0, 0, 0);
  }
  #pragma unroll
  for (int t = 0; t < 4; t++) {
    int c0 = 8 * t + 4 * g;
    int kb = c0 >> 4, sub = c0 & 15;
    ushort4v s0, s1;
    #pragma unroll
    for (int u = 0; u < 4; u++) {
      s0[u] = f2h(acc0[4 * t + u] + bias[c0 + u]);
      s1[u] = f2h(acc1[4 * t + u] + bias[c0 + u + 32]);
    }
    *(ushort4v*)(ypad + clb(b, h + 11, kb, px + 11, PR) + sub) = s0;
    *(ushort4v*)(ypad + clb(b, h + 11, kb + 2, px + 11, PR) + sub) = s1;
  }
}

// ---------------- stage 2: cdcm via fp16 MFMA, out fp16 blocked-CL pad-1 ----
__global__ __launch_bounds__(256, 4) void k_cdcm_mfma(
    const unsigned short* __restrict__ ypad,
    const unsigned short* __restrict__ apack,
    unsigned short* __restrict__ spad)
{
  int b, h; swz_bh(b, h);
  const int tid = threadIdx.x, wv = tid >> 6, l = tid & 63;
  const int ln31 = l & 31, g = l >> 5;

  v16f acc0, acc1;
  #pragma unroll
  for (int r = 0; r < 16; r++) { acc0[r] = 0.f; acc1[r] = 0.f; }

  const unsigned short* apl = apack + l * 8;

  #pragma unroll
  for (int d = 0; d < 4; d++) {
    const int dil = 5 + 2 * d;
    #pragma unroll
    for (int ky = 0; ky < 3; ky++) {
      const int row = h + 11 + (ky - 1) * dil;
      #pragma unroll
      for (int kx = 0; kx < 3; kx++) {
        const int col = wv * 32 + ln31 + (kx - 1) * dil + 11;
        const int tap = d * 9 + ky * 3 + kx;
        const unsigned short* ap = apl + tap * 4096;
        #pragma unroll
        for (int kb = 0; kb < 4; kb++) {
          v8h Bf = *(const v8h*)(ypad + clb(b, row, kb, col, PR) + g * 8);
          v8h A0 = *(const v8h*)(ap + kb * 1024);
          v8h A1 = *(const v8h*)(ap + kb * 1024 + 512);
          acc0 = __builtin_amdgcn_mfma_f32_32x32x16_f16(A0, Bf, acc0, 0, 0, 0);
          acc1 = __builtin_amdgcn_mfma_f32_32x32x16_f16(A1, Bf, acc1, 0, 0, 0);
        }
      }
    }
  }
  const int px = wv * 32 + ln31;
  #pragma unroll
  for (int t = 0; t < 4; t++) {
    int c0 = 8 * t + 4 * g;
    int kb = c0 >> 4, sub = c0 & 15;
    ushort4v s0, s1;
    #pragma unroll
    for (int u = 0; u < 4; u++) {
      s0[u] = f2h(acc0[4 * t + u]);
      s1[u] = f2h(acc1[4 * t + u]);
    }
    *(ushort4v*)(spad + clb(b, h + 1, kb, px + 1, PE) + sub) = s0;
    *(ushort4v*)(spad + clb(b, h + 1, kb + 2, px + 1, PE) + sub) = s1;
  }
}

// ---------------- stage 3: depthwise (VALU) + pointwise (MFMA) --------------
__global__ __launch_bounds__(256, 4) void k_dwpw_mfma(
    const unsigned short* __restrict__ spad,
    const float* __restrict__ dww, const float* __restrict__ dwb,
    const unsigned short* __restrict__ appw, const float* __restrict__ pwb,
    unsigned short* __restrict__ y2pad)
{
  __shared__ float wdw[576];
  __shared__ float bdw[64];
  const int tid = threadIdx.x;
  for (int t = tid; t < 576; t += 256) wdw[t] = dww[t];
  if (tid < 64) bdw[tid] = dwb[tid];
  __syncthreads();

  int b, h; swz_bh(b, h);
  const int wv = tid >> 6, l = tid & 63;
  const int ln31 = l & 31, g = l >> 5;
  const int w = wv * 32 + ln31;

  v16f acc0, acc1;
  #pragma unroll
  for (int r = 0; r < 16; r++) { acc0[r] = 0.f; acc1[r] = 0.f; }
  const unsigned short* apl = appw + l * 8;

  #pragma unroll
  for (int kb = 0; kb < 4; kb++) {
    const int c0 = kb * 16 + g * 8;
    v8h t[9];
    #pragma unroll
    for (int k = 0; k < 9; k++) {
      const int dy = k / 3 - 1, dx = k % 3 - 1;
      t[k] = *(const v8h*)(spad + clb(b, h + 1 + dy, kb, w + 1 + dx, PE) + g * 8);
    }
    v8h dvh;
    #pragma unroll
    for (int e = 0; e < 8; e++) {
      const int c = c0 + e;
      float a = 4.f * bdw[c];
      #pragma unroll
      for (int k = 0; k < 9; k++) a += wdw[c * 9 + k] * (float)t[k][e];
      dvh[e] = (_Float16)a;
    }
    v8h A0 = *(const v8h*)(apl + (kb * 2) * 512);
    v8h A1 = *(const v8h*)(apl + (kb * 2 + 1) * 512);
    acc0 = __builtin_amdgcn_mfma_f32_32x32x16_f16(A0, dvh, acc0, 0, 0, 0);
    acc1 = __builtin_amdgcn_mfma_f32_32x32x16_f16(A1, dvh, acc1, 0, 0, 0);
  }
  #pragma unroll
  for (int t = 0; t < 4; t++) {
    int c0 = 8 * t + 4 * g;
    int kb = c0 >> 4, sub = c0 & 15;
    ushort4v s0, s1;
    #pragma unroll
    for (int u = 0; u < 4; u++) {
      s0[u] = f2h(acc0[4 * t + u] + 4.f * pwb[c0 + u]);
      s1[u] = f2h(acc1[4 * t + u] + 4.f * pwb[c0 + u + 32]);
    }
    *(ushort4v*)(y2pad + clb(b, h + 1, kb, w + 1, PE) + sub) = s0;
    *(ushort4v*)(y2pad + clb(b, h + 1, kb + 2, w + 1, PE) + sub) = s1;
  }
}

// ---------------- stage 4: involution, packed-fp16 softmax + MFMA -----------
__global__ __launch_bounds__(256, 3) void k_invol_mfma(
    const unsigned short* __restrict__ y2pad,
    const unsigned short* __restrict__ gwpk,
    const unsigned short* __restrict__ apk,
    const unsigned short* __restrict__ bpk,
    const unsigned short* __restrict__ apinv,
    const float* __restrict__ cbias,
    unsigned short* __restrict__ ipad)
{
  __shared__ __align__(16) unsigned short gws[5184];  // [cblk8][tap81][ch8]
  __shared__ __align__(16) unsigned short As[576];    // [cblk8][o9][ch8]
  __shared__ __align__(16) unsigned short Bs[576];
  const int tid = threadIdx.x;
  for (int t = tid; t < 648; t += 256)
    ((ushort8v*)gws)[t] = ((const ushort8v*)gwpk)[t];
  if (tid < 72) {
    ((ushort8v*)As)[tid] = ((const ushort8v*)apk)[tid];
    ((ushort8v*)Bs)[tid] = ((const ushort8v*)bpk)[tid];
  }
  __syncthreads();

  int b, h; swz_bh(b, h);
  const int wv = tid >> 6, l = tid & 63;
  const int p32 = l & 31, g = l >> 5;
  const int w = wv * 32 + p32;

  v16f acc0, acc1;
  #pragma unroll
  for (int r = 0; r < 16; r++) { acc0[r] = 0.f; acc1[r] = 0.f; }

  for (int cb4 = 0; cb4 < 4; cb4++) {
    const int cblk = cb4 * 2 + g;
    const unsigned short* gwp = gws + cblk * 648;
    const unsigned short* Ap = As + cblk * 72;
    const unsigned short* Bp = Bs + cblk * 72;

    v8h pt[9];
    #pragma unroll
    for (int k = 0; k < 9; k++) {
      const int dy = k / 3 - 1, dx = k % 3 - 1;
      pt[k] = *(const v8h*)(y2pad + clb(b, h + 1 + dy, cb4, w + 1 + dx, PE) + g * 8);
    }
    // gw matmul + BN, all packed fp16 (weights broadcast from LDS)
    v8h s[9];
    #pragma unroll
    for (int o = 0; o < 9; o++) {
      v8h a = (*(const v8h*)(gwp + o * 72)) * pt[0];
      #pragma unroll
      for (int i = 1; i < 9; i++)
        a += (*(const v8h*)(gwp + o * 72 + i * 8)) * pt[i];
      s[o] = a * (*(const v8h*)(Ap + o * 8)) + (*(const v8h*)(Bp + o * 8));
    }
    // softmax over the 9 taps (shift-free: |s| << 1, fp16-safe)
    v8h esum = {0, 0, 0, 0, 0, 0, 0, 0};
    #pragma unroll
    for (int o = 0; o < 9; o++) { s[o] = exp8h(s[o]); esum += s[o]; }
    v8h inv = rcp8h(esum);
    #pragma unroll
    for (int k = 0; k < 9; k++) pt[k] = pt[k] * s[k] * inv;

    const unsigned short* ap = apinv + l * 8;
    #pragma unroll
    for (int k = 0; k < 9; k++) {
      const unsigned short* a2 = ap + ((k * 4 + cb4) * 2) * 512;
      v8h A0 = *(const v8h*)(a2);
      v8h A1 = *(const v8h*)(a2 + 512);
      acc0 = __builtin_amdgcn_mfma_f32_32x32x16_f16(A0, pt[k], acc0, 0, 0, 0);
      acc1 = __builtin_amdgcn_mfma_f32_32x32x16_f16(A1, pt[k], acc1, 0, 0, 0);
    }
  }
  #pragma unroll
  for (int t = 0; t < 4; t++) {
    int c0 = 8 * t + 4 * g;
    int kb = c0 >> 4, sub = c0 & 15;
    ushort4v s0, s1;
    #pragma unroll
    for (int u = 0; u < 4; u++) {
      s0[u] = f2h(acc0[4 * t + u] + cbias[c0 + u]);
      s1[u] = f2h(acc1[4 * t + u] + cbias[c0 + u + 32]);
    }
    *(ushort4v*)(ipad + clb(b, h, kb, w, 128) + sub) = s0;
    *(ushort4v*)(ipad + clb(b, h, kb + 2, w, 128) + sub) = s1;
  }
}

// ---------------- stage 5: fr 1x1 + residual (identity MFMA) ----------------
__global__ __launch_bounds__(256, 4) void k_fr_mfma(
    const unsigned short* __restrict__ ipad,
    const unsigned short* __restrict__ apfr,
    const unsigned short* __restrict__ apid,
    const float* __restrict__ bias,
    unsigned short* __restrict__ opad)
{
  int b, h; swz_bh(b, h);
  const int tid = threadIdx.x, wv = tid >> 6, l = tid & 63;
  const int ln31 = l & 31, g = l >> 5;
  const int px = wv * 32 + ln31;
  v16f acc0, acc1;
  #pragma unroll
  for (int r = 0; r < 16; r++) { acc0[r] = 0.f; acc1[r] = 0.f; }
  const unsigned short* apl = apfr + l * 8;
  const unsigned short* idl = apid + l * 8;
  #pragma unroll
  for (int kb = 0; kb < 4; kb++) {
    v8h Bf = *(const v8h*)(ipad + clb(b, h, kb, px, 128) + g * 8);
    v8h A0 = *(const v8h*)(apl + (kb * 2) * 512);
    v8h A1 = *(const v8h*)(apl + (kb * 2 + 1) * 512);
    v8h I0 = *(const v8h*)(idl + (kb * 2) * 512);
    v8h I1 = *(const v8h*)(idl + (kb * 2 + 1) * 512);
    acc0 = __builtin_amdgcn_mfma_f32_32x32x16_f16(A0, Bf, acc0, 0, 0, 0);
    acc1 = __builtin_amdgcn_mfma_f32_32x32x16_f16(A1, Bf, acc1, 0, 0, 0);
    acc0 = __builtin_amdgcn_mfma_f32_32x32x16_f16(I0, Bf, acc0, 0, 0, 0);
    acc1 = __builtin_amdgcn_mfma_f32_32x32x16_f16(I1, Bf, acc1, 0, 0, 0);
  }
  #pragma unroll
  for (int t = 0; t < 4; t++) {
    int c0 = 8 * t + 4 * g;
    int kb = c0 >> 4, sub = c0 & 15;
    ushort4v s0, s1;
    #pragma unroll
    for (int u = 0; u < 4; u++) {
      s0[u] = f2h(acc0[4 * t + u] + bias[c0 + u]);
      s1[u] = f2h(acc1[4 * t + u] + bias[c0 + u + 32]);
    }
    *(ushort4v*)(opad + clb(b, h + 1, kb, px + 1, PE) + sub) = s0;
    *(ushort4v*)(opad + clb(b, h + 1, kb + 2, px + 1, PE) + sub) = s1;
  }
}

// ---------------- stage 6: ensemble conv3x3 via MFMA + BN + ReLU ------------
__global__ __launch_bounds__(256, 4) void k_ens_mfma(
    const unsigned short* __restrict__ opad,
    const unsigned short* __restrict__ apens,
    const float* __restrict__ esc, const float* __restrict__ ebi,
    float* __restrict__ out)
{
  int b, h; swz_bh(b, h);
  const int tid = threadIdx.x, wv = tid >> 6, l = tid & 63;
  const int ln31 = l & 31, g = l >> 5;

  v16f acc0, acc1;
  #pragma unroll
  for (int r = 0; r < 16; r++) { acc0[r] = 0.f; acc1[r] = 0.f; }

  const unsigned short* apl = apens + l * 8;

  #pragma unroll
  for (int ky = 0; ky < 3; ky++) {
    #pragma unroll
    for (int kx = 0; kx < 3; kx++) {
      const int tap = ky * 3 + kx;
      const int row = h + ky;              // (h+1) + (ky-1)
      const int col = wv * 32 + ln31 + kx; // (+1) + (kx-1)
      const unsigned short* ap = apl + tap * 4096;
      #pragma unroll
      for (int kb = 0; kb < 4; kb++) {
        v8h Bf = *(const v8h*)(opad + clb(b, row, kb, col, PE) + g * 8);
        v8h A0 = *(const v8h*)(ap + kb * 1024);
        v8h A1 = *(const v8h*)(ap + kb * 1024 + 512);
        acc0 = __builtin_amdgcn_mfma_f32_32x32x16_f16(A0, Bf, acc0, 0, 0, 0);
        acc1 = __builtin_amdgcn_mfma_f32_32x32x16_f16(A1, Bf, acc1, 0, 0, 0);
      }
    }
  }
  float* sp = out + ((size_t)b * Cn) * Pn + h * Wn + wv * 32 + ln31;
  #pragma unroll
  for (int r = 0; r < 16; r++) {
    int o0 = (r & 3) + 8 * (r >> 2) + 4 * g;
    float v0 = acc0[r] * esc[o0] + ebi[o0];
    float v1 = acc1[r] * esc[o0 + 32] + ebi[o0 + 32];
    sp[(size_t)o0 * Pn] = fmaxf(v0, 0.f);
    sp[(size_t)(o0 + 32) * Pn] = fmaxf(v1, 0.f);
  }
}

extern "C" void kernel_launch(void* const* d_in, const int* in_sizes, int n_in,
                              void* d_out, int out_size, void* d_ws, size_t ws_size,
                              hipStream_t stream)
{
  const float* x    = (const float*)d_in[0];
  const float* w1   = (const float*)d_in[1];
  const float* b1   = (const float*)d_in[2];
  const float* w5   = (const float*)d_in[3];
  const float* w7   = (const float*)d_in[4];
  const float* w9   = (const float*)d_in[5];
  const float* w11  = (const float*)d_in[6];
  const float* dww  = (const float*)d_in[7];
  const float* dwb  = (const float*)d_in[8];
  const float* pww  = (const float*)d_in[9];
  const float* pwb  = (const float*)d_in[10];
  const float* gww  = (const float*)d_in[11];
  const float* gwb  = (const float*)d_in[12];
  const float* gbg  = (const float*)d_in[13];
  const float* gbb  = (const float*)d_in[14];
  const float* gbm  = (const float*)d_in[15];
  const float* gbv  = (const float*)d_in[16];
  const float* cw   = (const float*)d_in[17];
  const float* cb   = (const float*)d_in[18];
  const float* frw  = (const float*)d_in[19];
  const float* frb  = (const float*)d_in[20];
  const float* ensw = (const float*)d_in[21];
  const float* ensb = (const float*)d_in[22];
  const float* bng  = (const float*)d_in[23];
  const float* bnb  = (const float*)d_in[24];
  const float* bnm  = (const float*)d_in[25];
  const float* bnv  = (const float*)d_in[26];

  // ws: ypad (pad-11) region, overlaid later by y2pad then opad (pad-1)
  unsigned short* wsu   = (unsigned short*)d_ws;
  unsigned short* ypad  = wsu;
  unsigned short* y2pad = wsu;
  unsigned short* opad  = wsu;
  unsigned short* apack = wsu + YPAD_ELEMS;         // 147456
  unsigned short* apinv = apack + 147456;           // 36864
  unsigned short* apens = apinv + 36864;            // 36864
  unsigned short* appw1 = apens + 36864;            // 4096
  unsigned short* appw  = appw1 + 4096;             // 4096
  unsigned short* apfr  = appw + 4096;              // 4096
  unsigned short* apid  = apfr + 4096;              // 4096
  unsigned short* gwpk  = apid + 4096;              // 5184
  unsigned short* apk   = gwpk + 5184;              // 576
  unsigned short* bpk   = apk + 576;                // 576
  float* esc = (float*)(bpk + 576);                 // 64
  float* ebi = esc + 64;                            // 64

  // d_out: spad (fp16 blocked-CL pad-1) -> ipad (blocked-CL) -> planar fp32
  unsigned short* spad = (unsigned short*)d_out;
  unsigned short* ipad = (unsigned short*)d_out;
  float* D = (float*)d_out;

  k_prep<<<953, 256, 0, stream>>>(w1, w5, w7, w9, w11, pww, frw, cw,
                                  gww, gwb, gbg, gbb, gbm, gbv, ensw, ensb,
                                  bng, bnb, bnm, bnv,
                                  apack, apinv, apens, appw1, appw, apfr, apid,
                                  gwpk, apk, bpk, esc, ebi);
  // border zeros that are safe now: ypad (ws, pad 11), spad (d_out, pad 1)
  k_zb<<<192, 256, 0, stream>>>(ypad, PR, 11);
  k_zb<<<17, 256, 0, stream>>>(spad, PE, 1);

  // 1) ypad = conv1x1(relu(x))           x (planar f32) -> ypad (blocked CL)
  k_pw1x<<<1024, 256, 0, stream>>>(x, appw1, b1, ypad);
  // 2) spad = sum_d dilconv_d(y)         ypad -> spad (d_out, pad-1)
  k_cdcm_mfma<<<1024, 256, 0, stream>>>(ypad, apack, spad);
  // ws region now dead (ypad fully consumed): zero pad-1 borders for
  // y2pad/opad. These borders survive stages 3-5 (interior-only writes).
  k_zb<<<17, 256, 0, stream>>>(y2pad, PE, 1);
  // 3) y2pad = PW(DW(spad))              spad -> y2pad (ws, pad-1)
  k_dwpw_mfma<<<1024, 256, 0, stream>>>(spad, dww, dwb, appw, pwb, y2pad);
  // 4) ipad = involution(y2pad)          y2pad -> ipad (d_out)
  k_invol_mfma<<<1024, 256, 0, stream>>>(y2pad, gwpk, apk, bpk, apinv, cb, ipad);
  // 5) opad = fr(ipad) + ipad            ipad -> opad (ws, pad-1)
  k_fr_mfma<<<1024, 256, 0, stream>>>(ipad, apfr, apid, frb, opad);
  // 6) out = relu(BN(ens3x3(opad)))      opad -> D (planar fp32)
  k_ens_mfma<<<1024, 256, 0, stream>>>(opad, apens, esc, ebi, D);
}

// Round 9
// 166.530 us; speedup vs baseline: 14.0048x; 1.1158x over previous
//
#include <hip/hip_runtime.h>
#include <hip/hip_bf16.h>
#include <hip/hip_fp16.h>

#define EPSV 1e-5f
#define Bn 8
#define Cn 64
#define Hn 128
#define Wn 128
#define Pn (Hn*Wn)          // 16384
#define PR 150              // cdcm pad: 11 + 128 + 11
#define PE 130              // 1-pad: 1 + 128 + 1
#define YPAD_ELEMS (Bn*PR*PR*Cn)   // 11,520,000 fp16

typedef _Float16 v8h __attribute__((ext_vector_type(8)));
typedef float v16f __attribute__((ext_vector_type(16)));
typedef unsigned short ushort8v __attribute__((ext_vector_type(8)));
typedef unsigned short ushort4v __attribute__((ext_vector_type(4)));

__device__ __forceinline__ unsigned short f2h(float v) {
  _Float16 h = (_Float16)v;
  return *reinterpret_cast<const unsigned short*>(&h);
}

__device__ __forceinline__ v8h exp8h(v8h x) {
  union { v8h v; __half2 h[4]; } u; u.v = x;
  #pragma unroll
  for (int i = 0; i < 4; i++) u.h[i] = h2exp(u.h[i]);
  return u.v;
}
__device__ __forceinline__ v8h rcp8h(v8h x) {
  union { v8h v; __half2 h[4]; } u; u.v = x;
  #pragma unroll
  for (int i = 0; i < 4; i++) u.h[i] = h2rcp(u.h[i]);
  return u.v;
}

// channel-blocked CL addressing: [b][row][kb(4)][col][16], elems
__device__ __forceinline__ size_t clb(int b, int row, int kb, int col, int PD) {
  return ((((size_t)b * PD + row) * 4 + kb) * PD + col) * 16;
}

// batch-major XCD swizzle: 1024 blocks, XCD r gets batch r's rows in order
__device__ __forceinline__ void swz_bh(int& b, int& h) {
  int bid = blockIdx.x;
  int w = (bid & 7) * 128 + (bid >> 3);
  b = w >> 7; h = w & 127;
}

// ---------------- prep: weight packs + BN folds ----------------
// A-pack layout: [tap][kb][mh][lane*8+e], m=mh*32+(l&31), c=kb*16+(l>>5)*8+e
__global__ __launch_bounds__(256) void k_prep(
    const float* __restrict__ w1, const float* __restrict__ w5,
    const float* __restrict__ w7, const float* __restrict__ w9,
    const float* __restrict__ w11, const float* __restrict__ pww,
    const float* __restrict__ frw, const float* __restrict__ cw,
    const float* __restrict__ gww, const float* __restrict__ gwb,
    const float* __restrict__ gbg, const float* __restrict__ gbb,
    const float* __restrict__ gbm, const float* __restrict__ gbv,
    const float* __restrict__ ensw, const float* __restrict__ ensb,
    const float* __restrict__ bng, const float* __restrict__ bnb,
    const float* __restrict__ bnm, const float* __restrict__ bnv,
    unsigned short* __restrict__ apack, unsigned short* __restrict__ apinv,
    unsigned short* __restrict__ apens, unsigned short* __restrict__ appw1,
    unsigned short* __restrict__ appw, unsigned short* __restrict__ apfr,
    unsigned short* __restrict__ apid, unsigned short* __restrict__ gwpk,
    unsigned short* __restrict__ apk, unsigned short* __restrict__ bpk,
    float* __restrict__ esc, float* __restrict__ ebi)
{
  int id = blockIdx.x * 256 + threadIdx.x;
  if (id < 147456) {               // cdcm: 36 taps
    int e = id & 7, l = (id >> 3) & 63, mh = (id >> 9) & 1,
        kb = (id >> 10) & 3, tap = id >> 12;
    int d = tap / 9, k9 = tap - 9 * d;
    int m = mh * 32 + (l & 31);
    int c = kb * 16 + (l >> 5) * 8 + e;
    const float* src = (d == 0) ? w5 : (d == 1) ? w7 : (d == 2) ? w9 : w11;
    apack[id] = f2h(src[(m * 64 + c) * 9 + k9]);
    return;
  }
  id -= 147456;
  if (id < 36864) {                // involution conv_w: 9 taps
    int e = id & 7, l = (id >> 3) & 63, mh = (id >> 9) & 1,
        kb = (id >> 10) & 3, tap = id >> 12;
    int m = mh * 32 + (l & 31);
    int c = kb * 16 + (l >> 5) * 8 + e;
    apinv[id] = f2h(cw[(m * 64 + c) * 9 + tap]);
    return;
  }
  id -= 36864;
  if (id < 36864) {                // ensemble mean weights: 9 taps
    int e = id & 7, l = (id >> 3) & 63, mh = (id >> 9) & 1,
        kb = (id >> 10) & 3, tap = id >> 12;
    int m = mh * 32 + (l & 31);
    int c = kb * 16 + (l >> 5) * 8 + e;
    float v = (ensw[((0 * 64 + m) * 64 + c) * 9 + tap] +
               ensw[((64 + m) * 64 + c) * 9 + tap] +
               ensw[((128 + m) * 64 + c) * 9 + tap]) * (1.f / 3.f);
    apens[id] = f2h(v);
    return;
  }
  id -= 36864;
  if (id < 4096) {                 // conv1 1x1
    int e = id & 7, l = (id >> 3) & 63, mh = (id >> 9) & 1, kb = (id >> 10) & 3;
    int m = mh * 32 + (l & 31);
    int c = kb * 16 + (l >> 5) * 8 + e;
    appw1[id] = f2h(w1[m * 64 + c]);
    return;
  }
  id -= 4096;
  if (id < 4096) {                 // dsc pointwise 1x1
    int e = id & 7, l = (id >> 3) & 63, mh = (id >> 9) & 1, kb = (id >> 10) & 3;
    int m = mh * 32 + (l & 31);
    int c = kb * 16 + (l >> 5) * 8 + e;
    appw[id] = f2h(pww[m * 64 + c]);
    return;
  }
  id -= 4096;
  if (id < 4096) {                 // fr 1x1
    int e = id & 7, l = (id >> 3) & 63, mh = (id >> 9) & 1, kb = (id >> 10) & 3;
    int m = mh * 32 + (l & 31);
    int c = kb * 16 + (l >> 5) * 8 + e;
    apfr[id] = f2h(frw[m * 64 + c]);
    return;
  }
  id -= 4096;
  if (id < 4096) {                 // identity (residual via MFMA)
    int e = id & 7, l = (id >> 3) & 63, mh = (id >> 9) & 1, kb = (id >> 10) & 3;
    int m = mh * 32 + (l & 31);
    int c = kb * 16 + (l >> 5) * 8 + e;
    apid[id] = f2h((m == c) ? 1.f : 0.f);
    return;
  }
  id -= 4096;
  if (id < 5184) {                 // packed gw weights [cblk8][tap81][ch8]
    int cblk = id / 648, r = id - cblk * 648;
    int tap = r >> 3, ch = r & 7;
    int c = cblk * 8 + ch;
    gwpk[id] = f2h(gww[c * 81 + tap]);
    return;
  }
  id -= 5184;
  if (id < 576) {                  // packed BN scale [cblk8][o9][ch8]
    int cblk = id / 72, r = id - cblk * 72;
    int o = r >> 3, ch = r & 7;
    int c = cblk * 8 + ch;
    float A = gbg[c * 9 + o] / sqrtf(gbv[c * 9 + o] + EPSV);
    apk[id] = f2h(A);
    return;
  }
  id -= 576;
  if (id < 576) {                  // packed BN shift
    int cblk = id / 72, r = id - cblk * 72;
    int o = r >> 3, ch = r & 7;
    int c = cblk * 8 + ch;
    float A = gbg[c * 9 + o] / sqrtf(gbv[c * 9 + o] + EPSV);
    float B = (gwb[c * 9 + o] - gbm[c * 9 + o]) * A + gbb[c * 9 + o];
    bpk[id] = f2h(B);
    return;
  }
  id -= 576;
  if (id < 64) {                   // final BN fold (+ mean ensemble bias)
    float s = bng[id] / sqrtf(bnv[id] + EPSV);
    esc[id] = s;
    float bm = (ensb[id] + ensb[64 + id] + ensb[128 + id]) * (1.f / 3.f);
    ebi[id] = (bm - bnm[id]) * s + bnb[id];
  }
}

// ---------------- zero border pixels of a blocked-CL padded buffer ----------
__global__ __launch_bounds__(256) void k_zb(unsigned short* __restrict__ buf,
                                            int PD, int pad)
{
  int per_b = 2 * pad * PD + 128 * 2 * pad;
  int id = blockIdx.x * 256 + threadIdx.x;
  int b = id / per_b;
  if (b >= Bn) return;
  int r = id - b * per_b;
  int tb = 2 * pad * PD;
  int row, col;
  if (r < tb) {
    int rr = r / PD; col = r - rr * PD;
    row = (rr < pad) ? rr : (rr + 128);
  } else {
    int r2 = r - tb;
    row = pad + r2 / (2 * pad);
    int cc = r2 - (r2 / (2 * pad)) * (2 * pad);
    col = (cc < pad) ? cc : (cc + 128);
  }
  ushort8v z = {0, 0, 0, 0, 0, 0, 0, 0};
  #pragma unroll
  for (int kb = 0; kb < 4; kb++) {
    unsigned short* p = buf + clb(b, row, kb, col, PD);
    *(ushort8v*)p = z;
    *(ushort8v*)(p + 8) = z;
  }
}

// ---------------- stage 1: conv1x1(relu(x)) via MFMA, planar fp32 in --------
__global__ __launch_bounds__(256, 4) void k_pw1x(const float* __restrict__ x,
    const unsigned short* __restrict__ apw, const float* __restrict__ bias,
    unsigned short* __restrict__ ypad)
{
  int b, h; swz_bh(b, h);
  const int tid = threadIdx.x, wv = tid >> 6, l = tid & 63;
  const int ln31 = l & 31, g = l >> 5;
  const int px = wv * 32 + ln31;
  const float* xb = x + ((size_t)b * Cn) * Pn + h * Wn + px;
  v16f acc0, acc1;
  #pragma unroll
  for (int r = 0; r < 16; r++) { acc0[r] = 0.f; acc1[r] = 0.f; }
  const unsigned short* apl = apw + l * 8;
  #pragma unroll
  for (int kb = 0; kb < 4; kb++) {
    int c0 = kb * 16 + g * 8;
    v8h Bf;
    #pragma unroll
    for (int e = 0; e < 8; e++)
      Bf[e] = (_Float16)fmaxf(xb[(size_t)(c0 + e) * Pn], 0.f);
    v8h A0 = *(const v8h*)(apl + (kb * 2) * 512);
    v8h A1 = *(const v8h*)(apl + (kb * 2 + 1) * 512);
    acc0 = __builtin_amdgcn_mfma_f32_32x32x16_f16(A0, Bf, acc0, 0, 0, 0);
    acc1 = __builtin_amdgcn_mfma_f32_32x32x16_f16(A1, Bf, acc1, 0, 0, 0);
  }
  #pragma unroll
  for (int t = 0; t < 4; t++) {
    int c0 = 8 * t + 4 * g;
    int kb = c0 >> 4, sub = c0 & 15;
    ushort4v s0, s1;
    #pragma unroll
    for (int u = 0; u < 4; u++) {
      s0[u] = f2h(acc0[4 * t + u] + bias[c0 + u]);
      s1[u] = f2h(acc1[4 * t + u] + bias[c0 + u + 32]);
    }
    *(ushort4v*)(ypad + clb(b, h + 11, kb, px + 11, PR) + sub) = s0;
    *(ushort4v*)(ypad + clb(b, h + 11, kb + 2, px + 11, PR) + sub) = s1;
  }
}

// ---------------- stage 2: cdcm via fp16 MFMA + LDS-staged weights ----------
// Per dilation: stage 9 taps x 8KB of A-fragments into LDS (72 KB), then
// all 4 waves read them via ds_read (removes 4/5 of the L2 A-traffic).
__global__ __launch_bounds__(256) void k_cdcm_mfma(
    const unsigned short* __restrict__ ypad,
    const unsigned short* __restrict__ apack,
    unsigned short* __restrict__ spad)
{
  __shared__ __align__(16) unsigned short Abuf[36864];  // 72 KB: 9 taps
  int b, h; swz_bh(b, h);
  const int tid = threadIdx.x, wv = tid >> 6, l = tid & 63;
  const int ln31 = l & 31, g = l >> 5;

  v16f acc0, acc1;
  #pragma unroll
  for (int r = 0; r < 16; r++) { acc0[r] = 0.f; acc1[r] = 0.f; }

  const unsigned short* abl = Abuf + l * 8;

  for (int d = 0; d < 4; d++) {
    __syncthreads();
    {
      const ushort8v* src = (const ushort8v*)(apack + d * 36864);
      ushort8v* dst = (ushort8v*)Abuf;
      #pragma unroll
      for (int it = 0; it < 18; it++)
        dst[tid + it * 256] = src[tid + it * 256];
    }
    __syncthreads();

    const int dil = 5 + 2 * d;
    #pragma unroll
    for (int ky = 0; ky < 3; ky++) {
      const int row = h + 11 + (ky - 1) * dil;
      #pragma unroll
      for (int kx = 0; kx < 3; kx++) {
        const int col = wv * 32 + ln31 + (kx - 1) * dil + 11;
        const int t9 = ky * 3 + kx;
        const unsigned short* ap = abl + t9 * 4096;
        #pragma unroll
        for (int kb = 0; kb < 4; kb++) {
          v8h Bf = *(const v8h*)(ypad + clb(b, row, kb, col, PR) + g * 8);
          v8h A0 = *(const v8h*)(ap + kb * 1024);
          v8h A1 = *(const v8h*)(ap + kb * 1024 + 512);
          acc0 = __builtin_amdgcn_mfma_f32_32x32x16_f16(A0, Bf, acc0, 0, 0, 0);
          acc1 = __builtin_amdgcn_mfma_f32_32x32x16_f16(A1, Bf, acc1, 0, 0, 0);
        }
      }
    }
  }
  const int px = wv * 32 + ln31;
  #pragma unroll
  for (int t = 0; t < 4; t++) {
    int c0 = 8 * t + 4 * g;
    int kb = c0 >> 4, sub = c0 & 15;
    ushort4v s0, s1;
    #pragma unroll
    for (int u = 0; u < 4; u++) {
      s0[u] = f2h(acc0[4 * t + u]);
      s1[u] = f2h(acc1[4 * t + u]);
    }
    *(ushort4v*)(spad + clb(b, h + 1, kb, px + 1, PE) + sub) = s0;
    *(ushort4v*)(spad + clb(b, h + 1, kb + 2, px + 1, PE) + sub) = s1;
  }
}

// ---------------- stage 3: depthwise (VALU) + pointwise (MFMA) --------------
__global__ __launch_bounds__(256, 4) void k_dwpw_mfma(
    const unsigned short* __restrict__ spad,
    const float* __restrict__ dww, const float* __restrict__ dwb,
    const unsigned short* __restrict__ appw, const float* __restrict__ pwb,
    unsigned short* __restrict__ y2pad)
{
  __shared__ float wdw[576];
  __shared__ float bdw[64];
  const int tid = threadIdx.x;
  for (int t = tid; t < 576; t += 256) wdw[t] = dww[t];
  if (tid < 64) bdw[tid] = dwb[tid];
  __syncthreads();

  int b, h; swz_bh(b, h);
  const int wv = tid >> 6, l = tid & 63;
  const int ln31 = l & 31, g = l >> 5;
  const int w = wv * 32 + ln31;

  v16f acc0, acc1;
  #pragma unroll
  for (int r = 0; r < 16; r++) { acc0[r] = 0.f; acc1[r] = 0.f; }
  const unsigned short* apl = appw + l * 8;

  #pragma unroll
  for (int kb = 0; kb < 4; kb++) {
    const int c0 = kb * 16 + g * 8;
    v8h t[9];
    #pragma unroll
    for (int k = 0; k < 9; k++) {
      const int dy = k / 3 - 1, dx = k % 3 - 1;
      t[k] = *(const v8h*)(spad + clb(b, h + 1 + dy, kb, w + 1 + dx, PE) + g * 8);
    }
    v8h dvh;
    #pragma unroll
    for (int e = 0; e < 8; e++) {
      const int c = c0 + e;
      float a = 4.f * bdw[c];
      #pragma unroll
      for (int k = 0; k < 9; k++) a += wdw[c * 9 + k] * (float)t[k][e];
      dvh[e] = (_Float16)a;
    }
    v8h A0 = *(const v8h*)(apl + (kb * 2) * 512);
    v8h A1 = *(const v8h*)(apl + (kb * 2 + 1) * 512);
    acc0 = __builtin_amdgcn_mfma_f32_32x32x16_f16(A0, dvh, acc0, 0, 0, 0);
    acc1 = __builtin_amdgcn_mfma_f32_32x32x16_f16(A1, dvh, acc1, 0, 0, 0);
  }
  #pragma unroll
  for (int t = 0; t < 4; t++) {
    int c0 = 8 * t + 4 * g;
    int kb = c0 >> 4, sub = c0 & 15;
    ushort4v s0, s1;
    #pragma unroll
    for (int u = 0; u < 4; u++) {
      s0[u] = f2h(acc0[4 * t + u] + 4.f * pwb[c0 + u]);
      s1[u] = f2h(acc1[4 * t + u] + 4.f * pwb[c0 + u + 32]);
    }
    *(ushort4v*)(y2pad + clb(b, h + 1, kb, w + 1, PE) + sub) = s0;
    *(ushort4v*)(y2pad + clb(b, h + 1, kb + 2, w + 1, PE) + sub) = s1;
  }
}

// ---------------- stage 4: involution, packed-fp16 softmax + MFMA -----------
__global__ __launch_bounds__(256, 3) void k_invol_mfma(
    const unsigned short* __restrict__ y2pad,
    const unsigned short* __restrict__ gwpk,
    const unsigned short* __restrict__ apk,
    const unsigned short* __restrict__ bpk,
    const unsigned short* __restrict__ apinv,
    const float* __restrict__ cbias,
    unsigned short* __restrict__ ipad)
{
  __shared__ __align__(16) unsigned short gws[5184];  // [cblk8][tap81][ch8]
  __shared__ __align__(16) unsigned short As[576];    // [cblk8][o9][ch8]
  __shared__ __align__(16) unsigned short Bs[576];
  const int tid = threadIdx.x;
  for (int t = tid; t < 648; t += 256)
    ((ushort8v*)gws)[t] = ((const ushort8v*)gwpk)[t];
  if (tid < 72) {
    ((ushort8v*)As)[tid] = ((const ushort8v*)apk)[tid];
    ((ushort8v*)Bs)[tid] = ((const ushort8v*)bpk)[tid];
  }
  __syncthreads();

  int b, h; swz_bh(b, h);
  const int wv = tid >> 6, l = tid & 63;
  const int p32 = l & 31, g = l >> 5;
  const int w = wv * 32 + p32;

  v16f acc0, acc1;
  #pragma unroll
  for (int r = 0; r < 16; r++) { acc0[r] = 0.f; acc1[r] = 0.f; }

  for (int cb4 = 0; cb4 < 4; cb4++) {
    const int cblk = cb4 * 2 + g;
    const unsigned short* gwp = gws + cblk * 648;
    const unsigned short* Ap = As + cblk * 72;
    const unsigned short* Bp = Bs + cblk * 72;

    v8h pt[9];
    #pragma unroll
    for (int k = 0; k < 9; k++) {
      const int dy = k / 3 - 1, dx = k % 3 - 1;
      pt[k] = *(const v8h*)(y2pad + clb(b, h + 1 + dy, cb4, w + 1 + dx, PE) + g * 8);
    }
    // gw matmul + BN, all packed fp16 (weights broadcast from LDS)
    v8h s[9];
    #pragma unroll
    for (int o = 0; o < 9; o++) {
      v8h a = (*(const v8h*)(gwp + o * 72)) * pt[0];
      #pragma unroll
      for (int i = 1; i < 9; i++)
        a += (*(const v8h*)(gwp + o * 72 + i * 8)) * pt[i];
      s[o] = a * (*(const v8h*)(Ap + o * 8)) + (*(const v8h*)(Bp + o * 8));
    }
    // softmax over the 9 taps (shift-free: |s| << 1, fp16-safe)
    v8h esum = {0, 0, 0, 0, 0, 0, 0, 0};
    #pragma unroll
    for (int o = 0; o < 9; o++) { s[o] = exp8h(s[o]); esum += s[o]; }
    v8h inv = rcp8h(esum);
    #pragma unroll
    for (int k = 0; k < 9; k++) pt[k] = pt[k] * s[k] * inv;

    const unsigned short* ap = apinv + l * 8;
    #pragma unroll
    for (int k = 0; k < 9; k++) {
      const unsigned short* a2 = ap + ((k * 4 + cb4) * 2) * 512;
      v8h A0 = *(const v8h*)(a2);
      v8h A1 = *(const v8h*)(a2 + 512);
      acc0 = __builtin_amdgcn_mfma_f32_32x32x16_f16(A0, pt[k], acc0, 0, 0, 0);
      acc1 = __builtin_amdgcn_mfma_f32_32x32x16_f16(A1, pt[k], acc1, 0, 0, 0);
    }
  }
  #pragma unroll
  for (int t = 0; t < 4; t++) {
    int c0 = 8 * t + 4 * g;
    int kb = c0 >> 4, sub = c0 & 15;
    ushort4v s0, s1;
    #pragma unroll
    for (int u = 0; u < 4; u++) {
      s0[u] = f2h(acc0[4 * t + u] + cbias[c0 + u]);
      s1[u] = f2h(acc1[4 * t + u] + cbias[c0 + u + 32]);
    }
    *(ushort4v*)(ipad + clb(b, h, kb, w, 128) + sub) = s0;
    *(ushort4v*)(ipad + clb(b, h, kb + 2, w, 128) + sub) = s1;
  }
}

// ---------------- stage 5: fr 1x1 + residual (identity MFMA) ----------------
__global__ __launch_bounds__(256, 4) void k_fr_mfma(
    const unsigned short* __restrict__ ipad,
    const unsigned short* __restrict__ apfr,
    const unsigned short* __restrict__ apid,
    const float* __restrict__ bias,
    unsigned short* __restrict__ opad)
{
  int b, h; swz_bh(b, h);
  const int tid = threadIdx.x, wv = tid >> 6, l = tid & 63;
  const int ln31 = l & 31, g = l >> 5;
  const int px = wv * 32 + ln31;
  v16f acc0, acc1;
  #pragma unroll
  for (int r = 0; r < 16; r++) { acc0[r] = 0.f; acc1[r] = 0.f; }
  const unsigned short* apl = apfr + l * 8;
  const unsigned short* idl = apid + l * 8;
  #pragma unroll
  for (int kb = 0; kb < 4; kb++) {
    v8h Bf = *(const v8h*)(ipad + clb(b, h, kb, px, 128) + g * 8);
    v8h A0 = *(const v8h*)(apl + (kb * 2) * 512);
    v8h A1 = *(const v8h*)(apl + (kb * 2 + 1) * 512);
    v8h I0 = *(const v8h*)(idl + (kb * 2) * 512);
    v8h I1 = *(const v8h*)(idl + (kb * 2 + 1) * 512);
    acc0 = __builtin_amdgcn_mfma_f32_32x32x16_f16(A0, Bf, acc0, 0, 0, 0);
    acc1 = __builtin_amdgcn_mfma_f32_32x32x16_f16(A1, Bf, acc1, 0, 0, 0);
    acc0 = __builtin_amdgcn_mfma_f32_32x32x16_f16(I0, Bf, acc0, 0, 0, 0);
    acc1 = __builtin_amdgcn_mfma_f32_32x32x16_f16(I1, Bf, acc1, 0, 0, 0);
  }
  #pragma unroll
  for (int t = 0; t < 4; t++) {
    int c0 = 8 * t + 4 * g;
    int kb = c0 >> 4, sub = c0 & 15;
    ushort4v s0, s1;
    #pragma unroll
    for (int u = 0; u < 4; u++) {
      s0[u] = f2h(acc0[4 * t + u] + bias[c0 + u]);
      s1[u] = f2h(acc1[4 * t + u] + bias[c0 + u + 32]);
    }
    *(ushort4v*)(opad + clb(b, h + 1, kb, px + 1, PE) + sub) = s0;
    *(ushort4v*)(opad + clb(b, h + 1, kb + 2, px + 1, PE) + sub) = s1;
  }
}

// ---------------- stage 6: ensemble conv3x3 via MFMA + LDS weights ----------
__global__ __launch_bounds__(256) void k_ens_mfma(
    const unsigned short* __restrict__ opad,
    const unsigned short* __restrict__ apens,
    const float* __restrict__ esc, const float* __restrict__ ebi,
    float* __restrict__ out)
{
  __shared__ __align__(16) unsigned short Abuf[36864];  // 72 KB: 9 taps
  const int tid = threadIdx.x;
  {
    const ushort8v* src = (const ushort8v*)apens;
    ushort8v* dst = (ushort8v*)Abuf;
    #pragma unroll
    for (int it = 0; it < 18; it++)
      dst[tid + it * 256] = src[tid + it * 256];
  }
  __syncthreads();

  int b, h; swz_bh(b, h);
  const int wv = tid >> 6, l = tid & 63;
  const int ln31 = l & 31, g = l >> 5;

  v16f acc0, acc1;
  #pragma unroll
  for (int r = 0; r < 16; r++) { acc0[r] = 0.f; acc1[r] = 0.f; }

  const unsigned short* abl = Abuf + l * 8;

  #pragma unroll
  for (int ky = 0; ky < 3; ky++) {
    #pragma unroll
    for (int kx = 0; kx < 3; kx++) {
      const int tap = ky * 3 + kx;
      const int row = h + ky;              // (h+1) + (ky-1)
      const int col = wv * 32 + ln31 + kx; // (+1) + (kx-1)
      const unsigned short* ap = abl + tap * 4096;
      #pragma unroll
      for (int kb = 0; kb < 4; kb++) {
        v8h Bf = *(const v8h*)(opad + clb(b, row, kb, col, PE) + g * 8);
        v8h A0 = *(const v8h*)(ap + kb * 1024);
        v8h A1 = *(const v8h*)(ap + kb * 1024 + 512);
        acc0 = __builtin_amdgcn_mfma_f32_32x32x16_f16(A0, Bf, acc0, 0, 0, 0);
        acc1 = __builtin_amdgcn_mfma_f32_32x32x16_f16(A1, Bf, acc1, 0, 0, 0);
      }
    }
  }
  float* sp = out + ((size_t)b * Cn) * Pn + h * Wn + wv * 32 + ln31;
  #pragma unroll
  for (int r = 0; r < 16; r++) {
    int o0 = (r & 3) + 8 * (r >> 2) + 4 * g;
    float v0 = acc0[r] * esc[o0] + ebi[o0];
    float v1 = acc1[r] * esc[o0 + 32] + ebi[o0 + 32];
    sp[(size_t)o0 * Pn] = fmaxf(v0, 0.f);
    sp[(size_t)(o0 + 32) * Pn] = fmaxf(v1, 0.f);
  }
}

extern "C" void kernel_launch(void* const* d_in, const int* in_sizes, int n_in,
                              void* d_out, int out_size, void* d_ws, size_t ws_size,
                              hipStream_t stream)
{
  const float* x    = (const float*)d_in[0];
  const float* w1   = (const float*)d_in[1];
  const float* b1   = (const float*)d_in[2];
  const float* w5   = (const float*)d_in[3];
  const float* w7   = (const float*)d_in[4];
  const float* w9   = (const float*)d_in[5];
  const float* w11  = (const float*)d_in[6];
  const float* dww  = (const float*)d_in[7];
  const float* dwb  = (const float*)d_in[8];
  const float* pww  = (const float*)d_in[9];
  const float* pwb  = (const float*)d_in[10];
  const float* gww  = (const float*)d_in[11];
  const float* gwb  = (const float*)d_in[12];
  const float* gbg  = (const float*)d_in[13];
  const float* gbb  = (const float*)d_in[14];
  const float* gbm  = (const float*)d_in[15];
  const float* gbv  = (const float*)d_in[16];
  const float* cw   = (const float*)d_in[17];
  const float* cb   = (const float*)d_in[18];
  const float* frw  = (const float*)d_in[19];
  const float* frb  = (const float*)d_in[20];
  const float* ensw = (const float*)d_in[21];
  const float* ensb = (const float*)d_in[22];
  const float* bng  = (const float*)d_in[23];
  const float* bnb  = (const float*)d_in[24];
  const float* bnm  = (const float*)d_in[25];
  const float* bnv  = (const float*)d_in[26];

  // ws: ypad (pad-11) region, overlaid later by y2pad then opad (pad-1)
  unsigned short* wsu   = (unsigned short*)d_ws;
  unsigned short* ypad  = wsu;
  unsigned short* y2pad = wsu;
  unsigned short* opad  = wsu;
  unsigned short* apack = wsu + YPAD_ELEMS;         // 147456
  unsigned short* apinv = apack + 147456;           // 36864
  unsigned short* apens = apinv + 36864;            // 36864
  unsigned short* appw1 = apens + 36864;            // 4096
  unsigned short* appw  = appw1 + 4096;             // 4096
  unsigned short* apfr  = appw + 4096;              // 4096
  unsigned short* apid  = apfr + 4096;              // 4096
  unsigned short* gwpk  = apid + 4096;              // 5184
  unsigned short* apk   = gwpk + 5184;              // 576
  unsigned short* bpk   = apk + 576;                // 576
  float* esc = (float*)(bpk + 576);                 // 64
  float* ebi = esc + 64;                            // 64

  // d_out: spad (fp16 blocked-CL pad-1) -> ipad (blocked-CL) -> planar fp32
  unsigned short* spad = (unsigned short*)d_out;
  unsigned short* ipad = (unsigned short*)d_out;
  float* D = (float*)d_out;

  k_prep<<<953, 256, 0, stream>>>(w1, w5, w7, w9, w11, pww, frw, cw,
                                  gww, gwb, gbg, gbb, gbm, gbv, ensw, ensb,
                                  bng, bnb, bnm, bnv,
                                  apack, apinv, apens, appw1, appw, apfr, apid,
                                  gwpk, apk, bpk, esc, ebi);
  // border zeros that are safe now: ypad (ws, pad 11), spad (d_out, pad 1)
  k_zb<<<192, 256, 0, stream>>>(ypad, PR, 11);
  k_zb<<<17, 256, 0, stream>>>(spad, PE, 1);

  // 1) ypad = conv1x1(relu(x))           x (planar f32) -> ypad (blocked CL)
  k_pw1x<<<1024, 256, 0, stream>>>(x, appw1, b1, ypad);
  // 2) spad = sum_d dilconv_d(y)         ypad -> spad (d_out, pad-1)
  k_cdcm_mfma<<<1024, 256, 0, stream>>>(ypad, apack, spad);
  // ws region now dead (ypad fully consumed): zero pad-1 borders for
  // y2pad/opad. These borders survive stages 3-5 (interior-only writes).
  k_zb<<<17, 256, 0, stream>>>(y2pad, PE, 1);
  // 3) y2pad = PW(DW(spad))              spad -> y2pad (ws, pad-1)
  k_dwpw_mfma<<<1024, 256, 0, stream>>>(spad, dww, dwb, appw, pwb, y2pad);
  // 4) ipad = involution(y2pad)          y2pad -> ipad (d_out)
  k_invol_mfma<<<1024, 256, 0, stream>>>(y2pad, gwpk, apk, bpk, apinv, cb, ipad);
  // 5) opad = fr(ipad) + ipad            ipad -> opad (ws, pad-1)
  k_fr_mfma<<<1024, 256, 0, stream>>>(ipad, apfr, apid, frb, opad);
  // 6) out = relu(BN(ens3x3(opad)))      opad -> D (planar fp32)
  k_ens_mfma<<<1024, 256, 0, stream>>>(opad, apens, esc, ebi, D);
}

// Round 10
// 164.683 us; speedup vs baseline: 14.1619x; 1.0112x over previous
//
#include <hip/hip_runtime.h>
#include <hip/hip_bf16.h>
#include <hip/hip_fp16.h>

#define EPSV 1e-5f
#define Bn 8
#define Cn 64
#define Hn 128
#define Wn 128
#define Pn (Hn*Wn)          // 16384
#define PR 150              // cdcm pad: 11 + 128 + 11
#define PE 130              // 1-pad: 1 + 128 + 1
#define YPAD_ELEMS (Bn*PR*PR*Cn)   // 11,520,000 fp16

typedef _Float16 v8h __attribute__((ext_vector_type(8)));
typedef float v16f __attribute__((ext_vector_type(16)));
typedef unsigned short ushort8v __attribute__((ext_vector_type(8)));
typedef unsigned short ushort4v __attribute__((ext_vector_type(4)));

__device__ __forceinline__ unsigned short f2h(float v) {
  _Float16 h = (_Float16)v;
  return *reinterpret_cast<const unsigned short*>(&h);
}
__device__ __forceinline__ float h2f(unsigned short u) {
  return (float)(*reinterpret_cast<const _Float16*>(&u));
}

__device__ __forceinline__ v8h exp8h(v8h x) {
  union { v8h v; __half2 h[4]; } u; u.v = x;
  #pragma unroll
  for (int i = 0; i < 4; i++) u.h[i] = h2exp(u.h[i]);
  return u.v;
}
__device__ __forceinline__ v8h rcp8h(v8h x) {
  union { v8h v; __half2 h[4]; } u; u.v = x;
  #pragma unroll
  for (int i = 0; i < 4; i++) u.h[i] = h2rcp(u.h[i]);
  return u.v;
}

// channel-blocked CL addressing: [b][row][kb(4)][col][16], elems
__device__ __forceinline__ size_t clb(int b, int row, int kb, int col, int PD) {
  return ((((size_t)b * PD + row) * 4 + kb) * PD + col) * 16;
}

// batch-major XCD swizzle: 1024 blocks, XCD r gets batch r's rows in order
__device__ __forceinline__ void swz_bh(int& b, int& h) {
  int bid = blockIdx.x;
  int w = (bid & 7) * 128 + (bid >> 3);
  b = w >> 7; h = w & 127;
}

// ---------------- prep: weight packs + BN folds ----------------
// A-pack layout: [tap][kb][mh][lane*8+e], m=mh*32+(l&31), c=kb*16+(l>>5)*8+e
__global__ __launch_bounds__(256) void k_prep(
    const float* __restrict__ w1, const float* __restrict__ w5,
    const float* __restrict__ w7, const float* __restrict__ w9,
    const float* __restrict__ w11, const float* __restrict__ pww,
    const float* __restrict__ frw, const float* __restrict__ cw,
    const float* __restrict__ gww, const float* __restrict__ gwb,
    const float* __restrict__ gbg, const float* __restrict__ gbb,
    const float* __restrict__ gbm, const float* __restrict__ gbv,
    const float* __restrict__ ensw, const float* __restrict__ ensb,
    const float* __restrict__ bng, const float* __restrict__ bnb,
    const float* __restrict__ bnm, const float* __restrict__ bnv,
    unsigned short* __restrict__ apack, unsigned short* __restrict__ apinv,
    unsigned short* __restrict__ apens, unsigned short* __restrict__ appw1,
    unsigned short* __restrict__ appw, unsigned short* __restrict__ apfr,
    unsigned short* __restrict__ gwpk,
    unsigned short* __restrict__ apk, unsigned short* __restrict__ bpk,
    float* __restrict__ esc, float* __restrict__ ebi)
{
  int id = blockIdx.x * 256 + threadIdx.x;
  if (id < 147456) {               // cdcm: 36 taps
    int e = id & 7, l = (id >> 3) & 63, mh = (id >> 9) & 1,
        kb = (id >> 10) & 3, tap = id >> 12;
    int d = tap / 9, k9 = tap - 9 * d;
    int m = mh * 32 + (l & 31);
    int c = kb * 16 + (l >> 5) * 8 + e;
    const float* src = (d == 0) ? w5 : (d == 1) ? w7 : (d == 2) ? w9 : w11;
    apack[id] = f2h(src[(m * 64 + c) * 9 + k9]);
    return;
  }
  id -= 147456;
  if (id < 36864) {                // involution conv_w: 9 taps
    int e = id & 7, l = (id >> 3) & 63, mh = (id >> 9) & 1,
        kb = (id >> 10) & 3, tap = id >> 12;
    int m = mh * 32 + (l & 31);
    int c = kb * 16 + (l >> 5) * 8 + e;
    apinv[id] = f2h(cw[(m * 64 + c) * 9 + tap]);
    return;
  }
  id -= 36864;
  if (id < 36864) {                // ensemble mean weights: 9 taps
    int e = id & 7, l = (id >> 3) & 63, mh = (id >> 9) & 1,
        kb = (id >> 10) & 3, tap = id >> 12;
    int m = mh * 32 + (l & 31);
    int c = kb * 16 + (l >> 5) * 8 + e;
    float v = (ensw[((0 * 64 + m) * 64 + c) * 9 + tap] +
               ensw[((64 + m) * 64 + c) * 9 + tap] +
               ensw[((128 + m) * 64 + c) * 9 + tap]) * (1.f / 3.f);
    apens[id] = f2h(v);
    return;
  }
  id -= 36864;
  if (id < 4096) {                 // conv1 1x1
    int e = id & 7, l = (id >> 3) & 63, mh = (id >> 9) & 1, kb = (id >> 10) & 3;
    int m = mh * 32 + (l & 31);
    int c = kb * 16 + (l >> 5) * 8 + e;
    appw1[id] = f2h(w1[m * 64 + c]);
    return;
  }
  id -= 4096;
  if (id < 4096) {                 // dsc pointwise 1x1
    int e = id & 7, l = (id >> 3) & 63, mh = (id >> 9) & 1, kb = (id >> 10) & 3;
    int m = mh * 32 + (l & 31);
    int c = kb * 16 + (l >> 5) * 8 + e;
    appw[id] = f2h(pww[m * 64 + c]);
    return;
  }
  id -= 4096;
  if (id < 4096) {                 // fr 1x1
    int e = id & 7, l = (id >> 3) & 63, mh = (id >> 9) & 1, kb = (id >> 10) & 3;
    int m = mh * 32 + (l & 31);
    int c = kb * 16 + (l >> 5) * 8 + e;
    apfr[id] = f2h(frw[m * 64 + c]);
    return;
  }
  id -= 4096;
  if (id < 5184) {                 // packed gw weights [cblk8][tap81][ch8]
    int cblk = id / 648, r = id - cblk * 648;
    int tap = r >> 3, ch = r & 7;
    int c = cblk * 8 + ch;
    gwpk[id] = f2h(gww[c * 81 + tap]);
    return;
  }
  id -= 5184;
  if (id < 576) {                  // packed BN scale [cblk8][o9][ch8]
    int cblk = id / 72, r = id - cblk * 72;
    int o = r >> 3, ch = r & 7;
    int c = cblk * 8 + ch;
    float A = gbg[c * 9 + o] / sqrtf(gbv[c * 9 + o] + EPSV);
    apk[id] = f2h(A);
    return;
  }
  id -= 576;
  if (id < 576) {                  // packed BN shift
    int cblk = id / 72, r = id - cblk * 72;
    int o = r >> 3, ch = r & 7;
    int c = cblk * 8 + ch;
    float A = gbg[c * 9 + o] / sqrtf(gbv[c * 9 + o] + EPSV);
    float B = (gwb[c * 9 + o] - gbm[c * 9 + o]) * A + gbb[c * 9 + o];
    bpk[id] = f2h(B);
    return;
  }
  id -= 576;
  if (id < 64) {                   // final BN fold (+ mean ensemble bias)
    float s = bng[id] / sqrtf(bnv[id] + EPSV);
    esc[id] = s;
    float bm = (ensb[id] + ensb[64 + id] + ensb[128 + id]) * (1.f / 3.f);
    ebi[id] = (bm - bnm[id]) * s + bnb[id];
  }
}

// ---------------- zero border pixels of a blocked-CL padded buffer ----------
__global__ __launch_bounds__(256) void k_zb(unsigned short* __restrict__ buf,
                                            int PD, int pad)
{
  int per_b = 2 * pad * PD + 128 * 2 * pad;
  int id = blockIdx.x * 256 + threadIdx.x;
  int b = id / per_b;
  if (b >= Bn) return;
  int r = id - b * per_b;
  int tb = 2 * pad * PD;
  int row, col;
  if (r < tb) {
    int rr = r / PD; col = r - rr * PD;
    row = (rr < pad) ? rr : (rr + 128);
  } else {
    int r2 = r - tb;
    row = pad + r2 / (2 * pad);
    int cc = r2 - (r2 / (2 * pad)) * (2 * pad);
    col = (cc < pad) ? cc : (cc + 128);
  }
  ushort8v z = {0, 0, 0, 0, 0, 0, 0, 0};
  #pragma unroll
  for (int kb = 0; kb < 4; kb++) {
    unsigned short* p = buf + clb(b, row, kb, col, PD);
    *(ushort8v*)p = z;
    *(ushort8v*)(p + 8) = z;
  }
}

// ---------------- stage 1: conv1x1(relu(x)) via MFMA, planar fp32 in --------
__global__ __launch_bounds__(256, 4) void k_pw1x(const float* __restrict__ x,
    const unsigned short* __restrict__ apw, const float* __restrict__ bias,
    unsigned short* __restrict__ ypad)
{
  int b, h; swz_bh(b, h);
  const int tid = threadIdx.x, wv = tid >> 6, l = tid & 63;
  const int ln31 = l & 31, g = l >> 5;
  const int px = wv * 32 + ln31;
  const float* xb = x + ((size_t)b * Cn) * Pn + h * Wn + px;
  v16f acc0, acc1;
  #pragma unroll
  for (int r = 0; r < 16; r++) { acc0[r] = 0.f; acc1[r] = 0.f; }
  const unsigned short* apl = apw + l * 8;
  #pragma unroll
  for (int kb = 0; kb < 4; kb++) {
    int c0 = kb * 16 + g * 8;
    v8h Bf;
    #pragma unroll
    for (int e = 0; e < 8; e++)
      Bf[e] = (_Float16)fmaxf(xb[(size_t)(c0 + e) * Pn], 0.f);
    v8h A0 = *(const v8h*)(apl + (kb * 2) * 512);
    v8h A1 = *(const v8h*)(apl + (kb * 2 + 1) * 512);
    acc0 = __builtin_amdgcn_mfma_f32_32x32x16_f16(A0, Bf, acc0, 0, 0, 0);
    acc1 = __builtin_amdgcn_mfma_f32_32x32x16_f16(A1, Bf, acc1, 0, 0, 0);
  }
  #pragma unroll
  for (int t = 0; t < 4; t++) {
    int c0 = 8 * t + 4 * g;
    int kb = c0 >> 4, sub = c0 & 15;
    ushort4v s0, s1;
    #pragma unroll
    for (int u = 0; u < 4; u++) {
      s0[u] = f2h(acc0[4 * t + u] + bias[c0 + u]);
      s1[u] = f2h(acc1[4 * t + u] + bias[c0 + u + 32]);
    }
    *(ushort4v*)(ypad + clb(b, h + 11, kb, px + 11, PR) + sub) = s0;
    *(ushort4v*)(ypad + clb(b, h + 11, kb + 2, px + 11, PR) + sub) = s1;
  }
}

// ---------------- stage 2: cdcm, 2 rows/block, LDS-staged weights -----------
// grid 512: bid&7 = batch (XCD), bid>>3 = row-pair. Each A ds_read feeds
// 4 MFMAs (2 rows x 2 out-halves) -> LDS read traffic halved vs 1-row.
__global__ __launch_bounds__(256) void k_cdcm_mfma(
    const unsigned short* __restrict__ ypad,
    const unsigned short* __restrict__ apack,
    unsigned short* __restrict__ spad)
{
  __shared__ __align__(16) unsigned short Abuf[36864];  // 72 KB: 9 taps
  const int bid = blockIdx.x;
  const int b = bid & 7, h0 = (bid >> 3) * 2;
  const int tid = threadIdx.x, wv = tid >> 6, l = tid & 63;
  const int ln31 = l & 31, g = l >> 5;

  v16f a00, a01, a10, a11;   // [row][out-half]
  #pragma unroll
  for (int r = 0; r < 16; r++) { a00[r] = 0.f; a01[r] = 0.f; a10[r] = 0.f; a11[r] = 0.f; }

  const unsigned short* abl = Abuf + l * 8;

  for (int d = 0; d < 4; d++) {
    __syncthreads();
    {
      const ushort8v* src = (const ushort8v*)(apack + d * 36864);
      ushort8v* dst = (ushort8v*)Abuf;
      #pragma unroll
      for (int it = 0; it < 18; it++)
        dst[tid + it * 256] = src[tid + it * 256];
    }
    __syncthreads();

    const int dil = 5 + 2 * d;
    #pragma unroll
    for (int ky = 0; ky < 3; ky++) {
      const int r0 = h0 + 11 + (ky - 1) * dil;
      #pragma unroll
      for (int kx = 0; kx < 3; kx++) {
        const int col = wv * 32 + ln31 + (kx - 1) * dil + 11;
        const int t9 = ky * 3 + kx;
        const unsigned short* ap = abl + t9 * 4096;
        #pragma unroll
        for (int kb = 0; kb < 4; kb++) {
          v8h B0 = *(const v8h*)(ypad + clb(b, r0, kb, col, PR) + g * 8);
          v8h B1 = *(const v8h*)(ypad + clb(b, r0 + 1, kb, col, PR) + g * 8);
          v8h A0 = *(const v8h*)(ap + kb * 1024);
          v8h A1 = *(const v8h*)(ap + kb * 1024 + 512);
          a00 = __builtin_amdgcn_mfma_f32_32x32x16_f16(A0, B0, a00, 0, 0, 0);
          a01 = __builtin_amdgcn_mfma_f32_32x32x16_f16(A1, B0, a01, 0, 0, 0);
          a10 = __builtin_amdgcn_mfma_f32_32x32x16_f16(A0, B1, a10, 0, 0, 0);
          a11 = __builtin_amdgcn_mfma_f32_32x32x16_f16(A1, B1, a11, 0, 0, 0);
        }
      }
    }
  }
  const int px = wv * 32 + ln31;
  #pragma unroll
  for (int t = 0; t < 4; t++) {
    int c0 = 8 * t + 4 * g;
    int kb = c0 >> 4, sub = c0 & 15;
    ushort4v s0, s1, s2, s3;
    #pragma unroll
    for (int u = 0; u < 4; u++) {
      s0[u] = f2h(a00[4 * t + u]);
      s1[u] = f2h(a01[4 * t + u]);
      s2[u] = f2h(a10[4 * t + u]);
      s3[u] = f2h(a11[4 * t + u]);
    }
    *(ushort4v*)(spad + clb(b, h0 + 1, kb, px + 1, PE) + sub) = s0;
    *(ushort4v*)(spad + clb(b, h0 + 1, kb + 2, px + 1, PE) + sub) = s1;
    *(ushort4v*)(spad + clb(b, h0 + 2, kb, px + 1, PE) + sub) = s2;
    *(ushort4v*)(spad + clb(b, h0 + 2, kb + 2, px + 1, PE) + sub) = s3;
  }
}

// ---------------- stage 3: depthwise (VALU) + pointwise (MFMA) --------------
__global__ __launch_bounds__(256, 4) void k_dwpw_mfma(
    const unsigned short* __restrict__ spad,
    const float* __restrict__ dww, const float* __restrict__ dwb,
    const unsigned short* __restrict__ appw, const float* __restrict__ pwb,
    unsigned short* __restrict__ y2pad)
{
  __shared__ float wdw[576];
  __shared__ float bdw[64];
  const int tid = threadIdx.x;
  for (int t = tid; t < 576; t += 256) wdw[t] = dww[t];
  if (tid < 64) bdw[tid] = dwb[tid];
  __syncthreads();

  int b, h; swz_bh(b, h);
  const int wv = tid >> 6, l = tid & 63;
  const int ln31 = l & 31, g = l >> 5;
  const int w = wv * 32 + ln31;

  v16f acc0, acc1;
  #pragma unroll
  for (int r = 0; r < 16; r++) { acc0[r] = 0.f; acc1[r] = 0.f; }
  const unsigned short* apl = appw + l * 8;

  #pragma unroll
  for (int kb = 0; kb < 4; kb++) {
    const int c0 = kb * 16 + g * 8;
    v8h t[9];
    #pragma unroll
    for (int k = 0; k < 9; k++) {
      const int dy = k / 3 - 1, dx = k % 3 - 1;
      t[k] = *(const v8h*)(spad + clb(b, h + 1 + dy, kb, w + 1 + dx, PE) + g * 8);
    }
    v8h dvh;
    #pragma unroll
    for (int e = 0; e < 8; e++) {
      const int c = c0 + e;
      float a = 4.f * bdw[c];
      #pragma unroll
      for (int k = 0; k < 9; k++) a += wdw[c * 9 + k] * (float)t[k][e];
      dvh[e] = (_Float16)a;
    }
    v8h A0 = *(const v8h*)(apl + (kb * 2) * 512);
    v8h A1 = *(const v8h*)(apl + (kb * 2 + 1) * 512);
    acc0 = __builtin_amdgcn_mfma_f32_32x32x16_f16(A0, dvh, acc0, 0, 0, 0);
    acc1 = __builtin_amdgcn_mfma_f32_32x32x16_f16(A1, dvh, acc1, 0, 0, 0);
  }
  #pragma unroll
  for (int t = 0; t < 4; t++) {
    int c0 = 8 * t + 4 * g;
    int kb = c0 >> 4, sub = c0 & 15;
    ushort4v s0, s1;
    #pragma unroll
    for (int u = 0; u < 4; u++) {
      s0[u] = f2h(acc0[4 * t + u] + 4.f * pwb[c0 + u]);
      s1[u] = f2h(acc1[4 * t + u] + 4.f * pwb[c0 + u + 32]);
    }
    *(ushort4v*)(y2pad + clb(b, h + 1, kb, w + 1, PE) + sub) = s0;
    *(ushort4v*)(y2pad + clb(b, h + 1, kb + 2, w + 1, PE) + sub) = s1;
  }
}

// ---------------- stage 4: involution, packed-fp16 softmax + MFMA -----------
__global__ __launch_bounds__(256, 3) void k_invol_mfma(
    const unsigned short* __restrict__ y2pad,
    const unsigned short* __restrict__ gwpk,
    const unsigned short* __restrict__ apk,
    const unsigned short* __restrict__ bpk,
    const unsigned short* __restrict__ apinv,
    const float* __restrict__ cbias,
    unsigned short* __restrict__ ipad)
{
  __shared__ __align__(16) unsigned short gws[5184];  // [cblk8][tap81][ch8]
  __shared__ __align__(16) unsigned short As[576];    // [cblk8][o9][ch8]
  __shared__ __align__(16) unsigned short Bs[576];
  const int tid = threadIdx.x;
  for (int t = tid; t < 648; t += 256)
    ((ushort8v*)gws)[t] = ((const ushort8v*)gwpk)[t];
  if (tid < 72) {
    ((ushort8v*)As)[tid] = ((const ushort8v*)apk)[tid];
    ((ushort8v*)Bs)[tid] = ((const ushort8v*)bpk)[tid];
  }
  __syncthreads();

  int b, h; swz_bh(b, h);
  const int wv = tid >> 6, l = tid & 63;
  const int p32 = l & 31, g = l >> 5;
  const int w = wv * 32 + p32;

  v16f acc0, acc1;
  #pragma unroll
  for (int r = 0; r < 16; r++) { acc0[r] = 0.f; acc1[r] = 0.f; }

  for (int cb4 = 0; cb4 < 4; cb4++) {
    const int cblk = cb4 * 2 + g;
    const unsigned short* gwp = gws + cblk * 648;
    const unsigned short* Ap = As + cblk * 72;
    const unsigned short* Bp = Bs + cblk * 72;

    v8h pt[9];
    #pragma unroll
    for (int k = 0; k < 9; k++) {
      const int dy = k / 3 - 1, dx = k % 3 - 1;
      pt[k] = *(const v8h*)(y2pad + clb(b, h + 1 + dy, cb4, w + 1 + dx, PE) + g * 8);
    }
    // gw matmul + BN, all packed fp16 (weights broadcast from LDS)
    v8h s[9];
    #pragma unroll
    for (int o = 0; o < 9; o++) {
      v8h a = (*(const v8h*)(gwp + o * 72)) * pt[0];
      #pragma unroll
      for (int i = 1; i < 9; i++)
        a += (*(const v8h*)(gwp + o * 72 + i * 8)) * pt[i];
      s[o] = a * (*(const v8h*)(Ap + o * 8)) + (*(const v8h*)(Bp + o * 8));
    }
    // softmax over the 9 taps (shift-free: |s| << 1, fp16-safe)
    v8h esum = {0, 0, 0, 0, 0, 0, 0, 0};
    #pragma unroll
    for (int o = 0; o < 9; o++) { s[o] = exp8h(s[o]); esum += s[o]; }
    v8h inv = rcp8h(esum);
    #pragma unroll
    for (int k = 0; k < 9; k++) pt[k] = pt[k] * s[k] * inv;

    const unsigned short* ap = apinv + l * 8;
    #pragma unroll
    for (int k = 0; k < 9; k++) {
      const unsigned short* a2 = ap + ((k * 4 + cb4) * 2) * 512;
      v8h A0 = *(const v8h*)(a2);
      v8h A1 = *(const v8h*)(a2 + 512);
      acc0 = __builtin_amdgcn_mfma_f32_32x32x16_f16(A0, pt[k], acc0, 0, 0, 0);
      acc1 = __builtin_amdgcn_mfma_f32_32x32x16_f16(A1, pt[k], acc1, 0, 0, 0);
    }
  }
  #pragma unroll
  for (int t = 0; t < 4; t++) {
    int c0 = 8 * t + 4 * g;
    int kb = c0 >> 4, sub = c0 & 15;
    ushort4v s0, s1;
    #pragma unroll
    for (int u = 0; u < 4; u++) {
      s0[u] = f2h(acc0[4 * t + u] + cbias[c0 + u]);
      s1[u] = f2h(acc1[4 * t + u] + cbias[c0 + u + 32]);
    }
    *(ushort4v*)(ipad + clb(b, h, kb, w, 128) + sub) = s0;
    *(ushort4v*)(ipad + clb(b, h, kb + 2, w, 128) + sub) = s1;
  }
}

// ---------------- stage 5: fr 1x1 + residual (direct epilogue add) ----------
__global__ __launch_bounds__(256, 4) void k_fr_mfma(
    const unsigned short* __restrict__ ipad,
    const unsigned short* __restrict__ apfr,
    const float* __restrict__ bias,
    unsigned short* __restrict__ opad)
{
  int b, h; swz_bh(b, h);
  const int tid = threadIdx.x, wv = tid >> 6, l = tid & 63;
  const int ln31 = l & 31, g = l >> 5;
  const int px = wv * 32 + ln31;
  v16f acc0, acc1;
  #pragma unroll
  for (int r = 0; r < 16; r++) { acc0[r] = 0.f; acc1[r] = 0.f; }
  const unsigned short* apl = apfr + l * 8;
  #pragma unroll
  for (int kb = 0; kb < 4; kb++) {
    v8h Bf = *(const v8h*)(ipad + clb(b, h, kb, px, 128) + g * 8);
    v8h A0 = *(const v8h*)(apl + (kb * 2) * 512);
    v8h A1 = *(const v8h*)(apl + (kb * 2 + 1) * 512);
    acc0 = __builtin_amdgcn_mfma_f32_32x32x16_f16(A0, Bf, acc0, 0, 0, 0);
    acc1 = __builtin_amdgcn_mfma_f32_32x32x16_f16(A1, Bf, acc1, 0, 0, 0);
  }
  #pragma unroll
  for (int t = 0; t < 4; t++) {
    int c0 = 8 * t + 4 * g;
    int kb = c0 >> 4, sub = c0 & 15;
    // residual values live at exactly the epilogue addresses
    ushort4v r0 = *(const ushort4v*)(ipad + clb(b, h, kb, px, 128) + sub);
    ushort4v r1 = *(const ushort4v*)(ipad + clb(b, h, kb + 2, px, 128) + sub);
    ushort4v s0, s1;
    #pragma unroll
    for (int u = 0; u < 4; u++) {
      s0[u] = f2h(acc0[4 * t + u] + bias[c0 + u] + h2f(r0[u]));
      s1[u] = f2h(acc1[4 * t + u] + bias[c0 + u + 32] + h2f(r1[u]));
    }
    *(ushort4v*)(opad + clb(b, h + 1, kb, px + 1, PE) + sub) = s0;
    *(ushort4v*)(opad + clb(b, h + 1, kb + 2, px + 1, PE) + sub) = s1;
  }
}

// ---------------- stage 6: ensemble conv3x3, 2 rows/block, LDS weights ------
__global__ __launch_bounds__(256) void k_ens_mfma(
    const unsigned short* __restrict__ opad,
    const unsigned short* __restrict__ apens,
    const float* __restrict__ esc, const float* __restrict__ ebi,
    float* __restrict__ out)
{
  __shared__ __align__(16) unsigned short Abuf[36864];  // 72 KB: 9 taps
  const int tid = threadIdx.x;
  {
    const ushort8v* src = (const ushort8v*)apens;
    ushort8v* dst = (ushort8v*)Abuf;
    #pragma unroll
    for (int it = 0; it < 18; it++)
      dst[tid + it * 256] = src[tid + it * 256];
  }
  __syncthreads();

  const int bid = blockIdx.x;
  const int b = bid & 7, h0 = (bid >> 3) * 2;
  const int wv = tid >> 6, l = tid & 63;
  const int ln31 = l & 31, g = l >> 5;

  v16f a00, a01, a10, a11;
  #pragma unroll
  for (int r = 0; r < 16; r++) { a00[r] = 0.f; a01[r] = 0.f; a10[r] = 0.f; a11[r] = 0.f; }

  const unsigned short* abl = Abuf + l * 8;

  #pragma unroll
  for (int ky = 0; ky < 3; ky++) {
    #pragma unroll
    for (int kx = 0; kx < 3; kx++) {
      const int tap = ky * 3 + kx;
      const int r0 = h0 + ky;              // (h0+1) + (ky-1)
      const int col = wv * 32 + ln31 + kx; // (+1) + (kx-1)
      const unsigned short* ap = abl + tap * 4096;
      #pragma unroll
      for (int kb = 0; kb < 4; kb++) {
        v8h B0 = *(const v8h*)(opad + clb(b, r0, kb, col, PE) + g * 8);
        v8h B1 = *(const v8h*)(opad + clb(b, r0 + 1, kb, col, PE) + g * 8);
        v8h A0 = *(const v8h*)(ap + kb * 1024);
        v8h A1 = *(const v8h*)(ap + kb * 1024 + 512);
        a00 = __builtin_amdgcn_mfma_f32_32x32x16_f16(A0, B0, a00, 0, 0, 0);
        a01 = __builtin_amdgcn_mfma_f32_32x32x16_f16(A1, B0, a01, 0, 0, 0);
        a10 = __builtin_amdgcn_mfma_f32_32x32x16_f16(A0, B1, a10, 0, 0, 0);
        a11 = __builtin_amdgcn_mfma_f32_32x32x16_f16(A1, B1, a11, 0, 0, 0);
      }
    }
  }
  float* sp0 = out + ((size_t)b * Cn) * Pn + h0 * Wn + wv * 32 + ln31;
  float* sp1 = sp0 + Wn;
  #pragma unroll
  for (int r = 0; r < 16; r++) {
    int o0 = (r & 3) + 8 * (r >> 2) + 4 * g;
    float e0 = esc[o0], e1 = esc[o0 + 32];
    float i0 = ebi[o0], i1 = ebi[o0 + 32];
    sp0[(size_t)o0 * Pn] = fmaxf(a00[r] * e0 + i0, 0.f);
    sp0[(size_t)(o0 + 32) * Pn] = fmaxf(a01[r] * e1 + i1, 0.f);
    sp1[(size_t)o0 * Pn] = fmaxf(a10[r] * e0 + i0, 0.f);
    sp1[(size_t)(o0 + 32) * Pn] = fmaxf(a11[r] * e1 + i1, 0.f);
  }
}

extern "C" void kernel_launch(void* const* d_in, const int* in_sizes, int n_in,
                              void* d_out, int out_size, void* d_ws, size_t ws_size,
                              hipStream_t stream)
{
  const float* x    = (const float*)d_in[0];
  const float* w1   = (const float*)d_in[1];
  const float* b1   = (const float*)d_in[2];
  const float* w5   = (const float*)d_in[3];
  const float* w7   = (const float*)d_in[4];
  const float* w9   = (const float*)d_in[5];
  const float* w11  = (const float*)d_in[6];
  const float* dww  = (const float*)d_in[7];
  const float* dwb  = (const float*)d_in[8];
  const float* pww  = (const float*)d_in[9];
  const float* pwb  = (const float*)d_in[10];
  const float* gww  = (const float*)d_in[11];
  const float* gwb  = (const float*)d_in[12];
  const float* gbg  = (const float*)d_in[13];
  const float* gbb  = (const float*)d_in[14];
  const float* gbm  = (const float*)d_in[15];
  const float* gbv  = (const float*)d_in[16];
  const float* cw   = (const float*)d_in[17];
  const float* cb   = (const float*)d_in[18];
  const float* frw  = (const float*)d_in[19];
  const float* frb  = (const float*)d_in[20];
  const float* ensw = (const float*)d_in[21];
  const float* ensb = (const float*)d_in[22];
  const float* bng  = (const float*)d_in[23];
  const float* bnb  = (const float*)d_in[24];
  const float* bnm  = (const float*)d_in[25];
  const float* bnv  = (const float*)d_in[26];

  // ws: ypad (pad-11) region, overlaid later by y2pad then opad (pad-1)
  unsigned short* wsu   = (unsigned short*)d_ws;
  unsigned short* ypad  = wsu;
  unsigned short* y2pad = wsu;
  unsigned short* opad  = wsu;
  unsigned short* apack = wsu + YPAD_ELEMS;         // 147456
  unsigned short* apinv = apack + 147456;           // 36864
  unsigned short* apens = apinv + 36864;            // 36864
  unsigned short* appw1 = apens + 36864;            // 4096
  unsigned short* appw  = appw1 + 4096;             // 4096
  unsigned short* apfr  = appw + 4096;              // 4096
  unsigned short* gwpk  = apfr + 4096;              // 5184
  unsigned short* apk   = gwpk + 5184;              // 576
  unsigned short* bpk   = apk + 576;                // 576
  float* esc = (float*)(bpk + 576);                 // 64
  float* ebi = esc + 64;                            // 64

  // d_out: spad (fp16 blocked-CL pad-1) -> ipad (blocked-CL) -> planar fp32
  unsigned short* spad = (unsigned short*)d_out;
  unsigned short* ipad = (unsigned short*)d_out;
  float* D = (float*)d_out;

  k_prep<<<937, 256, 0, stream>>>(w1, w5, w7, w9, w11, pww, frw, cw,
                                  gww, gwb, gbg, gbb, gbm, gbv, ensw, ensb,
                                  bng, bnb, bnm, bnv,
                                  apack, apinv, apens, appw1, appw, apfr,
                                  gwpk, apk, bpk, esc, ebi);
  // border zeros that are safe now: ypad (ws, pad 11), spad (d_out, pad 1)
  k_zb<<<192, 256, 0, stream>>>(ypad, PR, 11);
  k_zb<<<17, 256, 0, stream>>>(spad, PE, 1);

  // 1) ypad = conv1x1(relu(x))           x (planar f32) -> ypad (blocked CL)
  k_pw1x<<<1024, 256, 0, stream>>>(x, appw1, b1, ypad);
  // 2) spad = sum_d dilconv_d(y)         ypad -> spad (d_out, pad-1)
  k_cdcm_mfma<<<512, 256, 0, stream>>>(ypad, apack, spad);
  // ws region now dead (ypad fully consumed): zero pad-1 borders for
  // y2pad/opad. These borders survive stages 3-5 (interior-only writes).
  k_zb<<<17, 256, 0, stream>>>(y2pad, PE, 1);
  // 3) y2pad = PW(DW(spad))              spad -> y2pad (ws, pad-1)
  k_dwpw_mfma<<<1024, 256, 0, stream>>>(spad, dww, dwb, appw, pwb, y2pad);
  // 4) ipad = involution(y2pad)          y2pad -> ipad (d_out)
  k_invol_mfma<<<1024, 256, 0, stream>>>(y2pad, gwpk, apk, bpk, apinv, cb, ipad);
  // 5) opad = fr(ipad) + ipad            ipad -> opad (ws, pad-1)
  k_fr_mfma<<<1024, 256, 0, stream>>>(ipad, apfr, frb, opad);
  // 6) out = relu(BN(ens3x3(opad)))      opad -> D (planar fp32)
  k_ens_mfma<<<512, 256, 0, stream>>>(opad, apens, esc, ebi, D);
}

// Round 11
// 160.835 us; speedup vs baseline: 14.5007x; 1.0239x over previous
//
#include <hip/hip_runtime.h>
#include <hip/hip_bf16.h>
#include <hip/hip_fp16.h>

#define EPSV 1e-5f
#define Bn 8
#define Cn 64
#define Hn 128
#define Wn 128
#define Pn (Hn*Wn)          // 16384
#define PR 150              // cdcm pad: 11 + 128 + 11
#define PE 130              // 1-pad: 1 + 128 + 1
#define YPAD_ELEMS (Bn*PR*PR*Cn)   // 11,520,000 fp16

typedef _Float16 v8h __attribute__((ext_vector_type(8)));
typedef float v16f __attribute__((ext_vector_type(16)));
typedef unsigned short ushort8v __attribute__((ext_vector_type(8)));
typedef unsigned short ushort4v __attribute__((ext_vector_type(4)));

__device__ __forceinline__ unsigned short f2h(float v) {
  _Float16 h = (_Float16)v;
  return *reinterpret_cast<const unsigned short*>(&h);
}
__device__ __forceinline__ float h2f(unsigned short u) {
  return (float)(*reinterpret_cast<const _Float16*>(&u));
}

__device__ __forceinline__ v8h exp8h(v8h x) {
  union { v8h v; __half2 h[4]; } u; u.v = x;
  #pragma unroll
  for (int i = 0; i < 4; i++) u.h[i] = h2exp(u.h[i]);
  return u.v;
}
__device__ __forceinline__ v8h rcp8h(v8h x) {
  union { v8h v; __half2 h[4]; } u; u.v = x;
  #pragma unroll
  for (int i = 0; i < 4; i++) u.h[i] = h2rcp(u.h[i]);
  return u.v;
}

// channel-blocked CL addressing: [b][row][kb(4)][col][16], elems
__device__ __forceinline__ size_t clb(int b, int row, int kb, int col, int PD) {
  return ((((size_t)b * PD + row) * 4 + kb) * PD + col) * 16;
}

// batch-major XCD swizzle: 1024 blocks, XCD r gets batch r's rows in order
__device__ __forceinline__ void swz_bh(int& b, int& h) {
  int bid = blockIdx.x;
  int w = (bid & 7) * 128 + (bid >> 3);
  b = w >> 7; h = w & 127;
}

// ---------------- prep: weight packs + BN folds + border zeros --------------
// cdcm A-pack layout (chunked): [d][kbp][tap9][kbl][mh][512]
// other A-packs: [tap][kb][mh][lane*8+e], m=mh*32+(l&31), c=kb*16+(l>>5)*8+e
__global__ __launch_bounds__(256) void k_prep(
    const float* __restrict__ w1, const float* __restrict__ w5,
    const float* __restrict__ w7, const float* __restrict__ w9,
    const float* __restrict__ w11, const float* __restrict__ pww,
    const float* __restrict__ frw, const float* __restrict__ cw,
    const float* __restrict__ gww, const float* __restrict__ gwb,
    const float* __restrict__ gbg, const float* __restrict__ gbb,
    const float* __restrict__ gbm, const float* __restrict__ gbv,
    const float* __restrict__ ensw, const float* __restrict__ ensb,
    const float* __restrict__ bng, const float* __restrict__ bnb,
    const float* __restrict__ bnm, const float* __restrict__ bnv,
    unsigned short* __restrict__ apack, unsigned short* __restrict__ apinv,
    unsigned short* __restrict__ apens, unsigned short* __restrict__ appw1,
    unsigned short* __restrict__ appw, unsigned short* __restrict__ apfr,
    unsigned short* __restrict__ gwpk,
    unsigned short* __restrict__ apk, unsigned short* __restrict__ bpk,
    float* __restrict__ esc, float* __restrict__ ebi,
    unsigned short* __restrict__ ypad, unsigned short* __restrict__ spad)
{
  int id = blockIdx.x * 256 + threadIdx.x;
  if (id < 147456) {               // cdcm: chunked [d][kbp][t9][kbl][mh][512]
    int e = id & 7, l = (id >> 3) & 63, mh = (id >> 9) & 1,
        kbl = (id >> 10) & 1;
    int r2 = id >> 11;             // [0, 72): r2 = (d*2+kbp)*9 + t9
    int t9 = r2 % 9; int dk = r2 / 9;
    int kbp = dk & 1, d = dk >> 1;
    int m = mh * 32 + (l & 31);
    int c = (kbp * 2 + kbl) * 16 + (l >> 5) * 8 + e;
    const float* src = (d == 0) ? w5 : (d == 1) ? w7 : (d == 2) ? w9 : w11;
    apack[id] = f2h(src[(m * 64 + c) * 9 + t9]);
    return;
  }
  id -= 147456;
  if (id < 36864) {                // involution conv_w: 9 taps
    int e = id & 7, l = (id >> 3) & 63, mh = (id >> 9) & 1,
        kb = (id >> 10) & 3, tap = id >> 12;
    int m = mh * 32 + (l & 31);
    int c = kb * 16 + (l >> 5) * 8 + e;
    apinv[id] = f2h(cw[(m * 64 + c) * 9 + tap]);
    return;
  }
  id -= 36864;
  if (id < 36864) {                // ensemble mean weights: 9 taps
    int e = id & 7, l = (id >> 3) & 63, mh = (id >> 9) & 1,
        kb = (id >> 10) & 3, tap = id >> 12;
    int m = mh * 32 + (l & 31);
    int c = kb * 16 + (l >> 5) * 8 + e;
    float v = (ensw[((0 * 64 + m) * 64 + c) * 9 + tap] +
               ensw[((64 + m) * 64 + c) * 9 + tap] +
               ensw[((128 + m) * 64 + c) * 9 + tap]) * (1.f / 3.f);
    apens[id] = f2h(v);
    return;
  }
  id -= 36864;
  if (id < 4096) {                 // conv1 1x1
    int e = id & 7, l = (id >> 3) & 63, mh = (id >> 9) & 1, kb = (id >> 10) & 3;
    int m = mh * 32 + (l & 31);
    int c = kb * 16 + (l >> 5) * 8 + e;
    appw1[id] = f2h(w1[m * 64 + c]);
    return;
  }
  id -= 4096;
  if (id < 4096) {                 // dsc pointwise 1x1
    int e = id & 7, l = (id >> 3) & 63, mh = (id >> 9) & 1, kb = (id >> 10) & 3;
    int m = mh * 32 + (l & 31);
    int c = kb * 16 + (l >> 5) * 8 + e;
    appw[id] = f2h(pww[m * 64 + c]);
    return;
  }
  id -= 4096;
  if (id < 4096) {                 // fr 1x1
    int e = id & 7, l = (id >> 3) & 63, mh = (id >> 9) & 1, kb = (id >> 10) & 3;
    int m = mh * 32 + (l & 31);
    int c = kb * 16 + (l >> 5) * 8 + e;
    apfr[id] = f2h(frw[m * 64 + c]);
    return;
  }
  id -= 4096;
  if (id < 5184) {                 // packed gw weights [cblk8][tap81][ch8]
    int cblk = id / 648, r = id - cblk * 648;
    int tap = r >> 3, ch = r & 7;
    int c = cblk * 8 + ch;
    gwpk[id] = f2h(gww[c * 81 + tap]);
    return;
  }
  id -= 5184;
  if (id < 576) {                  // packed BN scale [cblk8][o9][ch8]
    int cblk = id / 72, r = id - cblk * 72;
    int o = r >> 3, ch = r & 7;
    int c = cblk * 8 + ch;
    float A = gbg[c * 9 + o] / sqrtf(gbv[c * 9 + o] + EPSV);
    apk[id] = f2h(A);
    return;
  }
  id -= 576;
  if (id < 576) {                  // packed BN shift
    int cblk = id / 72, r = id - cblk * 72;
    int o = r >> 3, ch = r & 7;
    int c = cblk * 8 + ch;
    float A = gbg[c * 9 + o] / sqrtf(gbv[c * 9 + o] + EPSV);
    float B = (gwb[c * 9 + o] - gbm[c * 9 + o]) * A + gbb[c * 9 + o];
    bpk[id] = f2h(B);
    return;
  }
  id -= 576;
  if (id < 64) {                   // final BN fold (+ mean ensemble bias)
    float s = bng[id] / sqrtf(bnv[id] + EPSV);
    esc[id] = s;
    float bm = (ensb[id] + ensb[64 + id] + ensb[128 + id]) * (1.f / 3.f);
    ebi[id] = (bm - bnm[id]) * s + bnb[id];
    return;
  }
  id -= 64;
  ushort8v z = {0, 0, 0, 0, 0, 0, 0, 0};
  const int perY = 22 * PR + 128 * 22;      // 6116: ypad border (pad 11)
  if (id < perY * Bn) {
    int b = id / perY; int r = id - b * perY;
    int tb = 22 * PR;
    int row, col;
    if (r < tb) {
      int rr = r / PR; col = r - rr * PR;
      row = (rr < 11) ? rr : (rr + 128);
    } else {
      int r2 = r - tb;
      row = 11 + r2 / 22;
      int cc = r2 % 22;
      col = (cc < 11) ? cc : (cc + 128);
    }
    #pragma unroll
    for (int kb = 0; kb < 4; kb++) {
      unsigned short* p = ypad + clb(b, row, kb, col, PR);
      *(ushort8v*)p = z;
      *(ushort8v*)(p + 8) = z;
    }
    return;
  }
  id -= perY * Bn;
  const int perS = 2 * PE + 256;            // 516: spad border (pad 1)
  if (id < perS * Bn) {
    int b = id / perS; int r = id - b * perS;
    int tb = 2 * PE;
    int row, col;
    if (r < tb) {
      int rr = r / PE; col = r - rr * PE;
      row = (rr < 1) ? 0 : 129;
    } else {
      int r2 = r - tb;
      row = 1 + r2 / 2;
      col = (r2 & 1) ? 129 : 0;
    }
    #pragma unroll
    for (int kb = 0; kb < 4; kb++) {
      unsigned short* p = spad + clb(b, row, kb, col, PE);
      *(ushort8v*)p = z;
      *(ushort8v*)(p + 8) = z;
    }
  }
}

// ---------------- stage 1: conv1x1(relu(x)) via MFMA, planar fp32 in --------
__global__ __launch_bounds__(256, 4) void k_pw1x(const float* __restrict__ x,
    const unsigned short* __restrict__ apw, const float* __restrict__ bias,
    unsigned short* __restrict__ ypad)
{
  int b, h; swz_bh(b, h);
  const int tid = threadIdx.x, wv = tid >> 6, l = tid & 63;
  const int ln31 = l & 31, g = l >> 5;
  const int px = wv * 32 + ln31;
  const float* xb = x + ((size_t)b * Cn) * Pn + h * Wn + px;
  v16f acc0, acc1;
  #pragma unroll
  for (int r = 0; r < 16; r++) { acc0[r] = 0.f; acc1[r] = 0.f; }
  const unsigned short* apl = apw + l * 8;
  #pragma unroll
  for (int kb = 0; kb < 4; kb++) {
    int c0 = kb * 16 + g * 8;
    v8h Bf;
    #pragma unroll
    for (int e = 0; e < 8; e++)
      Bf[e] = (_Float16)fmaxf(xb[(size_t)(c0 + e) * Pn], 0.f);
    v8h A0 = *(const v8h*)(apl + (kb * 2) * 512);
    v8h A1 = *(const v8h*)(apl + (kb * 2 + 1) * 512);
    acc0 = __builtin_amdgcn_mfma_f32_32x32x16_f16(A0, Bf, acc0, 0, 0, 0);
    acc1 = __builtin_amdgcn_mfma_f32_32x32x16_f16(A1, Bf, acc1, 0, 0, 0);
  }
  #pragma unroll
  for (int t = 0; t < 4; t++) {
    int c0 = 8 * t + 4 * g;
    int kb = c0 >> 4, sub = c0 & 15;
    ushort4v s0, s1;
    #pragma unroll
    for (int u = 0; u < 4; u++) {
      s0[u] = f2h(acc0[4 * t + u] + bias[c0 + u]);
      s1[u] = f2h(acc1[4 * t + u] + bias[c0 + u + 32]);
    }
    *(ushort4v*)(ypad + clb(b, h + 11, kb, px + 11, PR) + sub) = s0;
    *(ushort4v*)(ypad + clb(b, h + 11, kb + 2, px + 11, PR) + sub) = s1;
  }
}

// ---------------- stage 2: cdcm, 36KB chunk staging, 4 blocks/CU ------------
// grid 1024, 1 row/block. 8 chunks of (d, kb-pair): 9 taps x 2 kb = 36 KB.
__global__ __launch_bounds__(256, 4) void k_cdcm_mfma(
    const unsigned short* __restrict__ ypad,
    const unsigned short* __restrict__ apack,
    unsigned short* __restrict__ spad)
{
  __shared__ __align__(16) unsigned short Abuf[18432];  // 36 KB
  int b, h; swz_bh(b, h);
  const int tid = threadIdx.x, wv = tid >> 6, l = tid & 63;
  const int ln31 = l & 31, g = l >> 5;

  v16f acc0, acc1;
  #pragma unroll
  for (int r = 0; r < 16; r++) { acc0[r] = 0.f; acc1[r] = 0.f; }

  const unsigned short* abl = Abuf + l * 8;

  for (int d = 0; d < 4; d++) {
    const int dil = 5 + 2 * d;
    for (int kbp = 0; kbp < 2; kbp++) {
      __syncthreads();
      {
        const ushort8v* src = (const ushort8v*)(apack + (d * 2 + kbp) * 18432);
        ushort8v* dst = (ushort8v*)Abuf;
        #pragma unroll
        for (int it = 0; it < 9; it++)
          dst[tid + it * 256] = src[tid + it * 256];
      }
      __syncthreads();
      #pragma unroll
      for (int ky = 0; ky < 3; ky++) {
        const int row = h + 11 + (ky - 1) * dil;
        #pragma unroll
        for (int kx = 0; kx < 3; kx++) {
          const int col = wv * 32 + ln31 + (kx - 1) * dil + 11;
          const int t9 = ky * 3 + kx;
          #pragma unroll
          for (int kbl = 0; kbl < 2; kbl++) {
            const int kb = kbp * 2 + kbl;
            v8h Bf = *(const v8h*)(ypad + clb(b, row, kb, col, PR) + g * 8);
            const unsigned short* ap = abl + (t9 * 2 + kbl) * 1024;
            v8h A0 = *(const v8h*)(ap);
            v8h A1 = *(const v8h*)(ap + 512);
            acc0 = __builtin_amdgcn_mfma_f32_32x32x16_f16(A0, Bf, acc0, 0, 0, 0);
            acc1 = __builtin_amdgcn_mfma_f32_32x32x16_f16(A1, Bf, acc1, 0, 0, 0);
          }
        }
      }
    }
  }
  const int px = wv * 32 + ln31;
  #pragma unroll
  for (int t = 0; t < 4; t++) {
    int c0 = 8 * t + 4 * g;
    int kb = c0 >> 4, sub = c0 & 15;
    ushort4v s0, s1;
    #pragma unroll
    for (int u = 0; u < 4; u++) {
      s0[u] = f2h(acc0[4 * t + u]);
      s1[u] = f2h(acc1[4 * t + u]);
    }
    *(ushort4v*)(spad + clb(b, h + 1, kb, px + 1, PE) + sub) = s0;
    *(ushort4v*)(spad + clb(b, h + 1, kb + 2, px + 1, PE) + sub) = s1;
  }
}

// ---------------- stage 3: depthwise (VALU) + pointwise (MFMA) --------------
// Blocks h==0/h==1 also zero y2pad's pad-1 borders (safe: nothing reads
// y2pad until invol; border writes disjoint from all interior writes).
__global__ __launch_bounds__(256, 4) void k_dwpw_mfma(
    const unsigned short* __restrict__ spad,
    const float* __restrict__ dww, const float* __restrict__ dwb,
    const unsigned short* __restrict__ appw, const float* __restrict__ pwb,
    unsigned short* __restrict__ y2pad)
{
  __shared__ float wdw[576];
  __shared__ float bdw[64];
  const int tid = threadIdx.x;
  for (int t = tid; t < 576; t += 256) wdw[t] = dww[t];
  if (tid < 64) bdw[tid] = dwb[tid];
  __syncthreads();

  int b, h; swz_bh(b, h);

  ushort8v z = {0, 0, 0, 0, 0, 0, 0, 0};
  if (h == 0) {
    for (int px = tid; px < 260; px += 256) {
      int row = (px < 130) ? 0 : 129;
      int col = (px < 130) ? px : px - 130;
      #pragma unroll
      for (int kb = 0; kb < 4; kb++) {
        unsigned short* p = y2pad + clb(b, row, kb, col, PE);
        *(ushort8v*)p = z;
        *(ushort8v*)(p + 8) = z;
      }
    }
  } else if (h == 1) {
    int row = 1 + (tid & 127);
    int col = (tid >> 7) ? 129 : 0;
    #pragma unroll
    for (int kb = 0; kb < 4; kb++) {
      unsigned short* p = y2pad + clb(b, row, kb, col, PE);
      *(ushort8v*)p = z;
      *(ushort8v*)(p + 8) = z;
    }
  }

  const int wv = tid >> 6, l = tid & 63;
  const int ln31 = l & 31, g = l >> 5;
  const int w = wv * 32 + ln31;

  v16f acc0, acc1;
  #pragma unroll
  for (int r = 0; r < 16; r++) { acc0[r] = 0.f; acc1[r] = 0.f; }
  const unsigned short* apl = appw + l * 8;

  #pragma unroll
  for (int kb = 0; kb < 4; kb++) {
    const int c0 = kb * 16 + g * 8;
    v8h t[9];
    #pragma unroll
    for (int k = 0; k < 9; k++) {
      const int dy = k / 3 - 1, dx = k % 3 - 1;
      t[k] = *(const v8h*)(spad + clb(b, h + 1 + dy, kb, w + 1 + dx, PE) + g * 8);
    }
    v8h dvh;
    #pragma unroll
    for (int e = 0; e < 8; e++) {
      const int c = c0 + e;
      float a = 4.f * bdw[c];
      #pragma unroll
      for (int k = 0; k < 9; k++) a += wdw[c * 9 + k] * (float)t[k][e];
      dvh[e] = (_Float16)a;
    }
    v8h A0 = *(const v8h*)(apl + (kb * 2) * 512);
    v8h A1 = *(const v8h*)(apl + (kb * 2 + 1) * 512);
    acc0 = __builtin_amdgcn_mfma_f32_32x32x16_f16(A0, dvh, acc0, 0, 0, 0);
    acc1 = __builtin_amdgcn_mfma_f32_32x32x16_f16(A1, dvh, acc1, 0, 0, 0);
  }
  #pragma unroll
  for (int t = 0; t < 4; t++) {
    int c0 = 8 * t + 4 * g;
    int kb = c0 >> 4, sub = c0 & 15;
    ushort4v s0, s1;
    #pragma unroll
    for (int u = 0; u < 4; u++) {
      s0[u] = f2h(acc0[4 * t + u] + 4.f * pwb[c0 + u]);
      s1[u] = f2h(acc1[4 * t + u] + 4.f * pwb[c0 + u + 32]);
    }
    *(ushort4v*)(y2pad + clb(b, h + 1, kb, w + 1, PE) + sub) = s0;
    *(ushort4v*)(y2pad + clb(b, h + 1, kb + 2, w + 1, PE) + sub) = s1;
  }
}

// ---------------- stage 4: involution, packed-fp16 softmax + MFMA -----------
__global__ __launch_bounds__(256, 3) void k_invol_mfma(
    const unsigned short* __restrict__ y2pad,
    const unsigned short* __restrict__ gwpk,
    const unsigned short* __restrict__ apk,
    const unsigned short* __restrict__ bpk,
    const unsigned short* __restrict__ apinv,
    const float* __restrict__ cbias,
    unsigned short* __restrict__ ipad)
{
  __shared__ __align__(16) unsigned short gws[5184];  // [cblk8][tap81][ch8]
  __shared__ __align__(16) unsigned short As[576];    // [cblk8][o9][ch8]
  __shared__ __align__(16) unsigned short Bs[576];
  const int tid = threadIdx.x;
  for (int t = tid; t < 648; t += 256)
    ((ushort8v*)gws)[t] = ((const ushort8v*)gwpk)[t];
  if (tid < 72) {
    ((ushort8v*)As)[tid] = ((const ushort8v*)apk)[tid];
    ((ushort8v*)Bs)[tid] = ((const ushort8v*)bpk)[tid];
  }
  __syncthreads();

  int b, h; swz_bh(b, h);
  const int wv = tid >> 6, l = tid & 63;
  const int p32 = l & 31, g = l >> 5;
  const int w = wv * 32 + p32;

  v16f acc0, acc1;
  #pragma unroll
  for (int r = 0; r < 16; r++) { acc0[r] = 0.f; acc1[r] = 0.f; }

  for (int cb4 = 0; cb4 < 4; cb4++) {
    const int cblk = cb4 * 2 + g;
    const unsigned short* gwp = gws + cblk * 648;
    const unsigned short* Ap = As + cblk * 72;
    const unsigned short* Bp = Bs + cblk * 72;

    v8h pt[9];
    #pragma unroll
    for (int k = 0; k < 9; k++) {
      const int dy = k / 3 - 1, dx = k % 3 - 1;
      pt[k] = *(const v8h*)(y2pad + clb(b, h + 1 + dy, cb4, w + 1 + dx, PE) + g * 8);
    }
    // gw matmul + BN, all packed fp16 (weights broadcast from LDS)
    v8h s[9];
    #pragma unroll
    for (int o = 0; o < 9; o++) {
      v8h a = (*(const v8h*)(gwp + o * 72)) * pt[0];
      #pragma unroll
      for (int i = 1; i < 9; i++)
        a += (*(const v8h*)(gwp + o * 72 + i * 8)) * pt[i];
      s[o] = a * (*(const v8h*)(Ap + o * 8)) + (*(const v8h*)(Bp + o * 8));
    }
    // softmax over the 9 taps (shift-free: |s| << 1, fp16-safe)
    v8h esum = {0, 0, 0, 0, 0, 0, 0, 0};
    #pragma unroll
    for (int o = 0; o < 9; o++) { s[o] = exp8h(s[o]); esum += s[o]; }
    v8h inv = rcp8h(esum);
    #pragma unroll
    for (int k = 0; k < 9; k++) pt[k] = pt[k] * s[k] * inv;

    const unsigned short* ap = apinv + l * 8;
    #pragma unroll
    for (int k = 0; k < 9; k++) {
      const unsigned short* a2 = ap + ((k * 4 + cb4) * 2) * 512;
      v8h A0 = *(const v8h*)(a2);
      v8h A1 = *(const v8h*)(a2 + 512);
      acc0 = __builtin_amdgcn_mfma_f32_32x32x16_f16(A0, pt[k], acc0, 0, 0, 0);
      acc1 = __builtin_amdgcn_mfma_f32_32x32x16_f16(A1, pt[k], acc1, 0, 0, 0);
    }
  }
  #pragma unroll
  for (int t = 0; t < 4; t++) {
    int c0 = 8 * t + 4 * g;
    int kb = c0 >> 4, sub = c0 & 15;
    ushort4v s0, s1;
    #pragma unroll
    for (int u = 0; u < 4; u++) {
      s0[u] = f2h(acc0[4 * t + u] + cbias[c0 + u]);
      s1[u] = f2h(acc1[4 * t + u] + cbias[c0 + u + 32]);
    }
    *(ushort4v*)(ipad + clb(b, h, kb, w, 128) + sub) = s0;
    *(ushort4v*)(ipad + clb(b, h, kb + 2, w, 128) + sub) = s1;
  }
}

// ---------------- stage 5: fr 1x1 + residual (direct epilogue add) ----------
__global__ __launch_bounds__(256, 4) void k_fr_mfma(
    const unsigned short* __restrict__ ipad,
    const unsigned short* __restrict__ apfr,
    const float* __restrict__ bias,
    unsigned short* __restrict__ opad)
{
  int b, h; swz_bh(b, h);
  const int tid = threadIdx.x, wv = tid >> 6, l = tid & 63;
  const int ln31 = l & 31, g = l >> 5;
  const int px = wv * 32 + ln31;
  v16f acc0, acc1;
  #pragma unroll
  for (int r = 0; r < 16; r++) { acc0[r] = 0.f; acc1[r] = 0.f; }
  const unsigned short* apl = apfr + l * 8;
  #pragma unroll
  for (int kb = 0; kb < 4; kb++) {
    v8h Bf = *(const v8h*)(ipad + clb(b, h, kb, px, 128) + g * 8);
    v8h A0 = *(const v8h*)(apl + (kb * 2) * 512);
    v8h A1 = *(const v8h*)(apl + (kb * 2 + 1) * 512);
    acc0 = __builtin_amdgcn_mfma_f32_32x32x16_f16(A0, Bf, acc0, 0, 0, 0);
    acc1 = __builtin_amdgcn_mfma_f32_32x32x16_f16(A1, Bf, acc1, 0, 0, 0);
  }
  #pragma unroll
  for (int t = 0; t < 4; t++) {
    int c0 = 8 * t + 4 * g;
    int kb = c0 >> 4, sub = c0 & 15;
    // residual values live at exactly the epilogue addresses
    ushort4v r0 = *(const ushort4v*)(ipad + clb(b, h, kb, px, 128) + sub);
    ushort4v r1 = *(const ushort4v*)(ipad + clb(b, h, kb + 2, px, 128) + sub);
    ushort4v s0, s1;
    #pragma unroll
    for (int u = 0; u < 4; u++) {
      s0[u] = f2h(acc0[4 * t + u] + bias[c0 + u] + h2f(r0[u]));
      s1[u] = f2h(acc1[4 * t + u] + bias[c0 + u + 32] + h2f(r1[u]));
    }
    *(ushort4v*)(opad + clb(b, h + 1, kb, px + 1, PE) + sub) = s0;
    *(ushort4v*)(opad + clb(b, h + 1, kb + 2, px + 1, PE) + sub) = s1;
  }
}

// ---------------- stage 6: ensemble conv3x3, 2 rows/block, LDS weights ------
__global__ __launch_bounds__(256) void k_ens_mfma(
    const unsigned short* __restrict__ opad,
    const unsigned short* __restrict__ apens,
    const float* __restrict__ esc, const float* __restrict__ ebi,
    float* __restrict__ out)
{
  __shared__ __align__(16) unsigned short Abuf[36864];  // 72 KB: 9 taps
  const int tid = threadIdx.x;
  {
    const ushort8v* src = (const ushort8v*)apens;
    ushort8v* dst = (ushort8v*)Abuf;
    #pragma unroll
    for (int it = 0; it < 18; it++)
      dst[tid + it * 256] = src[tid + it * 256];
  }
  __syncthreads();

  const int bid = blockIdx.x;
  const int b = bid & 7, h0 = (bid >> 3) * 2;
  const int wv = tid >> 6, l = tid & 63;
  const int ln31 = l & 31, g = l >> 5;

  v16f a00, a01, a10, a11;
  #pragma unroll
  for (int r = 0; r < 16; r++) { a00[r] = 0.f; a01[r] = 0.f; a10[r] = 0.f; a11[r] = 0.f; }

  const unsigned short* abl = Abuf + l * 8;

  #pragma unroll
  for (int ky = 0; ky < 3; ky++) {
    #pragma unroll
    for (int kx = 0; kx < 3; kx++) {
      const int tap = ky * 3 + kx;
      const int r0 = h0 + ky;              // (h0+1) + (ky-1)
      const int col = wv * 32 + ln31 + kx; // (+1) + (kx-1)
      const unsigned short* ap = abl + tap * 4096;
      #pragma unroll
      for (int kb = 0; kb < 4; kb++) {
        v8h B0 = *(const v8h*)(opad + clb(b, r0, kb, col, PE) + g * 8);
        v8h B1 = *(const v8h*)(opad + clb(b, r0 + 1, kb, col, PE) + g * 8);
        v8h A0 = *(const v8h*)(ap + kb * 1024);
        v8h A1 = *(const v8h*)(ap + kb * 1024 + 512);
        a00 = __builtin_amdgcn_mfma_f32_32x32x16_f16(A0, B0, a00, 0, 0, 0);
        a01 = __builtin_amdgcn_mfma_f32_32x32x16_f16(A1, B0, a01, 0, 0, 0);
        a10 = __builtin_amdgcn_mfma_f32_32x32x16_f16(A0, B1, a10, 0, 0, 0);
        a11 = __builtin_amdgcn_mfma_f32_32x32x16_f16(A1, B1, a11, 0, 0, 0);
      }
    }
  }
  float* sp0 = out + ((size_t)b * Cn) * Pn + h0 * Wn + wv * 32 + ln31;
  float* sp1 = sp0 + Wn;
  #pragma unroll
  for (int r = 0; r < 16; r++) {
    int o0 = (r & 3) + 8 * (r >> 2) + 4 * g;
    float e0 = esc[o0], e1 = esc[o0 + 32];
    float i0 = ebi[o0], i1 = ebi[o0 + 32];
    sp0[(size_t)o0 * Pn] = fmaxf(a00[r] * e0 + i0, 0.f);
    sp0[(size_t)(o0 + 32) * Pn] = fmaxf(a01[r] * e1 + i1, 0.f);
    sp1[(size_t)o0 * Pn] = fmaxf(a10[r] * e0 + i0, 0.f);
    sp1[(size_t)(o0 + 32) * Pn] = fmaxf(a11[r] * e1 + i1, 0.f);
  }
}

extern "C" void kernel_launch(void* const* d_in, const int* in_sizes, int n_in,
                              void* d_out, int out_size, void* d_ws, size_t ws_size,
                              hipStream_t stream)
{
  const float* x    = (const float*)d_in[0];
  const float* w1   = (const float*)d_in[1];
  const float* b1   = (const float*)d_in[2];
  const float* w5   = (const float*)d_in[3];
  const float* w7   = (const float*)d_in[4];
  const float* w9   = (const float*)d_in[5];
  const float* w11  = (const float*)d_in[6];
  const float* dww  = (const float*)d_in[7];
  const float* dwb  = (const float*)d_in[8];
  const float* pww  = (const float*)d_in[9];
  const float* pwb  = (const float*)d_in[10];
  const float* gww  = (const float*)d_in[11];
  const float* gwb  = (const float*)d_in[12];
  const float* gbg  = (const float*)d_in[13];
  const float* gbb  = (const float*)d_in[14];
  const float* gbm  = (const float*)d_in[15];
  const float* gbv  = (const float*)d_in[16];
  const float* cw   = (const float*)d_in[17];
  const float* cb   = (const float*)d_in[18];
  const float* frw  = (const float*)d_in[19];
  const float* frb  = (const float*)d_in[20];
  const float* ensw = (const float*)d_in[21];
  const float* ensb = (const float*)d_in[22];
  const float* bng  = (const float*)d_in[23];
  const float* bnb  = (const float*)d_in[24];
  const float* bnm  = (const float*)d_in[25];
  const float* bnv  = (const float*)d_in[26];

  // ws: ypad (pad-11) region, overlaid later by y2pad then opad (pad-1)
  unsigned short* wsu   = (unsigned short*)d_ws;
  unsigned short* ypad  = wsu;
  unsigned short* y2pad = wsu;
  unsigned short* opad  = wsu;
  unsigned short* apack = wsu + YPAD_ELEMS;         // 147456
  unsigned short* apinv = apack + 147456;           // 36864
  unsigned short* apens = apinv + 36864;            // 36864
  unsigned short* appw1 = apens + 36864;            // 4096
  unsigned short* appw  = appw1 + 4096;             // 4096
  unsigned short* apfr  = appw + 4096;              // 4096
  unsigned short* gwpk  = apfr + 4096;              // 5184
  unsigned short* apk   = gwpk + 5184;              // 576
  unsigned short* bpk   = apk + 576;                // 576
  float* esc = (float*)(bpk + 576);                 // 64
  float* ebi = esc + 64;                            // 64

  // d_out: spad (fp16 blocked-CL pad-1) -> ipad (blocked-CL) -> planar fp32
  unsigned short* spad = (unsigned short*)d_out;
  unsigned short* ipad = (unsigned short*)d_out;
  float* D = (float*)d_out;

  // prep also zeroes ypad borders (pad 11) and spad borders (pad 1)
  k_prep<<<1145, 256, 0, stream>>>(w1, w5, w7, w9, w11, pww, frw, cw,
                                   gww, gwb, gbg, gbb, gbm, gbv, ensw, ensb,
                                   bng, bnb, bnm, bnv,
                                   apack, apinv, apens, appw1, appw, apfr,
                                   gwpk, apk, bpk, esc, ebi,
                                   ypad, spad);

  // 1) ypad = conv1x1(relu(x))           x (planar f32) -> ypad (blocked CL)
  k_pw1x<<<1024, 256, 0, stream>>>(x, appw1, b1, ypad);
  // 2) spad = sum_d dilconv_d(y)         ypad -> spad (d_out, pad-1)
  k_cdcm_mfma<<<1024, 256, 0, stream>>>(ypad, apack, spad);
  // 3) y2pad = PW(DW(spad))              spad -> y2pad (ws, pad-1)
  //    (blocks h=0/1 also zero y2pad borders; ypad is dead by now)
  k_dwpw_mfma<<<1024, 256, 0, stream>>>(spad, dww, dwb, appw, pwb, y2pad);
  // 4) ipad = involution(y2pad)          y2pad -> ipad (d_out)
  k_invol_mfma<<<1024, 256, 0, stream>>>(y2pad, gwpk, apk, bpk, apinv, cb, ipad);
  // 5) opad = fr(ipad) + ipad            ipad -> opad (ws, pad-1)
  k_fr_mfma<<<1024, 256, 0, stream>>>(ipad, apfr, frb, opad);
  // 6) out = relu(BN(ens3x3(opad)))      opad -> D (planar fp32)
  k_ens_mfma<<<512, 256, 0, stream>>>(opad, apens, esc, ebi, D);
}

// Round 12
// 150.039 us; speedup vs baseline: 15.5441x; 1.0720x over previous
//
#include <hip/hip_runtime.h>
#include <hip/hip_bf16.h>
#include <hip/hip_fp16.h>

#define EPSV 1e-5f
#define Bn 8
#define Cn 64
#define Hn 128
#define Wn 128
#define Pn (Hn*Wn)          // 16384
#define PR 150              // cdcm pad: 11 + 128 + 11
#define PE 130              // 1-pad: 1 + 128 + 1
#define YPAD_ELEMS (Bn*PR*PR*Cn)   // 11,520,000 fp16

typedef _Float16 v8h __attribute__((ext_vector_type(8)));
typedef float v16f __attribute__((ext_vector_type(16)));
typedef unsigned short ushort8v __attribute__((ext_vector_type(8)));
typedef unsigned short ushort4v __attribute__((ext_vector_type(4)));

__device__ __forceinline__ unsigned short f2h(float v) {
  _Float16 h = (_Float16)v;
  return *reinterpret_cast<const unsigned short*>(&h);
}
__device__ __forceinline__ float h2f(unsigned short u) {
  return (float)(*reinterpret_cast<const _Float16*>(&u));
}

__device__ __forceinline__ v8h exp8h(v8h x) {
  union { v8h v; __half2 h[4]; } u; u.v = x;
  #pragma unroll
  for (int i = 0; i < 4; i++) u.h[i] = h2exp(u.h[i]);
  return u.v;
}
__device__ __forceinline__ v8h rcp8h(v8h x) {
  union { v8h v; __half2 h[4]; } u; u.v = x;
  #pragma unroll
  for (int i = 0; i < 4; i++) u.h[i] = h2rcp(u.h[i]);
  return u.v;
}

// async global->LDS, 16B per lane; LDS dest = uniform base + lane*16
__device__ __forceinline__ void gload_lds16(const void* g, void* l) {
  __builtin_amdgcn_global_load_lds(
      (const __attribute__((address_space(1))) unsigned int*)g,
      (__attribute__((address_space(3))) unsigned int*)l, 16, 0, 0);
}

// channel-blocked CL addressing: [b][row][kb(4)][col][16], elems
__device__ __forceinline__ size_t clb(int b, int row, int kb, int col, int PD) {
  return ((((size_t)b * PD + row) * 4 + kb) * PD + col) * 16;
}

// batch-major XCD swizzle: 1024 blocks, XCD r gets batch r's rows in order
__device__ __forceinline__ void swz_bh(int& b, int& h) {
  int bid = blockIdx.x;
  int w = (bid & 7) * 128 + (bid >> 3);
  b = w >> 7; h = w & 127;
}

// ---------------- prep: weight packs + BN folds + border zeros --------------
// cdcm A-pack layout (chunked): [d][kbp][tap9][kbl][mh][512]
// other A-packs: [tap][kb][mh][lane*8+e], m=mh*32+(l&31), c=kb*16+(l>>5)*8+e
__global__ __launch_bounds__(256) void k_prep(
    const float* __restrict__ w1, const float* __restrict__ w5,
    const float* __restrict__ w7, const float* __restrict__ w9,
    const float* __restrict__ w11, const float* __restrict__ pww,
    const float* __restrict__ frw, const float* __restrict__ cw,
    const float* __restrict__ gww, const float* __restrict__ gwb,
    const float* __restrict__ gbg, const float* __restrict__ gbb,
    const float* __restrict__ gbm, const float* __restrict__ gbv,
    const float* __restrict__ ensw, const float* __restrict__ ensb,
    const float* __restrict__ bng, const float* __restrict__ bnb,
    const float* __restrict__ bnm, const float* __restrict__ bnv,
    unsigned short* __restrict__ apack, unsigned short* __restrict__ apinv,
    unsigned short* __restrict__ apens, unsigned short* __restrict__ appw1,
    unsigned short* __restrict__ appw, unsigned short* __restrict__ apfr,
    unsigned short* __restrict__ gwpk,
    unsigned short* __restrict__ apk, unsigned short* __restrict__ bpk,
    float* __restrict__ esc, float* __restrict__ ebi,
    unsigned short* __restrict__ ypad, unsigned short* __restrict__ spad)
{
  int id = blockIdx.x * 256 + threadIdx.x;
  if (id < 147456) {               // cdcm: chunked [d][kbp][t9][kbl][mh][512]
    int e = id & 7, l = (id >> 3) & 63, mh = (id >> 9) & 1,
        kbl = (id >> 10) & 1;
    int r2 = id >> 11;             // [0, 72): r2 = (d*2+kbp)*9 + t9
    int t9 = r2 % 9; int dk = r2 / 9;
    int kbp = dk & 1, d = dk >> 1;
    int m = mh * 32 + (l & 31);
    int c = (kbp * 2 + kbl) * 16 + (l >> 5) * 8 + e;
    const float* src = (d == 0) ? w5 : (d == 1) ? w7 : (d == 2) ? w9 : w11;
    apack[id] = f2h(src[(m * 64 + c) * 9 + t9]);
    return;
  }
  id -= 147456;
  if (id < 36864) {                // involution conv_w: 9 taps
    int e = id & 7, l = (id >> 3) & 63, mh = (id >> 9) & 1,
        kb = (id >> 10) & 3, tap = id >> 12;
    int m = mh * 32 + (l & 31);
    int c = kb * 16 + (l >> 5) * 8 + e;
    apinv[id] = f2h(cw[(m * 64 + c) * 9 + tap]);
    return;
  }
  id -= 36864;
  if (id < 36864) {                // ensemble mean weights: 9 taps
    int e = id & 7, l = (id >> 3) & 63, mh = (id >> 9) & 1,
        kb = (id >> 10) & 3, tap = id >> 12;
    int m = mh * 32 + (l & 31);
    int c = kb * 16 + (l >> 5) * 8 + e;
    float v = (ensw[((0 * 64 + m) * 64 + c) * 9 + tap] +
               ensw[((64 + m) * 64 + c) * 9 + tap] +
               ensw[((128 + m) * 64 + c) * 9 + tap]) * (1.f / 3.f);
    apens[id] = f2h(v);
    return;
  }
  id -= 36864;
  if (id < 4096) {                 // conv1 1x1
    int e = id & 7, l = (id >> 3) & 63, mh = (id >> 9) & 1, kb = (id >> 10) & 3;
    int m = mh * 32 + (l & 31);
    int c = kb * 16 + (l >> 5) * 8 + e;
    appw1[id] = f2h(w1[m * 64 + c]);
    return;
  }
  id -= 4096;
  if (id < 4096) {                 // dsc pointwise 1x1
    int e = id & 7, l = (id >> 3) & 63, mh = (id >> 9) & 1, kb = (id >> 10) & 3;
    int m = mh * 32 + (l & 31);
    int c = kb * 16 + (l >> 5) * 8 + e;
    appw[id] = f2h(pww[m * 64 + c]);
    return;
  }
  id -= 4096;
  if (id < 4096) {                 // fr 1x1
    int e = id & 7, l = (id >> 3) & 63, mh = (id >> 9) & 1, kb = (id >> 10) & 3;
    int m = mh * 32 + (l & 31);
    int c = kb * 16 + (l >> 5) * 8 + e;
    apfr[id] = f2h(frw[m * 64 + c]);
    return;
  }
  id -= 4096;
  if (id < 5184) {                 // packed gw weights [cblk8][tap81][ch8]
    int cblk = id / 648, r = id - cblk * 648;
    int tap = r >> 3, ch = r & 7;
    int c = cblk * 8 + ch;
    gwpk[id] = f2h(gww[c * 81 + tap]);
    return;
  }
  id -= 5184;
  if (id < 576) {                  // packed BN scale [cblk8][o9][ch8]
    int cblk = id / 72, r = id - cblk * 72;
    int o = r >> 3, ch = r & 7;
    int c = cblk * 8 + ch;
    float A = gbg[c * 9 + o] / sqrtf(gbv[c * 9 + o] + EPSV);
    apk[id] = f2h(A);
    return;
  }
  id -= 576;
  if (id < 576) {                  // packed BN shift
    int cblk = id / 72, r = id - cblk * 72;
    int o = r >> 3, ch = r & 7;
    int c = cblk * 8 + ch;
    float A = gbg[c * 9 + o] / sqrtf(gbv[c * 9 + o] + EPSV);
    float B = (gwb[c * 9 + o] - gbm[c * 9 + o]) * A + gbb[c * 9 + o];
    bpk[id] = f2h(B);
    return;
  }
  id -= 576;
  if (id < 64) {                   // final BN fold (+ mean ensemble bias)
    float s = bng[id] / sqrtf(bnv[id] + EPSV);
    esc[id] = s;
    float bm = (ensb[id] + ensb[64 + id] + ensb[128 + id]) * (1.f / 3.f);
    ebi[id] = (bm - bnm[id]) * s + bnb[id];
    return;
  }
  id -= 64;
  ushort8v z = {0, 0, 0, 0, 0, 0, 0, 0};
  const int perY = 22 * PR + 128 * 22;      // 6116: ypad border (pad 11)
  if (id < perY * Bn) {
    int b = id / perY; int r = id - b * perY;
    int tb = 22 * PR;
    int row, col;
    if (r < tb) {
      int rr = r / PR; col = r - rr * PR;
      row = (rr < 11) ? rr : (rr + 128);
    } else {
      int r2 = r - tb;
      row = 11 + r2 / 22;
      int cc = r2 % 22;
      col = (cc < 11) ? cc : (cc + 128);
    }
    #pragma unroll
    for (int kb = 0; kb < 4; kb++) {
      unsigned short* p = ypad + clb(b, row, kb, col, PR);
      *(ushort8v*)p = z;
      *(ushort8v*)(p + 8) = z;
    }
    return;
  }
  id -= perY * Bn;
  const int perS = 2 * PE + 256;            // 516: spad border (pad 1)
  if (id < perS * Bn) {
    int b = id / perS; int r = id - b * perS;
    int tb = 2 * PE;
    int row, col;
    if (r < tb) {
      int rr = r / PE; col = r - rr * PE;
      row = (rr < 1) ? 0 : 129;
    } else {
      int r2 = r - tb;
      row = 1 + r2 / 2;
      col = (r2 & 1) ? 129 : 0;
    }
    #pragma unroll
    for (int kb = 0; kb < 4; kb++) {
      unsigned short* p = spad + clb(b, row, kb, col, PE);
      *(ushort8v*)p = z;
      *(ushort8v*)(p + 8) = z;
    }
  }
}

// ---------------- stage 1: conv1x1(relu(x)) via MFMA, planar fp32 in --------
__global__ __launch_bounds__(256, 4) void k_pw1x(const float* __restrict__ x,
    const unsigned short* __restrict__ apw, const float* __restrict__ bias,
    unsigned short* __restrict__ ypad)
{
  int b, h; swz_bh(b, h);
  const int tid = threadIdx.x, wv = tid >> 6, l = tid & 63;
  const int ln31 = l & 31, g = l >> 5;
  const int px = wv * 32 + ln31;
  const float* xb = x + ((size_t)b * Cn) * Pn + h * Wn + px;
  v16f acc0, acc1;
  #pragma unroll
  for (int r = 0; r < 16; r++) { acc0[r] = 0.f; acc1[r] = 0.f; }
  const unsigned short* apl = apw + l * 8;
  #pragma unroll
  for (int kb = 0; kb < 4; kb++) {
    int c0 = kb * 16 + g * 8;
    v8h Bf;
    #pragma unroll
    for (int e = 0; e < 8; e++)
      Bf[e] = (_Float16)fmaxf(xb[(size_t)(c0 + e) * Pn], 0.f);
    v8h A0 = *(const v8h*)(apl + (kb * 2) * 512);
    v8h A1 = *(const v8h*)(apl + (kb * 2 + 1) * 512);
    acc0 = __builtin_amdgcn_mfma_f32_32x32x16_f16(A0, Bf, acc0, 0, 0, 0);
    acc1 = __builtin_amdgcn_mfma_f32_32x32x16_f16(A1, Bf, acc1, 0, 0, 0);
  }
  #pragma unroll
  for (int t = 0; t < 4; t++) {
    int c0 = 8 * t + 4 * g;
    int kb = c0 >> 4, sub = c0 & 15;
    ushort4v s0, s1;
    #pragma unroll
    for (int u = 0; u < 4; u++) {
      s0[u] = f2h(acc0[4 * t + u] + bias[c0 + u]);
      s1[u] = f2h(acc1[4 * t + u] + bias[c0 + u + 32]);
    }
    *(ushort4v*)(ypad + clb(b, h + 11, kb, px + 11, PR) + sub) = s0;
    *(ushort4v*)(ypad + clb(b, h + 11, kb + 2, px + 11, PR) + sub) = s1;
  }
}

// ---------------- stage 2: cdcm, 2 rows/block, async dbuf A-staging ---------
// grid 512. 8 chunks of (d,kbp) = 36KB each, double-buffered in LDS via
// global_load_lds. Counted vmcnt(9) (never 0 mid-loop) + raw s_barrier:
// staging latency hides under previous chunk's B-loads + MFMA.
__global__ __launch_bounds__(256) void k_cdcm_mfma(
    const unsigned short* __restrict__ ypad,
    const unsigned short* __restrict__ apack,
    unsigned short* __restrict__ spad)
{
  __shared__ __align__(16) unsigned short Abuf[2][18432];  // 2 x 36 KB
  const int bid = blockIdx.x;
  const int b = bid & 7, h0 = (bid >> 3) * 2;
  const int tid = threadIdx.x, wv = tid >> 6, l = tid & 63;
  const int ln31 = l & 31, g = l >> 5;

  // issue chunk 0 (9 x 1KB per wave, linear)
  {
    const char* src = (const char*)apack;
    char* dst = (char*)&Abuf[0][0];
    #pragma unroll
    for (int it = 0; it < 9; it++) {
      int off = (wv * 9 + it) * 1024;
      gload_lds16(src + off + l * 16, dst + off);
    }
  }

  v16f a00, a01, a10, a11;   // [row][out-half]
  #pragma unroll
  for (int r = 0; r < 16; r++) { a00[r] = 0.f; a01[r] = 0.f; a10[r] = 0.f; a11[r] = 0.f; }

  #pragma unroll
  for (int d = 0; d < 4; d++) {
    const int dil = 5 + 2 * d;
    #pragma unroll
    for (int kbp = 0; kbp < 2; kbp++) {
      const int c = d * 2 + kbp;
      if (c < 7) {                 // prefetch next chunk into other buffer
        const char* src = (const char*)(apack + (c + 1) * 18432);
        char* dst = (char*)&Abuf[(c + 1) & 1][0];
        #pragma unroll
        for (int it = 0; it < 9; it++) {
          int off = (wv * 9 + it) * 1024;
          gload_lds16(src + off + l * 16, dst + off);
        }
        asm volatile("s_waitcnt vmcnt(9)" ::: "memory");  // chunk c landed
      } else {
        asm volatile("s_waitcnt vmcnt(0)" ::: "memory");  // last chunk: drain
      }
      asm volatile("s_barrier" ::: "memory");

      const unsigned short* abl = &Abuf[c & 1][0] + l * 8;
      #pragma unroll
      for (int ky = 0; ky < 3; ky++) {
        const int r0 = h0 + 11 + (ky - 1) * dil;
        #pragma unroll
        for (int kx = 0; kx < 3; kx++) {
          const int col = wv * 32 + ln31 + (kx - 1) * dil + 11;
          const int t9 = ky * 3 + kx;
          #pragma unroll
          for (int kbl = 0; kbl < 2; kbl++) {
            const int kb = kbp * 2 + kbl;
            v8h B0 = *(const v8h*)(ypad + clb(b, r0, kb, col, PR) + g * 8);
            v8h B1 = *(const v8h*)(ypad + clb(b, r0 + 1, kb, col, PR) + g * 8);
            const unsigned short* ap = abl + (t9 * 2 + kbl) * 1024;
            v8h A0 = *(const v8h*)(ap);
            v8h A1 = *(const v8h*)(ap + 512);
            a00 = __builtin_amdgcn_mfma_f32_32x32x16_f16(A0, B0, a00, 0, 0, 0);
            a01 = __builtin_amdgcn_mfma_f32_32x32x16_f16(A1, B0, a01, 0, 0, 0);
            a10 = __builtin_amdgcn_mfma_f32_32x32x16_f16(A0, B1, a10, 0, 0, 0);
            a11 = __builtin_amdgcn_mfma_f32_32x32x16_f16(A1, B1, a11, 0, 0, 0);
          }
        }
      }
      asm volatile("s_barrier" ::: "memory");  // all waves done with buf[c&1]
    }
  }
  const int px = wv * 32 + ln31;
  #pragma unroll
  for (int t = 0; t < 4; t++) {
    int c0 = 8 * t + 4 * g;
    int kb = c0 >> 4, sub = c0 & 15;
    ushort4v s0, s1, s2, s3;
    #pragma unroll
    for (int u = 0; u < 4; u++) {
      s0[u] = f2h(a00[4 * t + u]);
      s1[u] = f2h(a01[4 * t + u]);
      s2[u] = f2h(a10[4 * t + u]);
      s3[u] = f2h(a11[4 * t + u]);
    }
    *(ushort4v*)(spad + clb(b, h0 + 1, kb, px + 1, PE) + sub) = s0;
    *(ushort4v*)(spad + clb(b, h0 + 1, kb + 2, px + 1, PE) + sub) = s1;
    *(ushort4v*)(spad + clb(b, h0 + 2, kb, px + 1, PE) + sub) = s2;
    *(ushort4v*)(spad + clb(b, h0 + 2, kb + 2, px + 1, PE) + sub) = s3;
  }
}

// ---------------- stage 3: depthwise (VALU) + pointwise (MFMA) --------------
// Blocks h==0/h==1 also zero y2pad's pad-1 borders (safe: nothing reads
// y2pad until invol; border writes disjoint from all interior writes).
__global__ __launch_bounds__(256, 4) void k_dwpw_mfma(
    const unsigned short* __restrict__ spad,
    const float* __restrict__ dww, const float* __restrict__ dwb,
    const unsigned short* __restrict__ appw, const float* __restrict__ pwb,
    unsigned short* __restrict__ y2pad)
{
  __shared__ float wdw[576];
  __shared__ float bdw[64];
  const int tid = threadIdx.x;
  for (int t = tid; t < 576; t += 256) wdw[t] = dww[t];
  if (tid < 64) bdw[tid] = dwb[tid];
  __syncthreads();

  int b, h; swz_bh(b, h);

  ushort8v z = {0, 0, 0, 0, 0, 0, 0, 0};
  if (h == 0) {
    for (int px = tid; px < 260; px += 256) {
      int row = (px < 130) ? 0 : 129;
      int col = (px < 130) ? px : px - 130;
      #pragma unroll
      for (int kb = 0; kb < 4; kb++) {
        unsigned short* p = y2pad + clb(b, row, kb, col, PE);
        *(ushort8v*)p = z;
        *(ushort8v*)(p + 8) = z;
      }
    }
  } else if (h == 1) {
    int row = 1 + (tid & 127);
    int col = (tid >> 7) ? 129 : 0;
    #pragma unroll
    for (int kb = 0; kb < 4; kb++) {
      unsigned short* p = y2pad + clb(b, row, kb, col, PE);
      *(ushort8v*)p = z;
      *(ushort8v*)(p + 8) = z;
    }
  }

  const int wv = tid >> 6, l = tid & 63;
  const int ln31 = l & 31, g = l >> 5;
  const int w = wv * 32 + ln31;

  v16f acc0, acc1;
  #pragma unroll
  for (int r = 0; r < 16; r++) { acc0[r] = 0.f; acc1[r] = 0.f; }
  const unsigned short* apl = appw + l * 8;

  #pragma unroll
  for (int kb = 0; kb < 4; kb++) {
    const int c0 = kb * 16 + g * 8;
    v8h t[9];
    #pragma unroll
    for (int k = 0; k < 9; k++) {
      const int dy = k / 3 - 1, dx = k % 3 - 1;
      t[k] = *(const v8h*)(spad + clb(b, h + 1 + dy, kb, w + 1 + dx, PE) + g * 8);
    }
    v8h dvh;
    #pragma unroll
    for (int e = 0; e < 8; e++) {
      const int c = c0 + e;
      float a = 4.f * bdw[c];
      #pragma unroll
      for (int k = 0; k < 9; k++) a += wdw[c * 9 + k] * (float)t[k][e];
      dvh[e] = (_Float16)a;
    }
    v8h A0 = *(const v8h*)(apl + (kb * 2) * 512);
    v8h A1 = *(const v8h*)(apl + (kb * 2 + 1) * 512);
    acc0 = __builtin_amdgcn_mfma_f32_32x32x16_f16(A0, dvh, acc0, 0, 0, 0);
    acc1 = __builtin_amdgcn_mfma_f32_32x32x16_f16(A1, dvh, acc1, 0, 0, 0);
  }
  #pragma unroll
  for (int t = 0; t < 4; t++) {
    int c0 = 8 * t + 4 * g;
    int kb = c0 >> 4, sub = c0 & 15;
    ushort4v s0, s1;
    #pragma unroll
    for (int u = 0; u < 4; u++) {
      s0[u] = f2h(acc0[4 * t + u] + 4.f * pwb[c0 + u]);
      s1[u] = f2h(acc1[4 * t + u] + 4.f * pwb[c0 + u + 32]);
    }
    *(ushort4v*)(y2pad + clb(b, h + 1, kb, w + 1, PE) + sub) = s0;
    *(ushort4v*)(y2pad + clb(b, h + 1, kb + 2, w + 1, PE) + sub) = s1;
  }
}

// ---------------- stage 4: involution, packed-fp16 softmax + MFMA -----------
__global__ __launch_bounds__(256, 3) void k_invol_mfma(
    const unsigned short* __restrict__ y2pad,
    const unsigned short* __restrict__ gwpk,
    const unsigned short* __restrict__ apk,
    const unsigned short* __restrict__ bpk,
    const unsigned short* __restrict__ apinv,
    const float* __restrict__ cbias,
    unsigned short* __restrict__ ipad)
{
  __shared__ __align__(16) unsigned short gws[5184];  // [cblk8][tap81][ch8]
  __shared__ __align__(16) unsigned short As[576];    // [cblk8][o9][ch8]
  __shared__ __align__(16) unsigned short Bs[576];
  const int tid = threadIdx.x;
  for (int t = tid; t < 648; t += 256)
    ((ushort8v*)gws)[t] = ((const ushort8v*)gwpk)[t];
  if (tid < 72) {
    ((ushort8v*)As)[tid] = ((const ushort8v*)apk)[tid];
    ((ushort8v*)Bs)[tid] = ((const ushort8v*)bpk)[tid];
  }
  __syncthreads();

  int b, h; swz_bh(b, h);
  const int wv = tid >> 6, l = tid & 63;
  const int p32 = l & 31, g = l >> 5;
  const int w = wv * 32 + p32;

  v16f acc0, acc1;
  #pragma unroll
  for (int r = 0; r < 16; r++) { acc0[r] = 0.f; acc1[r] = 0.f; }

  for (int cb4 = 0; cb4 < 4; cb4++) {
    const int cblk = cb4 * 2 + g;
    const unsigned short* gwp = gws + cblk * 648;
    const unsigned short* Ap = As + cblk * 72;
    const unsigned short* Bp = Bs + cblk * 72;

    v8h pt[9];
    #pragma unroll
    for (int k = 0; k < 9; k++) {
      const int dy = k / 3 - 1, dx = k % 3 - 1;
      pt[k] = *(const v8h*)(y2pad + clb(b, h + 1 + dy, cb4, w + 1 + dx, PE) + g * 8);
    }
    // gw matmul + BN, all packed fp16 (weights broadcast from LDS)
    v8h s[9];
    #pragma unroll
    for (int o = 0; o < 9; o++) {
      v8h a = (*(const v8h*)(gwp + o * 72)) * pt[0];
      #pragma unroll
      for (int i = 1; i < 9; i++)
        a += (*(const v8h*)(gwp + o * 72 + i * 8)) * pt[i];
      s[o] = a * (*(const v8h*)(Ap + o * 8)) + (*(const v8h*)(Bp + o * 8));
    }
    // softmax over the 9 taps (shift-free: |s| << 1, fp16-safe)
    v8h esum = {0, 0, 0, 0, 0, 0, 0, 0};
    #pragma unroll
    for (int o = 0; o < 9; o++) { s[o] = exp8h(s[o]); esum += s[o]; }
    v8h inv = rcp8h(esum);
    #pragma unroll
    for (int k = 0; k < 9; k++) pt[k] = pt[k] * s[k] * inv;

    const unsigned short* ap = apinv + l * 8;
    #pragma unroll
    for (int k = 0; k < 9; k++) {
      const unsigned short* a2 = ap + ((k * 4 + cb4) * 2) * 512;
      v8h A0 = *(const v8h*)(a2);
      v8h A1 = *(const v8h*)(a2 + 512);
      acc0 = __builtin_amdgcn_mfma_f32_32x32x16_f16(A0, pt[k], acc0, 0, 0, 0);
      acc1 = __builtin_amdgcn_mfma_f32_32x32x16_f16(A1, pt[k], acc1, 0, 0, 0);
    }
  }
  #pragma unroll
  for (int t = 0; t < 4; t++) {
    int c0 = 8 * t + 4 * g;
    int kb = c0 >> 4, sub = c0 & 15;
    ushort4v s0, s1;
    #pragma unroll
    for (int u = 0; u < 4; u++) {
      s0[u] = f2h(acc0[4 * t + u] + cbias[c0 + u]);
      s1[u] = f2h(acc1[4 * t + u] + cbias[c0 + u + 32]);
    }
    *(ushort4v*)(ipad + clb(b, h, kb, w, 128) + sub) = s0;
    *(ushort4v*)(ipad + clb(b, h, kb + 2, w, 128) + sub) = s1;
  }
}

// ---------------- stage 5: fr 1x1 + residual (direct epilogue add) ----------
__global__ __launch_bounds__(256, 4) void k_fr_mfma(
    const unsigned short* __restrict__ ipad,
    const unsigned short* __restrict__ apfr,
    const float* __restrict__ bias,
    unsigned short* __restrict__ opad)
{
  int b, h; swz_bh(b, h);
  const int tid = threadIdx.x, wv = tid >> 6, l = tid & 63;
  const int ln31 = l & 31, g = l >> 5;
  const int px = wv * 32 + ln31;
  v16f acc0, acc1;
  #pragma unroll
  for (int r = 0; r < 16; r++) { acc0[r] = 0.f; acc1[r] = 0.f; }
  const unsigned short* apl = apfr + l * 8;
  #pragma unroll
  for (int kb = 0; kb < 4; kb++) {
    v8h Bf = *(const v8h*)(ipad + clb(b, h, kb, px, 128) + g * 8);
    v8h A0 = *(const v8h*)(apl + (kb * 2) * 512);
    v8h A1 = *(const v8h*)(apl + (kb * 2 + 1) * 512);
    acc0 = __builtin_amdgcn_mfma_f32_32x32x16_f16(A0, Bf, acc0, 0, 0, 0);
    acc1 = __builtin_amdgcn_mfma_f32_32x32x16_f16(A1, Bf, acc1, 0, 0, 0);
  }
  #pragma unroll
  for (int t = 0; t < 4; t++) {
    int c0 = 8 * t + 4 * g;
    int kb = c0 >> 4, sub = c0 & 15;
    // residual values live at exactly the epilogue addresses
    ushort4v r0 = *(const ushort4v*)(ipad + clb(b, h, kb, px, 128) + sub);
    ushort4v r1 = *(const ushort4v*)(ipad + clb(b, h, kb + 2, px, 128) + sub);
    ushort4v s0, s1;
    #pragma unroll
    for (int u = 0; u < 4; u++) {
      s0[u] = f2h(acc0[4 * t + u] + bias[c0 + u] + h2f(r0[u]));
      s1[u] = f2h(acc1[4 * t + u] + bias[c0 + u + 32] + h2f(r1[u]));
    }
    *(ushort4v*)(opad + clb(b, h + 1, kb, px + 1, PE) + sub) = s0;
    *(ushort4v*)(opad + clb(b, h + 1, kb + 2, px + 1, PE) + sub) = s1;
  }
}

// ---------------- stage 6: ensemble conv3x3, 2 rows/block, LDS weights ------
__global__ __launch_bounds__(256) void k_ens_mfma(
    const unsigned short* __restrict__ opad,
    const unsigned short* __restrict__ apens,
    const float* __restrict__ esc, const float* __restrict__ ebi,
    float* __restrict__ out)
{
  __shared__ __align__(16) unsigned short Abuf[36864];  // 72 KB: 9 taps
  const int tid = threadIdx.x;
  {
    const ushort8v* src = (const ushort8v*)apens;
    ushort8v* dst = (ushort8v*)Abuf;
    #pragma unroll
    for (int it = 0; it < 18; it++)
      dst[tid + it * 256] = src[tid + it * 256];
  }
  __syncthreads();

  const int bid = blockIdx.x;
  const int b = bid & 7, h0 = (bid >> 3) * 2;
  const int wv = tid >> 6, l = tid & 63;
  const int ln31 = l & 31, g = l >> 5;

  v16f a00, a01, a10, a11;
  #pragma unroll
  for (int r = 0; r < 16; r++) { a00[r] = 0.f; a01[r] = 0.f; a10[r] = 0.f; a11[r] = 0.f; }

  const unsigned short* abl = Abuf + l * 8;

  #pragma unroll
  for (int ky = 0; ky < 3; ky++) {
    #pragma unroll
    for (int kx = 0; kx < 3; kx++) {
      const int tap = ky * 3 + kx;
      const int r0 = h0 + ky;              // (h0+1) + (ky-1)
      const int col = wv * 32 + ln31 + kx; // (+1) + (kx-1)
      const unsigned short* ap = abl + tap * 4096;
      #pragma unroll
      for (int kb = 0; kb < 4; kb++) {
        v8h B0 = *(const v8h*)(opad + clb(b, r0, kb, col, PE) + g * 8);
        v8h B1 = *(const v8h*)(opad + clb(b, r0 + 1, kb, col, PE) + g * 8);
        v8h A0 = *(const v8h*)(ap + kb * 1024);
        v8h A1 = *(const v8h*)(ap + kb * 1024 + 512);
        a00 = __builtin_amdgcn_mfma_f32_32x32x16_f16(A0, B0, a00, 0, 0, 0);
        a01 = __builtin_amdgcn_mfma_f32_32x32x16_f16(A1, B0, a01, 0, 0, 0);
        a10 = __builtin_amdgcn_mfma_f32_32x32x16_f16(A0, B1, a10, 0, 0, 0);
        a11 = __builtin_amdgcn_mfma_f32_32x32x16_f16(A1, B1, a11, 0, 0, 0);
      }
    }
  }
  float* sp0 = out + ((size_t)b * Cn) * Pn + h0 * Wn + wv * 32 + ln31;
  float* sp1 = sp0 + Wn;
  #pragma unroll
  for (int r = 0; r < 16; r++) {
    int o0 = (r & 3) + 8 * (r >> 2) + 4 * g;
    float e0 = esc[o0], e1 = esc[o0 + 32];
    float i0 = ebi[o0], i1 = ebi[o0 + 32];
    sp0[(size_t)o0 * Pn] = fmaxf(a00[r] * e0 + i0, 0.f);
    sp0[(size_t)(o0 + 32) * Pn] = fmaxf(a01[r] * e1 + i1, 0.f);
    sp1[(size_t)o0 * Pn] = fmaxf(a10[r] * e0 + i0, 0.f);
    sp1[(size_t)(o0 + 32) * Pn] = fmaxf(a11[r] * e1 + i1, 0.f);
  }
}

extern "C" void kernel_launch(void* const* d_in, const int* in_sizes, int n_in,
                              void* d_out, int out_size, void* d_ws, size_t ws_size,
                              hipStream_t stream)
{
  const float* x    = (const float*)d_in[0];
  const float* w1   = (const float*)d_in[1];
  const float* b1   = (const float*)d_in[2];
  const float* w5   = (const float*)d_in[3];
  const float* w7   = (const float*)d_in[4];
  const float* w9   = (const float*)d_in[5];
  const float* w11  = (const float*)d_in[6];
  const float* dww  = (const float*)d_in[7];
  const float* dwb  = (const float*)d_in[8];
  const float* pww  = (const float*)d_in[9];
  const float* pwb  = (const float*)d_in[10];
  const float* gww  = (const float*)d_in[11];
  const float* gwb  = (const float*)d_in[12];
  const float* gbg  = (const float*)d_in[13];
  const float* gbb  = (const float*)d_in[14];
  const float* gbm  = (const float*)d_in[15];
  const float* gbv  = (const float*)d_in[16];
  const float* cw   = (const float*)d_in[17];
  const float* cb   = (const float*)d_in[18];
  const float* frw  = (const float*)d_in[19];
  const float* frb  = (const float*)d_in[20];
  const float* ensw = (const float*)d_in[21];
  const float* ensb = (const float*)d_in[22];
  const float* bng  = (const float*)d_in[23];
  const float* bnb  = (const float*)d_in[24];
  const float* bnm  = (const float*)d_in[25];
  const float* bnv  = (const float*)d_in[26];

  // ws: ypad (pad-11) region, overlaid later by y2pad then opad (pad-1)
  unsigned short* wsu   = (unsigned short*)d_ws;
  unsigned short* ypad  = wsu;
  unsigned short* y2pad = wsu;
  unsigned short* opad  = wsu;
  unsigned short* apack = wsu + YPAD_ELEMS;         // 147456
  unsigned short* apinv = apack + 147456;           // 36864
  unsigned short* apens = apinv + 36864;            // 36864
  unsigned short* appw1 = apens + 36864;            // 4096
  unsigned short* appw  = appw1 + 4096;             // 4096
  unsigned short* apfr  = appw + 4096;              // 4096
  unsigned short* gwpk  = apfr + 4096;              // 5184
  unsigned short* apk   = gwpk + 5184;              // 576
  unsigned short* bpk   = apk + 576;                // 576
  float* esc = (float*)(bpk + 576);                 // 64
  float* ebi = esc + 64;                            // 64

  // d_out: spad (fp16 blocked-CL pad-1) -> ipad (blocked-CL) -> planar fp32
  unsigned short* spad = (unsigned short*)d_out;
  unsigned short* ipad = (unsigned short*)d_out;
  float* D = (float*)d_out;

  // prep also zeroes ypad borders (pad 11) and spad borders (pad 1)
  k_prep<<<1145, 256, 0, stream>>>(w1, w5, w7, w9, w11, pww, frw, cw,
                                   gww, gwb, gbg, gbb, gbm, gbv, ensw, ensb,
                                   bng, bnb, bnm, bnv,
                                   apack, apinv, apens, appw1, appw, apfr,
                                   gwpk, apk, bpk, esc, ebi,
                                   ypad, spad);

  // 1) ypad = conv1x1(relu(x))           x (planar f32) -> ypad (blocked CL)
  k_pw1x<<<1024, 256, 0, stream>>>(x, appw1, b1, ypad);
  // 2) spad = sum_d dilconv_d(y)         ypad -> spad (d_out, pad-1)
  k_cdcm_mfma<<<512, 256, 0, stream>>>(ypad, apack, spad);
  // 3) y2pad = PW(DW(spad))              spad -> y2pad (ws, pad-1)
  //    (blocks h=0/1 also zero y2pad borders; ypad is dead by now)
  k_dwpw_mfma<<<1024, 256, 0, stream>>>(spad, dww, dwb, appw, pwb, y2pad);
  // 4) ipad = involution(y2pad)          y2pad -> ipad (d_out)
  k_invol_mfma<<<1024, 256, 0, stream>>>(y2pad, gwpk, apk, bpk, apinv, cb, ipad);
  // 5) opad = fr(ipad) + ipad            ipad -> opad (ws, pad-1)
  k_fr_mfma<<<1024, 256, 0, stream>>>(ipad, apfr, frb, opad);
  // 6) out = relu(BN(ens3x3(opad)))      opad -> D (planar fp32)
  k_ens_mfma<<<512, 256, 0, stream>>>(opad, apens, esc, ebi, D);
}

// Round 13
// 149.727 us; speedup vs baseline: 15.5765x; 1.0021x over previous
//
#include <hip/hip_runtime.h>
#include <hip/hip_bf16.h>
#include <hip/hip_fp16.h>

#define EPSV 1e-5f
#define Bn 8
#define Cn 64
#define Hn 128
#define Wn 128
#define Pn (Hn*Wn)          // 16384
#define PR 150              // cdcm pad: 11 + 128 + 11
#define PE 130              // 1-pad: 1 + 128 + 1
#define YPAD_ELEMS (Bn*PR*PR*Cn)   // 11,520,000 fp16

typedef _Float16 v8h __attribute__((ext_vector_type(8)));
typedef float v16f __attribute__((ext_vector_type(16)));
typedef unsigned short ushort8v __attribute__((ext_vector_type(8)));
typedef unsigned short ushort4v __attribute__((ext_vector_type(4)));

__device__ __forceinline__ unsigned short f2h(float v) {
  _Float16 h = (_Float16)v;
  return *reinterpret_cast<const unsigned short*>(&h);
}
__device__ __forceinline__ float h2f(unsigned short u) {
  return (float)(*reinterpret_cast<const _Float16*>(&u));
}

__device__ __forceinline__ v8h exp8h(v8h x) {
  union { v8h v; __half2 h[4]; } u; u.v = x;
  #pragma unroll
  for (int i = 0; i < 4; i++) u.h[i] = h2exp(u.h[i]);
  return u.v;
}
__device__ __forceinline__ v8h rcp8h(v8h x) {
  union { v8h v; __half2 h[4]; } u; u.v = x;
  #pragma unroll
  for (int i = 0; i < 4; i++) u.h[i] = h2rcp(u.h[i]);
  return u.v;
}

// async global->LDS, 16B per lane; LDS dest = uniform base + lane*16
__device__ __forceinline__ void gload_lds16(const void* g, void* l) {
  __builtin_amdgcn_global_load_lds(
      (const __attribute__((address_space(1))) unsigned int*)g,
      (__attribute__((address_space(3))) unsigned int*)l, 16, 0, 0);
}

// channel-blocked CL addressing: [b][row][kb(4)][col][16], elems
__device__ __forceinline__ size_t clb(int b, int row, int kb, int col, int PD) {
  return ((((size_t)b * PD + row) * 4 + kb) * PD + col) * 16;
}

// batch-major XCD swizzle: 1024 blocks, XCD r gets batch r's rows in order
__device__ __forceinline__ void swz_bh(int& b, int& h) {
  int bid = blockIdx.x;
  int w = (bid & 7) * 128 + (bid >> 3);
  b = w >> 7; h = w & 127;
}

// ---------------- prep: weight packs + BN folds + border zeros --------------
// cdcm A-pack layout (18KB chunks): [d][kb][tap9][mh][512]
// other A-packs: [tap][kb][mh][lane*8+e], m=mh*32+(l&31), c=kb*16+(l>>5)*8+e
__global__ __launch_bounds__(256) void k_prep(
    const float* __restrict__ w1, const float* __restrict__ w5,
    const float* __restrict__ w7, const float* __restrict__ w9,
    const float* __restrict__ w11, const float* __restrict__ pww,
    const float* __restrict__ frw, const float* __restrict__ cw,
    const float* __restrict__ gww, const float* __restrict__ gwb,
    const float* __restrict__ gbg, const float* __restrict__ gbb,
    const float* __restrict__ gbm, const float* __restrict__ gbv,
    const float* __restrict__ ensw, const float* __restrict__ ensb,
    const float* __restrict__ bng, const float* __restrict__ bnb,
    const float* __restrict__ bnm, const float* __restrict__ bnv,
    unsigned short* __restrict__ apack, unsigned short* __restrict__ apinv,
    unsigned short* __restrict__ apens, unsigned short* __restrict__ appw1,
    unsigned short* __restrict__ appw, unsigned short* __restrict__ apfr,
    unsigned short* __restrict__ gwpk,
    unsigned short* __restrict__ apk, unsigned short* __restrict__ bpk,
    float* __restrict__ esc, float* __restrict__ ebi,
    unsigned short* __restrict__ ypad, unsigned short* __restrict__ spad)
{
  int id = blockIdx.x * 256 + threadIdx.x;
  if (id < 147456) {               // cdcm: chunked [d][kb][t9][mh][512]
    int c0 = id / 9216;            // ci = d*4 + kb
    int d = c0 >> 2, kb = c0 & 3;
    int r = id - c0 * 9216;
    int t9 = r / 1024;
    int r2 = r & 1023;
    int mh = r2 >> 9, l = (r2 >> 3) & 63, e = r2 & 7;
    int m = mh * 32 + (l & 31);
    int c = kb * 16 + (l >> 5) * 8 + e;
    const float* src = (d == 0) ? w5 : (d == 1) ? w7 : (d == 2) ? w9 : w11;
    apack[id] = f2h(src[(m * 64 + c) * 9 + t9]);
    return;
  }
  id -= 147456;
  if (id < 36864) {                // involution conv_w: 9 taps
    int e = id & 7, l = (id >> 3) & 63, mh = (id >> 9) & 1,
        kb = (id >> 10) & 3, tap = id >> 12;
    int m = mh * 32 + (l & 31);
    int c = kb * 16 + (l >> 5) * 8 + e;
    apinv[id] = f2h(cw[(m * 64 + c) * 9 + tap]);
    return;
  }
  id -= 36864;
  if (id < 36864) {                // ensemble mean weights: 9 taps
    int e = id & 7, l = (id >> 3) & 63, mh = (id >> 9) & 1,
        kb = (id >> 10) & 3, tap = id >> 12;
    int m = mh * 32 + (l & 31);
    int c = kb * 16 + (l >> 5) * 8 + e;
    float v = (ensw[((0 * 64 + m) * 64 + c) * 9 + tap] +
               ensw[((64 + m) * 64 + c) * 9 + tap] +
               ensw[((128 + m) * 64 + c) * 9 + tap]) * (1.f / 3.f);
    apens[id] = f2h(v);
    return;
  }
  id -= 36864;
  if (id < 4096) {                 // conv1 1x1
    int e = id & 7, l = (id >> 3) & 63, mh = (id >> 9) & 1, kb = (id >> 10) & 3;
    int m = mh * 32 + (l & 31);
    int c = kb * 16 + (l >> 5) * 8 + e;
    appw1[id] = f2h(w1[m * 64 + c]);
    return;
  }
  id -= 4096;
  if (id < 4096) {                 // dsc pointwise 1x1
    int e = id & 7, l = (id >> 3) & 63, mh = (id >> 9) & 1, kb = (id >> 10) & 3;
    int m = mh * 32 + (l & 31);
    int c = kb * 16 + (l >> 5) * 8 + e;
    appw[id] = f2h(pww[m * 64 + c]);
    return;
  }
  id -= 4096;
  if (id < 4096) {                 // fr 1x1
    int e = id & 7, l = (id >> 3) & 63, mh = (id >> 9) & 1, kb = (id >> 10) & 3;
    int m = mh * 32 + (l & 31);
    int c = kb * 16 + (l >> 5) * 8 + e;
    apfr[id] = f2h(frw[m * 64 + c]);
    return;
  }
  id -= 4096;
  if (id < 5184) {                 // packed gw weights [cblk8][tap81][ch8]
    int cblk = id / 648, r = id - cblk * 648;
    int tap = r >> 3, ch = r & 7;
    int c = cblk * 8 + ch;
    gwpk[id] = f2h(gww[c * 81 + tap]);
    return;
  }
  id -= 5184;
  if (id < 576) {                  // packed BN scale [cblk8][o9][ch8]
    int cblk = id / 72, r = id - cblk * 72;
    int o = r >> 3, ch = r & 7;
    int c = cblk * 8 + ch;
    float A = gbg[c * 9 + o] / sqrtf(gbv[c * 9 + o] + EPSV);
    apk[id] = f2h(A);
    return;
  }
  id -= 576;
  if (id < 576) {                  // packed BN shift
    int cblk = id / 72, r = id - cblk * 72;
    int o = r >> 3, ch = r & 7;
    int c = cblk * 8 + ch;
    float A = gbg[c * 9 + o] / sqrtf(gbv[c * 9 + o] + EPSV);
    float B = (gwb[c * 9 + o] - gbm[c * 9 + o]) * A + gbb[c * 9 + o];
    bpk[id] = f2h(B);
    return;
  }
  id -= 576;
  if (id < 64) {                   // final BN fold (+ mean ensemble bias)
    float s = bng[id] / sqrtf(bnv[id] + EPSV);
    esc[id] = s;
    float bm = (ensb[id] + ensb[64 + id] + ensb[128 + id]) * (1.f / 3.f);
    ebi[id] = (bm - bnm[id]) * s + bnb[id];
    return;
  }
  id -= 64;
  ushort8v z = {0, 0, 0, 0, 0, 0, 0, 0};
  const int perY = 22 * PR + 128 * 22;      // 6116: ypad border (pad 11)
  if (id < perY * Bn) {
    int b = id / perY; int r = id - b * perY;
    int tb = 22 * PR;
    int row, col;
    if (r < tb) {
      int rr = r / PR; col = r - rr * PR;
      row = (rr < 11) ? rr : (rr + 128);
    } else {
      int r2 = r - tb;
      row = 11 + r2 / 22;
      int cc = r2 % 22;
      col = (cc < 11) ? cc : (cc + 128);
    }
    #pragma unroll
    for (int kb = 0; kb < 4; kb++) {
      unsigned short* p = ypad + clb(b, row, kb, col, PR);
      *(ushort8v*)p = z;
      *(ushort8v*)(p + 8) = z;
    }
    return;
  }
  id -= perY * Bn;
  const int perS = 2 * PE + 256;            // 516: spad border (pad 1)
  if (id < perS * Bn) {
    int b = id / perS; int r = id - b * perS;
    int tb = 2 * PE;
    int row, col;
    if (r < tb) {
      int rr = r / PE; col = r - rr * PE;
      row = (rr < 1) ? 0 : 129;
    } else {
      int r2 = r - tb;
      row = 1 + r2 / 2;
      col = (r2 & 1) ? 129 : 0;
    }
    #pragma unroll
    for (int kb = 0; kb < 4; kb++) {
      unsigned short* p = spad + clb(b, row, kb, col, PE);
      *(ushort8v*)p = z;
      *(ushort8v*)(p + 8) = z;
    }
  }
}

// ---------------- stage 1: conv1x1(relu(x)) via MFMA, planar fp32 in --------
__global__ __launch_bounds__(256, 4) void k_pw1x(const float* __restrict__ x,
    const unsigned short* __restrict__ apw, const float* __restrict__ bias,
    unsigned short* __restrict__ ypad)
{
  int b, h; swz_bh(b, h);
  const int tid = threadIdx.x, wv = tid >> 6, l = tid & 63;
  const int ln31 = l & 31, g = l >> 5;
  const int px = wv * 32 + ln31;
  const float* xb = x + ((size_t)b * Cn) * Pn + h * Wn + px;
  v16f acc0, acc1;
  #pragma unroll
  for (int r = 0; r < 16; r++) { acc0[r] = 0.f; acc1[r] = 0.f; }
  const unsigned short* apl = apw + l * 8;
  #pragma unroll
  for (int kb = 0; kb < 4; kb++) {
    int c0 = kb * 16 + g * 8;
    v8h Bf;
    #pragma unroll
    for (int e = 0; e < 8; e++)
      Bf[e] = (_Float16)fmaxf(xb[(size_t)(c0 + e) * Pn], 0.f);
    v8h A0 = *(const v8h*)(apl + (kb * 2) * 512);
    v8h A1 = *(const v8h*)(apl + (kb * 2 + 1) * 512);
    acc0 = __builtin_amdgcn_mfma_f32_32x32x16_f16(A0, Bf, acc0, 0, 0, 0);
    acc1 = __builtin_amdgcn_mfma_f32_32x32x16_f16(A1, Bf, acc1, 0, 0, 0);
  }
  #pragma unroll
  for (int t = 0; t < 4; t++) {
    int c0 = 8 * t + 4 * g;
    int kb = c0 >> 4, sub = c0 & 15;
    ushort4v s0, s1;
    #pragma unroll
    for (int u = 0; u < 4; u++) {
      s0[u] = f2h(acc0[4 * t + u] + bias[c0 + u]);
      s1[u] = f2h(acc1[4 * t + u] + bias[c0 + u + 32]);
    }
    *(ushort4v*)(ypad + clb(b, h + 11, kb, px + 11, PR) + sub) = s0;
    *(ushort4v*)(ypad + clb(b, h + 11, kb + 2, px + 11, PR) + sub) = s1;
  }
}

// ---------------- stage 2: cdcm, 2 rows/block, 18KB async dbuf, 4 blk/CU ----
// grid 512. 16 chunks of (d,kb) = 18KB, double-buffered (36KB LDS total).
// Waves 0-1 stage 5 granules, waves 2-3 stage 4; counted per-wave vmcnt.
__global__ __launch_bounds__(256, 4) void k_cdcm_mfma(
    const unsigned short* __restrict__ ypad,
    const unsigned short* __restrict__ apack,
    unsigned short* __restrict__ spad)
{
  __shared__ __align__(16) unsigned short Abuf[2][9216];  // 2 x 18 KB
  const int bid = blockIdx.x;
  const int b = bid & 7, h0 = (bid >> 3) * 2;
  const int tid = threadIdx.x, wv = tid >> 6, l = tid & 63;
  const int ln31 = l & 31, g = l >> 5;
  const int ng = (wv < 2) ? 5 : 4;   // granules this wave stages (18 total)

  // issue chunk 0
  {
    const char* src = (const char*)apack;
    char* dst = (char*)&Abuf[0][0];
    for (int i = 0; i < ng; i++) {
      int off = (wv + i * 4) * 1024;
      gload_lds16(src + off + l * 16, dst + off);
    }
  }

  v16f a00, a01, a10, a11;   // [row][out-half]
  #pragma unroll
  for (int r = 0; r < 16; r++) { a00[r] = 0.f; a01[r] = 0.f; a10[r] = 0.f; a11[r] = 0.f; }

  #pragma unroll
  for (int d = 0; d < 4; d++) {
    const int dil = 5 + 2 * d;
    #pragma unroll
    for (int kb = 0; kb < 4; kb++) {
      const int ci = d * 4 + kb;
      if (ci < 15) {               // prefetch next chunk into other buffer
        const char* src = (const char*)(apack + (ci + 1) * 9216);
        char* dst = (char*)&Abuf[(ci + 1) & 1][0];
        for (int i = 0; i < ng; i++) {
          int off = (wv + i * 4) * 1024;
          gload_lds16(src + off + l * 16, dst + off);
        }
        if (wv < 2) asm volatile("s_waitcnt vmcnt(5)" ::: "memory");
        else        asm volatile("s_waitcnt vmcnt(4)" ::: "memory");
      } else {
        asm volatile("s_waitcnt vmcnt(0)" ::: "memory");
      }
      asm volatile("s_barrier" ::: "memory");

      __builtin_amdgcn_s_setprio(1);
      const unsigned short* abl = &Abuf[ci & 1][0] + l * 8;
      #pragma unroll
      for (int ky = 0; ky < 3; ky++) {
        const int r0 = h0 + 11 + (ky - 1) * dil;
        #pragma unroll
        for (int kx = 0; kx < 3; kx++) {
          const int col = wv * 32 + ln31 + (kx - 1) * dil + 11;
          const int t9 = ky * 3 + kx;
          v8h B0 = *(const v8h*)(ypad + clb(b, r0, kb, col, PR) + g * 8);
          v8h B1 = *(const v8h*)(ypad + clb(b, r0 + 1, kb, col, PR) + g * 8);
          const unsigned short* ap = abl + t9 * 1024;
          v8h A0 = *(const v8h*)(ap);
          v8h A1 = *(const v8h*)(ap + 512);
          a00 = __builtin_amdgcn_mfma_f32_32x32x16_f16(A0, B0, a00, 0, 0, 0);
          a01 = __builtin_amdgcn_mfma_f32_32x32x16_f16(A1, B0, a01, 0, 0, 0);
          a10 = __builtin_amdgcn_mfma_f32_32x32x16_f16(A0, B1, a10, 0, 0, 0);
          a11 = __builtin_amdgcn_mfma_f32_32x32x16_f16(A1, B1, a11, 0, 0, 0);
        }
      }
      __builtin_amdgcn_s_setprio(0);
      asm volatile("s_barrier" ::: "memory");  // waves done with buf[ci&1]
    }
  }
  const int px = wv * 32 + ln31;
  #pragma unroll
  for (int t = 0; t < 4; t++) {
    int c0 = 8 * t + 4 * g;
    int kb = c0 >> 4, sub = c0 & 15;
    ushort4v s0, s1, s2, s3;
    #pragma unroll
    for (int u = 0; u < 4; u++) {
      s0[u] = f2h(a00[4 * t + u]);
      s1[u] = f2h(a01[4 * t + u]);
      s2[u] = f2h(a10[4 * t + u]);
      s3[u] = f2h(a11[4 * t + u]);
    }
    *(ushort4v*)(spad + clb(b, h0 + 1, kb, px + 1, PE) + sub) = s0;
    *(ushort4v*)(spad + clb(b, h0 + 1, kb + 2, px + 1, PE) + sub) = s1;
    *(ushort4v*)(spad + clb(b, h0 + 2, kb, px + 1, PE) + sub) = s2;
    *(ushort4v*)(spad + clb(b, h0 + 2, kb + 2, px + 1, PE) + sub) = s3;
  }
}

// ---------------- stage 3: depthwise (VALU) + pointwise (MFMA) --------------
// Blocks h==0/h==1 also zero y2pad's pad-1 borders (safe: nothing reads
// y2pad until invol; border writes disjoint from all interior writes).
__global__ __launch_bounds__(256, 4) void k_dwpw_mfma(
    const unsigned short* __restrict__ spad,
    const float* __restrict__ dww, const float* __restrict__ dwb,
    const unsigned short* __restrict__ appw, const float* __restrict__ pwb,
    unsigned short* __restrict__ y2pad)
{
  __shared__ float wdw[576];
  __shared__ float bdw[64];
  const int tid = threadIdx.x;
  for (int t = tid; t < 576; t += 256) wdw[t] = dww[t];
  if (tid < 64) bdw[tid] = dwb[tid];
  __syncthreads();

  int b, h; swz_bh(b, h);

  ushort8v z = {0, 0, 0, 0, 0, 0, 0, 0};
  if (h == 0) {
    for (int px = tid; px < 260; px += 256) {
      int row = (px < 130) ? 0 : 129;
      int col = (px < 130) ? px : px - 130;
      #pragma unroll
      for (int kb = 0; kb < 4; kb++) {
        unsigned short* p = y2pad + clb(b, row, kb, col, PE);
        *(ushort8v*)p = z;
        *(ushort8v*)(p + 8) = z;
      }
    }
  } else if (h == 1) {
    int row = 1 + (tid & 127);
    int col = (tid >> 7) ? 129 : 0;
    #pragma unroll
    for (int kb = 0; kb < 4; kb++) {
      unsigned short* p = y2pad + clb(b, row, kb, col, PE);
      *(ushort8v*)p = z;
      *(ushort8v*)(p + 8) = z;
    }
  }

  const int wv = tid >> 6, l = tid & 63;
  const int ln31 = l & 31, g = l >> 5;
  const int w = wv * 32 + ln31;

  v16f acc0, acc1;
  #pragma unroll
  for (int r = 0; r < 16; r++) { acc0[r] = 0.f; acc1[r] = 0.f; }
  const unsigned short* apl = appw + l * 8;

  #pragma unroll
  for (int kb = 0; kb < 4; kb++) {
    const int c0 = kb * 16 + g * 8;
    v8h t[9];
    #pragma unroll
    for (int k = 0; k < 9; k++) {
      const int dy = k / 3 - 1, dx = k % 3 - 1;
      t[k] = *(const v8h*)(spad + clb(b, h + 1 + dy, kb, w + 1 + dx, PE) + g * 8);
    }
    v8h dvh;
    #pragma unroll
    for (int e = 0; e < 8; e++) {
      const int c = c0 + e;
      float a = 4.f * bdw[c];
      #pragma unroll
      for (int k = 0; k < 9; k++) a += wdw[c * 9 + k] * (float)t[k][e];
      dvh[e] = (_Float16)a;
    }
    v8h A0 = *(const v8h*)(apl + (kb * 2) * 512);
    v8h A1 = *(const v8h*)(apl + (kb * 2 + 1) * 512);
    acc0 = __builtin_amdgcn_mfma_f32_32x32x16_f16(A0, dvh, acc0, 0, 0, 0);
    acc1 = __builtin_amdgcn_mfma_f32_32x32x16_f16(A1, dvh, acc1, 0, 0, 0);
  }
  #pragma unroll
  for (int t = 0; t < 4; t++) {
    int c0 = 8 * t + 4 * g;
    int kb = c0 >> 4, sub = c0 & 15;
    ushort4v s0, s1;
    #pragma unroll
    for (int u = 0; u < 4; u++) {
      s0[u] = f2h(acc0[4 * t + u] + 4.f * pwb[c0 + u]);
      s1[u] = f2h(acc1[4 * t + u] + 4.f * pwb[c0 + u + 32]);
    }
    *(ushort4v*)(y2pad + clb(b, h + 1, kb, w + 1, PE) + sub) = s0;
    *(ushort4v*)(y2pad + clb(b, h + 1, kb + 2, w + 1, PE) + sub) = s1;
  }
}

// ---------------- stage 4: involution, packed-fp16 softmax + MFMA -----------
__global__ __launch_bounds__(256, 3) void k_invol_mfma(
    const unsigned short* __restrict__ y2pad,
    const unsigned short* __restrict__ gwpk,
    const unsigned short* __restrict__ apk,
    const unsigned short* __restrict__ bpk,
    const unsigned short* __restrict__ apinv,
    const float* __restrict__ cbias,
    unsigned short* __restrict__ ipad)
{
  __shared__ __align__(16) unsigned short gws[5184];  // [cblk8][tap81][ch8]
  __shared__ __align__(16) unsigned short As[576];    // [cblk8][o9][ch8]
  __shared__ __align__(16) unsigned short Bs[576];
  const int tid = threadIdx.x;
  for (int t = tid; t < 648; t += 256)
    ((ushort8v*)gws)[t] = ((const ushort8v*)gwpk)[t];
  if (tid < 72) {
    ((ushort8v*)As)[tid] = ((const ushort8v*)apk)[tid];
    ((ushort8v*)Bs)[tid] = ((const ushort8v*)bpk)[tid];
  }
  __syncthreads();

  int b, h; swz_bh(b, h);
  const int wv = tid >> 6, l = tid & 63;
  const int p32 = l & 31, g = l >> 5;
  const int w = wv * 32 + p32;

  v16f acc0, acc1;
  #pragma unroll
  for (int r = 0; r < 16; r++) { acc0[r] = 0.f; acc1[r] = 0.f; }

  for (int cb4 = 0; cb4 < 4; cb4++) {
    const int cblk = cb4 * 2 + g;
    const unsigned short* gwp = gws + cblk * 648;
    const unsigned short* Ap = As + cblk * 72;
    const unsigned short* Bp = Bs + cblk * 72;

    v8h pt[9];
    #pragma unroll
    for (int k = 0; k < 9; k++) {
      const int dy = k / 3 - 1, dx = k % 3 - 1;
      pt[k] = *(const v8h*)(y2pad + clb(b, h + 1 + dy, cb4, w + 1 + dx, PE) + g * 8);
    }
    // gw matmul + BN, all packed fp16 (weights broadcast from LDS)
    v8h s[9];
    #pragma unroll
    for (int o = 0; o < 9; o++) {
      v8h a = (*(const v8h*)(gwp + o * 72)) * pt[0];
      #pragma unroll
      for (int i = 1; i < 9; i++)
        a += (*(const v8h*)(gwp + o * 72 + i * 8)) * pt[i];
      s[o] = a * (*(const v8h*)(Ap + o * 8)) + (*(const v8h*)(Bp + o * 8));
    }
    // softmax over the 9 taps (shift-free: |s| << 1, fp16-safe)
    v8h esum = {0, 0, 0, 0, 0, 0, 0, 0};
    #pragma unroll
    for (int o = 0; o < 9; o++) { s[o] = exp8h(s[o]); esum += s[o]; }
    v8h inv = rcp8h(esum);
    #pragma unroll
    for (int k = 0; k < 9; k++) pt[k] = pt[k] * s[k] * inv;

    const unsigned short* ap = apinv + l * 8;
    __builtin_amdgcn_s_setprio(1);
    #pragma unroll
    for (int k = 0; k < 9; k++) {
      const unsigned short* a2 = ap + ((k * 4 + cb4) * 2) * 512;
      v8h A0 = *(const v8h*)(a2);
      v8h A1 = *(const v8h*)(a2 + 512);
      acc0 = __builtin_amdgcn_mfma_f32_32x32x16_f16(A0, pt[k], acc0, 0, 0, 0);
      acc1 = __builtin_amdgcn_mfma_f32_32x32x16_f16(A1, pt[k], acc1, 0, 0, 0);
    }
    __builtin_amdgcn_s_setprio(0);
  }
  #pragma unroll
  for (int t = 0; t < 4; t++) {
    int c0 = 8 * t + 4 * g;
    int kb = c0 >> 4, sub = c0 & 15;
    ushort4v s0, s1;
    #pragma unroll
    for (int u = 0; u < 4; u++) {
      s0[u] = f2h(acc0[4 * t + u] + cbias[c0 + u]);
      s1[u] = f2h(acc1[4 * t + u] + cbias[c0 + u + 32]);
    }
    *(ushort4v*)(ipad + clb(b, h, kb, w, 128) + sub) = s0;
    *(ushort4v*)(ipad + clb(b, h, kb + 2, w, 128) + sub) = s1;
  }
}

// ---------------- stage 5: fr 1x1 + residual (direct epilogue add) ----------
__global__ __launch_bounds__(256, 4) void k_fr_mfma(
    const unsigned short* __restrict__ ipad,
    const unsigned short* __restrict__ apfr,
    const float* __restrict__ bias,
    unsigned short* __restrict__ opad)
{
  int b, h; swz_bh(b, h);
  const int tid = threadIdx.x, wv = tid >> 6, l = tid & 63;
  const int ln31 = l & 31, g = l >> 5;
  const int px = wv * 32 + ln31;
  v16f acc0, acc1;
  #pragma unroll
  for (int r = 0; r < 16; r++) { acc0[r] = 0.f; acc1[r] = 0.f; }
  const unsigned short* apl = apfr + l * 8;
  #pragma unroll
  for (int kb = 0; kb < 4; kb++) {
    v8h Bf = *(const v8h*)(ipad + clb(b, h, kb, px, 128) + g * 8);
    v8h A0 = *(const v8h*)(apl + (kb * 2) * 512);
    v8h A1 = *(const v8h*)(apl + (kb * 2 + 1) * 512);
    acc0 = __builtin_amdgcn_mfma_f32_32x32x16_f16(A0, Bf, acc0, 0, 0, 0);
    acc1 = __builtin_amdgcn_mfma_f32_32x32x16_f16(A1, Bf, acc1, 0, 0, 0);
  }
  #pragma unroll
  for (int t = 0; t < 4; t++) {
    int c0 = 8 * t + 4 * g;
    int kb = c0 >> 4, sub = c0 & 15;
    // residual values live at exactly the epilogue addresses
    ushort4v r0 = *(const ushort4v*)(ipad + clb(b, h, kb, px, 128) + sub);
    ushort4v r1 = *(const ushort4v*)(ipad + clb(b, h, kb + 2, px, 128) + sub);
    ushort4v s0, s1;
    #pragma unroll
    for (int u = 0; u < 4; u++) {
      s0[u] = f2h(acc0[4 * t + u] + bias[c0 + u] + h2f(r0[u]));
      s1[u] = f2h(acc1[4 * t + u] + bias[c0 + u + 32] + h2f(r1[u]));
    }
    *(ushort4v*)(opad + clb(b, h + 1, kb, px + 1, PE) + sub) = s0;
    *(ushort4v*)(opad + clb(b, h + 1, kb + 2, px + 1, PE) + sub) = s1;
  }
}

// ---------------- stage 6: ensemble conv3x3, 2 rows/block, LDS weights ------
__global__ __launch_bounds__(256) void k_ens_mfma(
    const unsigned short* __restrict__ opad,
    const unsigned short* __restrict__ apens,
    const float* __restrict__ esc, const float* __restrict__ ebi,
    float* __restrict__ out)
{
  __shared__ __align__(16) unsigned short Abuf[36864];  // 72 KB: 9 taps
  const int tid = threadIdx.x;
  {
    const ushort8v* src = (const ushort8v*)apens;
    ushort8v* dst = (ushort8v*)Abuf;
    #pragma unroll
    for (int it = 0; it < 18; it++)
      dst[tid + it * 256] = src[tid + it * 256];
  }
  __syncthreads();

  const int bid = blockIdx.x;
  const int b = bid & 7, h0 = (bid >> 3) * 2;
  const int wv = tid >> 6, l = tid & 63;
  const int ln31 = l & 31, g = l >> 5;

  v16f a00, a01, a10, a11;
  #pragma unroll
  for (int r = 0; r < 16; r++) { a00[r] = 0.f; a01[r] = 0.f; a10[r] = 0.f; a11[r] = 0.f; }

  const unsigned short* abl = Abuf + l * 8;

  #pragma unroll
  for (int ky = 0; ky < 3; ky++) {
    #pragma unroll
    for (int kx = 0; kx < 3; kx++) {
      const int tap = ky * 3 + kx;
      const int r0 = h0 + ky;              // (h0+1) + (ky-1)
      const int col = wv * 32 + ln31 + kx; // (+1) + (kx-1)
      const unsigned short* ap = abl + tap * 4096;
      #pragma unroll
      for (int kb = 0; kb < 4; kb++) {
        v8h B0 = *(const v8h*)(opad + clb(b, r0, kb, col, PE) + g * 8);
        v8h B1 = *(const v8h*)(opad + clb(b, r0 + 1, kb, col, PE) + g * 8);
        v8h A0 = *(const v8h*)(ap + kb * 1024);
        v8h A1 = *(const v8h*)(ap + kb * 1024 + 512);
        a00 = __builtin_amdgcn_mfma_f32_32x32x16_f16(A0, B0, a00, 0, 0, 0);
        a01 = __builtin_amdgcn_mfma_f32_32x32x16_f16(A1, B0, a01, 0, 0, 0);
        a10 = __builtin_amdgcn_mfma_f32_32x32x16_f16(A0, B1, a10, 0, 0, 0);
        a11 = __builtin_amdgcn_mfma_f32_32x32x16_f16(A1, B1, a11, 0, 0, 0);
      }
    }
  }
  float* sp0 = out + ((size_t)b * Cn) * Pn + h0 * Wn + wv * 32 + ln31;
  float* sp1 = sp0 + Wn;
  #pragma unroll
  for (int r = 0; r < 16; r++) {
    int o0 = (r & 3) + 8 * (r >> 2) + 4 * g;
    float e0 = esc[o0], e1 = esc[o0 + 32];
    float i0 = ebi[o0], i1 = ebi[o0 + 32];
    sp0[(size_t)o0 * Pn] = fmaxf(a00[r] * e0 + i0, 0.f);
    sp0[(size_t)(o0 + 32) * Pn] = fmaxf(a01[r] * e1 + i1, 0.f);
    sp1[(size_t)o0 * Pn] = fmaxf(a10[r] * e0 + i0, 0.f);
    sp1[(size_t)(o0 + 32) * Pn] = fmaxf(a11[r] * e1 + i1, 0.f);
  }
}

extern "C" void kernel_launch(void* const* d_in, const int* in_sizes, int n_in,
                              void* d_out, int out_size, void* d_ws, size_t ws_size,
                              hipStream_t stream)
{
  const float* x    = (const float*)d_in[0];
  const float* w1   = (const float*)d_in[1];
  const float* b1   = (const float*)d_in[2];
  const float* w5   = (const float*)d_in[3];
  const float* w7   = (const float*)d_in[4];
  const float* w9   = (const float*)d_in[5];
  const float* w11  = (const float*)d_in[6];
  const float* dww  = (const float*)d_in[7];
  const float* dwb  = (const float*)d_in[8];
  const float* pww  = (const float*)d_in[9];
  const float* pwb  = (const float*)d_in[10];
  const float* gww  = (const float*)d_in[11];
  const float* gwb  = (const float*)d_in[12];
  const float* gbg  = (const float*)d_in[13];
  const float* gbb  = (const float*)d_in[14];
  const float* gbm  = (const float*)d_in[15];
  const float* gbv  = (const float*)d_in[16];
  const float* cw   = (const float*)d_in[17];
  const float* cb   = (const float*)d_in[18];
  const float* frw  = (const float*)d_in[19];
  const float* frb  = (const float*)d_in[20];
  const float* ensw = (const float*)d_in[21];
  const float* ensb = (const float*)d_in[22];
  const float* bng  = (const float*)d_in[23];
  const float* bnb  = (const float*)d_in[24];
  const float* bnm  = (const float*)d_in[25];
  const float* bnv  = (const float*)d_in[26];

  // ws: ypad (pad-11) region, overlaid later by y2pad then opad (pad-1)
  unsigned short* wsu   = (unsigned short*)d_ws;
  unsigned short* ypad  = wsu;
  unsigned short* y2pad = wsu;
  unsigned short* opad  = wsu;
  unsigned short* apack = wsu + YPAD_ELEMS;         // 147456
  unsigned short* apinv = apack + 147456;           // 36864
  unsigned short* apens = apinv + 36864;            // 36864
  unsigned short* appw1 = apens + 36864;            // 4096
  unsigned short* appw  = appw1 + 4096;             // 4096
  unsigned short* apfr  = appw + 4096;              // 4096
  unsigned short* gwpk  = apfr + 4096;              // 5184
  unsigned short* apk   = gwpk + 5184;              // 576
  unsigned short* bpk   = apk + 576;                // 576
  float* esc = (float*)(bpk + 576);                 // 64
  float* ebi = esc + 64;                            // 64

  // d_out: spad (fp16 blocked-CL pad-1) -> ipad (blocked-CL) -> planar fp32
  unsigned short* spad = (unsigned short*)d_out;
  unsigned short* ipad = (unsigned short*)d_out;
  float* D = (float*)d_out;

  // prep also zeroes ypad borders (pad 11) and spad borders (pad 1)
  k_prep<<<1145, 256, 0, stream>>>(w1, w5, w7, w9, w11, pww, frw, cw,
                                   gww, gwb, gbg, gbb, gbm, gbv, ensw, ensb,
                                   bng, bnb, bnm, bnv,
                                   apack, apinv, apens, appw1, appw, apfr,
                                   gwpk, apk, bpk, esc, ebi,
                                   ypad, spad);

  // 1) ypad = conv1x1(relu(x))           x (planar f32) -> ypad (blocked CL)
  k_pw1x<<<1024, 256, 0, stream>>>(x, appw1, b1, ypad);
  // 2) spad = sum_d dilconv_d(y)         ypad -> spad (d_out, pad-1)
  k_cdcm_mfma<<<512, 256, 0, stream>>>(ypad, apack, spad);
  // 3) y2pad = PW(DW(spad))              spad -> y2pad (ws, pad-1)
  //    (blocks h=0/1 also zero y2pad borders; ypad is dead by now)
  k_dwpw_mfma<<<1024, 256, 0, stream>>>(spad, dww, dwb, appw, pwb, y2pad);
  // 4) ipad = involution(y2pad)          y2pad -> ipad (d_out)
  k_invol_mfma<<<1024, 256, 0, stream>>>(y2pad, gwpk, apk, bpk, apinv, cb, ipad);
  // 5) opad = fr(ipad) + ipad            ipad -> opad (ws, pad-1)
  k_fr_mfma<<<1024, 256, 0, stream>>>(ipad, apfr, frb, opad);
  // 6) out = relu(BN(ens3x3(opad)))      opad -> D (planar fp32)
  k_ens_mfma<<<512, 256, 0, stream>>>(opad, apens, esc, ebi, D);
}

// Round 14
// 149.577 us; speedup vs baseline: 15.5921x; 1.0010x over previous
//
#include <hip/hip_runtime.h>
#include <hip/hip_bf16.h>
#include <hip/hip_fp16.h>

#define EPSV 1e-5f
#define Bn 8
#define Cn 64
#define Hn 128
#define Wn 128
#define Pn (Hn*Wn)          // 16384
#define PR 150              // cdcm pad: 11 + 128 + 11
#define PE 130              // 1-pad: 1 + 128 + 1
#define YPAD_ELEMS (Bn*PR*PR*Cn)   // 11,520,000 fp16

typedef _Float16 v8h __attribute__((ext_vector_type(8)));
typedef float v16f __attribute__((ext_vector_type(16)));
typedef unsigned short ushort8v __attribute__((ext_vector_type(8)));
typedef unsigned short ushort4v __attribute__((ext_vector_type(4)));

__device__ __forceinline__ unsigned short f2h(float v) {
  _Float16 h = (_Float16)v;
  return *reinterpret_cast<const unsigned short*>(&h);
}
__device__ __forceinline__ float h2f(unsigned short u) {
  return (float)(*reinterpret_cast<const _Float16*>(&u));
}

__device__ __forceinline__ v8h exp8h(v8h x) {
  union { v8h v; __half2 h[4]; } u; u.v = x;
  #pragma unroll
  for (int i = 0; i < 4; i++) u.h[i] = h2exp(u.h[i]);
  return u.v;
}
__device__ __forceinline__ v8h rcp8h(v8h x) {
  union { v8h v; __half2 h[4]; } u; u.v = x;
  #pragma unroll
  for (int i = 0; i < 4; i++) u.h[i] = h2rcp(u.h[i]);
  return u.v;
}

// async global->LDS, 16B per lane; LDS dest = uniform base + lane*16
__device__ __forceinline__ void gload_lds16(const void* g, void* l) {
  __builtin_amdgcn_global_load_lds(
      (const __attribute__((address_space(1))) unsigned int*)g,
      (__attribute__((address_space(3))) unsigned int*)l, 16, 0, 0);
}

// channel-blocked CL addressing: [b][row][kb(4)][col][16], elems
__device__ __forceinline__ size_t clb(int b, int row, int kb, int col, int PD) {
  return ((((size_t)b * PD + row) * 4 + kb) * PD + col) * 16;
}

// batch-major XCD swizzle: 1024 blocks, XCD r gets batch r's rows in order
__device__ __forceinline__ void swz_bh(int& b, int& h) {
  int bid = blockIdx.x;
  int w = (bid & 7) * 128 + (bid >> 3);
  b = w >> 7; h = w & 127;
}

// ---------------- prep: weight packs + BN folds + border zeros --------------
// cdcm A-pack layout (18KB chunks): [d][kb][tap9][mh][512]
// other A-packs: [tap][kb][mh][lane*8+e], m=mh*32+(l&31), c=kb*16+(l>>5)*8+e
__global__ __launch_bounds__(256) void k_prep(
    const float* __restrict__ w1, const float* __restrict__ w5,
    const float* __restrict__ w7, const float* __restrict__ w9,
    const float* __restrict__ w11, const float* __restrict__ pww,
    const float* __restrict__ frw, const float* __restrict__ cw,
    const float* __restrict__ gww, const float* __restrict__ gwb,
    const float* __restrict__ gbg, const float* __restrict__ gbb,
    const float* __restrict__ gbm, const float* __restrict__ gbv,
    const float* __restrict__ ensw, const float* __restrict__ ensb,
    const float* __restrict__ bng, const float* __restrict__ bnb,
    const float* __restrict__ bnm, const float* __restrict__ bnv,
    unsigned short* __restrict__ apack, unsigned short* __restrict__ apinv,
    unsigned short* __restrict__ apens, unsigned short* __restrict__ appw1,
    unsigned short* __restrict__ appw, unsigned short* __restrict__ apfr,
    unsigned short* __restrict__ gwpk,
    unsigned short* __restrict__ apk, unsigned short* __restrict__ bpk,
    float* __restrict__ esc, float* __restrict__ ebi,
    unsigned short* __restrict__ ypad, unsigned short* __restrict__ spad)
{
  int id = blockIdx.x * 256 + threadIdx.x;
  if (id < 147456) {               // cdcm: chunked [d][kb][t9][mh][512]
    int c0 = id / 9216;            // ci = d*4 + kb
    int d = c0 >> 2, kb = c0 & 3;
    int r = id - c0 * 9216;
    int t9 = r / 1024;
    int r2 = r & 1023;
    int mh = r2 >> 9, l = (r2 >> 3) & 63, e = r2 & 7;
    int m = mh * 32 + (l & 31);
    int c = kb * 16 + (l >> 5) * 8 + e;
    const float* src = (d == 0) ? w5 : (d == 1) ? w7 : (d == 2) ? w9 : w11;
    apack[id] = f2h(src[(m * 64 + c) * 9 + t9]);
    return;
  }
  id -= 147456;
  if (id < 36864) {                // involution conv_w: 9 taps
    int e = id & 7, l = (id >> 3) & 63, mh = (id >> 9) & 1,
        kb = (id >> 10) & 3, tap = id >> 12;
    int m = mh * 32 + (l & 31);
    int c = kb * 16 + (l >> 5) * 8 + e;
    apinv[id] = f2h(cw[(m * 64 + c) * 9 + tap]);
    return;
  }
  id -= 36864;
  if (id < 36864) {                // ensemble mean weights: 9 taps
    int e = id & 7, l = (id >> 3) & 63, mh = (id >> 9) & 1,
        kb = (id >> 10) & 3, tap = id >> 12;
    int m = mh * 32 + (l & 31);
    int c = kb * 16 + (l >> 5) * 8 + e;
    float v = (ensw[((0 * 64 + m) * 64 + c) * 9 + tap] +
               ensw[((64 + m) * 64 + c) * 9 + tap] +
               ensw[((128 + m) * 64 + c) * 9 + tap]) * (1.f / 3.f);
    apens[id] = f2h(v);
    return;
  }
  id -= 36864;
  if (id < 4096) {                 // conv1 1x1
    int e = id & 7, l = (id >> 3) & 63, mh = (id >> 9) & 1, kb = (id >> 10) & 3;
    int m = mh * 32 + (l & 31);
    int c = kb * 16 + (l >> 5) * 8 + e;
    appw1[id] = f2h(w1[m * 64 + c]);
    return;
  }
  id -= 4096;
  if (id < 4096) {                 // dsc pointwise 1x1
    int e = id & 7, l = (id >> 3) & 63, mh = (id >> 9) & 1, kb = (id >> 10) & 3;
    int m = mh * 32 + (l & 31);
    int c = kb * 16 + (l >> 5) * 8 + e;
    appw[id] = f2h(pww[m * 64 + c]);
    return;
  }
  id -= 4096;
  if (id < 4096) {                 // fr 1x1
    int e = id & 7, l = (id >> 3) & 63, mh = (id >> 9) & 1, kb = (id >> 10) & 3;
    int m = mh * 32 + (l & 31);
    int c = kb * 16 + (l >> 5) * 8 + e;
    apfr[id] = f2h(frw[m * 64 + c]);
    return;
  }
  id -= 4096;
  if (id < 5184) {                 // packed gw weights [cblk8][tap81][ch8]
    int cblk = id / 648, r = id - cblk * 648;
    int tap = r >> 3, ch = r & 7;
    int c = cblk * 8 + ch;
    gwpk[id] = f2h(gww[c * 81 + tap]);
    return;
  }
  id -= 5184;
  if (id < 576) {                  // packed BN scale [cblk8][o9][ch8]
    int cblk = id / 72, r = id - cblk * 72;
    int o = r >> 3, ch = r & 7;
    int c = cblk * 8 + ch;
    float A = gbg[c * 9 + o] / sqrtf(gbv[c * 9 + o] + EPSV);
    apk[id] = f2h(A);
    return;
  }
  id -= 576;
  if (id < 576) {                  // packed BN shift
    int cblk = id / 72, r = id - cblk * 72;
    int o = r >> 3, ch = r & 7;
    int c = cblk * 8 + ch;
    float A = gbg[c * 9 + o] / sqrtf(gbv[c * 9 + o] + EPSV);
    float B = (gwb[c * 9 + o] - gbm[c * 9 + o]) * A + gbb[c * 9 + o];
    bpk[id] = f2h(B);
    return;
  }
  id -= 576;
  if (id < 64) {                   // final BN fold (+ mean ensemble bias)
    float s = bng[id] / sqrtf(bnv[id] + EPSV);
    esc[id] = s;
    float bm = (ensb[id] + ensb[64 + id] + ensb[128 + id]) * (1.f / 3.f);
    ebi[id] = (bm - bnm[id]) * s + bnb[id];
    return;
  }
  id -= 64;
  ushort8v z = {0, 0, 0, 0, 0, 0, 0, 0};
  const int perY = 22 * PR + 128 * 22;      // 6116: ypad border (pad 11)
  if (id < perY * Bn) {
    int b = id / perY; int r = id - b * perY;
    int tb = 22 * PR;
    int row, col;
    if (r < tb) {
      int rr = r / PR; col = r - rr * PR;
      row = (rr < 11) ? rr : (rr + 128);
    } else {
      int r2 = r - tb;
      row = 11 + r2 / 22;
      int cc = r2 % 22;
      col = (cc < 11) ? cc : (cc + 128);
    }
    #pragma unroll
    for (int kb = 0; kb < 4; kb++) {
      unsigned short* p = ypad + clb(b, row, kb, col, PR);
      *(ushort8v*)p = z;
      *(ushort8v*)(p + 8) = z;
    }
    return;
  }
  id -= perY * Bn;
  const int perS = 2 * PE + 256;            // 516: spad border (pad 1)
  if (id < perS * Bn) {
    int b = id / perS; int r = id - b * perS;
    int tb = 2 * PE;
    int row, col;
    if (r < tb) {
      int rr = r / PE; col = r - rr * PE;
      row = (rr < 1) ? 0 : 129;
    } else {
      int r2 = r - tb;
      row = 1 + r2 / 2;
      col = (r2 & 1) ? 129 : 0;
    }
    #pragma unroll
    for (int kb = 0; kb < 4; kb++) {
      unsigned short* p = spad + clb(b, row, kb, col, PE);
      *(ushort8v*)p = z;
      *(ushort8v*)(p + 8) = z;
    }
  }
}

// ---------------- stage 1: conv1x1(relu(x)) via MFMA, planar fp32 in --------
__global__ __launch_bounds__(256, 4) void k_pw1x(const float* __restrict__ x,
    const unsigned short* __restrict__ apw, const float* __restrict__ bias,
    unsigned short* __restrict__ ypad)
{
  int b, h; swz_bh(b, h);
  const int tid = threadIdx.x, wv = tid >> 6, l = tid & 63;
  const int ln31 = l & 31, g = l >> 5;
  const int px = wv * 32 + ln31;
  const float* xb = x + ((size_t)b * Cn) * Pn + h * Wn + px;
  v16f acc0, acc1;
  #pragma unroll
  for (int r = 0; r < 16; r++) { acc0[r] = 0.f; acc1[r] = 0.f; }
  const unsigned short* apl = apw + l * 8;
  #pragma unroll
  for (int kb = 0; kb < 4; kb++) {
    int c0 = kb * 16 + g * 8;
    v8h Bf;
    #pragma unroll
    for (int e = 0; e < 8; e++)
      Bf[e] = (_Float16)fmaxf(xb[(size_t)(c0 + e) * Pn], 0.f);
    v8h A0 = *(const v8h*)(apl + (kb * 2) * 512);
    v8h A1 = *(const v8h*)(apl + (kb * 2 + 1) * 512);
    acc0 = __builtin_amdgcn_mfma_f32_32x32x16_f16(A0, Bf, acc0, 0, 0, 0);
    acc1 = __builtin_amdgcn_mfma_f32_32x32x16_f16(A1, Bf, acc1, 0, 0, 0);
  }
  #pragma unroll
  for (int t = 0; t < 4; t++) {
    int c0 = 8 * t + 4 * g;
    int kb = c0 >> 4, sub = c0 & 15;
    ushort4v s0, s1;
    #pragma unroll
    for (int u = 0; u < 4; u++) {
      s0[u] = f2h(acc0[4 * t + u] + bias[c0 + u]);
      s1[u] = f2h(acc1[4 * t + u] + bias[c0 + u + 32]);
    }
    *(ushort4v*)(ypad + clb(b, h + 11, kb, px + 11, PR) + sub) = s0;
    *(ushort4v*)(ypad + clb(b, h + 11, kb + 2, px + 11, PR) + sub) = s1;
  }
}

// ---------------- stage 2: cdcm, 1 row/block, 18KB async dbuf, 4 blk/CU -----
// grid 1024. 16 chunks of (d,kb) = 18KB, double-buffered (36KB LDS).
// Waves 0-1 stage 5 granules, waves 2-3 stage 4; counted per-wave vmcnt
// (never 0 mid-loop). 4 blocks/CU = 16 waves: other blocks' MFMA phases
// fill this block's vmcnt/barrier stalls.
__global__ __launch_bounds__(256, 4) void k_cdcm_mfma(
    const unsigned short* __restrict__ ypad,
    const unsigned short* __restrict__ apack,
    unsigned short* __restrict__ spad)
{
  __shared__ __align__(16) unsigned short Abuf[2][9216];  // 2 x 18 KB
  int b, h; swz_bh(b, h);
  const int tid = threadIdx.x, wv = tid >> 6, l = tid & 63;
  const int ln31 = l & 31, g = l >> 5;
  const int ng = (wv < 2) ? 5 : 4;   // granules this wave stages (18 total)

  // issue chunk 0
  {
    const char* src = (const char*)apack;
    char* dst = (char*)&Abuf[0][0];
    for (int i = 0; i < ng; i++) {
      int off = (wv + i * 4) * 1024;
      gload_lds16(src + off + l * 16, dst + off);
    }
  }

  v16f acc0, acc1;
  #pragma unroll
  for (int r = 0; r < 16; r++) { acc0[r] = 0.f; acc1[r] = 0.f; }

  #pragma unroll
  for (int d = 0; d < 4; d++) {
    const int dil = 5 + 2 * d;
    #pragma unroll
    for (int kb = 0; kb < 4; kb++) {
      const int ci = d * 4 + kb;
      if (ci < 15) {               // prefetch next chunk into other buffer
        const char* src = (const char*)(apack + (ci + 1) * 9216);
        char* dst = (char*)&Abuf[(ci + 1) & 1][0];
        for (int i = 0; i < ng; i++) {
          int off = (wv + i * 4) * 1024;
          gload_lds16(src + off + l * 16, dst + off);
        }
        if (wv < 2) asm volatile("s_waitcnt vmcnt(5)" ::: "memory");
        else        asm volatile("s_waitcnt vmcnt(4)" ::: "memory");
      } else {
        asm volatile("s_waitcnt vmcnt(0)" ::: "memory");
      }
      asm volatile("s_barrier" ::: "memory");

      __builtin_amdgcn_s_setprio(1);
      const unsigned short* abl = &Abuf[ci & 1][0] + l * 8;
      #pragma unroll
      for (int ky = 0; ky < 3; ky++) {
        const int row = h + 11 + (ky - 1) * dil;
        #pragma unroll
        for (int kx = 0; kx < 3; kx++) {
          const int col = wv * 32 + ln31 + (kx - 1) * dil + 11;
          const int t9 = ky * 3 + kx;
          v8h Bf = *(const v8h*)(ypad + clb(b, row, kb, col, PR) + g * 8);
          const unsigned short* ap = abl + t9 * 1024;
          v8h A0 = *(const v8h*)(ap);
          v8h A1 = *(const v8h*)(ap + 512);
          acc0 = __builtin_amdgcn_mfma_f32_32x32x16_f16(A0, Bf, acc0, 0, 0, 0);
          acc1 = __builtin_amdgcn_mfma_f32_32x32x16_f16(A1, Bf, acc1, 0, 0, 0);
        }
      }
      __builtin_amdgcn_s_setprio(0);
      asm volatile("s_barrier" ::: "memory");  // waves done with buf[ci&1]
    }
  }
  const int px = wv * 32 + ln31;
  #pragma unroll
  for (int t = 0; t < 4; t++) {
    int c0 = 8 * t + 4 * g;
    int kb = c0 >> 4, sub = c0 & 15;
    ushort4v s0, s1;
    #pragma unroll
    for (int u = 0; u < 4; u++) {
      s0[u] = f2h(acc0[4 * t + u]);
      s1[u] = f2h(acc1[4 * t + u]);
    }
    *(ushort4v*)(spad + clb(b, h + 1, kb, px + 1, PE) + sub) = s0;
    *(ushort4v*)(spad + clb(b, h + 1, kb + 2, px + 1, PE) + sub) = s1;
  }
}

// ---------------- stage 3: depthwise (VALU) + pointwise (MFMA) --------------
// Blocks h==0/h==1 also zero y2pad's pad-1 borders (safe: nothing reads
// y2pad until invol; border writes disjoint from all interior writes).
__global__ __launch_bounds__(256, 4) void k_dwpw_mfma(
    const unsigned short* __restrict__ spad,
    const float* __restrict__ dww, const float* __restrict__ dwb,
    const unsigned short* __restrict__ appw, const float* __restrict__ pwb,
    unsigned short* __restrict__ y2pad)
{
  __shared__ float wdw[576];
  __shared__ float bdw[64];
  const int tid = threadIdx.x;
  for (int t = tid; t < 576; t += 256) wdw[t] = dww[t];
  if (tid < 64) bdw[tid] = dwb[tid];
  __syncthreads();

  int b, h; swz_bh(b, h);

  ushort8v z = {0, 0, 0, 0, 0, 0, 0, 0};
  if (h == 0) {
    for (int px = tid; px < 260; px += 256) {
      int row = (px < 130) ? 0 : 129;
      int col = (px < 130) ? px : px - 130;
      #pragma unroll
      for (int kb = 0; kb < 4; kb++) {
        unsigned short* p = y2pad + clb(b, row, kb, col, PE);
        *(ushort8v*)p = z;
        *(ushort8v*)(p + 8) = z;
      }
    }
  } else if (h == 1) {
    int row = 1 + (tid & 127);
    int col = (tid >> 7) ? 129 : 0;
    #pragma unroll
    for (int kb = 0; kb < 4; kb++) {
      unsigned short* p = y2pad + clb(b, row, kb, col, PE);
      *(ushort8v*)p = z;
      *(ushort8v*)(p + 8) = z;
    }
  }

  const int wv = tid >> 6, l = tid & 63;
  const int ln31 = l & 31, g = l >> 5;
  const int w = wv * 32 + ln31;

  v16f acc0, acc1;
  #pragma unroll
  for (int r = 0; r < 16; r++) { acc0[r] = 0.f; acc1[r] = 0.f; }
  const unsigned short* apl = appw + l * 8;

  #pragma unroll
  for (int kb = 0; kb < 4; kb++) {
    const int c0 = kb * 16 + g * 8;
    v8h t[9];
    #pragma unroll
    for (int k = 0; k < 9; k++) {
      const int dy = k / 3 - 1, dx = k % 3 - 1;
      t[k] = *(const v8h*)(spad + clb(b, h + 1 + dy, kb, w + 1 + dx, PE) + g * 8);
    }
    v8h dvh;
    #pragma unroll
    for (int e = 0; e < 8; e++) {
      const int c = c0 + e;
      float a = 4.f * bdw[c];
      #pragma unroll
      for (int k = 0; k < 9; k++) a += wdw[c * 9 + k] * (float)t[k][e];
      dvh[e] = (_Float16)a;
    }
    v8h A0 = *(const v8h*)(apl + (kb * 2) * 512);
    v8h A1 = *(const v8h*)(apl + (kb * 2 + 1) * 512);
    acc0 = __builtin_amdgcn_mfma_f32_32x32x16_f16(A0, dvh, acc0, 0, 0, 0);
    acc1 = __builtin_amdgcn_mfma_f32_32x32x16_f16(A1, dvh, acc1, 0, 0, 0);
  }
  #pragma unroll
  for (int t = 0; t < 4; t++) {
    int c0 = 8 * t + 4 * g;
    int kb = c0 >> 4, sub = c0 & 15;
    ushort4v s0, s1;
    #pragma unroll
    for (int u = 0; u < 4; u++) {
      s0[u] = f2h(acc0[4 * t + u] + 4.f * pwb[c0 + u]);
      s1[u] = f2h(acc1[4 * t + u] + 4.f * pwb[c0 + u + 32]);
    }
    *(ushort4v*)(y2pad + clb(b, h + 1, kb, w + 1, PE) + sub) = s0;
    *(ushort4v*)(y2pad + clb(b, h + 1, kb + 2, w + 1, PE) + sub) = s1;
  }
}

// ---------------- stage 4: involution, packed-fp16 softmax + MFMA -----------
__global__ __launch_bounds__(256, 3) void k_invol_mfma(
    const unsigned short* __restrict__ y2pad,
    const unsigned short* __restrict__ gwpk,
    const unsigned short* __restrict__ apk,
    const unsigned short* __restrict__ bpk,
    const unsigned short* __restrict__ apinv,
    const float* __restrict__ cbias,
    unsigned short* __restrict__ ipad)
{
  __shared__ __align__(16) unsigned short gws[5184];  // [cblk8][tap81][ch8]
  __shared__ __align__(16) unsigned short As[576];    // [cblk8][o9][ch8]
  __shared__ __align__(16) unsigned short Bs[576];
  const int tid = threadIdx.x;
  for (int t = tid; t < 648; t += 256)
    ((ushort8v*)gws)[t] = ((const ushort8v*)gwpk)[t];
  if (tid < 72) {
    ((ushort8v*)As)[tid] = ((const ushort8v*)apk)[tid];
    ((ushort8v*)Bs)[tid] = ((const ushort8v*)bpk)[tid];
  }
  __syncthreads();

  int b, h; swz_bh(b, h);
  const int wv = tid >> 6, l = tid & 63;
  const int p32 = l & 31, g = l >> 5;
  const int w = wv * 32 + p32;

  v16f acc0, acc1;
  #pragma unroll
  for (int r = 0; r < 16; r++) { acc0[r] = 0.f; acc1[r] = 0.f; }

  for (int cb4 = 0; cb4 < 4; cb4++) {
    const int cblk = cb4 * 2 + g;
    const unsigned short* gwp = gws + cblk * 648;
    const unsigned short* Ap = As + cblk * 72;
    const unsigned short* Bp = Bs + cblk * 72;

    v8h pt[9];
    #pragma unroll
    for (int k = 0; k < 9; k++) {
      const int dy = k / 3 - 1, dx = k % 3 - 1;
      pt[k] = *(const v8h*)(y2pad + clb(b, h + 1 + dy, cb4, w + 1 + dx, PE) + g * 8);
    }
    // gw matmul + BN, all packed fp16 (weights broadcast from LDS)
    v8h s[9];
    #pragma unroll
    for (int o = 0; o < 9; o++) {
      v8h a = (*(const v8h*)(gwp + o * 72)) * pt[0];
      #pragma unroll
      for (int i = 1; i < 9; i++)
        a += (*(const v8h*)(gwp + o * 72 + i * 8)) * pt[i];
      s[o] = a * (*(const v8h*)(Ap + o * 8)) + (*(const v8h*)(Bp + o * 8));
    }
    // softmax over the 9 taps (shift-free: |s| << 1, fp16-safe)
    v8h esum = {0, 0, 0, 0, 0, 0, 0, 0};
    #pragma unroll
    for (int o = 0; o < 9; o++) { s[o] = exp8h(s[o]); esum += s[o]; }
    v8h inv = rcp8h(esum);
    #pragma unroll
    for (int k = 0; k < 9; k++) pt[k] = pt[k] * s[k] * inv;

    const unsigned short* ap = apinv + l * 8;
    __builtin_amdgcn_s_setprio(1);
    #pragma unroll
    for (int k = 0; k < 9; k++) {
      const unsigned short* a2 = ap + ((k * 4 + cb4) * 2) * 512;
      v8h A0 = *(const v8h*)(a2);
      v8h A1 = *(const v8h*)(a2 + 512);
      acc0 = __builtin_amdgcn_mfma_f32_32x32x16_f16(A0, pt[k], acc0, 0, 0, 0);
      acc1 = __builtin_amdgcn_mfma_f32_32x32x16_f16(A1, pt[k], acc1, 0, 0, 0);
    }
    __builtin_amdgcn_s_setprio(0);
  }
  #pragma unroll
  for (int t = 0; t < 4; t++) {
    int c0 = 8 * t + 4 * g;
    int kb = c0 >> 4, sub = c0 & 15;
    ushort4v s0, s1;
    #pragma unroll
    for (int u = 0; u < 4; u++) {
      s0[u] = f2h(acc0[4 * t + u] + cbias[c0 + u]);
      s1[u] = f2h(acc1[4 * t + u] + cbias[c0 + u + 32]);
    }
    *(ushort4v*)(ipad + clb(b, h, kb, w, 128) + sub) = s0;
    *(ushort4v*)(ipad + clb(b, h, kb + 2, w, 128) + sub) = s1;
  }
}

// ---------------- stage 5: fr 1x1 + residual (direct epilogue add) ----------
__global__ __launch_bounds__(256, 4) void k_fr_mfma(
    const unsigned short* __restrict__ ipad,
    const unsigned short* __restrict__ apfr,
    const float* __restrict__ bias,
    unsigned short* __restrict__ opad)
{
  int b, h; swz_bh(b, h);
  const int tid = threadIdx.x, wv = tid >> 6, l = tid & 63;
  const int ln31 = l & 31, g = l >> 5;
  const int px = wv * 32 + ln31;
  v16f acc0, acc1;
  #pragma unroll
  for (int r = 0; r < 16; r++) { acc0[r] = 0.f; acc1[r] = 0.f; }
  const unsigned short* apl = apfr + l * 8;
  #pragma unroll
  for (int kb = 0; kb < 4; kb++) {
    v8h Bf = *(const v8h*)(ipad + clb(b, h, kb, px, 128) + g * 8);
    v8h A0 = *(const v8h*)(apl + (kb * 2) * 512);
    v8h A1 = *(const v8h*)(apl + (kb * 2 + 1) * 512);
    acc0 = __builtin_amdgcn_mfma_f32_32x32x16_f16(A0, Bf, acc0, 0, 0, 0);
    acc1 = __builtin_amdgcn_mfma_f32_32x32x16_f16(A1, Bf, acc1, 0, 0, 0);
  }
  #pragma unroll
  for (int t = 0; t < 4; t++) {
    int c0 = 8 * t + 4 * g;
    int kb = c0 >> 4, sub = c0 & 15;
    // residual values live at exactly the epilogue addresses
    ushort4v r0 = *(const ushort4v*)(ipad + clb(b, h, kb, px, 128) + sub);
    ushort4v r1 = *(const ushort4v*)(ipad + clb(b, h, kb + 2, px, 128) + sub);
    ushort4v s0, s1;
    #pragma unroll
    for (int u = 0; u < 4; u++) {
      s0[u] = f2h(acc0[4 * t + u] + bias[c0 + u] + h2f(r0[u]));
      s1[u] = f2h(acc1[4 * t + u] + bias[c0 + u + 32] + h2f(r1[u]));
    }
    *(ushort4v*)(opad + clb(b, h + 1, kb, px + 1, PE) + sub) = s0;
    *(ushort4v*)(opad + clb(b, h + 1, kb + 2, px + 1, PE) + sub) = s1;
  }
}

// ---------------- stage 6: ensemble conv3x3, 2 rows/block, LDS weights ------
__global__ __launch_bounds__(256) void k_ens_mfma(
    const unsigned short* __restrict__ opad,
    const unsigned short* __restrict__ apens,
    const float* __restrict__ esc, const float* __restrict__ ebi,
    float* __restrict__ out)
{
  __shared__ __align__(16) unsigned short Abuf[36864];  // 72 KB: 9 taps
  const int tid = threadIdx.x;
  {
    const ushort8v* src = (const ushort8v*)apens;
    ushort8v* dst = (ushort8v*)Abuf;
    #pragma unroll
    for (int it = 0; it < 18; it++)
      dst[tid + it * 256] = src[tid + it * 256];
  }
  __syncthreads();

  const int bid = blockIdx.x;
  const int b = bid & 7, h0 = (bid >> 3) * 2;
  const int wv = tid >> 6, l = tid & 63;
  const int ln31 = l & 31, g = l >> 5;

  v16f a00, a01, a10, a11;
  #pragma unroll
  for (int r = 0; r < 16; r++) { a00[r] = 0.f; a01[r] = 0.f; a10[r] = 0.f; a11[r] = 0.f; }

  const unsigned short* abl = Abuf + l * 8;

  #pragma unroll
  for (int ky = 0; ky < 3; ky++) {
    #pragma unroll
    for (int kx = 0; kx < 3; kx++) {
      const int tap = ky * 3 + kx;
      const int r0 = h0 + ky;              // (h0+1) + (ky-1)
      const int col = wv * 32 + ln31 + kx; // (+1) + (kx-1)
      const unsigned short* ap = abl + tap * 4096;
      #pragma unroll
      for (int kb = 0; kb < 4; kb++) {
        v8h B0 = *(const v8h*)(opad + clb(b, r0, kb, col, PE) + g * 8);
        v8h B1 = *(const v8h*)(opad + clb(b, r0 + 1, kb, col, PE) + g * 8);
        v8h A0 = *(const v8h*)(ap + kb * 1024);
        v8h A1 = *(const v8h*)(ap + kb * 1024 + 512);
        a00 = __builtin_amdgcn_mfma_f32_32x32x16_f16(A0, B0, a00, 0, 0, 0);
        a01 = __builtin_amdgcn_mfma_f32_32x32x16_f16(A1, B0, a01, 0, 0, 0);
        a10 = __builtin_amdgcn_mfma_f32_32x32x16_f16(A0, B1, a10, 0, 0, 0);
        a11 = __builtin_amdgcn_mfma_f32_32x32x16_f16(A1, B1, a11, 0, 0, 0);
      }
    }
  }
  float* sp0 = out + ((size_t)b * Cn) * Pn + h0 * Wn + wv * 32 + ln31;
  float* sp1 = sp0 + Wn;
  #pragma unroll
  for (int r = 0; r < 16; r++) {
    int o0 = (r & 3) + 8 * (r >> 2) + 4 * g;
    float e0 = esc[o0], e1 = esc[o0 + 32];
    float i0 = ebi[o0], i1 = ebi[o0 + 32];
    sp0[(size_t)o0 * Pn] = fmaxf(a00[r] * e0 + i0, 0.f);
    sp0[(size_t)(o0 + 32) * Pn] = fmaxf(a01[r] * e1 + i1, 0.f);
    sp1[(size_t)o0 * Pn] = fmaxf(a10[r] * e0 + i0, 0.f);
    sp1[(size_t)(o0 + 32) * Pn] = fmaxf(a11[r] * e1 + i1, 0.f);
  }
}

extern "C" void kernel_launch(void* const* d_in, const int* in_sizes, int n_in,
                              void* d_out, int out_size, void* d_ws, size_t ws_size,
                              hipStream_t stream)
{
  const float* x    = (const float*)d_in[0];
  const float* w1   = (const float*)d_in[1];
  const float* b1   = (const float*)d_in[2];
  const float* w5   = (const float*)d_in[3];
  const float* w7   = (const float*)d_in[4];
  const float* w9   = (const float*)d_in[5];
  const float* w11  = (const float*)d_in[6];
  const float* dww  = (const float*)d_in[7];
  const float* dwb  = (const float*)d_in[8];
  const float* pww  = (const float*)d_in[9];
  const float* pwb  = (const float*)d_in[10];
  const float* gww  = (const float*)d_in[11];
  const float* gwb  = (const float*)d_in[12];
  const float* gbg  = (const float*)d_in[13];
  const float* gbb  = (const float*)d_in[14];
  const float* gbm  = (const float*)d_in[15];
  const float* gbv  = (const float*)d_in[16];
  const float* cw   = (const float*)d_in[17];
  const float* cb   = (const float*)d_in[18];
  const float* frw  = (const float*)d_in[19];
  const float* frb  = (const float*)d_in[20];
  const float* ensw = (const float*)d_in[21];
  const float* ensb = (const float*)d_in[22];
  const float* bng  = (const float*)d_in[23];
  const float* bnb  = (const float*)d_in[24];
  const float* bnm  = (const float*)d_in[25];
  const float* bnv  = (const float*)d_in[26];

  // ws: ypad (pad-11) region, overlaid later by y2pad then opad (pad-1)
  unsigned short* wsu   = (unsigned short*)d_ws;
  unsigned short* ypad  = wsu;
  unsigned short* y2pad = wsu;
  unsigned short* opad  = wsu;
  unsigned short* apack = wsu + YPAD_ELEMS;         // 147456
  unsigned short* apinv = apack + 147456;           // 36864
  unsigned short* apens = apinv + 36864;            // 36864
  unsigned short* appw1 = apens + 36864;            // 4096
  unsigned short* appw  = appw1 + 4096;             // 4096
  unsigned short* apfr  = appw + 4096;              // 4096
  unsigned short* gwpk  = apfr + 4096;              // 5184
  unsigned short* apk   = gwpk + 5184;              // 576
  unsigned short* bpk   = apk + 576;                // 576
  float* esc = (float*)(bpk + 576);                 // 64
  float* ebi = esc + 64;                            // 64

  // d_out: spad (fp16 blocked-CL pad-1) -> ipad (blocked-CL) -> planar fp32
  unsigned short* spad = (unsigned short*)d_out;
  unsigned short* ipad = (unsigned short*)d_out;
  float* D = (float*)d_out;

  // prep also zeroes ypad borders (pad 11) and spad borders (pad 1)
  k_prep<<<1145, 256, 0, stream>>>(w1, w5, w7, w9, w11, pww, frw, cw,
                                   gww, gwb, gbg, gbb, gbm, gbv, ensw, ensb,
                                   bng, bnb, bnm, bnv,
                                   apack, apinv, apens, appw1, appw, apfr,
                                   gwpk, apk, bpk, esc, ebi,
                                   ypad, spad);

  // 1) ypad = conv1x1(relu(x))           x (planar f32) -> ypad (blocked CL)
  k_pw1x<<<1024, 256, 0, stream>>>(x, appw1, b1, ypad);
  // 2) spad = sum_d dilconv_d(y)         ypad -> spad (d_out, pad-1)
  k_cdcm_mfma<<<1024, 256, 0, stream>>>(ypad, apack, spad);
  // 3) y2pad = PW(DW(spad))              spad -> y2pad (ws, pad-1)
  //    (blocks h=0/1 also zero y2pad borders; ypad is dead by now)
  k_dwpw_mfma<<<1024, 256, 0, stream>>>(spad, dww, dwb, appw, pwb, y2pad);
  // 4) ipad = involution(y2pad)          y2pad -> ipad (d_out)
  k_invol_mfma<<<1024, 256, 0, stream>>>(y2pad, gwpk, apk, bpk, apinv, cb, ipad);
  // 5) opad = fr(ipad) + ipad            ipad -> opad (ws, pad-1)
  k_fr_mfma<<<1024, 256, 0, stream>>>(ipad, apfr, frb, opad);
  // 6) out = relu(BN(ens3x3(opad)))      opad -> D (planar fp32)
  k_ens_mfma<<<512, 256, 0, stream>>>(opad, apens, esc, ebi, D);
}

// Round 15
// 146.388 us; speedup vs baseline: 15.9318x; 1.0218x over previous
//
#include <hip/hip_runtime.h>
#include <hip/hip_bf16.h>
#include <hip/hip_fp16.h>

#define EPSV 1e-5f
#define Bn 8
#define Cn 64
#define Hn 128
#define Wn 128
#define Pn (Hn*Wn)          // 16384
#define PR 150              // cdcm pad: 11 + 128 + 11
#define PE 130              // 1-pad: 1 + 128 + 1
#define YPAD_ELEMS (Bn*PR*PR*Cn)   // 11,520,000 fp16

typedef _Float16 v8h __attribute__((ext_vector_type(8)));
typedef float v16f __attribute__((ext_vector_type(16)));
typedef unsigned short ushort8v __attribute__((ext_vector_type(8)));
typedef unsigned short ushort4v __attribute__((ext_vector_type(4)));

__device__ __forceinline__ unsigned short f2h(float v) {
  _Float16 h = (_Float16)v;
  return *reinterpret_cast<const unsigned short*>(&h);
}
__device__ __forceinline__ float h2f(unsigned short u) {
  return (float)(*reinterpret_cast<const _Float16*>(&u));
}

__device__ __forceinline__ v8h exp8h(v8h x) {
  union { v8h v; __half2 h[4]; } u; u.v = x;
  #pragma unroll
  for (int i = 0; i < 4; i++) u.h[i] = h2exp(u.h[i]);
  return u.v;
}
__device__ __forceinline__ v8h rcp8h(v8h x) {
  union { v8h v; __half2 h[4]; } u; u.v = x;
  #pragma unroll
  for (int i = 0; i < 4; i++) u.h[i] = h2rcp(u.h[i]);
  return u.v;
}

// async global->LDS, 16B per lane; LDS dest = uniform base + lane*16
__device__ __forceinline__ void gload_lds16(const void* g, void* l) {
  __builtin_amdgcn_global_load_lds(
      (const __attribute__((address_space(1))) unsigned int*)g,
      (__attribute__((address_space(3))) unsigned int*)l, 16, 0, 0);
}

// channel-blocked CL addressing: [b][row][kb(4)][col][16], elems
__device__ __forceinline__ size_t clb(int b, int row, int kb, int col, int PD) {
  return ((((size_t)b * PD + row) * 4 + kb) * PD + col) * 16;
}

// batch-major XCD swizzle: 1024 blocks, XCD r gets batch r's rows in order
__device__ __forceinline__ void swz_bh(int& b, int& h) {
  int bid = blockIdx.x;
  int w = (bid & 7) * 128 + (bid >> 3);
  b = w >> 7; h = w & 127;
}

// ---------------- prep: weight packs + BN folds + border zeros --------------
// cdcm A-pack layout (18KB chunks): [d][kb][tap9][mh][512]
// other A-packs: [tap][kb][mh][lane*8+e], m=mh*32+(l&31), c=kb*16+(l>>5)*8+e
__global__ __launch_bounds__(256) void k_prep(
    const float* __restrict__ w1, const float* __restrict__ w5,
    const float* __restrict__ w7, const float* __restrict__ w9,
    const float* __restrict__ w11, const float* __restrict__ pww,
    const float* __restrict__ frw, const float* __restrict__ cw,
    const float* __restrict__ gww, const float* __restrict__ gwb,
    const float* __restrict__ gbg, const float* __restrict__ gbb,
    const float* __restrict__ gbm, const float* __restrict__ gbv,
    const float* __restrict__ ensw, const float* __restrict__ ensb,
    const float* __restrict__ bng, const float* __restrict__ bnb,
    const float* __restrict__ bnm, const float* __restrict__ bnv,
    unsigned short* __restrict__ apack, unsigned short* __restrict__ apinv,
    unsigned short* __restrict__ apens, unsigned short* __restrict__ appw1,
    unsigned short* __restrict__ appw, unsigned short* __restrict__ apfr,
    unsigned short* __restrict__ gwpk,
    unsigned short* __restrict__ apk, unsigned short* __restrict__ bpk,
    float* __restrict__ esc, float* __restrict__ ebi,
    unsigned short* __restrict__ ypad, unsigned short* __restrict__ spad)
{
  int id = blockIdx.x * 256 + threadIdx.x;
  if (id < 147456) {               // cdcm: chunked [d][kb][t9][mh][512]
    int c0 = id / 9216;            // ci = d*4 + kb
    int d = c0 >> 2, kb = c0 & 3;
    int r = id - c0 * 9216;
    int t9 = r / 1024;
    int r2 = r & 1023;
    int mh = r2 >> 9, l = (r2 >> 3) & 63, e = r2 & 7;
    int m = mh * 32 + (l & 31);
    int c = kb * 16 + (l >> 5) * 8 + e;
    const float* src = (d == 0) ? w5 : (d == 1) ? w7 : (d == 2) ? w9 : w11;
    apack[id] = f2h(src[(m * 64 + c) * 9 + t9]);
    return;
  }
  id -= 147456;
  if (id < 36864) {                // involution conv_w: 9 taps
    int e = id & 7, l = (id >> 3) & 63, mh = (id >> 9) & 1,
        kb = (id >> 10) & 3, tap = id >> 12;
    int m = mh * 32 + (l & 31);
    int c = kb * 16 + (l >> 5) * 8 + e;
    apinv[id] = f2h(cw[(m * 64 + c) * 9 + tap]);
    return;
  }
  id -= 36864;
  if (id < 36864) {                // ensemble mean weights: 9 taps
    int e = id & 7, l = (id >> 3) & 63, mh = (id >> 9) & 1,
        kb = (id >> 10) & 3, tap = id >> 12;
    int m = mh * 32 + (l & 31);
    int c = kb * 16 + (l >> 5) * 8 + e;
    float v = (ensw[((0 * 64 + m) * 64 + c) * 9 + tap] +
               ensw[((64 + m) * 64 + c) * 9 + tap] +
               ensw[((128 + m) * 64 + c) * 9 + tap]) * (1.f / 3.f);
    apens[id] = f2h(v);
    return;
  }
  id -= 36864;
  if (id < 4096) {                 // conv1 1x1
    int e = id & 7, l = (id >> 3) & 63, mh = (id >> 9) & 1, kb = (id >> 10) & 3;
    int m = mh * 32 + (l & 31);
    int c = kb * 16 + (l >> 5) * 8 + e;
    appw1[id] = f2h(w1[m * 64 + c]);
    return;
  }
  id -= 4096;
  if (id < 4096) {                 // dsc pointwise 1x1
    int e = id & 7, l = (id >> 3) & 63, mh = (id >> 9) & 1, kb = (id >> 10) & 3;
    int m = mh * 32 + (l & 31);
    int c = kb * 16 + (l >> 5) * 8 + e;
    appw[id] = f2h(pww[m * 64 + c]);
    return;
  }
  id -= 4096;
  if (id < 4096) {                 // fr 1x1
    int e = id & 7, l = (id >> 3) & 63, mh = (id >> 9) & 1, kb = (id >> 10) & 3;
    int m = mh * 32 + (l & 31);
    int c = kb * 16 + (l >> 5) * 8 + e;
    apfr[id] = f2h(frw[m * 64 + c]);
    return;
  }
  id -= 4096;
  if (id < 5184) {                 // packed gw weights [cblk8][tap81][ch8]
    int cblk = id / 648, r = id - cblk * 648;
    int tap = r >> 3, ch = r & 7;
    int c = cblk * 8 + ch;
    gwpk[id] = f2h(gww[c * 81 + tap]);
    return;
  }
  id -= 5184;
  if (id < 576) {                  // packed BN scale [cblk8][o9][ch8]
    int cblk = id / 72, r = id - cblk * 72;
    int o = r >> 3, ch = r & 7;
    int c = cblk * 8 + ch;
    float A = gbg[c * 9 + o] / sqrtf(gbv[c * 9 + o] + EPSV);
    apk[id] = f2h(A);
    return;
  }
  id -= 576;
  if (id < 576) {                  // packed BN shift
    int cblk = id / 72, r = id - cblk * 72;
    int o = r >> 3, ch = r & 7;
    int c = cblk * 8 + ch;
    float A = gbg[c * 9 + o] / sqrtf(gbv[c * 9 + o] + EPSV);
    float B = (gwb[c * 9 + o] - gbm[c * 9 + o]) * A + gbb[c * 9 + o];
    bpk[id] = f2h(B);
    return;
  }
  id -= 576;
  if (id < 64) {                   // final BN fold (+ mean ensemble bias)
    float s = bng[id] / sqrtf(bnv[id] + EPSV);
    esc[id] = s;
    float bm = (ensb[id] + ensb[64 + id] + ensb[128 + id]) * (1.f / 3.f);
    ebi[id] = (bm - bnm[id]) * s + bnb[id];
    return;
  }
  id -= 64;
  ushort8v z = {0, 0, 0, 0, 0, 0, 0, 0};
  const int perY = 22 * PR + 128 * 22;      // 6116: ypad border (pad 11)
  if (id < perY * Bn) {
    int b = id / perY; int r = id - b * perY;
    int tb = 22 * PR;
    int row, col;
    if (r < tb) {
      int rr = r / PR; col = r - rr * PR;
      row = (rr < 11) ? rr : (rr + 128);
    } else {
      int r2 = r - tb;
      row = 11 + r2 / 22;
      int cc = r2 % 22;
      col = (cc < 11) ? cc : (cc + 128);
    }
    #pragma unroll
    for (int kb = 0; kb < 4; kb++) {
      unsigned short* p = ypad + clb(b, row, kb, col, PR);
      *(ushort8v*)p = z;
      *(ushort8v*)(p + 8) = z;
    }
    return;
  }
  id -= perY * Bn;
  const int perS = 2 * PE + 256;            // 516: spad border (pad 1)
  if (id < perS * Bn) {
    int b = id / perS; int r = id - b * perS;
    int tb = 2 * PE;
    int row, col;
    if (r < tb) {
      int rr = r / PE; col = r - rr * PE;
      row = (rr < 1) ? 0 : 129;
    } else {
      int r2 = r - tb;
      row = 1 + r2 / 2;
      col = (r2 & 1) ? 129 : 0;
    }
    #pragma unroll
    for (int kb = 0; kb < 4; kb++) {
      unsigned short* p = spad + clb(b, row, kb, col, PE);
      *(ushort8v*)p = z;
      *(ushort8v*)(p + 8) = z;
    }
  }
}

// ---------------- stage 1: conv1x1(relu(x)) via MFMA, planar fp32 in --------
__global__ __launch_bounds__(256, 4) void k_pw1x(const float* __restrict__ x,
    const unsigned short* __restrict__ apw, const float* __restrict__ bias,
    unsigned short* __restrict__ ypad)
{
  int b, h; swz_bh(b, h);
  const int tid = threadIdx.x, wv = tid >> 6, l = tid & 63;
  const int ln31 = l & 31, g = l >> 5;
  const int px = wv * 32 + ln31;
  const float* xb = x + ((size_t)b * Cn) * Pn + h * Wn + px;
  v16f acc0, acc1;
  #pragma unroll
  for (int r = 0; r < 16; r++) { acc0[r] = 0.f; acc1[r] = 0.f; }
  const unsigned short* apl = apw + l * 8;
  #pragma unroll
  for (int kb = 0; kb < 4; kb++) {
    int c0 = kb * 16 + g * 8;
    v8h Bf;
    #pragma unroll
    for (int e = 0; e < 8; e++)
      Bf[e] = (_Float16)fmaxf(xb[(size_t)(c0 + e) * Pn], 0.f);
    v8h A0 = *(const v8h*)(apl + (kb * 2) * 512);
    v8h A1 = *(const v8h*)(apl + (kb * 2 + 1) * 512);
    acc0 = __builtin_amdgcn_mfma_f32_32x32x16_f16(A0, Bf, acc0, 0, 0, 0);
    acc1 = __builtin_amdgcn_mfma_f32_32x32x16_f16(A1, Bf, acc1, 0, 0, 0);
  }
  #pragma unroll
  for (int t = 0; t < 4; t++) {
    int c0 = 8 * t + 4 * g;
    int kb = c0 >> 4, sub = c0 & 15;
    ushort4v s0, s1;
    #pragma unroll
    for (int u = 0; u < 4; u++) {
      s0[u] = f2h(acc0[4 * t + u] + bias[c0 + u]);
      s1[u] = f2h(acc1[4 * t + u] + bias[c0 + u + 32]);
    }
    *(ushort4v*)(ypad + clb(b, h + 11, kb, px + 11, PR) + sub) = s0;
    *(ushort4v*)(ypad + clb(b, h + 11, kb + 2, px + 11, PR) + sub) = s1;
  }
}

// ---------------- stage 2: cdcm, persistent 16-wave block (1/CU) ------------
// grid 256, block 1024. bid&7 = batch (XCD), bid>>3 = row-group of 4 rows.
// Wave w: row rg*4+(w>>2), px (w&3)*32..+31. 16 chunks (d,kb) of 18KB,
// double-buffered; A staged ONCE per CU per chunk (granule w per wave,
// waves 0-1 take 2); counted per-wave vmcnt, never 0 mid-loop. The 4x
// longer MFMA phase per barrier hides both staging and B-load latency.
__global__ __launch_bounds__(1024, 1) void k_cdcm_mfma(
    const unsigned short* __restrict__ ypad,
    const unsigned short* __restrict__ apack,
    unsigned short* __restrict__ spad)
{
  __shared__ __align__(16) unsigned short Abuf[2][9216];  // 2 x 18 KB
  const int bid = blockIdx.x;
  const int b = bid & 7, rg = bid >> 3;
  const int tid = threadIdx.x, wv = tid >> 6, l = tid & 63;
  const int ln31 = l & 31, g = l >> 5;
  const int h = rg * 4 + (wv >> 2);
  const int seg = (wv & 3) * 32;
  const int ng = (wv < 2) ? 2 : 1;   // granules this wave stages (18 total)

  // issue chunk 0
  {
    const char* src = (const char*)apack;
    char* dst = (char*)&Abuf[0][0];
    for (int i = 0; i < ng; i++) {
      int off = (wv + i * 16) * 1024;
      gload_lds16(src + off + l * 16, dst + off);
    }
  }

  v16f acc0, acc1;
  #pragma unroll
  for (int r = 0; r < 16; r++) { acc0[r] = 0.f; acc1[r] = 0.f; }

  #pragma unroll
  for (int d = 0; d < 4; d++) {
    const int dil = 5 + 2 * d;
    #pragma unroll
    for (int kb = 0; kb < 4; kb++) {
      const int ci = d * 4 + kb;
      if (ci < 15) {               // prefetch next chunk into other buffer
        const char* src = (const char*)(apack + (ci + 1) * 9216);
        char* dst = (char*)&Abuf[(ci + 1) & 1][0];
        for (int i = 0; i < ng; i++) {
          int off = (wv + i * 16) * 1024;
          gload_lds16(src + off + l * 16, dst + off);
        }
        if (wv < 2) asm volatile("s_waitcnt vmcnt(2)" ::: "memory");
        else        asm volatile("s_waitcnt vmcnt(1)" ::: "memory");
      } else {
        asm volatile("s_waitcnt vmcnt(0)" ::: "memory");
      }
      asm volatile("s_barrier" ::: "memory");

      __builtin_amdgcn_s_setprio(1);
      const unsigned short* abl = &Abuf[ci & 1][0] + l * 8;
      #pragma unroll
      for (int ky = 0; ky < 3; ky++) {
        const int row = h + 11 + (ky - 1) * dil;
        #pragma unroll
        for (int kx = 0; kx < 3; kx++) {
          const int col = seg + ln31 + (kx - 1) * dil + 11;
          const int t9 = ky * 3 + kx;
          v8h Bf = *(const v8h*)(ypad + clb(b, row, kb, col, PR) + g * 8);
          const unsigned short* ap = abl + t9 * 1024;
          v8h A0 = *(const v8h*)(ap);
          v8h A1 = *(const v8h*)(ap + 512);
          acc0 = __builtin_amdgcn_mfma_f32_32x32x16_f16(A0, Bf, acc0, 0, 0, 0);
          acc1 = __builtin_amdgcn_mfma_f32_32x32x16_f16(A1, Bf, acc1, 0, 0, 0);
        }
      }
      __builtin_amdgcn_s_setprio(0);
      asm volatile("s_barrier" ::: "memory");  // waves done with buf[ci&1]
    }
  }
  const int px = seg + ln31;
  #pragma unroll
  for (int t = 0; t < 4; t++) {
    int c0 = 8 * t + 4 * g;
    int kb = c0 >> 4, sub = c0 & 15;
    ushort4v s0, s1;
    #pragma unroll
    for (int u = 0; u < 4; u++) {
      s0[u] = f2h(acc0[4 * t + u]);
      s1[u] = f2h(acc1[4 * t + u]);
    }
    *(ushort4v*)(spad + clb(b, h + 1, kb, px + 1, PE) + sub) = s0;
    *(ushort4v*)(spad + clb(b, h + 1, kb + 2, px + 1, PE) + sub) = s1;
  }
}

// ---------------- stage 3: depthwise (VALU) + pointwise (MFMA) --------------
// Blocks h==0/h==1 also zero y2pad's pad-1 borders (safe: nothing reads
// y2pad until invol; border writes disjoint from all interior writes).
__global__ __launch_bounds__(256, 4) void k_dwpw_mfma(
    const unsigned short* __restrict__ spad,
    const float* __restrict__ dww, const float* __restrict__ dwb,
    const unsigned short* __restrict__ appw, const float* __restrict__ pwb,
    unsigned short* __restrict__ y2pad)
{
  __shared__ float wdw[576];
  __shared__ float bdw[64];
  const int tid = threadIdx.x;
  for (int t = tid; t < 576; t += 256) wdw[t] = dww[t];
  if (tid < 64) bdw[tid] = dwb[tid];
  __syncthreads();

  int b, h; swz_bh(b, h);

  ushort8v z = {0, 0, 0, 0, 0, 0, 0, 0};
  if (h == 0) {
    for (int px = tid; px < 260; px += 256) {
      int row = (px < 130) ? 0 : 129;
      int col = (px < 130) ? px : px - 130;
      #pragma unroll
      for (int kb = 0; kb < 4; kb++) {
        unsigned short* p = y2pad + clb(b, row, kb, col, PE);
        *(ushort8v*)p = z;
        *(ushort8v*)(p + 8) = z;
      }
    }
  } else if (h == 1) {
    int row = 1 + (tid & 127);
    int col = (tid >> 7) ? 129 : 0;
    #pragma unroll
    for (int kb = 0; kb < 4; kb++) {
      unsigned short* p = y2pad + clb(b, row, kb, col, PE);
      *(ushort8v*)p = z;
      *(ushort8v*)(p + 8) = z;
    }
  }

  const int wv = tid >> 6, l = tid & 63;
  const int ln31 = l & 31, g = l >> 5;
  const int w = wv * 32 + ln31;

  v16f acc0, acc1;
  #pragma unroll
  for (int r = 0; r < 16; r++) { acc0[r] = 0.f; acc1[r] = 0.f; }
  const unsigned short* apl = appw + l * 8;

  #pragma unroll
  for (int kb = 0; kb < 4; kb++) {
    const int c0 = kb * 16 + g * 8;
    v8h t[9];
    #pragma unroll
    for (int k = 0; k < 9; k++) {
      const int dy = k / 3 - 1, dx = k % 3 - 1;
      t[k] = *(const v8h*)(spad + clb(b, h + 1 + dy, kb, w + 1 + dx, PE) + g * 8);
    }
    v8h dvh;
    #pragma unroll
    for (int e = 0; e < 8; e++) {
      const int c = c0 + e;
      float a = 4.f * bdw[c];
      #pragma unroll
      for (int k = 0; k < 9; k++) a += wdw[c * 9 + k] * (float)t[k][e];
      dvh[e] = (_Float16)a;
    }
    v8h A0 = *(const v8h*)(apl + (kb * 2) * 512);
    v8h A1 = *(const v8h*)(apl + (kb * 2 + 1) * 512);
    acc0 = __builtin_amdgcn_mfma_f32_32x32x16_f16(A0, dvh, acc0, 0, 0, 0);
    acc1 = __builtin_amdgcn_mfma_f32_32x32x16_f16(A1, dvh, acc1, 0, 0, 0);
  }
  #pragma unroll
  for (int t = 0; t < 4; t++) {
    int c0 = 8 * t + 4 * g;
    int kb = c0 >> 4, sub = c0 & 15;
    ushort4v s0, s1;
    #pragma unroll
    for (int u = 0; u < 4; u++) {
      s0[u] = f2h(acc0[4 * t + u] + 4.f * pwb[c0 + u]);
      s1[u] = f2h(acc1[4 * t + u] + 4.f * pwb[c0 + u + 32]);
    }
    *(ushort4v*)(y2pad + clb(b, h + 1, kb, w + 1, PE) + sub) = s0;
    *(ushort4v*)(y2pad + clb(b, h + 1, kb + 2, w + 1, PE) + sub) = s1;
  }
}

// ---------------- stage 4: involution, packed-fp16 softmax + MFMA -----------
__global__ __launch_bounds__(256, 3) void k_invol_mfma(
    const unsigned short* __restrict__ y2pad,
    const unsigned short* __restrict__ gwpk,
    const unsigned short* __restrict__ apk,
    const unsigned short* __restrict__ bpk,
    const unsigned short* __restrict__ apinv,
    const float* __restrict__ cbias,
    unsigned short* __restrict__ ipad)
{
  __shared__ __align__(16) unsigned short gws[5184];  // [cblk8][tap81][ch8]
  __shared__ __align__(16) unsigned short As[576];    // [cblk8][o9][ch8]
  __shared__ __align__(16) unsigned short Bs[576];
  const int tid = threadIdx.x;
  for (int t = tid; t < 648; t += 256)
    ((ushort8v*)gws)[t] = ((const ushort8v*)gwpk)[t];
  if (tid < 72) {
    ((ushort8v*)As)[tid] = ((const ushort8v*)apk)[tid];
    ((ushort8v*)Bs)[tid] = ((const ushort8v*)bpk)[tid];
  }
  __syncthreads();

  int b, h; swz_bh(b, h);
  const int wv = tid >> 6, l = tid & 63;
  const int p32 = l & 31, g = l >> 5;
  const int w = wv * 32 + p32;

  v16f acc0, acc1;
  #pragma unroll
  for (int r = 0; r < 16; r++) { acc0[r] = 0.f; acc1[r] = 0.f; }

  for (int cb4 = 0; cb4 < 4; cb4++) {
    const int cblk = cb4 * 2 + g;
    const unsigned short* gwp = gws + cblk * 648;
    const unsigned short* Ap = As + cblk * 72;
    const unsigned short* Bp = Bs + cblk * 72;

    v8h pt[9];
    #pragma unroll
    for (int k = 0; k < 9; k++) {
      const int dy = k / 3 - 1, dx = k % 3 - 1;
      pt[k] = *(const v8h*)(y2pad + clb(b, h + 1 + dy, cb4, w + 1 + dx, PE) + g * 8);
    }
    // gw matmul + BN, all packed fp16 (weights broadcast from LDS)
    v8h s[9];
    #pragma unroll
    for (int o = 0; o < 9; o++) {
      v8h a = (*(const v8h*)(gwp + o * 72)) * pt[0];
      #pragma unroll
      for (int i = 1; i < 9; i++)
        a += (*(const v8h*)(gwp + o * 72 + i * 8)) * pt[i];
      s[o] = a * (*(const v8h*)(Ap + o * 8)) + (*(const v8h*)(Bp + o * 8));
    }
    // softmax over the 9 taps (shift-free: |s| << 1, fp16-safe)
    v8h esum = {0, 0, 0, 0, 0, 0, 0, 0};
    #pragma unroll
    for (int o = 0; o < 9; o++) { s[o] = exp8h(s[o]); esum += s[o]; }
    v8h inv = rcp8h(esum);
    #pragma unroll
    for (int k = 0; k < 9; k++) pt[k] = pt[k] * s[k] * inv;

    const unsigned short* ap = apinv + l * 8;
    __builtin_amdgcn_s_setprio(1);
    #pragma unroll
    for (int k = 0; k < 9; k++) {
      const unsigned short* a2 = ap + ((k * 4 + cb4) * 2) * 512;
      v8h A0 = *(const v8h*)(a2);
      v8h A1 = *(const v8h*)(a2 + 512);
      acc0 = __builtin_amdgcn_mfma_f32_32x32x16_f16(A0, pt[k], acc0, 0, 0, 0);
      acc1 = __builtin_amdgcn_mfma_f32_32x32x16_f16(A1, pt[k], acc1, 0, 0, 0);
    }
    __builtin_amdgcn_s_setprio(0);
  }
  #pragma unroll
  for (int t = 0; t < 4; t++) {
    int c0 = 8 * t + 4 * g;
    int kb = c0 >> 4, sub = c0 & 15;
    ushort4v s0, s1;
    #pragma unroll
    for (int u = 0; u < 4; u++) {
      s0[u] = f2h(acc0[4 * t + u] + cbias[c0 + u]);
      s1[u] = f2h(acc1[4 * t + u] + cbias[c0 + u + 32]);
    }
    *(ushort4v*)(ipad + clb(b, h, kb, w, 128) + sub) = s0;
    *(ushort4v*)(ipad + clb(b, h, kb + 2, w, 128) + sub) = s1;
  }
}

// ---------------- stage 5: fr 1x1 + residual (direct epilogue add) ----------
__global__ __launch_bounds__(256, 4) void k_fr_mfma(
    const unsigned short* __restrict__ ipad,
    const unsigned short* __restrict__ apfr,
    const float* __restrict__ bias,
    unsigned short* __restrict__ opad)
{
  int b, h; swz_bh(b, h);
  const int tid = threadIdx.x, wv = tid >> 6, l = tid & 63;
  const int ln31 = l & 31, g = l >> 5;
  const int px = wv * 32 + ln31;
  v16f acc0, acc1;
  #pragma unroll
  for (int r = 0; r < 16; r++) { acc0[r] = 0.f; acc1[r] = 0.f; }
  const unsigned short* apl = apfr + l * 8;
  #pragma unroll
  for (int kb = 0; kb < 4; kb++) {
    v8h Bf = *(const v8h*)(ipad + clb(b, h, kb, px, 128) + g * 8);
    v8h A0 = *(const v8h*)(apl + (kb * 2) * 512);
    v8h A1 = *(const v8h*)(apl + (kb * 2 + 1) * 512);
    acc0 = __builtin_amdgcn_mfma_f32_32x32x16_f16(A0, Bf, acc0, 0, 0, 0);
    acc1 = __builtin_amdgcn_mfma_f32_32x32x16_f16(A1, Bf, acc1, 0, 0, 0);
  }
  #pragma unroll
  for (int t = 0; t < 4; t++) {
    int c0 = 8 * t + 4 * g;
    int kb = c0 >> 4, sub = c0 & 15;
    // residual values live at exactly the epilogue addresses
    ushort4v r0 = *(const ushort4v*)(ipad + clb(b, h, kb, px, 128) + sub);
    ushort4v r1 = *(const ushort4v*)(ipad + clb(b, h, kb + 2, px, 128) + sub);
    ushort4v s0, s1;
    #pragma unroll
    for (int u = 0; u < 4; u++) {
      s0[u] = f2h(acc0[4 * t + u] + bias[c0 + u] + h2f(r0[u]));
      s1[u] = f2h(acc1[4 * t + u] + bias[c0 + u + 32] + h2f(r1[u]));
    }
    *(ushort4v*)(opad + clb(b, h + 1, kb, px + 1, PE) + sub) = s0;
    *(ushort4v*)(opad + clb(b, h + 1, kb + 2, px + 1, PE) + sub) = s1;
  }
}

// ---------------- stage 6: ensemble conv3x3, 2 rows/block, LDS weights ------
__global__ __launch_bounds__(256) void k_ens_mfma(
    const unsigned short* __restrict__ opad,
    const unsigned short* __restrict__ apens,
    const float* __restrict__ esc, const float* __restrict__ ebi,
    float* __restrict__ out)
{
  __shared__ __align__(16) unsigned short Abuf[36864];  // 72 KB: 9 taps
  const int tid = threadIdx.x;
  {
    const ushort8v* src = (const ushort8v*)apens;
    ushort8v* dst = (ushort8v*)Abuf;
    #pragma unroll
    for (int it = 0; it < 18; it++)
      dst[tid + it * 256] = src[tid + it * 256];
  }
  __syncthreads();

  const int bid = blockIdx.x;
  const int b = bid & 7, h0 = (bid >> 3) * 2;
  const int wv = tid >> 6, l = tid & 63;
  const int ln31 = l & 31, g = l >> 5;

  v16f a00, a01, a10, a11;
  #pragma unroll
  for (int r = 0; r < 16; r++) { a00[r] = 0.f; a01[r] = 0.f; a10[r] = 0.f; a11[r] = 0.f; }

  const unsigned short* abl = Abuf + l * 8;

  #pragma unroll
  for (int ky = 0; ky < 3; ky++) {
    #pragma unroll
    for (int kx = 0; kx < 3; kx++) {
      const int tap = ky * 3 + kx;
      const int r0 = h0 + ky;              // (h0+1) + (ky-1)
      const int col = wv * 32 + ln31 + kx; // (+1) + (kx-1)
      const unsigned short* ap = abl + tap * 4096;
      #pragma unroll
      for (int kb = 0; kb < 4; kb++) {
        v8h B0 = *(const v8h*)(opad + clb(b, r0, kb, col, PE) + g * 8);
        v8h B1 = *(const v8h*)(opad + clb(b, r0 + 1, kb, col, PE) + g * 8);
        v8h A0 = *(const v8h*)(ap + kb * 1024);
        v8h A1 = *(const v8h*)(ap + kb * 1024 + 512);
        a00 = __builtin_amdgcn_mfma_f32_32x32x16_f16(A0, B0, a00, 0, 0, 0);
        a01 = __builtin_amdgcn_mfma_f32_32x32x16_f16(A1, B0, a01, 0, 0, 0);
        a10 = __builtin_amdgcn_mfma_f32_32x32x16_f16(A0, B1, a10, 0, 0, 0);
        a11 = __builtin_amdgcn_mfma_f32_32x32x16_f16(A1, B1, a11, 0, 0, 0);
      }
    }
  }
  float* sp0 = out + ((size_t)b * Cn) * Pn + h0 * Wn + wv * 32 + ln31;
  float* sp1 = sp0 + Wn;
  #pragma unroll
  for (int r = 0; r < 16; r++) {
    int o0 = (r & 3) + 8 * (r >> 2) + 4 * g;
    float e0 = esc[o0], e1 = esc[o0 + 32];
    float i0 = ebi[o0], i1 = ebi[o0 + 32];
    sp0[(size_t)o0 * Pn] = fmaxf(a00[r] * e0 + i0, 0.f);
    sp0[(size_t)(o0 + 32) * Pn] = fmaxf(a01[r] * e1 + i1, 0.f);
    sp1[(size_t)o0 * Pn] = fmaxf(a10[r] * e0 + i0, 0.f);
    sp1[(size_t)(o0 + 32) * Pn] = fmaxf(a11[r] * e1 + i1, 0.f);
  }
}

extern "C" void kernel_launch(void* const* d_in, const int* in_sizes, int n_in,
                              void* d_out, int out_size, void* d_ws, size_t ws_size,
                              hipStream_t stream)
{
  const float* x    = (const float*)d_in[0];
  const float* w1   = (const float*)d_in[1];
  const float* b1   = (const float*)d_in[2];
  const float* w5   = (const float*)d_in[3];
  const float* w7   = (const float*)d_in[4];
  const float* w9   = (const float*)d_in[5];
  const float* w11  = (const float*)d_in[6];
  const float* dww  = (const float*)d_in[7];
  const float* dwb  = (const float*)d_in[8];
  const float* pww  = (const float*)d_in[9];
  const float* pwb  = (const float*)d_in[10];
  const float* gww  = (const float*)d_in[11];
  const float* gwb  = (const float*)d_in[12];
  const float* gbg  = (const float*)d_in[13];
  const float* gbb  = (const float*)d_in[14];
  const float* gbm  = (const float*)d_in[15];
  const float* gbv  = (const float*)d_in[16];
  const float* cw   = (const float*)d_in[17];
  const float* cb   = (const float*)d_in[18];
  const float* frw  = (const float*)d_in[19];
  const float* frb  = (const float*)d_in[20];
  const float* ensw = (const float*)d_in[21];
  const float* ensb = (const float*)d_in[22];
  const float* bng  = (const float*)d_in[23];
  const float* bnb  = (const float*)d_in[24];
  const float* bnm  = (const float*)d_in[25];
  const float* bnv  = (const float*)d_in[26];

  // ws: ypad (pad-11) region, overlaid later by y2pad then opad (pad-1)
  unsigned short* wsu   = (unsigned short*)d_ws;
  unsigned short* ypad  = wsu;
  unsigned short* y2pad = wsu;
  unsigned short* opad  = wsu;
  unsigned short* apack = wsu + YPAD_ELEMS;         // 147456
  unsigned short* apinv = apack + 147456;           // 36864
  unsigned short* apens = apinv + 36864;            // 36864
  unsigned short* appw1 = apens + 36864;            // 4096
  unsigned short* appw  = appw1 + 4096;             // 4096
  unsigned short* apfr  = appw + 4096;              // 4096
  unsigned short* gwpk  = apfr + 4096;              // 5184
  unsigned short* apk   = gwpk + 5184;              // 576
  unsigned short* bpk   = apk + 576;                // 576
  float* esc = (float*)(bpk + 576);                 // 64
  float* ebi = esc + 64;                            // 64

  // d_out: spad (fp16 blocked-CL pad-1) -> ipad (blocked-CL) -> planar fp32
  unsigned short* spad = (unsigned short*)d_out;
  unsigned short* ipad = (unsigned short*)d_out;
  float* D = (float*)d_out;

  // prep also zeroes ypad borders (pad 11) and spad borders (pad 1)
  k_prep<<<1145, 256, 0, stream>>>(w1, w5, w7, w9, w11, pww, frw, cw,
                                   gww, gwb, gbg, gbb, gbm, gbv, ensw, ensb,
                                   bng, bnb, bnm, bnv,
                                   apack, apinv, apens, appw1, appw, apfr,
                                   gwpk, apk, bpk, esc, ebi,
                                   ypad, spad);

  // 1) ypad = conv1x1(relu(x))           x (planar f32) -> ypad (blocked CL)
  k_pw1x<<<1024, 256, 0, stream>>>(x, appw1, b1, ypad);
  // 2) spad = sum_d dilconv_d(y)         ypad -> spad (d_out, pad-1)
  k_cdcm_mfma<<<256, 1024, 0, stream>>>(ypad, apack, spad);
  // 3) y2pad = PW(DW(spad))              spad -> y2pad (ws, pad-1)
  //    (blocks h=0/1 also zero y2pad borders; ypad is dead by now)
  k_dwpw_mfma<<<1024, 256, 0, stream>>>(spad, dww, dwb, appw, pwb, y2pad);
  // 4) ipad = involution(y2pad)          y2pad -> ipad (d_out)
  k_invol_mfma<<<1024, 256, 0, stream>>>(y2pad, gwpk, apk, bpk, apinv, cb, ipad);
  // 5) opad = fr(ipad) + ipad            ipad -> opad (ws, pad-1)
  k_fr_mfma<<<1024, 256, 0, stream>>>(ipad, apfr, frb, opad);
  // 6) out = relu(BN(ens3x3(opad)))      opad -> D (planar fp32)
  k_ens_mfma<<<512, 256, 0, stream>>>(opad, apens, esc, ebi, D);
}